// Round 1
// baseline (4225.631 us; speedup 1.0000x reference)
//
#include <hip/hip_runtime.h>

// ---------------------------------------------------------------------------
// VQ-VAE forward, all f32.  Geometry is fixed:
//   N=128, enc1: 1->32 4x4 s2 (128->64), enc2: 32->64 4x4 s2 (64->32),
//   3x3 64->64 @32x32 (enc3, res_e1, dec1, res_d1), 1x1 64->64 (res_e2,
//   enc4, res_d2), VQ K=512 D=64, dec2: up2x+3x3 64->32 (@64x64),
//   dec3: up2x+3x3 32->1 (@128x128).
// ---------------------------------------------------------------------------

template<int ACT> __device__ __forceinline__ float actf(float x){
  if (ACT == 1) return x > 0.f ? x : 0.01f * x;   // leaky relu, slope .01
  if (ACT == 2) return fmaxf(x, 0.f);             // relu
  return x;
}

// ---------------- enc1: 1->32, 4x4 stride2 pad1, 128->64, lrelu ------------
__global__ __launch_bounds__(256) void k_enc1(
    const float* __restrict__ in, const float* __restrict__ w,
    const float* __restrict__ b, float* __restrict__ out) {
  int idx = blockIdx.x * 256 + threadIdx.x;        // [128,32,64,64]
  int ox = idx & 63, oy = (idx >> 6) & 63, co = (idx >> 12) & 31, n = idx >> 17;
  const float* ip = in + n * 16384;
  const float* wp = w + co * 16;
  float acc = b[co];
  int iy0 = 2 * oy - 1, ix0 = 2 * ox - 1;
#pragma unroll
  for (int ky = 0; ky < 4; ++ky) {
    int iy = iy0 + ky;
    if ((unsigned)iy >= 128u) continue;
#pragma unroll
    for (int kx = 0; kx < 4; ++kx) {
      int ix = ix0 + kx;
      if ((unsigned)ix >= 128u) continue;
      acc = fmaf(ip[iy * 128 + ix], wp[ky * 4 + kx], acc);
    }
  }
  out[idx] = actf<1>(acc);
}

// ---------------- enc2: 32->64, 4x4 stride2 pad1, 64->32, lrelu ------------
__global__ __launch_bounds__(256) void k_enc2(
    const float* __restrict__ in, const float* __restrict__ w,
    const float* __restrict__ b, float* __restrict__ out) {
  int bid = blockIdx.x;                 // 2048 = 128n * 4coG * 4yT
  int n = bid >> 4, coG = (bid >> 2) & 3, yT = bid & 3;
  int co0 = coG * 16, y0 = yT * 8;
  int t = threadIdx.x;
  int coq = t >> 6, ty = (t >> 3) & 7, xq = t & 7;   // thread: 4co x 4x

  __shared__ float s_in[8 * 18 * 67];   // ci-group 8, 18 rows, 66 cols (pad 67)
  __shared__ float s_w[16 * 8 * 16];

  float acc[4][4];
#pragma unroll
  for (int c = 0; c < 4; ++c)
#pragma unroll
    for (int xx = 0; xx < 4; ++xx) acc[c][xx] = 0.f;

  for (int g = 0; g < 4; ++g) {
    int ci0 = g * 8;
    for (int i = t; i < 8 * 18 * 66; i += 256) {
      int ci = i / 1188, rem = i - ci * 1188;
      int r = rem / 66, c = rem - r * 66;
      int iy = 2 * y0 - 1 + r, ix = c - 1;
      float v = 0.f;
      if ((unsigned)iy < 64u && (unsigned)ix < 64u)
        v = in[((n * 32 + ci0 + ci) * 64 + iy) * 64 + ix];
      s_in[(ci * 18 + r) * 67 + c] = v;
    }
    for (int i = t; i < 16 * 8 * 16; i += 256) {
      int o = i >> 7, rem = i & 127;
      int ci = rem >> 4, k = rem & 15;
      s_w[i] = w[((co0 + o) * 32 + ci0 + ci) * 16 + k];
    }
    __syncthreads();
    for (int ci = 0; ci < 8; ++ci) {
#pragma unroll
      for (int ky = 0; ky < 4; ++ky) {
        float rv[10];
        int base = (ci * 18 + 2 * ty + ky) * 67 + xq * 8;
#pragma unroll
        for (int j = 0; j < 10; ++j) rv[j] = s_in[base + j];
#pragma unroll
        for (int c = 0; c < 4; ++c)
#pragma unroll
          for (int kx = 0; kx < 4; ++kx) {
            float wv = s_w[((coq * 4 + c) * 8 + ci) * 16 + ky * 4 + kx];
#pragma unroll
            for (int xx = 0; xx < 4; ++xx)
              acc[c][xx] = fmaf(rv[2 * xx + kx], wv, acc[c][xx]);
          }
      }
    }
    __syncthreads();
  }
#pragma unroll
  for (int c = 0; c < 4; ++c) {
    int co = co0 + coq * 4 + c;
    float bv = b[co];
    int base = ((n * 64 + co) * 32 + y0 + ty) * 32 + xq * 4;
    float4 v = make_float4(actf<1>(acc[c][0] + bv), actf<1>(acc[c][1] + bv),
                           actf<1>(acc[c][2] + bv), actf<1>(acc[c][3] + bv));
    *reinterpret_cast<float4*>(&out[base]) = v;
  }
}

// ---------------- 3x3 64->64 stride1 pad1 @32x32 ---------------------------
template<int ACT, bool BIAS>
__global__ __launch_bounds__(256) void k_conv3(
    const float* __restrict__ in, const float* __restrict__ w,
    const float* __restrict__ bias, float* __restrict__ out) {
  int bid = blockIdx.x;                  // 1024 = 128n * 4coG * 2yH
  int n = bid >> 3, coG = (bid >> 1) & 3, yH = bid & 1;
  int co0 = coG * 16, y0 = yH * 16;
  int t = threadIdx.x;
  int coq = t >> 6, ty = (t >> 2) & 15, xo = t & 3;   // thread: 4co x 8x

  __shared__ float s_in[16 * 18 * 35];   // ci-group 16, 18 rows, 34 cols (pad 35)
  __shared__ float s_w[16 * 16 * 9];

  float acc[4][8];
#pragma unroll
  for (int c = 0; c < 4; ++c)
#pragma unroll
    for (int xx = 0; xx < 8; ++xx) acc[c][xx] = 0.f;

  for (int g = 0; g < 4; ++g) {
    int ci0 = g * 16;
    for (int i = t; i < 16 * 18 * 34; i += 256) {
      int ci = i / 612, rem = i - ci * 612;
      int r = rem / 34, c = rem - r * 34;
      int iy = y0 - 1 + r, ix = c - 1;
      float v = 0.f;
      if ((unsigned)iy < 32u && (unsigned)ix < 32u)
        v = in[((n * 64 + ci0 + ci) * 32 + iy) * 32 + ix];
      s_in[(ci * 18 + r) * 35 + c] = v;
    }
    for (int i = t; i < 16 * 16 * 9; i += 256) {
      int o = i / 144, rem = i - o * 144;
      int ci = rem / 9, k = rem - ci * 9;
      s_w[i] = w[((co0 + o) * 64 + ci0 + ci) * 9 + k];
    }
    __syncthreads();
    for (int ci = 0; ci < 16; ++ci) {
#pragma unroll
      for (int ky = 0; ky < 3; ++ky) {
        float rv[10];
        int base = (ci * 18 + ty + ky) * 35 + xo * 8;
#pragma unroll
        for (int j = 0; j < 10; ++j) rv[j] = s_in[base + j];
#pragma unroll
        for (int c = 0; c < 4; ++c)
#pragma unroll
          for (int kx = 0; kx < 3; ++kx) {
            float wv = s_w[((coq * 4 + c) * 16 + ci) * 9 + ky * 3 + kx];
#pragma unroll
            for (int xx = 0; xx < 8; ++xx)
              acc[c][xx] = fmaf(rv[xx + kx], wv, acc[c][xx]);
          }
      }
    }
    __syncthreads();
  }
#pragma unroll
  for (int c = 0; c < 4; ++c) {
    int co = co0 + coq * 4 + c;
    float bv = BIAS ? bias[co] : 0.f;
    int base = ((n * 64 + co) * 32 + y0 + ty) * 32 + xo * 8;
    float o[8];
#pragma unroll
    for (int xx = 0; xx < 8; ++xx) o[xx] = actf<ACT>(acc[c][xx] + bv);
    *reinterpret_cast<float4*>(&out[base]) = make_float4(o[0], o[1], o[2], o[3]);
    *reinterpret_cast<float4*>(&out[base + 4]) = make_float4(o[4], o[5], o[6], o[7]);
  }
}

// ---------------- 1x1 64->64 (channel matmul), opt bias / add --------------
template<int ACT, bool BIAS, bool ADD>
__global__ __launch_bounds__(256) void k_1x1(
    const float* __restrict__ in, const float* __restrict__ w,
    const float* __restrict__ bias, const float* __restrict__ add,
    float* __restrict__ out) {
  int bid = blockIdx.x;                  // 512 = 128n * 4sT
  int n = bid >> 2;
  int s = ((bid & 3) << 8) + threadIdx.x;
  __shared__ float s_w[4096];
  for (int i = threadIdx.x; i < 4096; i += 256) s_w[i] = w[i];
  __syncthreads();
  float x[64];
#pragma unroll
  for (int ci = 0; ci < 64; ++ci) x[ci] = in[(n * 64 + ci) * 1024 + s];
  for (int co = 0; co < 64; ++co) {
    float acc = BIAS ? bias[co] : 0.f;
    const float* wr = &s_w[co * 64];
#pragma unroll
    for (int ci = 0; ci < 64; ++ci) acc = fmaf(wr[ci], x[ci], acc);
    if (ADD) acc += add[(n * 64 + co) * 1024 + s];
    out[(n * 64 + co) * 1024 + s] = actf<ACT>(acc);
  }
}

// ---------------- codebook squared norms -----------------------------------
__global__ __launch_bounds__(256) void k_cbnorm(const float* __restrict__ cb,
                                                float* __restrict__ nrm) {
  int c = blockIdx.x * 256 + threadIdx.x;
  if (c < 512) {
    float s = 0.f;
    for (int k = 0; k < 64; ++k) { float v = cb[c * 64 + k]; s = fmaf(v, v, s); }
    nrm[c] = s;
  }
}

// ---------------- VQ: argmin over 512 codes, write q, loss partials --------
__global__ __launch_bounds__(256) void k_vq(
    const float* __restrict__ lat, const float* __restrict__ cb,
    const float* __restrict__ nrm, float* __restrict__ q,
    double* __restrict__ part) {
  int bid = blockIdx.x;                  // 2048 blocks * 64 positions
  int t = threadIdx.x;
  int n = bid >> 4;
  int s0 = (bid & 15) << 6;
  __shared__ float s_lat[64 * 65];
  __shared__ float s_d[256];
  __shared__ int s_i[256];
  __shared__ double s_r[256];
  for (int i = t; i < 4096; i += 256) {
    int k = i >> 6, lp = i & 63;
    s_lat[lp * 65 + k] = lat[(n * 64 + k) * 1024 + s0 + lp];
  }
  __syncthreads();
  int lp = t >> 2, qd = t & 3;
  const float* lrow = &s_lat[lp * 65];
  float best = 3.4e38f;
  int bidx = 0;
  for (int j = 0; j < 128; j += 2) {
    int code = qd * 128 + j;
    const float* cp0 = &cb[code * 64];
    const float* cp1 = cp0 + 64;
    float d0 = 0.f, d1 = 0.f;
#pragma unroll 16
    for (int k = 0; k < 64; ++k) {
      float l = lrow[k];
      d0 = fmaf(l, cp0[k], d0);
      d1 = fmaf(l, cp1[k], d1);
    }
    d0 = nrm[code] - 2.f * d0;          // |lat|^2 constant: ordering unchanged
    d1 = nrm[code + 1] - 2.f * d1;
    if (d0 < best) { best = d0; bidx = code; }      // strict <: lowest index
    if (d1 < best) { best = d1; bidx = code + 1; }  // wins ties (argmin sem.)
  }
  s_d[t] = best; s_i[t] = bidx;
  __syncthreads();
  if (qd == 0) {
    float b0 = s_d[t]; int i0 = s_i[t];
#pragma unroll
    for (int qq = 1; qq < 4; ++qq)
      if (s_d[t + qq] < b0) { b0 = s_d[t + qq]; i0 = s_i[t + qq]; }
    s_i[t] = i0;
  }
  __syncthreads();
  int bsel = s_i[lp << 2];
  const float* cw = &cb[bsel * 64];
  float psum = 0.f;
#pragma unroll
  for (int kk = 0; kk < 16; ++kk) {
    int k = qd * 16 + kk;
    float c = cw[k];
    float diff = c - lrow[k];
    psum = fmaf(diff, diff, psum);
    q[(n * 64 + k) * 1024 + s0 + lp] = c;
  }
  s_r[t] = (double)psum;
  __syncthreads();
  for (int str = 128; str > 0; str >>= 1) {
    if (t < str) s_r[t] += s_r[t + str];
    __syncthreads();
  }
  if (t == 0) part[bid] = s_r[0];
}

// ---------------- loss finalize --------------------------------------------
__global__ __launch_bounds__(256) void k_loss(const double* __restrict__ part,
                                              float* __restrict__ out) {
  __shared__ double s[256];
  int t = threadIdx.x;
  double acc = 0.0;
  for (int i = t; i < 2048; i += 256) acc += part[i];
  s[t] = acc;
  __syncthreads();
  for (int str = 128; str > 0; str >>= 1) {
    if (t < str) s[t] += s[t + str];
    __syncthreads();
  }
  if (t == 0) {
    double mean = s[0] / 8388608.0;
    out[2097152] = (float)mean;          // embedding loss
    out[2097153] = (float)(0.25 * mean); // BETA * commitment
  }
}

// ---------------- dec2: fused upsample2x(ac) + 3x3 64->32 + lrelu ----------
__global__ __launch_bounds__(256) void k_dec2(
    const float* __restrict__ in, const float* __restrict__ w,
    const float* __restrict__ bias, float* __restrict__ out) {
  int bid = blockIdx.x;                  // 2048 = 128n * 4coG * 4yT
  int n = bid >> 4, coG = (bid >> 2) & 3, yT = bid & 3;
  int co0 = coG * 8, y0 = yT * 16;
  int t = threadIdx.x;
  int coq = t >> 7, ty = (t >> 3) & 15, xo = t & 7;   // thread: 4co x 8x

  __shared__ float s_up[8 * 18 * 67];
  __shared__ float s_src[8 * 11 * 33];
  __shared__ float s_w[8 * 8 * 9];

  const float sc = 31.0f / 63.0f;
  int r0 = (int)floorf(fmaxf((float)(y0 - 1), 0.f) * sc);

  float acc[4][8];
#pragma unroll
  for (int c = 0; c < 4; ++c)
#pragma unroll
    for (int xx = 0; xx < 8; ++xx) acc[c][xx] = 0.f;

  for (int g = 0; g < 8; ++g) {
    int ci0 = g * 8;
    for (int i = t; i < 8 * 11 * 32; i += 256) {
      int ci = i / 352, rem = i - ci * 352;
      int rr = rem >> 5, cx = rem & 31;
      int row = r0 + rr;
      float v = (row < 32) ? in[((n * 64 + ci0 + ci) * 32 + row) * 32 + cx] : 0.f;
      s_src[(ci * 11 + rr) * 33 + cx] = v;
    }
    for (int i = t; i < 8 * 8 * 9; i += 256) {
      int o = i / 72, rem = i - o * 72;
      int ci = rem / 9, k = rem - ci * 9;
      s_w[i] = w[((co0 + o) * 64 + ci0 + ci) * 9 + k];
    }
    __syncthreads();
    for (int i = t; i < 8 * 18 * 66; i += 256) {
      int ci = i / 1188, rem = i - ci * 1188;
      int uu = rem / 66, cc = rem - uu * 66;
      int uy = y0 - 1 + uu, ux = cc - 1;
      float v = 0.f;
      if ((unsigned)uy < 64u && (unsigned)ux < 64u) {
        float sy = uy * sc, sx = ux * sc;
        int iy0 = (int)floorf(sy), ix0 = (int)floorf(sx);
        float wy = sy - (float)iy0, wx = sx - (float)ix0;
        int iy1 = min(iy0 + 1, 31), ix1 = min(ix0 + 1, 31);
        const float* sp = &s_src[ci * 11 * 33];
        int ry = iy0 - r0, ry1 = iy1 - r0;
        float h0 = sp[ry * 33 + ix0] * (1.f - wy) + sp[ry1 * 33 + ix0] * wy;
        float h1 = sp[ry * 33 + ix1] * (1.f - wy) + sp[ry1 * 33 + ix1] * wy;
        v = h0 * (1.f - wx) + h1 * wx;
      }
      s_up[(ci * 18 + uu) * 67 + cc] = v;
    }
    __syncthreads();
    for (int ci = 0; ci < 8; ++ci) {
#pragma unroll
      for (int ky = 0; ky < 3; ++ky) {
        float rv[10];
        int base = (ci * 18 + ty + ky) * 67 + xo * 8;
#pragma unroll
        for (int j = 0; j < 10; ++j) rv[j] = s_up[base + j];
#pragma unroll
        for (int c = 0; c < 4; ++c)
#pragma unroll
          for (int kx = 0; kx < 3; ++kx) {
            float wv = s_w[((coq * 4 + c) * 8 + ci) * 9 + ky * 3 + kx];
#pragma unroll
            for (int xx = 0; xx < 8; ++xx)
              acc[c][xx] = fmaf(rv[xx + kx], wv, acc[c][xx]);
          }
      }
    }
    __syncthreads();
  }
#pragma unroll
  for (int c = 0; c < 4; ++c) {
    int co = co0 + coq * 4 + c;
    float bv = bias[co];
    int base = ((n * 32 + co) * 64 + y0 + ty) * 64 + xo * 8;
    float o[8];
#pragma unroll
    for (int xx = 0; xx < 8; ++xx) o[xx] = actf<1>(acc[c][xx] + bv);
    *reinterpret_cast<float4*>(&out[base]) = make_float4(o[0], o[1], o[2], o[3]);
    *reinterpret_cast<float4*>(&out[base + 4]) = make_float4(o[4], o[5], o[6], o[7]);
  }
}

// ---------------- dec3: fused upsample2x(ac) + 3x3 32->1 + relu ------------
__global__ __launch_bounds__(256) void k_dec3(
    const float* __restrict__ in, const float* __restrict__ w,
    const float* __restrict__ bias, float* __restrict__ out) {
  int bid = blockIdx.x;                  // 2048 = 128n * 8yT * 2xT
  int n = bid >> 4, yT = (bid >> 1) & 7, xT = bid & 1;
  int y0 = yT * 16, x0 = xT * 64;
  int t = threadIdx.x;
  int ty = t >> 4, xq = t & 15;          // thread: 4x

  __shared__ float s_up[8 * 18 * 67];
  __shared__ float s_src[8 * 11 * 35];
  __shared__ float s_w[288];

  const float sc = 63.0f / 127.0f;
  int r0 = (int)floorf(fmaxf((float)(y0 - 1), 0.f) * sc);
  int c0 = (int)floorf(fmaxf((float)(x0 - 1), 0.f) * sc);

  for (int i = t; i < 288; i += 256) s_w[i] = w[i];   // [1][32][3][3]

  float acc[4] = {0.f, 0.f, 0.f, 0.f};

  for (int g = 0; g < 4; ++g) {
    int ci0 = g * 8;
    for (int i = t; i < 8 * 11 * 35; i += 256) {
      int ci = i / 385, rem = i - ci * 385;
      int rr = rem / 35, cx = rem - rr * 35;
      int row = r0 + rr, col = c0 + cx;
      float v = (row < 64 && col < 64)
                    ? in[((n * 32 + ci0 + ci) * 64 + row) * 64 + col] : 0.f;
      s_src[(ci * 11 + rr) * 35 + cx] = v;
    }
    __syncthreads();
    for (int i = t; i < 8 * 18 * 66; i += 256) {
      int ci = i / 1188, rem = i - ci * 1188;
      int uu = rem / 66, cc = rem - uu * 66;
      int uy = y0 - 1 + uu, ux = x0 - 1 + cc;
      float v = 0.f;
      if ((unsigned)uy < 128u && (unsigned)ux < 128u) {
        float sy = uy * sc, sx = ux * sc;
        int iy0 = (int)floorf(sy), ix0 = (int)floorf(sx);
        float wy = sy - (float)iy0, wx = sx - (float)ix0;
        int iy1 = min(iy0 + 1, 63), ix1 = min(ix0 + 1, 63);
        const float* sp = &s_src[ci * 11 * 35];
        int ry = iy0 - r0, ry1 = iy1 - r0;
        int rx = ix0 - c0, rx1 = ix1 - c0;
        float h0 = sp[ry * 35 + rx] * (1.f - wy) + sp[ry1 * 35 + rx] * wy;
        float h1 = sp[ry * 35 + rx1] * (1.f - wy) + sp[ry1 * 35 + rx1] * wy;
        v = h0 * (1.f - wx) + h1 * wx;
      }
      s_up[(ci * 18 + uu) * 67 + cc] = v;
    }
    __syncthreads();
    for (int ci = 0; ci < 8; ++ci) {
#pragma unroll
      for (int ky = 0; ky < 3; ++ky) {
        float rv[6];
        int base = (ci * 18 + ty + ky) * 67 + xq * 4;
#pragma unroll
        for (int j = 0; j < 6; ++j) rv[j] = s_up[base + j];
#pragma unroll
        for (int kx = 0; kx < 3; ++kx) {
          float wv = s_w[(ci0 + ci) * 9 + ky * 3 + kx];
#pragma unroll
          for (int xx = 0; xx < 4; ++xx)
            acc[xx] = fmaf(rv[xx + kx], wv, acc[xx]);
        }
      }
    }
    __syncthreads();
  }
  float bv = bias[0];
  int base = n * 16384 + (y0 + ty) * 128 + x0 + xq * 4;
  *reinterpret_cast<float4*>(&out[base]) =
      make_float4(actf<2>(acc[0] + bv), actf<2>(acc[1] + bv),
                  actf<2>(acc[2] + bv), actf<2>(acc[3] + bv));
}

// ---------------------------------------------------------------------------
extern "C" void kernel_launch(void* const* d_in, const int* in_sizes, int n_in,
                              void* d_out, int out_size, void* d_ws, size_t ws_size,
                              hipStream_t stream) {
  (void)in_sizes; (void)n_in; (void)out_size; (void)ws_size;
  const float* x_in     = (const float*)d_in[0];
  const float* enc_w1   = (const float*)d_in[1];
  const float* enc_b1   = (const float*)d_in[2];
  const float* enc_w2   = (const float*)d_in[3];
  const float* enc_b2   = (const float*)d_in[4];
  const float* enc_w3   = (const float*)d_in[5];
  const float* enc_b3   = (const float*)d_in[6];
  const float* res_e_w1 = (const float*)d_in[7];
  const float* res_e_w2 = (const float*)d_in[8];
  const float* enc_w4   = (const float*)d_in[9];
  const float* enc_b4   = (const float*)d_in[10];
  const float* codebook = (const float*)d_in[11];
  const float* dec_w1   = (const float*)d_in[12];
  const float* dec_b1   = (const float*)d_in[13];
  const float* res_d_w1 = (const float*)d_in[14];
  const float* res_d_w2 = (const float*)d_in[15];
  const float* dec_w2   = (const float*)d_in[16];
  const float* dec_b2   = (const float*)d_in[17];
  const float* dec_w3   = (const float*)d_in[18];
  const float* dec_b3   = (const float*)d_in[19];
  float* out = (float*)d_out;

  char* ws = (char*)d_ws;
  float*  B0    = (float*)(ws);                         // 33.55 MB each
  float*  B1    = (float*)(ws + 33554432);
  float*  B2    = (float*)(ws + 67108864);
  float*  B3    = (float*)(ws + 100663296);
  float*  B4    = (float*)(ws + 134217728);             // 67.1 MB
  double* PART  = (double*)(ws + 201326592);            // 2048 doubles
  float*  CNORM = (float*)(ws + 201326592 + 16384);     // 512 floats

  k_enc1<<<65536, 256, 0, stream>>>(x_in, enc_w1, enc_b1, B4);
  k_enc2<<<2048, 256, 0, stream>>>(B4, enc_w2, enc_b2, B0);
  k_conv3<1, true ><<<1024, 256, 0, stream>>>(B0, enc_w3, enc_b3, B1);
  k_conv3<2, false><<<1024, 256, 0, stream>>>(B1, res_e_w1, nullptr, B2);
  k_1x1<1, false, true ><<<512, 256, 0, stream>>>(B2, res_e_w2, nullptr, B1, B0);
  k_1x1<1, true,  false><<<512, 256, 0, stream>>>(B0, enc_w4, enc_b4, nullptr, B1);
  k_cbnorm<<<2, 256, 0, stream>>>(codebook, CNORM);
  k_vq<<<2048, 256, 0, stream>>>(B1, codebook, CNORM, B2, PART);
  k_conv3<1, true ><<<1024, 256, 0, stream>>>(B2, dec_w1, dec_b1, B0);
  k_conv3<2, false><<<1024, 256, 0, stream>>>(B0, res_d_w1, nullptr, B3);
  k_1x1<1, false, true ><<<512, 256, 0, stream>>>(B3, res_d_w2, nullptr, B0, B1);
  k_dec2<<<2048, 256, 0, stream>>>(B1, dec_w2, dec_b2, B4);
  k_dec3<<<2048, 256, 0, stream>>>(B4, dec_w3, dec_b3, out);
  k_loss<<<1, 256, 0, stream>>>(PART, out);
}

// Round 2
// 2239.649 us; speedup vs baseline: 1.8867x; 1.8867x over previous
//
#include <hip/hip_runtime.h>

// ---------------------------------------------------------------------------
// VQ-VAE forward, all f32.  Geometry is fixed:
//   N=128, enc1: 1->32 4x4 s2 (128->64), enc2: 32->64 4x4 s2 (64->32),
//   3x3 64->64 @32x32 (enc3, res_e1, dec1, res_d1), 1x1 64->64 (res_e2,
//   enc4, res_d2), VQ K=512 D=64, dec2: up2x+3x3 64->32 (@64x64),
//   dec3: up2x+3x3 32->1 (@128x128).
// ---------------------------------------------------------------------------

template<int ACT> __device__ __forceinline__ float actf(float x){
  if (ACT == 1) return x > 0.f ? x : 0.01f * x;   // leaky relu, slope .01
  if (ACT == 2) return fmaxf(x, 0.f);             // relu
  return x;
}

// ---------------- enc1: 1->32, 4x4 stride2 pad1, 128->64, lrelu ------------
__global__ __launch_bounds__(256) void k_enc1(
    const float* __restrict__ in, const float* __restrict__ w,
    const float* __restrict__ b, float* __restrict__ out) {
  int idx = blockIdx.x * 256 + threadIdx.x;        // [128,32,64,64]
  int ox = idx & 63, oy = (idx >> 6) & 63, co = (idx >> 12) & 31, n = idx >> 17;
  const float* ip = in + n * 16384;
  const float* wp = w + co * 16;
  float acc = b[co];
  int iy0 = 2 * oy - 1, ix0 = 2 * ox - 1;
#pragma unroll
  for (int ky = 0; ky < 4; ++ky) {
    int iy = iy0 + ky;
    if ((unsigned)iy >= 128u) continue;
#pragma unroll
    for (int kx = 0; kx < 4; ++kx) {
      int ix = ix0 + kx;
      if ((unsigned)ix >= 128u) continue;
      acc = fmaf(ip[iy * 128 + ix], wp[ky * 4 + kx], acc);
    }
  }
  out[idx] = actf<1>(acc);
}

// ---------------- enc2: 32->64, 4x4 stride2 pad1, 64->32, lrelu ------------
__global__ __launch_bounds__(256) void k_enc2(
    const float* __restrict__ in, const float* __restrict__ w,
    const float* __restrict__ b, float* __restrict__ out) {
  int bid = blockIdx.x;                 // 2048 = 128n * 4coG * 4yT
  int n = bid >> 4, coG = (bid >> 2) & 3, yT = bid & 3;
  int co0 = coG * 16, y0 = yT * 8;
  int t = threadIdx.x;
  int coq = t >> 6, ty = (t >> 3) & 7, xq = t & 7;   // thread: 4co x 4x

  __shared__ float s_in[8 * 18 * 67];   // ci-group 8, 18 rows, 66 cols (pad 67)
  __shared__ float s_w[16 * 8 * 16];

  float acc[4][4];
#pragma unroll
  for (int c = 0; c < 4; ++c)
#pragma unroll
    for (int xx = 0; xx < 4; ++xx) acc[c][xx] = 0.f;

  for (int g = 0; g < 4; ++g) {
    int ci0 = g * 8;
    for (int i = t; i < 8 * 18 * 66; i += 256) {
      int ci = i / 1188, rem = i - ci * 1188;
      int r = rem / 66, c = rem - r * 66;
      int iy = 2 * y0 - 1 + r, ix = c - 1;
      float v = 0.f;
      if ((unsigned)iy < 64u && (unsigned)ix < 64u)
        v = in[((n * 32 + ci0 + ci) * 64 + iy) * 64 + ix];
      s_in[(ci * 18 + r) * 67 + c] = v;
    }
    for (int i = t; i < 16 * 8 * 16; i += 256) {
      int o = i >> 7, rem = i & 127;
      int ci = rem >> 4, k = rem & 15;
      s_w[i] = w[((co0 + o) * 32 + ci0 + ci) * 16 + k];
    }
    __syncthreads();
    for (int ci = 0; ci < 8; ++ci) {
#pragma unroll
      for (int ky = 0; ky < 4; ++ky) {
        float rv[10];
        int base = (ci * 18 + 2 * ty + ky) * 67 + xq * 8;
#pragma unroll
        for (int j = 0; j < 10; ++j) rv[j] = s_in[base + j];
#pragma unroll
        for (int c = 0; c < 4; ++c)
#pragma unroll
          for (int kx = 0; kx < 4; ++kx) {
            float wv = s_w[((coq * 4 + c) * 8 + ci) * 16 + ky * 4 + kx];
#pragma unroll
            for (int xx = 0; xx < 4; ++xx)
              acc[c][xx] = fmaf(rv[2 * xx + kx], wv, acc[c][xx]);
          }
      }
    }
    __syncthreads();
  }
#pragma unroll
  for (int c = 0; c < 4; ++c) {
    int co = co0 + coq * 4 + c;
    float bv = b[co];
    int base = ((n * 64 + co) * 32 + y0 + ty) * 32 + xq * 4;
    float4 v = make_float4(actf<1>(acc[c][0] + bv), actf<1>(acc[c][1] + bv),
                           actf<1>(acc[c][2] + bv), actf<1>(acc[c][3] + bv));
    *reinterpret_cast<float4*>(&out[base]) = v;
  }
}

// ---------------- 3x3 64->64 stride1 pad1 @32x32 ---------------------------
template<int ACT, bool BIAS>
__global__ __launch_bounds__(256) void k_conv3(
    const float* __restrict__ in, const float* __restrict__ w,
    const float* __restrict__ bias, float* __restrict__ out) {
  int bid = blockIdx.x;                  // 1024 = 128n * 4coG * 2yH
  int n = bid >> 3, coG = (bid >> 1) & 3, yH = bid & 1;
  int co0 = coG * 16, y0 = yH * 16;
  int t = threadIdx.x;
  int coq = t >> 6, ty = (t >> 2) & 15, xo = t & 3;   // thread: 4co x 8x

  __shared__ float s_in[16 * 18 * 35];   // ci-group 16, 18 rows, 34 cols (pad 35)
  __shared__ float s_w[16 * 16 * 9];

  float acc[4][8];
#pragma unroll
  for (int c = 0; c < 4; ++c)
#pragma unroll
    for (int xx = 0; xx < 8; ++xx) acc[c][xx] = 0.f;

  for (int g = 0; g < 4; ++g) {
    int ci0 = g * 16;
    for (int i = t; i < 16 * 18 * 34; i += 256) {
      int ci = i / 612, rem = i - ci * 612;
      int r = rem / 34, c = rem - r * 34;
      int iy = y0 - 1 + r, ix = c - 1;
      float v = 0.f;
      if ((unsigned)iy < 32u && (unsigned)ix < 32u)
        v = in[((n * 64 + ci0 + ci) * 32 + iy) * 32 + ix];
      s_in[(ci * 18 + r) * 35 + c] = v;
    }
    for (int i = t; i < 16 * 16 * 9; i += 256) {
      int o = i / 144, rem = i - o * 144;
      int ci = rem / 9, k = rem - ci * 9;
      s_w[i] = w[((co0 + o) * 64 + ci0 + ci) * 9 + k];
    }
    __syncthreads();
    for (int ci = 0; ci < 16; ++ci) {
#pragma unroll
      for (int ky = 0; ky < 3; ++ky) {
        float rv[10];
        int base = (ci * 18 + ty + ky) * 35 + xo * 8;
#pragma unroll
        for (int j = 0; j < 10; ++j) rv[j] = s_in[base + j];
#pragma unroll
        for (int c = 0; c < 4; ++c)
#pragma unroll
          for (int kx = 0; kx < 3; ++kx) {
            float wv = s_w[((coq * 4 + c) * 16 + ci) * 9 + ky * 3 + kx];
#pragma unroll
            for (int xx = 0; xx < 8; ++xx)
              acc[c][xx] = fmaf(rv[xx + kx], wv, acc[c][xx]);
          }
      }
    }
    __syncthreads();
  }
#pragma unroll
  for (int c = 0; c < 4; ++c) {
    int co = co0 + coq * 4 + c;
    float bv = BIAS ? bias[co] : 0.f;
    int base = ((n * 64 + co) * 32 + y0 + ty) * 32 + xo * 8;
    float o[8];
#pragma unroll
    for (int xx = 0; xx < 8; ++xx) o[xx] = actf<ACT>(acc[c][xx] + bv);
    *reinterpret_cast<float4*>(&out[base]) = make_float4(o[0], o[1], o[2], o[3]);
    *reinterpret_cast<float4*>(&out[base + 4]) = make_float4(o[4], o[5], o[6], o[7]);
  }
}

// ---------------- 1x1 64->64 (channel matmul), opt bias / add --------------
template<int ACT, bool BIAS, bool ADD>
__global__ __launch_bounds__(256) void k_1x1(
    const float* __restrict__ in, const float* __restrict__ w,
    const float* __restrict__ bias, const float* __restrict__ add,
    float* __restrict__ out) {
  int bid = blockIdx.x;                  // 512 = 128n * 4sT
  int n = bid >> 2;
  int s = ((bid & 3) << 8) + threadIdx.x;
  __shared__ float s_w[4096];
  for (int i = threadIdx.x; i < 4096; i += 256) s_w[i] = w[i];
  __syncthreads();
  float x[64];
#pragma unroll
  for (int ci = 0; ci < 64; ++ci) x[ci] = in[(n * 64 + ci) * 1024 + s];
  for (int co = 0; co < 64; ++co) {
    float acc = BIAS ? bias[co] : 0.f;
    const float* wr = &s_w[co * 64];
#pragma unroll
    for (int ci = 0; ci < 64; ++ci) acc = fmaf(wr[ci], x[ci], acc);
    if (ADD) acc += add[(n * 64 + co) * 1024 + s];
    out[(n * 64 + co) * 1024 + s] = actf<ACT>(acc);
  }
}

// ---------------- codebook prep: norms + k-major transpose -----------------
__global__ __launch_bounds__(256) void k_cbnorm(const float* __restrict__ cb,
                                                float* __restrict__ nrm) {
  int c = blockIdx.x * 256 + threadIdx.x;
  if (c < 512) {
    float s = 0.f;
    for (int k = 0; k < 64; ++k) { float v = cb[c * 64 + k]; s = fmaf(v, v, s); }
    nrm[c] = s;
  }
}

__global__ __launch_bounds__(256) void k_cbprep(const float* __restrict__ cb,
                                                float* __restrict__ cbT) {
  int i = blockIdx.x * 256 + threadIdx.x;   // 32768 = 512 codes x 64 dims
  int c = i >> 6, k = i & 63;
  cbT[k * 512 + c] = cb[i];
}

// ---------------- VQ: register-tiled distance GEMM + argmin ----------------
// block: 64 positions; thread tile: 4 pos x 8 codes (two b128 quads).
__global__ __launch_bounds__(256) void k_vq2(
    const float* __restrict__ lat, const float* __restrict__ cbT,
    const float* __restrict__ cb, const float* __restrict__ nrm,
    float* __restrict__ q, double* __restrict__ part) {
  int bid = blockIdx.x;                  // 2048 = 128 n x 16 s-tiles
  int n = bid >> 4, s0 = (bid & 15) << 6;
  int t = threadIdx.x;

  __shared__ float s_lat[64 * 64];       // [k][pos]   16 KB
  __shared__ float s_cb[64 * 128];       // [k][code]  32 KB (reused for reduce)
  __shared__ float s_nrm[512];
  __shared__ int   s_sel[64];
  __shared__ double s_r[256];

  for (int i = t; i < 4096; i += 256) {
    int k = i >> 6, p = i & 63;
    s_lat[k * 64 + p] = lat[(n * 64 + k) * 1024 + s0 + p];
  }
  for (int i = t; i < 512; i += 256) s_nrm[i] = nrm[i];

  int cl = t & 15, pg = t >> 4;          // code-lane (16), pos-group (16)
  int p0 = pg * 4;
  float best[4] = {3.4e38f, 3.4e38f, 3.4e38f, 3.4e38f};
  int bidx[4] = {0, 0, 0, 0};

  for (int g = 0; g < 4; ++g) {
    __syncthreads();                     // also covers s_lat/s_nrm on g=0
    for (int i = t; i < 2048; i += 256) {            // stage 128-code group
      int k = i >> 5, cc = (i & 31) << 2;
      *reinterpret_cast<float4*>(&s_cb[k * 128 + cc]) =
          *reinterpret_cast<const float4*>(&cbT[k * 512 + g * 128 + cc]);
    }
    __syncthreads();

    float acc[4][8];
#pragma unroll
    for (int p = 0; p < 4; ++p)
#pragma unroll
      for (int c = 0; c < 8; ++c) acc[p][c] = 0.f;

#pragma unroll 4
    for (int k = 0; k < 64; ++k) {
      float4 lv = *reinterpret_cast<const float4*>(&s_lat[k * 64 + p0]);
      float4 ca = *reinterpret_cast<const float4*>(&s_cb[k * 128 + (cl << 2)]);
      float4 cbq = *reinterpret_cast<const float4*>(&s_cb[k * 128 + 64 + (cl << 2)]);
      float l[4] = {lv.x, lv.y, lv.z, lv.w};
      float cv[8] = {ca.x, ca.y, ca.z, ca.w, cbq.x, cbq.y, cbq.z, cbq.w};
#pragma unroll
      for (int p = 0; p < 4; ++p)
#pragma unroll
        for (int c = 0; c < 8; ++c)
          acc[p][c] = fmaf(l[p], cv[c], acc[p][c]);
    }

#pragma unroll
    for (int half = 0; half < 2; ++half)
#pragma unroll
      for (int j = 0; j < 4; ++j) {
        int c = half * 4 + j;
        int code = g * 128 + half * 64 + (cl << 2) + j;   // ascending per scan
        float nv = s_nrm[code];
#pragma unroll
        for (int p = 0; p < 4; ++p) {
          float d = fmaf(-2.f, acc[p][c], nv);
          if (d < best[p]) { best[p] = d; bidx[p] = code; }
        }
      }
  }

  __syncthreads();
  float* s_rd = s_cb;                    // reuse: [pos][16] dist
  int*   s_ri = (int*)(s_cb + 1024);     //        [pos][16] idx
#pragma unroll
  for (int p = 0; p < 4; ++p) {
    s_rd[(p0 + p) * 16 + cl] = best[p];
    s_ri[(p0 + p) * 16 + cl] = bidx[p];
  }
  __syncthreads();
  if (t < 64) {
    float bd = s_rd[t * 16]; int bi = s_ri[t * 16];
#pragma unroll
    for (int m = 1; m < 16; ++m) {
      float d = s_rd[t * 16 + m]; int ii = s_ri[t * 16 + m];
      if (d < bd || (d == bd && ii < bi)) { bd = d; bi = ii; }
    }
    s_sel[t] = bi;
  }
  __syncthreads();

  int pos = t & 63, dg = t >> 6;
  int bsel = s_sel[pos];
  const float* cw = cb + bsel * 64 + dg * 16;
  float psum = 0.f;
#pragma unroll
  for (int kk = 0; kk < 16; ++kk) {
    int k = dg * 16 + kk;
    float cv = cw[kk];
    float l = s_lat[k * 64 + pos];
    float df = cv - l;
    psum = fmaf(df, df, psum);
    q[(n * 64 + k) * 1024 + s0 + pos] = cv;
  }
  s_r[t] = (double)psum;
  __syncthreads();
  for (int str = 128; str > 0; str >>= 1) {
    if (t < str) s_r[t] += s_r[t + str];
    __syncthreads();
  }
  if (t == 0) part[bid] = s_r[0];
}

// ---------------- loss finalize --------------------------------------------
__global__ __launch_bounds__(256) void k_loss(const double* __restrict__ part,
                                              float* __restrict__ out) {
  __shared__ double s[256];
  int t = threadIdx.x;
  double acc = 0.0;
  for (int i = t; i < 2048; i += 256) acc += part[i];
  s[t] = acc;
  __syncthreads();
  for (int str = 128; str > 0; str >>= 1) {
    if (t < str) s[t] += s[t + str];
    __syncthreads();
  }
  if (t == 0) {
    double mean = s[0] / 8388608.0;
    out[2097152] = (float)mean;          // embedding loss
    out[2097153] = (float)(0.25 * mean); // BETA * commitment
  }
}

// ---------------- dec2: fused upsample2x(ac) + 3x3 64->32 + lrelu ----------
__global__ __launch_bounds__(256) void k_dec2(
    const float* __restrict__ in, const float* __restrict__ w,
    const float* __restrict__ bias, float* __restrict__ out) {
  int bid = blockIdx.x;                  // 2048 = 128n * 4coG * 4yT
  int n = bid >> 4, coG = (bid >> 2) & 3, yT = bid & 3;
  int co0 = coG * 8, y0 = yT * 16;
  int t = threadIdx.x;
  int coq = t >> 7, ty = (t >> 3) & 15, xo = t & 7;   // thread: 4co x 8x

  __shared__ float s_up[8 * 18 * 67];
  __shared__ float s_src[8 * 11 * 33];
  __shared__ float s_w[8 * 8 * 9];

  const float sc = 31.0f / 63.0f;
  int r0 = (int)floorf(fmaxf((float)(y0 - 1), 0.f) * sc);

  float acc[4][8];
#pragma unroll
  for (int c = 0; c < 4; ++c)
#pragma unroll
    for (int xx = 0; xx < 8; ++xx) acc[c][xx] = 0.f;

  for (int g = 0; g < 8; ++g) {
    int ci0 = g * 8;
    for (int i = t; i < 8 * 11 * 32; i += 256) {
      int ci = i / 352, rem = i - ci * 352;
      int rr = rem >> 5, cx = rem & 31;
      int row = r0 + rr;
      float v = (row < 32) ? in[((n * 64 + ci0 + ci) * 32 + row) * 32 + cx] : 0.f;
      s_src[(ci * 11 + rr) * 33 + cx] = v;
    }
    for (int i = t; i < 8 * 8 * 9; i += 256) {
      int o = i / 72, rem = i - o * 72;
      int ci = rem / 9, k = rem - ci * 9;
      s_w[i] = w[((co0 + o) * 64 + ci0 + ci) * 9 + k];
    }
    __syncthreads();
    for (int i = t; i < 8 * 18 * 66; i += 256) {
      int ci = i / 1188, rem = i - ci * 1188;
      int uu = rem / 66, cc = rem - uu * 66;
      int uy = y0 - 1 + uu, ux = cc - 1;
      float v = 0.f;
      if ((unsigned)uy < 64u && (unsigned)ux < 64u) {
        float sy = uy * sc, sx = ux * sc;
        int iy0 = (int)floorf(sy), ix0 = (int)floorf(sx);
        float wy = sy - (float)iy0, wx = sx - (float)ix0;
        int iy1 = min(iy0 + 1, 31), ix1 = min(ix0 + 1, 31);
        const float* sp = &s_src[ci * 11 * 33];
        int ry = iy0 - r0, ry1 = iy1 - r0;
        float h0 = sp[ry * 33 + ix0] * (1.f - wy) + sp[ry1 * 33 + ix0] * wy;
        float h1 = sp[ry * 33 + ix1] * (1.f - wy) + sp[ry1 * 33 + ix1] * wy;
        v = h0 * (1.f - wx) + h1 * wx;
      }
      s_up[(ci * 18 + uu) * 67 + cc] = v;
    }
    __syncthreads();
    for (int ci = 0; ci < 8; ++ci) {
#pragma unroll
      for (int ky = 0; ky < 3; ++ky) {
        float rv[10];
        int base = (ci * 18 + ty + ky) * 67 + xo * 8;
#pragma unroll
        for (int j = 0; j < 10; ++j) rv[j] = s_up[base + j];
#pragma unroll
        for (int c = 0; c < 4; ++c)
#pragma unroll
          for (int kx = 0; kx < 3; ++kx) {
            float wv = s_w[((coq * 4 + c) * 8 + ci) * 9 + ky * 3 + kx];
#pragma unroll
            for (int xx = 0; xx < 8; ++xx)
              acc[c][xx] = fmaf(rv[xx + kx], wv, acc[c][xx]);
          }
      }
    }
    __syncthreads();
  }
#pragma unroll
  for (int c = 0; c < 4; ++c) {
    int co = co0 + coq * 4 + c;
    float bv = bias[co];
    int base = ((n * 32 + co) * 64 + y0 + ty) * 64 + xo * 8;
    float o[8];
#pragma unroll
    for (int xx = 0; xx < 8; ++xx) o[xx] = actf<1>(acc[c][xx] + bv);
    *reinterpret_cast<float4*>(&out[base]) = make_float4(o[0], o[1], o[2], o[3]);
    *reinterpret_cast<float4*>(&out[base + 4]) = make_float4(o[4], o[5], o[6], o[7]);
  }
}

// ---------------- dec3: fused upsample2x(ac) + 3x3 32->1 + relu ------------
__global__ __launch_bounds__(256) void k_dec3(
    const float* __restrict__ in, const float* __restrict__ w,
    const float* __restrict__ bias, float* __restrict__ out) {
  int bid = blockIdx.x;                  // 2048 = 128n * 8yT * 2xT
  int n = bid >> 4, yT = (bid >> 1) & 7, xT = bid & 1;
  int y0 = yT * 16, x0 = xT * 64;
  int t = threadIdx.x;
  int ty = t >> 4, xq = t & 15;          // thread: 4x

  __shared__ float s_up[8 * 18 * 67];
  __shared__ float s_src[8 * 11 * 35];
  __shared__ float s_w[288];

  const float sc = 63.0f / 127.0f;
  int r0 = (int)floorf(fmaxf((float)(y0 - 1), 0.f) * sc);
  int c0 = (int)floorf(fmaxf((float)(x0 - 1), 0.f) * sc);

  for (int i = t; i < 288; i += 256) s_w[i] = w[i];   // [1][32][3][3]

  float acc[4] = {0.f, 0.f, 0.f, 0.f};

  for (int g = 0; g < 4; ++g) {
    int ci0 = g * 8;
    for (int i = t; i < 8 * 11 * 35; i += 256) {
      int ci = i / 385, rem = i - ci * 385;
      int rr = rem / 35, cx = rem - rr * 35;
      int row = r0 + rr, col = c0 + cx;
      float v = (row < 64 && col < 64)
                    ? in[((n * 32 + ci0 + ci) * 64 + row) * 64 + col] : 0.f;
      s_src[(ci * 11 + rr) * 35 + cx] = v;
    }
    __syncthreads();
    for (int i = t; i < 8 * 18 * 66; i += 256) {
      int ci = i / 1188, rem = i - ci * 1188;
      int uu = rem / 66, cc = rem - uu * 66;
      int uy = y0 - 1 + uu, ux = x0 - 1 + cc;
      float v = 0.f;
      if ((unsigned)uy < 128u && (unsigned)ux < 128u) {
        float sy = uy * sc, sx = ux * sc;
        int iy0 = (int)floorf(sy), ix0 = (int)floorf(sx);
        float wy = sy - (float)iy0, wx = sx - (float)ix0;
        int iy1 = min(iy0 + 1, 63), ix1 = min(ix0 + 1, 63);
        const float* sp = &s_src[ci * 11 * 35];
        int ry = iy0 - r0, ry1 = iy1 - r0;
        int rx = ix0 - c0, rx1 = ix1 - c0;
        float h0 = sp[ry * 35 + rx] * (1.f - wy) + sp[ry1 * 35 + rx] * wy;
        float h1 = sp[ry * 35 + rx1] * (1.f - wy) + sp[ry1 * 35 + rx1] * wy;
        v = h0 * (1.f - wx) + h1 * wx;
      }
      s_up[(ci * 18 + uu) * 67 + cc] = v;
    }
    __syncthreads();
    for (int ci = 0; ci < 8; ++ci) {
#pragma unroll
      for (int ky = 0; ky < 3; ++ky) {
        float rv[6];
        int base = (ci * 18 + ty + ky) * 67 + xq * 4;
#pragma unroll
        for (int j = 0; j < 6; ++j) rv[j] = s_up[base + j];
#pragma unroll
        for (int kx = 0; kx < 3; ++kx) {
          float wv = s_w[(ci0 + ci) * 9 + ky * 3 + kx];
#pragma unroll
          for (int xx = 0; xx < 4; ++xx)
            acc[xx] = fmaf(rv[xx + kx], wv, acc[xx]);
        }
      }
    }
    __syncthreads();
  }
  float bv = bias[0];
  int base = n * 16384 + (y0 + ty) * 128 + x0 + xq * 4;
  *reinterpret_cast<float4*>(&out[base]) =
      make_float4(actf<2>(acc[0] + bv), actf<2>(acc[1] + bv),
                  actf<2>(acc[2] + bv), actf<2>(acc[3] + bv));
}

// ---------------------------------------------------------------------------
extern "C" void kernel_launch(void* const* d_in, const int* in_sizes, int n_in,
                              void* d_out, int out_size, void* d_ws, size_t ws_size,
                              hipStream_t stream) {
  (void)in_sizes; (void)n_in; (void)out_size; (void)ws_size;
  const float* x_in     = (const float*)d_in[0];
  const float* enc_w1   = (const float*)d_in[1];
  const float* enc_b1   = (const float*)d_in[2];
  const float* enc_w2   = (const float*)d_in[3];
  const float* enc_b2   = (const float*)d_in[4];
  const float* enc_w3   = (const float*)d_in[5];
  const float* enc_b3   = (const float*)d_in[6];
  const float* res_e_w1 = (const float*)d_in[7];
  const float* res_e_w2 = (const float*)d_in[8];
  const float* enc_w4   = (const float*)d_in[9];
  const float* enc_b4   = (const float*)d_in[10];
  const float* codebook = (const float*)d_in[11];
  const float* dec_w1   = (const float*)d_in[12];
  const float* dec_b1   = (const float*)d_in[13];
  const float* res_d_w1 = (const float*)d_in[14];
  const float* res_d_w2 = (const float*)d_in[15];
  const float* dec_w2   = (const float*)d_in[16];
  const float* dec_b2   = (const float*)d_in[17];
  const float* dec_w3   = (const float*)d_in[18];
  const float* dec_b3   = (const float*)d_in[19];
  float* out = (float*)d_out;

  char* ws = (char*)d_ws;
  float*  B0    = (float*)(ws);                         // 33.55 MB each
  float*  B1    = (float*)(ws + 33554432);
  float*  B2    = (float*)(ws + 67108864);
  float*  B3    = (float*)(ws + 100663296);
  float*  B4    = (float*)(ws + 134217728);             // 67.1 MB
  double* PART  = (double*)(ws + 201326592);            // 2048 doubles
  float*  CNORM = (float*)(ws + 201326592 + 16384);     // 512 floats
  float*  CBT   = (float*)(ws + 100663296);             // 128 KB, in B3 region:
                                                        // written pre-VQ, B3 is
                                                        // only used post-VQ.

  k_enc1<<<65536, 256, 0, stream>>>(x_in, enc_w1, enc_b1, B4);
  k_enc2<<<2048, 256, 0, stream>>>(B4, enc_w2, enc_b2, B0);
  k_conv3<1, true ><<<1024, 256, 0, stream>>>(B0, enc_w3, enc_b3, B1);
  k_conv3<2, false><<<1024, 256, 0, stream>>>(B1, res_e_w1, nullptr, B2);
  k_1x1<1, false, true ><<<512, 256, 0, stream>>>(B2, res_e_w2, nullptr, B1, B0);
  k_1x1<1, true,  false><<<512, 256, 0, stream>>>(B0, enc_w4, enc_b4, nullptr, B1);
  k_cbprep<<<128, 256, 0, stream>>>(codebook, CBT);
  k_cbnorm<<<2, 256, 0, stream>>>(codebook, CNORM);
  k_vq2<<<2048, 256, 0, stream>>>(B1, CBT, codebook, CNORM, B2, PART);
  k_conv3<1, true ><<<1024, 256, 0, stream>>>(B2, dec_w1, dec_b1, B0);
  k_conv3<2, false><<<1024, 256, 0, stream>>>(B0, res_d_w1, nullptr, B3);
  k_1x1<1, false, true ><<<512, 256, 0, stream>>>(B3, res_d_w2, nullptr, B0, B1);
  k_dec2<<<2048, 256, 0, stream>>>(B1, dec_w2, dec_b2, B4);
  k_dec3<<<2048, 256, 0, stream>>>(B4, dec_w3, dec_b3, out);
  k_loss<<<1, 256, 0, stream>>>(PART, out);
}

// Round 3
// 1955.153 us; speedup vs baseline: 2.1613x; 1.1455x over previous
//
#include <hip/hip_runtime.h>

// ---------------------------------------------------------------------------
// VQ-VAE forward, all f32.  Geometry is fixed:
//   N=128, enc1: 1->32 4x4 s2 (128->64), enc2: 32->64 4x4 s2 (64->32),
//   3x3 64->64 @32x32 (enc3, res_e1, dec1, res_d1), 1x1 64->64 (res_e2,
//   enc4, res_d2), VQ K=512 D=64, dec2: up2x+3x3 64->32 (@64x64),
//   dec3: up2x+3x3 32->1 (@128x128).
// ---------------------------------------------------------------------------

template<int ACT> __device__ __forceinline__ float actf(float x){
  if (ACT == 1) return x > 0.f ? x : 0.01f * x;   // leaky relu, slope .01
  if (ACT == 2) return fmaxf(x, 0.f);             // relu
  return x;
}

// ---------------- enc1: 1->32, 4x4 stride2 pad1, 128->64, lrelu ------------
__global__ __launch_bounds__(256) void k_enc1(
    const float* __restrict__ in, const float* __restrict__ w,
    const float* __restrict__ b, float* __restrict__ out) {
  int idx = blockIdx.x * 256 + threadIdx.x;        // [128,32,64,64]
  int ox = idx & 63, oy = (idx >> 6) & 63, co = (idx >> 12) & 31, n = idx >> 17;
  const float* ip = in + n * 16384;
  const float* wp = w + co * 16;
  float acc = b[co];
  int iy0 = 2 * oy - 1, ix0 = 2 * ox - 1;
#pragma unroll
  for (int ky = 0; ky < 4; ++ky) {
    int iy = iy0 + ky;
    if ((unsigned)iy >= 128u) continue;
#pragma unroll
    for (int kx = 0; kx < 4; ++kx) {
      int ix = ix0 + kx;
      if ((unsigned)ix >= 128u) continue;
      acc = fmaf(ip[iy * 128 + ix], wp[ky * 4 + kx], acc);
    }
  }
  out[idx] = actf<1>(acc);
}

// ---------------- enc2: 32->64, 4x4 stride2 pad1, 64->32, lrelu ------------
__global__ __launch_bounds__(256) void k_enc2(
    const float* __restrict__ in, const float* __restrict__ w,
    const float* __restrict__ b, float* __restrict__ out) {
  int bid = blockIdx.x;                 // 2048 = 128n * 4coG * 4yT
  int n = bid >> 4, coG = (bid >> 2) & 3, yT = bid & 3;
  int co0 = coG * 16, y0 = yT * 8;
  int t = threadIdx.x;
  int coq = t >> 6, ty = (t >> 3) & 7, xq = t & 7;   // thread: 4co x 4x

  __shared__ float s_in[8 * 18 * 67];   // ci-group 8, 18 rows, 66 cols (pad 67)
  __shared__ float s_w[16 * 8 * 16];

  float acc[4][4];
#pragma unroll
  for (int c = 0; c < 4; ++c)
#pragma unroll
    for (int xx = 0; xx < 4; ++xx) acc[c][xx] = 0.f;

  for (int g = 0; g < 4; ++g) {
    int ci0 = g * 8;
    for (int i = t; i < 8 * 18 * 66; i += 256) {
      int ci = i / 1188, rem = i - ci * 1188;
      int r = rem / 66, c = rem - r * 66;
      int iy = 2 * y0 - 1 + r, ix = c - 1;
      float v = 0.f;
      if ((unsigned)iy < 64u && (unsigned)ix < 64u)
        v = in[((n * 32 + ci0 + ci) * 64 + iy) * 64 + ix];
      s_in[(ci * 18 + r) * 67 + c] = v;
    }
    for (int i = t; i < 16 * 8 * 16; i += 256) {
      int o = i >> 7, rem = i & 127;
      int ci = rem >> 4, k = rem & 15;
      s_w[i] = w[((co0 + o) * 32 + ci0 + ci) * 16 + k];
    }
    __syncthreads();
    for (int ci = 0; ci < 8; ++ci) {
#pragma unroll
      for (int ky = 0; ky < 4; ++ky) {
        float rv[10];
        int base = (ci * 18 + 2 * ty + ky) * 67 + xq * 8;
#pragma unroll
        for (int j = 0; j < 10; ++j) rv[j] = s_in[base + j];
#pragma unroll
        for (int c = 0; c < 4; ++c)
#pragma unroll
          for (int kx = 0; kx < 4; ++kx) {
            float wv = s_w[((coq * 4 + c) * 8 + ci) * 16 + ky * 4 + kx];
#pragma unroll
            for (int xx = 0; xx < 4; ++xx)
              acc[c][xx] = fmaf(rv[2 * xx + kx], wv, acc[c][xx]);
          }
      }
    }
    __syncthreads();
  }
#pragma unroll
  for (int c = 0; c < 4; ++c) {
    int co = co0 + coq * 4 + c;
    float bv = b[co];
    int base = ((n * 64 + co) * 32 + y0 + ty) * 32 + xq * 4;
    float4 v = make_float4(actf<1>(acc[c][0] + bv), actf<1>(acc[c][1] + bv),
                           actf<1>(acc[c][2] + bv), actf<1>(acc[c][3] + bv));
    *reinterpret_cast<float4*>(&out[base]) = v;
  }
}

// ---------------- 3x3 64->64 stride1 pad1 @32x32 ---------------------------
template<int ACT, bool BIAS>
__global__ __launch_bounds__(256) void k_conv3(
    const float* __restrict__ in, const float* __restrict__ w,
    const float* __restrict__ bias, float* __restrict__ out) {
  int bid = blockIdx.x;                  // 1024 = 128n * 4coG * 2yH
  int n = bid >> 3, coG = (bid >> 1) & 3, yH = bid & 1;
  int co0 = coG * 16, y0 = yH * 16;
  int t = threadIdx.x;
  int coq = t >> 6, ty = (t >> 2) & 15, xo = t & 3;   // thread: 4co x 8x

  __shared__ float s_in[16 * 18 * 35];   // ci-group 16, 18 rows, 34 cols (pad 35)
  __shared__ float s_w[16 * 16 * 9];

  float acc[4][8];
#pragma unroll
  for (int c = 0; c < 4; ++c)
#pragma unroll
    for (int xx = 0; xx < 8; ++xx) acc[c][xx] = 0.f;

  for (int g = 0; g < 4; ++g) {
    int ci0 = g * 16;
    for (int i = t; i < 16 * 18 * 34; i += 256) {
      int ci = i / 612, rem = i - ci * 612;
      int r = rem / 34, c = rem - r * 34;
      int iy = y0 - 1 + r, ix = c - 1;
      float v = 0.f;
      if ((unsigned)iy < 32u && (unsigned)ix < 32u)
        v = in[((n * 64 + ci0 + ci) * 32 + iy) * 32 + ix];
      s_in[(ci * 18 + r) * 35 + c] = v;
    }
    for (int i = t; i < 16 * 16 * 9; i += 256) {
      int o = i / 144, rem = i - o * 144;
      int ci = rem / 9, k = rem - ci * 9;
      s_w[i] = w[((co0 + o) * 64 + ci0 + ci) * 9 + k];
    }
    __syncthreads();
    for (int ci = 0; ci < 16; ++ci) {
#pragma unroll
      for (int ky = 0; ky < 3; ++ky) {
        float rv[10];
        int base = (ci * 18 + ty + ky) * 35 + xo * 8;
#pragma unroll
        for (int j = 0; j < 10; ++j) rv[j] = s_in[base + j];
#pragma unroll
        for (int c = 0; c < 4; ++c)
#pragma unroll
          for (int kx = 0; kx < 3; ++kx) {
            float wv = s_w[((coq * 4 + c) * 16 + ci) * 9 + ky * 3 + kx];
#pragma unroll
            for (int xx = 0; xx < 8; ++xx)
              acc[c][xx] = fmaf(rv[xx + kx], wv, acc[c][xx]);
          }
      }
    }
    __syncthreads();
  }
#pragma unroll
  for (int c = 0; c < 4; ++c) {
    int co = co0 + coq * 4 + c;
    float bv = BIAS ? bias[co] : 0.f;
    int base = ((n * 64 + co) * 32 + y0 + ty) * 32 + xo * 8;
    float o[8];
#pragma unroll
    for (int xx = 0; xx < 8; ++xx) o[xx] = actf<ACT>(acc[c][xx] + bv);
    *reinterpret_cast<float4*>(&out[base]) = make_float4(o[0], o[1], o[2], o[3]);
    *reinterpret_cast<float4*>(&out[base + 4]) = make_float4(o[4], o[5], o[6], o[7]);
  }
}

// ---------------- 1x1 64->64 (channel matmul), opt bias / add --------------
template<int ACT, bool BIAS, bool ADD>
__global__ __launch_bounds__(256) void k_1x1(
    const float* __restrict__ in, const float* __restrict__ w,
    const float* __restrict__ bias, const float* __restrict__ add,
    float* __restrict__ out) {
  int bid = blockIdx.x;                  // 512 = 128n * 4sT
  int n = bid >> 2;
  int s = ((bid & 3) << 8) + threadIdx.x;
  __shared__ float s_w[4096];
  for (int i = threadIdx.x; i < 4096; i += 256) s_w[i] = w[i];
  __syncthreads();
  float x[64];
#pragma unroll
  for (int ci = 0; ci < 64; ++ci) x[ci] = in[(n * 64 + ci) * 1024 + s];
  for (int co = 0; co < 64; ++co) {
    float acc = BIAS ? bias[co] : 0.f;
    const float* wr = &s_w[co * 64];
#pragma unroll
    for (int ci = 0; ci < 64; ++ci) acc = fmaf(wr[ci], x[ci], acc);
    if (ADD) acc += add[(n * 64 + co) * 1024 + s];
    out[(n * 64 + co) * 1024 + s] = actf<ACT>(acc);
  }
}

// ---------------- codebook prep: norms + k-major transpose -----------------
__global__ __launch_bounds__(256) void k_cbnorm(const float* __restrict__ cb,
                                                float* __restrict__ nrm) {
  int c = blockIdx.x * 256 + threadIdx.x;
  if (c < 512) {
    float s = 0.f;
    for (int k = 0; k < 64; ++k) { float v = cb[c * 64 + k]; s = fmaf(v, v, s); }
    nrm[c] = s;
  }
}

__global__ __launch_bounds__(256) void k_cbprep(const float* __restrict__ cb,
                                                float* __restrict__ cbT) {
  int i = blockIdx.x * 256 + threadIdx.x;   // 32768 = 512 codes x 64 dims
  int c = i >> 6, k = i & 63;
  cbT[k * 512 + c] = cb[i];
}

// ---------------- VQ: register-tiled distance GEMM + argmin ----------------
__global__ __launch_bounds__(256) void k_vq2(
    const float* __restrict__ lat, const float* __restrict__ cbT,
    const float* __restrict__ cb, const float* __restrict__ nrm,
    float* __restrict__ q, double* __restrict__ part) {
  int bid = blockIdx.x;                  // 2048 = 128 n x 16 s-tiles
  int n = bid >> 4, s0 = (bid & 15) << 6;
  int t = threadIdx.x;

  __shared__ float s_lat[64 * 64];       // [k][pos]   16 KB
  __shared__ float s_cb[64 * 128];       // [k][code]  32 KB (reused for reduce)
  __shared__ float s_nrm[512];
  __shared__ int   s_sel[64];
  __shared__ double s_r[256];

  for (int i = t; i < 4096; i += 256) {
    int k = i >> 6, p = i & 63;
    s_lat[k * 64 + p] = lat[(n * 64 + k) * 1024 + s0 + p];
  }
  for (int i = t; i < 512; i += 256) s_nrm[i] = nrm[i];

  int cl = t & 15, pg = t >> 4;          // code-lane (16), pos-group (16)
  int p0 = pg * 4;
  float best[4] = {3.4e38f, 3.4e38f, 3.4e38f, 3.4e38f};
  int bidx[4] = {0, 0, 0, 0};

  for (int g = 0; g < 4; ++g) {
    __syncthreads();                     // also covers s_lat/s_nrm on g=0
    for (int i = t; i < 2048; i += 256) {            // stage 128-code group
      int k = i >> 5, cc = (i & 31) << 2;
      *reinterpret_cast<float4*>(&s_cb[k * 128 + cc]) =
          *reinterpret_cast<const float4*>(&cbT[k * 512 + g * 128 + cc]);
    }
    __syncthreads();

    float acc[4][8];
#pragma unroll
    for (int p = 0; p < 4; ++p)
#pragma unroll
      for (int c = 0; c < 8; ++c) acc[p][c] = 0.f;

#pragma unroll 4
    for (int k = 0; k < 64; ++k) {
      float4 lv = *reinterpret_cast<const float4*>(&s_lat[k * 64 + p0]);
      float4 ca = *reinterpret_cast<const float4*>(&s_cb[k * 128 + (cl << 2)]);
      float4 cbq = *reinterpret_cast<const float4*>(&s_cb[k * 128 + 64 + (cl << 2)]);
      float l[4] = {lv.x, lv.y, lv.z, lv.w};
      float cv[8] = {ca.x, ca.y, ca.z, ca.w, cbq.x, cbq.y, cbq.z, cbq.w};
#pragma unroll
      for (int p = 0; p < 4; ++p)
#pragma unroll
        for (int c = 0; c < 8; ++c)
          acc[p][c] = fmaf(l[p], cv[c], acc[p][c]);
    }

#pragma unroll
    for (int half = 0; half < 2; ++half)
#pragma unroll
      for (int j = 0; j < 4; ++j) {
        int c = half * 4 + j;
        int code = g * 128 + half * 64 + (cl << 2) + j;
        float nv = s_nrm[code];
#pragma unroll
        for (int p = 0; p < 4; ++p) {
          float d = fmaf(-2.f, acc[p][c], nv);
          if (d < best[p]) { best[p] = d; bidx[p] = code; }
        }
      }
  }

  __syncthreads();
  float* s_rd = s_cb;                    // reuse: [pos][16] dist
  int*   s_ri = (int*)(s_cb + 1024);     //        [pos][16] idx
#pragma unroll
  for (int p = 0; p < 4; ++p) {
    s_rd[(p0 + p) * 16 + cl] = best[p];
    s_ri[(p0 + p) * 16 + cl] = bidx[p];
  }
  __syncthreads();
  if (t < 64) {
    float bd = s_rd[t * 16]; int bi = s_ri[t * 16];
#pragma unroll
    for (int m = 1; m < 16; ++m) {
      float d = s_rd[t * 16 + m]; int ii = s_ri[t * 16 + m];
      if (d < bd || (d == bd && ii < bi)) { bd = d; bi = ii; }
    }
    s_sel[t] = bi;
  }
  __syncthreads();

  int pos = t & 63, dg = t >> 6;
  int bsel = s_sel[pos];
  const float* cw = cb + bsel * 64 + dg * 16;
  float psum = 0.f;
#pragma unroll
  for (int kk = 0; kk < 16; ++kk) {
    int k = dg * 16 + kk;
    float cv = cw[kk];
    float l = s_lat[k * 64 + pos];
    float df = cv - l;
    psum = fmaf(df, df, psum);
    q[(n * 64 + k) * 1024 + s0 + pos] = cv;
  }
  s_r[t] = (double)psum;
  __syncthreads();
  for (int str = 128; str > 0; str >>= 1) {
    if (t < str) s_r[t] += s_r[t + str];
    __syncthreads();
  }
  if (t == 0) part[bid] = s_r[0];
}

// ---------------- loss finalize --------------------------------------------
__global__ __launch_bounds__(256) void k_loss(const double* __restrict__ part,
                                              float* __restrict__ out) {
  __shared__ double s[256];
  int t = threadIdx.x;
  double acc = 0.0;
  for (int i = t; i < 2048; i += 256) acc += part[i];
  s[t] = acc;
  __syncthreads();
  for (int str = 128; str > 0; str >>= 1) {
    if (t < str) s[t] += s[t + str];
    __syncthreads();
  }
  if (t == 0) {
    double mean = s[0] / 8388608.0;
    out[2097152] = (float)mean;          // embedding loss
    out[2097153] = (float)(0.25 * mean); // BETA * commitment
  }
}

// ---------------- dec2: fused upsample2x(ac) + 3x3 64->32 + lrelu ----------
// Block = (n, 8-row strip), ALL 32 co.  Coeff tables hoisted; staging of the
// next ci-group overlaps the conv FMAs (2 barriers per group).
__global__ __launch_bounds__(256) void k_dec2(
    const float* __restrict__ in, const float* __restrict__ w,
    const float* __restrict__ bias, float* __restrict__ out) {
  int bid = blockIdx.x;                  // 1024 = 128n * 8yT
  int n = bid >> 3, yT = bid & 7;
  int y0 = yT * 8;
  int t = threadIdx.x;
  int coq = t >> 6, ty = (t >> 3) & 7, xo = t & 7;   // 8co x 1row x 8x

  __shared__ float s_src[8 * 8 * 33];    // 8 ci x 8 src rows x 33
  __shared__ float s_up[8 * 10 * 67];    // 8 ci x 10 up rows x 66 (pad 67)
  __shared__ float s_w[2][32 * 8 * 9];   // double-buffered weights
  __shared__ float s_wy[10], s_my[10];
  __shared__ int   s_ry0[10], s_ry1[10];
  __shared__ float s_wx[66], s_mx[66];
  __shared__ int   s_rx0[66], s_rx1[66];

  const float sc = 31.0f / 63.0f;
  int r0 = (y0 == 0) ? 0 : (int)floorf((float)(y0 - 1) * sc);

  if (t < 10) {                           // row tables
    int uy = y0 - 1 + t;
    int uyc = min(max(uy, 0), 63);
    float sy = (float)uyc * sc;
    int iy0 = (int)floorf(sy);
    s_wy[t] = sy - (float)iy0;
    s_my[t] = ((unsigned)uy < 64u) ? 1.f : 0.f;
    s_ry0[t] = iy0 - r0;
    s_ry1[t] = min(iy0 + 1, 31) - r0;
  }
  int xc = t - 64;                        // col tables on lanes 64..129
  if (xc >= 0 && xc < 66) {
    int ux = xc - 1;
    int uxc = min(max(ux, 0), 63);
    float sx = (float)uxc * sc;
    int ix0 = (int)floorf(sx);
    s_wx[xc] = sx - (float)ix0;
    s_mx[xc] = ((unsigned)ux < 64u) ? 1.f : 0.f;
    s_rx0[xc] = ix0;
    s_rx1[xc] = min(ix0 + 1, 31);
  }

  float acc[8][8];
#pragma unroll
  for (int c = 0; c < 8; ++c)
#pragma unroll
    for (int xx = 0; xx < 8; ++xx) acc[c][xx] = 0.f;

  // prologue stage g=0
  for (int i = t; i < 2048; i += 256) {               // 8ci x 8r x 32c
    int ci = i >> 8, rem = i & 255;
    int rr = rem >> 5, cx = rem & 31;
    int row = r0 + rr;
    s_src[(ci * 8 + rr) * 33 + cx] =
        (row < 32) ? in[((n * 64 + ci) * 32 + row) * 32 + cx] : 0.f;
  }
  for (int i = t; i < 2304; i += 256) {               // 32co x 8ci x 9
    int o = i / 72, rem = i - o * 72;
    s_w[0][i] = w[o * 576 + rem];                     // w[(o*64 + ci)*9 + k]
  }
  __syncthreads();

  for (int g = 0; g < 8; ++g) {
    // ---- interp: build s_up from s_src using tables ----
    for (int i = t; i < 5280; i += 256) {             // 8ci x 10 x 66
      int ci = i / 660, rem = i - ci * 660;
      int uu = rem / 66, cc = rem - uu * 66;
      const float* sp = &s_src[ci * 264];
      int ry0 = s_ry0[uu], ry1 = s_ry1[uu];
      int rx0 = s_rx0[cc], rx1 = s_rx1[cc];
      float wy = s_wy[uu], wx = s_wx[cc];
      float m = s_my[uu] * s_mx[cc];
      float a00 = sp[ry0 * 33 + rx0], a01 = sp[ry0 * 33 + rx1];
      float a10 = sp[ry1 * 33 + rx0], a11 = sp[ry1 * 33 + rx1];
      float h0 = fmaf(a10 - a00, wy, a00);
      float h1 = fmaf(a11 - a01, wy, a01);
      s_up[(ci * 10 + uu) * 67 + cc] = m * fmaf(h1 - h0, wx, h0);
    }
    __syncthreads();

    // ---- stage next group (overlaps with conv below) ----
    if (g < 7) {
      int ci0 = (g + 1) * 8;
      for (int i = t; i < 2048; i += 256) {
        int ci = i >> 8, rem = i & 255;
        int rr = rem >> 5, cx = rem & 31;
        int row = r0 + rr;
        s_src[(ci * 8 + rr) * 33 + cx] =
            (row < 32) ? in[((n * 64 + ci0 + ci) * 32 + row) * 32 + cx] : 0.f;
      }
      float* wb = s_w[(g + 1) & 1];
      for (int i = t; i < 2304; i += 256) {
        int o = i / 72, rem = i - o * 72;
        wb[i] = w[o * 576 + ci0 * 9 + rem];
      }
    }

    // ---- conv from s_up ----
    const float* wb = s_w[g & 1];
    for (int ci = 0; ci < 8; ++ci) {
#pragma unroll
      for (int ky = 0; ky < 3; ++ky) {
        float rv[10];
        int base = (ci * 10 + ty + ky) * 67 + xo * 8;
#pragma unroll
        for (int j = 0; j < 10; ++j) rv[j] = s_up[base + j];
#pragma unroll
        for (int c = 0; c < 8; ++c)
#pragma unroll
          for (int kx = 0; kx < 3; ++kx) {
            float wv = wb[((coq * 8 + c) * 8 + ci) * 9 + ky * 3 + kx];
#pragma unroll
            for (int xx = 0; xx < 8; ++xx)
              acc[c][xx] = fmaf(rv[xx + kx], wv, acc[c][xx]);
          }
      }
    }
    __syncthreads();
  }

#pragma unroll
  for (int c = 0; c < 8; ++c) {
    int co = coq * 8 + c;
    float bv = bias[co];
    int base = ((n * 32 + co) * 64 + y0 + ty) * 64 + xo * 8;
    float o[8];
#pragma unroll
    for (int xx = 0; xx < 8; ++xx) o[xx] = actf<1>(acc[c][xx] + bv);
    *reinterpret_cast<float4*>(&out[base]) = make_float4(o[0], o[1], o[2], o[3]);
    *reinterpret_cast<float4*>(&out[base + 4]) = make_float4(o[4], o[5], o[6], o[7]);
  }
}

// ---------------- dec3: fused upsample2x(ac) + 3x3 32->1 + relu ------------
__global__ __launch_bounds__(256) void k_dec3(
    const float* __restrict__ in, const float* __restrict__ w,
    const float* __restrict__ bias, float* __restrict__ out) {
  int bid = blockIdx.x;                  // 2048 = 128n * 8yT * 2xT
  int n = bid >> 4, yT = (bid >> 1) & 7, xT = bid & 1;
  int y0 = yT * 16, x0 = xT * 64;
  int t = threadIdx.x;
  int ty = t >> 4, xq = t & 15;          // 16 rows x 16 colgroups of 4

  __shared__ float s_up[8 * 18 * 67];
  __shared__ float s_src[8 * 11 * 35];
  __shared__ float s_w[288];
  __shared__ float s_wy[18], s_my[18];
  __shared__ int   s_ry0[18], s_ry1[18];
  __shared__ float s_wx[66], s_mx[66];
  __shared__ int   s_rx0[66], s_rx1[66];

  const float sc = 63.0f / 127.0f;
  int r0 = (y0 == 0) ? 0 : (int)floorf((float)(y0 - 1) * sc);
  int c0 = (x0 == 0) ? 0 : (int)floorf((float)(x0 - 1) * sc);

  if (t < 18) {
    int uy = y0 - 1 + t;
    int uyc = min(max(uy, 0), 127);
    float sy = (float)uyc * sc;
    int iy0 = (int)floorf(sy);
    s_wy[t] = sy - (float)iy0;
    s_my[t] = ((unsigned)uy < 128u) ? 1.f : 0.f;
    s_ry0[t] = iy0 - r0;
    s_ry1[t] = min(iy0 + 1, 63) - r0;
  }
  int xc = t - 64;
  if (xc >= 0 && xc < 66) {
    int ux = x0 - 1 + xc;
    int uxc = min(max(ux, 0), 127);
    float sx = (float)uxc * sc;
    int ix0 = (int)floorf(sx);
    s_wx[xc] = sx - (float)ix0;
    s_mx[xc] = ((unsigned)ux < 128u) ? 1.f : 0.f;
    s_rx0[xc] = ix0 - c0;
    s_rx1[xc] = min(ix0 + 1, 63) - c0;
  }
  for (int i = t; i < 288; i += 256) s_w[i] = w[i];   // [1][32][3][3]

  float acc[4] = {0.f, 0.f, 0.f, 0.f};

  // prologue stage g=0
  for (int i = t; i < 8 * 11 * 35; i += 256) {
    int ci = i / 385, rem = i - ci * 385;
    int rr = rem / 35, cx = rem - rr * 35;
    int row = r0 + rr, col = c0 + cx;
    s_src[(ci * 11 + rr) * 35 + cx] =
        (row < 64 && col < 64) ? in[((n * 32 + ci) * 64 + row) * 64 + col] : 0.f;
  }
  __syncthreads();

  for (int g = 0; g < 4; ++g) {
    // ---- interp ----
    for (int i = t; i < 8 * 18 * 66; i += 256) {
      int ci = i / 1188, rem = i - ci * 1188;
      int uu = rem / 66, cc = rem - uu * 66;
      const float* sp = &s_src[ci * 385];
      int ry0 = s_ry0[uu], ry1 = s_ry1[uu];
      int rx0 = s_rx0[cc], rx1 = s_rx1[cc];
      float wy = s_wy[uu], wx = s_wx[cc];
      float m = s_my[uu] * s_mx[cc];
      float a00 = sp[ry0 * 35 + rx0], a01 = sp[ry0 * 35 + rx1];
      float a10 = sp[ry1 * 35 + rx0], a11 = sp[ry1 * 35 + rx1];
      float h0 = fmaf(a10 - a00, wy, a00);
      float h1 = fmaf(a11 - a01, wy, a01);
      s_up[(ci * 18 + uu) * 67 + cc] = m * fmaf(h1 - h0, wx, h0);
    }
    __syncthreads();

    // ---- stage next ci-group (overlaps conv) ----
    if (g < 3) {
      int ci0 = (g + 1) * 8;
      for (int i = t; i < 8 * 11 * 35; i += 256) {
        int ci = i / 385, rem = i - ci * 385;
        int rr = rem / 35, cx = rem - rr * 35;
        int row = r0 + rr, col = c0 + cx;
        s_src[(ci * 11 + rr) * 35 + cx] =
            (row < 64 && col < 64)
                ? in[((n * 32 + ci0 + ci) * 64 + row) * 64 + col] : 0.f;
      }
    }

    // ---- conv ----
    int ci0 = g * 8;
    for (int ci = 0; ci < 8; ++ci) {
#pragma unroll
      for (int ky = 0; ky < 3; ++ky) {
        float rv[6];
        int base = (ci * 18 + ty + ky) * 67 + xq * 4;
#pragma unroll
        for (int j = 0; j < 6; ++j) rv[j] = s_up[base + j];
#pragma unroll
        for (int kx = 0; kx < 3; ++kx) {
          float wv = s_w[(ci0 + ci) * 9 + ky * 3 + kx];
#pragma unroll
          for (int xx = 0; xx < 4; ++xx)
            acc[xx] = fmaf(rv[xx + kx], wv, acc[xx]);
        }
      }
    }
    __syncthreads();
  }
  float bv = bias[0];
  int base = n * 16384 + (y0 + ty) * 128 + x0 + xq * 4;
  *reinterpret_cast<float4*>(&out[base]) =
      make_float4(actf<2>(acc[0] + bv), actf<2>(acc[1] + bv),
                  actf<2>(acc[2] + bv), actf<2>(acc[3] + bv));
}

// ---------------------------------------------------------------------------
extern "C" void kernel_launch(void* const* d_in, const int* in_sizes, int n_in,
                              void* d_out, int out_size, void* d_ws, size_t ws_size,
                              hipStream_t stream) {
  (void)in_sizes; (void)n_in; (void)out_size; (void)ws_size;
  const float* x_in     = (const float*)d_in[0];
  const float* enc_w1   = (const float*)d_in[1];
  const float* enc_b1   = (const float*)d_in[2];
  const float* enc_w2   = (const float*)d_in[3];
  const float* enc_b2   = (const float*)d_in[4];
  const float* enc_w3   = (const float*)d_in[5];
  const float* enc_b3   = (const float*)d_in[6];
  const float* res_e_w1 = (const float*)d_in[7];
  const float* res_e_w2 = (const float*)d_in[8];
  const float* enc_w4   = (const float*)d_in[9];
  const float* enc_b4   = (const float*)d_in[10];
  const float* codebook = (const float*)d_in[11];
  const float* dec_w1   = (const float*)d_in[12];
  const float* dec_b1   = (const float*)d_in[13];
  const float* res_d_w1 = (const float*)d_in[14];
  const float* res_d_w2 = (const float*)d_in[15];
  const float* dec_w2   = (const float*)d_in[16];
  const float* dec_b2   = (const float*)d_in[17];
  const float* dec_w3   = (const float*)d_in[18];
  const float* dec_b3   = (const float*)d_in[19];
  float* out = (float*)d_out;

  char* ws = (char*)d_ws;
  float*  B0    = (float*)(ws);                         // 33.55 MB each
  float*  B1    = (float*)(ws + 33554432);
  float*  B2    = (float*)(ws + 67108864);
  float*  B3    = (float*)(ws + 100663296);
  float*  B4    = (float*)(ws + 134217728);             // 67.1 MB
  double* PART  = (double*)(ws + 201326592);            // 2048 doubles
  float*  CNORM = (float*)(ws + 201326592 + 16384);     // 512 floats
  float*  CBT   = (float*)(ws + 100663296);             // 128 KB in B3 region

  k_enc1<<<65536, 256, 0, stream>>>(x_in, enc_w1, enc_b1, B4);
  k_enc2<<<2048, 256, 0, stream>>>(B4, enc_w2, enc_b2, B0);
  k_conv3<1, true ><<<1024, 256, 0, stream>>>(B0, enc_w3, enc_b3, B1);
  k_conv3<2, false><<<1024, 256, 0, stream>>>(B1, res_e_w1, nullptr, B2);
  k_1x1<1, false, true ><<<512, 256, 0, stream>>>(B2, res_e_w2, nullptr, B1, B0);
  k_1x1<1, true,  false><<<512, 256, 0, stream>>>(B0, enc_w4, enc_b4, nullptr, B1);
  k_cbprep<<<128, 256, 0, stream>>>(codebook, CBT);
  k_cbnorm<<<2, 256, 0, stream>>>(codebook, CNORM);
  k_vq2<<<2048, 256, 0, stream>>>(B1, CBT, codebook, CNORM, B2, PART);
  k_conv3<1, true ><<<1024, 256, 0, stream>>>(B2, dec_w1, dec_b1, B0);
  k_conv3<2, false><<<1024, 256, 0, stream>>>(B0, res_d_w1, nullptr, B3);
  k_1x1<1, false, true ><<<512, 256, 0, stream>>>(B3, res_d_w2, nullptr, B0, B1);
  k_dec2<<<1024, 256, 0, stream>>>(B1, dec_w2, dec_b2, B4);
  k_dec3<<<2048, 256, 0, stream>>>(B4, dec_w3, dec_b3, out);
  k_loss<<<1, 256, 0, stream>>>(PART, out);
}

// Round 4
// 1907.000 us; speedup vs baseline: 2.2159x; 1.0253x over previous
//
#include <hip/hip_runtime.h>

// ---------------------------------------------------------------------------
// VQ-VAE forward, all f32.  N=128.
// enc1: 1->32 4x4 s2 (128->64); enc2: 32->64 4x4 s2 (64->32);
// 3x3 64->64 @32x32 (enc3, res_e1, dec1, res_d1); 1x1 64->64 (x3);
// VQ K=512 D=64; dec2: up2x+3x3 64->32 (@64x64); dec3: up2x+3x3 32->1.
// ---------------------------------------------------------------------------

template<int ACT> __device__ __forceinline__ float actf(float x){
  if (ACT == 1) return x > 0.f ? x : 0.01f * x;   // leaky relu, slope .01
  if (ACT == 2) return fmaxf(x, 0.f);             // relu
  return x;
}

// ---------------- enc1: 1->32, 4x4 stride2 pad1, 128->64, lrelu ------------
__global__ __launch_bounds__(256) void k_enc1(
    const float* __restrict__ in, const float* __restrict__ w,
    const float* __restrict__ b, float* __restrict__ out) {
  int idx = blockIdx.x * 256 + threadIdx.x;        // [128,32,64,64]
  int ox = idx & 63, oy = (idx >> 6) & 63, co = (idx >> 12) & 31, n = idx >> 17;
  const float* ip = in + n * 16384;
  const float* wp = w + co * 16;
  float acc = b[co];
  int iy0 = 2 * oy - 1, ix0 = 2 * ox - 1;
#pragma unroll
  for (int ky = 0; ky < 4; ++ky) {
    int iy = iy0 + ky;
    if ((unsigned)iy >= 128u) continue;
#pragma unroll
    for (int kx = 0; kx < 4; ++kx) {
      int ix = ix0 + kx;
      if ((unsigned)ix >= 128u) continue;
      acc = fmaf(ip[iy * 128 + ix], wp[ky * 4 + kx], acc);
    }
  }
  out[idx] = actf<1>(acc);
}

// ---------------- enc2: 32->64, 4x4 s2 p1, 64->32, lrelu -------------------
// dbuf pipeline, ci-groups of 4, b128 rv reads (stride 68), co-fast weights.
__global__ __launch_bounds__(256) void k_enc2(
    const float* __restrict__ in, const float* __restrict__ w,
    const float* __restrict__ b, float* __restrict__ out) {
  int bid = blockIdx.x;                 // 2048 = 128n * 4coG * 4yT
  int n = bid >> 4, coG = (bid >> 2) & 3, yT = bid & 3;
  int co0 = coG * 16, y0 = yT * 8;
  int t = threadIdx.x;
  int coq = t >> 6, ty = (t >> 3) & 7, xq = t & 7;   // 4co x 8row x 8xg(4)

  __shared__ float s_in[2][4 * 18 * 68];
  __shared__ float s_w[2][4 * 16 * 16];   // [(ci*16+k)*16 + co]

  float acc[4][4];
#pragma unroll
  for (int c = 0; c < 4; ++c)
#pragma unroll
    for (int xx = 0; xx < 4; ++xx) acc[c][xx] = 0.f;

  // prologue: stage g=0
  {
    for (int i = t; i < 4 * 18 * 66; i += 256) {
      int ci = i / 1188, rem = i - ci * 1188;
      int r = rem / 66, c = rem - r * 66;
      int iy = 2 * y0 - 1 + r, ix = c - 1;
      float v = 0.f;
      if ((unsigned)iy < 64u && (unsigned)ix < 64u)
        v = in[((n * 32 + ci) * 64 + iy) * 64 + ix];
      s_in[0][(ci * 18 + r) * 68 + c] = v;
    }
    for (int i = t; i < 1024; i += 256) {
      int co = i & 15, j = i >> 4;
      int ci = j >> 4, k = j & 15;
      s_w[0][j * 16 + co] = w[((co0 + co) * 32 + ci) * 16 + k];
    }
  }
  __syncthreads();

  for (int g = 0; g < 8; ++g) {
    int buf = g & 1;
    if (g < 7) {                               // stage next (overlaps compute)
      int ci0 = (g + 1) * 4, nb = buf ^ 1;
      for (int i = t; i < 4 * 18 * 66; i += 256) {
        int ci = i / 1188, rem = i - ci * 1188;
        int r = rem / 66, c = rem - r * 66;
        int iy = 2 * y0 - 1 + r, ix = c - 1;
        float v = 0.f;
        if ((unsigned)iy < 64u && (unsigned)ix < 64u)
          v = in[((n * 32 + ci0 + ci) * 64 + iy) * 64 + ix];
        s_in[nb][(ci * 18 + r) * 68 + c] = v;
      }
      for (int i = t; i < 1024; i += 256) {
        int co = i & 15, j = i >> 4;
        int ci = j >> 4, k = j & 15;
        s_w[nb][j * 16 + co] = w[((co0 + co) * 32 + ci0 + ci) * 16 + k];
      }
    }
    for (int ci = 0; ci < 4; ++ci) {
#pragma unroll
      for (int ky = 0; ky < 4; ++ky) {
        int base = (ci * 18 + 2 * ty + ky) * 68 + xq * 8;
        float4 q0 = *reinterpret_cast<const float4*>(&s_in[buf][base]);
        float4 q1 = *reinterpret_cast<const float4*>(&s_in[buf][base + 4]);
        float4 q2 = *reinterpret_cast<const float4*>(&s_in[buf][base + 8]);
        float rv[12] = {q0.x, q0.y, q0.z, q0.w, q1.x, q1.y, q1.z, q1.w,
                        q2.x, q2.y, q2.z, q2.w};
#pragma unroll
        for (int kx = 0; kx < 4; ++kx) {
          float4 wq = *reinterpret_cast<const float4*>(
              &s_w[buf][(ci * 16 + ky * 4 + kx) * 16 + coq * 4]);
          float wv[4] = {wq.x, wq.y, wq.z, wq.w};
#pragma unroll
          for (int c = 0; c < 4; ++c)
#pragma unroll
            for (int xx = 0; xx < 4; ++xx)
              acc[c][xx] = fmaf(rv[2 * xx + kx], wv[c], acc[c][xx]);
        }
      }
    }
    __syncthreads();
  }
#pragma unroll
  for (int c = 0; c < 4; ++c) {
    int co = co0 + coq * 4 + c;
    float bv = b[co];
    int base = ((n * 64 + co) * 32 + y0 + ty) * 32 + xq * 4;
    float4 v = make_float4(actf<1>(acc[c][0] + bv), actf<1>(acc[c][1] + bv),
                           actf<1>(acc[c][2] + bv), actf<1>(acc[c][3] + bv));
    *reinterpret_cast<float4*>(&out[base]) = v;
  }
}

// ---------------- 3x3 64->64 stride1 pad1 @32x32 ---------------------------
// dbuf pipeline, ci-groups of 8, b128 rv (stride 36), co-fast weights.
template<int ACT, bool BIAS>
__global__ __launch_bounds__(256) void k_conv3(
    const float* __restrict__ in, const float* __restrict__ w,
    const float* __restrict__ bias, float* __restrict__ out) {
  int bid = blockIdx.x;                  // 1024 = 128n * 4coG * 2yH
  int n = bid >> 3, coG = (bid >> 1) & 3, yH = bid & 1;
  int co0 = coG * 16, y0 = yH * 16;
  int t = threadIdx.x;
  int coq = t >> 6, ty = (t >> 2) & 15, xo = t & 3;   // 4co x 16row x 4xg(8)

  __shared__ float s_in[2][8 * 18 * 36];
  __shared__ float s_w[2][8 * 9 * 16];   // [(ci*9+k)*16 + co]

  float acc[4][8];
#pragma unroll
  for (int c = 0; c < 4; ++c)
#pragma unroll
    for (int xx = 0; xx < 8; ++xx) acc[c][xx] = 0.f;

  {
    for (int i = t; i < 8 * 18 * 34; i += 256) {
      int ci = i / 612, rem = i - ci * 612;
      int r = rem / 34, c = rem - r * 34;
      int iy = y0 - 1 + r, ix = c - 1;
      float v = 0.f;
      if ((unsigned)iy < 32u && (unsigned)ix < 32u)
        v = in[((n * 64 + ci) * 32 + iy) * 32 + ix];
      s_in[0][(ci * 18 + r) * 36 + c] = v;
    }
    for (int i = t; i < 1152; i += 256) {
      int co = i & 15, j = i >> 4;
      int ci = j / 9, k = j - ci * 9;
      s_w[0][j * 16 + co] = w[((co0 + co) * 64 + ci) * 9 + k];
    }
  }
  __syncthreads();

  for (int g = 0; g < 8; ++g) {
    int buf = g & 1;
    if (g < 7) {
      int ci0 = (g + 1) * 8, nb = buf ^ 1;
      for (int i = t; i < 8 * 18 * 34; i += 256) {
        int ci = i / 612, rem = i - ci * 612;
        int r = rem / 34, c = rem - r * 34;
        int iy = y0 - 1 + r, ix = c - 1;
        float v = 0.f;
        if ((unsigned)iy < 32u && (unsigned)ix < 32u)
          v = in[((n * 64 + ci0 + ci) * 32 + iy) * 32 + ix];
        s_in[nb][(ci * 18 + r) * 36 + c] = v;
      }
      for (int i = t; i < 1152; i += 256) {
        int co = i & 15, j = i >> 4;
        int ci = j / 9, k = j - ci * 9;
        s_w[nb][j * 16 + co] = w[((co0 + co) * 64 + ci0 + ci) * 9 + k];
      }
    }
    for (int ci = 0; ci < 8; ++ci) {
#pragma unroll
      for (int ky = 0; ky < 3; ++ky) {
        int base = (ci * 18 + ty + ky) * 36 + xo * 8;
        float4 q0 = *reinterpret_cast<const float4*>(&s_in[buf][base]);
        float4 q1 = *reinterpret_cast<const float4*>(&s_in[buf][base + 4]);
        float4 q2 = *reinterpret_cast<const float4*>(&s_in[buf][base + 8]);
        float rv[12] = {q0.x, q0.y, q0.z, q0.w, q1.x, q1.y, q1.z, q1.w,
                        q2.x, q2.y, q2.z, q2.w};
#pragma unroll
        for (int kx = 0; kx < 3; ++kx) {
          float4 wq = *reinterpret_cast<const float4*>(
              &s_w[buf][(ci * 9 + ky * 3 + kx) * 16 + coq * 4]);
          float wv[4] = {wq.x, wq.y, wq.z, wq.w};
#pragma unroll
          for (int c = 0; c < 4; ++c)
#pragma unroll
            for (int xx = 0; xx < 8; ++xx)
              acc[c][xx] = fmaf(rv[xx + kx], wv[c], acc[c][xx]);
        }
      }
    }
    __syncthreads();
  }
#pragma unroll
  for (int c = 0; c < 4; ++c) {
    int co = co0 + coq * 4 + c;
    float bv = BIAS ? bias[co] : 0.f;
    int base = ((n * 64 + co) * 32 + y0 + ty) * 32 + xo * 8;
    float o[8];
#pragma unroll
    for (int xx = 0; xx < 8; ++xx) o[xx] = actf<ACT>(acc[c][xx] + bv);
    *reinterpret_cast<float4*>(&out[base]) = make_float4(o[0], o[1], o[2], o[3]);
    *reinterpret_cast<float4*>(&out[base + 4]) = make_float4(o[4], o[5], o[6], o[7]);
  }
}

// ---------------- 1x1 64->64 (channel matmul), opt bias / add --------------
template<int ACT, bool BIAS, bool ADD>
__global__ __launch_bounds__(256) void k_1x1(
    const float* __restrict__ in, const float* __restrict__ w,
    const float* __restrict__ bias, const float* __restrict__ add,
    float* __restrict__ out) {
  int bid = blockIdx.x;                  // 512 = 128n * 4sT
  int n = bid >> 2;
  int s = ((bid & 3) << 8) + threadIdx.x;
  __shared__ float s_w[4096];
  for (int i = threadIdx.x; i < 4096; i += 256) s_w[i] = w[i];
  __syncthreads();
  float x[64];
#pragma unroll
  for (int ci = 0; ci < 64; ++ci) x[ci] = in[(n * 64 + ci) * 1024 + s];
  for (int co = 0; co < 64; ++co) {
    float acc = BIAS ? bias[co] : 0.f;
    const float* wr = &s_w[co * 64];
#pragma unroll
    for (int ci = 0; ci < 64; ++ci) acc = fmaf(wr[ci], x[ci], acc);
    if (ADD) acc += add[(n * 64 + co) * 1024 + s];
    out[(n * 64 + co) * 1024 + s] = actf<ACT>(acc);
  }
}

// ---------------- codebook prep: norms + k-major transpose -----------------
__global__ __launch_bounds__(256) void k_cbnorm(const float* __restrict__ cb,
                                                float* __restrict__ nrm) {
  int c = blockIdx.x * 256 + threadIdx.x;
  if (c < 512) {
    float s = 0.f;
    for (int k = 0; k < 64; ++k) { float v = cb[c * 64 + k]; s = fmaf(v, v, s); }
    nrm[c] = s;
  }
}

__global__ __launch_bounds__(256) void k_cbprep(const float* __restrict__ cb,
                                                float* __restrict__ cbT) {
  int i = blockIdx.x * 256 + threadIdx.x;   // 32768 = 512 codes x 64 dims
  int c = i >> 6, k = i & 63;
  cbT[k * 512 + c] = cb[i];
}

// ---------------- VQ: register-tiled distance GEMM + argmin ----------------
__global__ __launch_bounds__(256) void k_vq2(
    const float* __restrict__ lat, const float* __restrict__ cbT,
    const float* __restrict__ cb, const float* __restrict__ nrm,
    float* __restrict__ q, double* __restrict__ part) {
  int bid = blockIdx.x;                  // 2048 = 128 n x 16 s-tiles
  int n = bid >> 4, s0 = (bid & 15) << 6;
  int t = threadIdx.x;

  __shared__ float s_lat[64 * 64];       // [k][pos]   16 KB
  __shared__ float s_cb[64 * 128];       // [k][code]  32 KB (reused for reduce)
  __shared__ float s_nrm[512];
  __shared__ int   s_sel[64];
  __shared__ double s_r[256];

  for (int i = t; i < 4096; i += 256) {
    int k = i >> 6, p = i & 63;
    s_lat[k * 64 + p] = lat[(n * 64 + k) * 1024 + s0 + p];
  }
  for (int i = t; i < 512; i += 256) s_nrm[i] = nrm[i];

  int cl = t & 15, pg = t >> 4;          // code-lane (16), pos-group (16)
  int p0 = pg * 4;
  float best[4] = {3.4e38f, 3.4e38f, 3.4e38f, 3.4e38f};
  int bidx[4] = {0, 0, 0, 0};

  for (int g = 0; g < 4; ++g) {
    __syncthreads();                     // also covers s_lat/s_nrm on g=0
    for (int i = t; i < 2048; i += 256) {            // stage 128-code group
      int k = i >> 5, cc = (i & 31) << 2;
      *reinterpret_cast<float4*>(&s_cb[k * 128 + cc]) =
          *reinterpret_cast<const float4*>(&cbT[k * 512 + g * 128 + cc]);
    }
    __syncthreads();

    float acc[4][8];
#pragma unroll
    for (int p = 0; p < 4; ++p)
#pragma unroll
      for (int c = 0; c < 8; ++c) acc[p][c] = 0.f;

#pragma unroll 4
    for (int k = 0; k < 64; ++k) {
      float4 lv = *reinterpret_cast<const float4*>(&s_lat[k * 64 + p0]);
      float4 ca = *reinterpret_cast<const float4*>(&s_cb[k * 128 + (cl << 2)]);
      float4 cbq = *reinterpret_cast<const float4*>(&s_cb[k * 128 + 64 + (cl << 2)]);
      float l[4] = {lv.x, lv.y, lv.z, lv.w};
      float cv[8] = {ca.x, ca.y, ca.z, ca.w, cbq.x, cbq.y, cbq.z, cbq.w};
#pragma unroll
      for (int p = 0; p < 4; ++p)
#pragma unroll
        for (int c = 0; c < 8; ++c)
          acc[p][c] = fmaf(l[p], cv[c], acc[p][c]);
    }

#pragma unroll
    for (int half = 0; half < 2; ++half)
#pragma unroll
      for (int j = 0; j < 4; ++j) {
        int c = half * 4 + j;
        int code = g * 128 + half * 64 + (cl << 2) + j;
        float nv = s_nrm[code];
#pragma unroll
        for (int p = 0; p < 4; ++p) {
          float d = fmaf(-2.f, acc[p][c], nv);
          if (d < best[p]) { best[p] = d; bidx[p] = code; }
        }
      }
  }

  __syncthreads();
  float* s_rd = s_cb;                    // reuse: [pos][16] dist
  int*   s_ri = (int*)(s_cb + 1024);     //        [pos][16] idx
#pragma unroll
  for (int p = 0; p < 4; ++p) {
    s_rd[(p0 + p) * 16 + cl] = best[p];
    s_ri[(p0 + p) * 16 + cl] = bidx[p];
  }
  __syncthreads();
  if (t < 64) {
    float bd = s_rd[t * 16]; int bi = s_ri[t * 16];
#pragma unroll
    for (int m = 1; m < 16; ++m) {
      float d = s_rd[t * 16 + m]; int ii = s_ri[t * 16 + m];
      if (d < bd || (d == bd && ii < bi)) { bd = d; bi = ii; }
    }
    s_sel[t] = bi;
  }
  __syncthreads();

  int pos = t & 63, dg = t >> 6;
  int bsel = s_sel[pos];
  const float* cw = cb + bsel * 64 + dg * 16;
  float psum = 0.f;
#pragma unroll
  for (int kk = 0; kk < 16; ++kk) {
    int k = dg * 16 + kk;
    float cv = cw[kk];
    float l = s_lat[k * 64 + pos];
    float df = cv - l;
    psum = fmaf(df, df, psum);
    q[(n * 64 + k) * 1024 + s0 + pos] = cv;
  }
  s_r[t] = (double)psum;
  __syncthreads();
  for (int str = 128; str > 0; str >>= 1) {
    if (t < str) s_r[t] += s_r[t + str];
    __syncthreads();
  }
  if (t == 0) part[bid] = s_r[0];
}

// ---------------- loss finalize --------------------------------------------
__global__ __launch_bounds__(256) void k_loss(const double* __restrict__ part,
                                              float* __restrict__ out) {
  __shared__ double s[256];
  int t = threadIdx.x;
  double acc = 0.0;
  for (int i = t; i < 2048; i += 256) acc += part[i];
  s[t] = acc;
  __syncthreads();
  for (int str = 128; str > 0; str >>= 1) {
    if (t < str) s[t] += s[t + str];
    __syncthreads();
  }
  if (t == 0) {
    double mean = s[0] / 8388608.0;
    out[2097152] = (float)mean;          // embedding loss
    out[2097153] = (float)(0.25 * mean); // BETA * commitment
  }
}

// ---------------- dec2: fused upsample2x(ac) + 3x3 64->32 + lrelu ----------
__global__ __launch_bounds__(256) void k_dec2(
    const float* __restrict__ in, const float* __restrict__ w,
    const float* __restrict__ bias, float* __restrict__ out) {
  int bid = blockIdx.x;                  // 1024 = 128n * 8yT
  int n = bid >> 3, yT = bid & 7;
  int y0 = yT * 8;
  int t = threadIdx.x;
  int coq = t >> 6, ty = (t >> 3) & 7, xo = t & 7;   // 8co x 8row x 8xg(8)

  __shared__ float s_src[8 * 8 * 33];    // 8 ci x 8 src rows x 33
  __shared__ float s_up[8 * 10 * 68];    // 8 ci x 10 up rows x 66 (pad 68)
  __shared__ float s_w[2][72 * 32];      // [(ci*9+k)*32 + co] dbuf
  __shared__ float s_wy[10], s_my[10];
  __shared__ int   s_ry0[10], s_ry1[10];
  __shared__ float s_wx[66], s_mx[66];
  __shared__ int   s_rx0[66], s_rx1[66];

  const float sc = 31.0f / 63.0f;
  int r0 = (y0 == 0) ? 0 : (int)floorf((float)(y0 - 1) * sc);

  if (t < 10) {                           // row tables
    int uy = y0 - 1 + t;
    int uyc = min(max(uy, 0), 63);
    float sy = (float)uyc * sc;
    int iy0 = (int)floorf(sy);
    s_wy[t] = sy - (float)iy0;
    s_my[t] = ((unsigned)uy < 64u) ? 1.f : 0.f;
    s_ry0[t] = iy0 - r0;
    s_ry1[t] = min(iy0 + 1, 31) - r0;
  }
  int xc = t - 64;                        // col tables on lanes 64..129
  if (xc >= 0 && xc < 66) {
    int ux = xc - 1;
    int uxc = min(max(ux, 0), 63);
    float sx = (float)uxc * sc;
    int ix0 = (int)floorf(sx);
    s_wx[xc] = sx - (float)ix0;
    s_mx[xc] = ((unsigned)ux < 64u) ? 1.f : 0.f;
    s_rx0[xc] = ix0;
    s_rx1[xc] = min(ix0 + 1, 31);
  }

  float acc[8][8];
#pragma unroll
  for (int c = 0; c < 8; ++c)
#pragma unroll
    for (int xx = 0; xx < 8; ++xx) acc[c][xx] = 0.f;

  // prologue stage g=0
  for (int i = t; i < 2048; i += 256) {               // 8ci x 8r x 32c
    int ci = i >> 8, rem = i & 255;
    int rr = rem >> 5, cx = rem & 31;
    int row = r0 + rr;
    s_src[(ci * 8 + rr) * 33 + cx] =
        (row < 32) ? in[((n * 64 + ci) * 32 + row) * 32 + cx] : 0.f;
  }
  for (int i = t; i < 2304; i += 256) {               // co-fast weights
    int co = i & 31, j = i >> 5;
    int ci = j / 9, k = j - ci * 9;
    s_w[0][j * 32 + co] = w[(co * 64 + ci) * 9 + k];
  }
  __syncthreads();

  for (int g = 0; g < 8; ++g) {
    // ---- interp: build s_up from s_src using tables ----
    for (int i = t; i < 5280; i += 256) {             // 8ci x 10 x 66
      int ci = i / 660, rem = i - ci * 660;
      int uu = rem / 66, cc = rem - uu * 66;
      const float* sp = &s_src[ci * 264];
      int ry0 = s_ry0[uu], ry1 = s_ry1[uu];
      int rx0 = s_rx0[cc], rx1 = s_rx1[cc];
      float wy = s_wy[uu], wx = s_wx[cc];
      float m = s_my[uu] * s_mx[cc];
      float a00 = sp[ry0 * 33 + rx0], a01 = sp[ry0 * 33 + rx1];
      float a10 = sp[ry1 * 33 + rx0], a11 = sp[ry1 * 33 + rx1];
      float h0 = fmaf(a10 - a00, wy, a00);
      float h1 = fmaf(a11 - a01, wy, a01);
      s_up[(ci * 10 + uu) * 68 + cc] = m * fmaf(h1 - h0, wx, h0);
    }
    __syncthreads();

    // ---- stage next group (overlaps with conv below) ----
    if (g < 7) {
      int ci0 = (g + 1) * 8;
      for (int i = t; i < 2048; i += 256) {
        int ci = i >> 8, rem = i & 255;
        int rr = rem >> 5, cx = rem & 31;
        int row = r0 + rr;
        s_src[(ci * 8 + rr) * 33 + cx] =
            (row < 32) ? in[((n * 64 + ci0 + ci) * 32 + row) * 32 + cx] : 0.f;
      }
      float* wb = s_w[(g + 1) & 1];
      for (int i = t; i < 2304; i += 256) {
        int co = i & 31, j = i >> 5;
        int ci = j / 9, k = j - ci * 9;
        wb[j * 32 + co] = w[(co * 64 + ci0 + ci) * 9 + k];
      }
    }

    // ---- conv from s_up ----
    const float* wb = s_w[g & 1];
    for (int ci = 0; ci < 8; ++ci) {
#pragma unroll
      for (int ky = 0; ky < 3; ++ky) {
        int base = (ci * 10 + ty + ky) * 68 + xo * 8;
        float4 q0 = *reinterpret_cast<const float4*>(&s_up[base]);
        float4 q1 = *reinterpret_cast<const float4*>(&s_up[base + 4]);
        float4 q2 = *reinterpret_cast<const float4*>(&s_up[base + 8]);
        float rv[12] = {q0.x, q0.y, q0.z, q0.w, q1.x, q1.y, q1.z, q1.w,
                        q2.x, q2.y, q2.z, q2.w};
#pragma unroll
        for (int kx = 0; kx < 3; ++kx) {
          int wbase = (ci * 9 + ky * 3 + kx) * 32 + coq * 8;
          float4 wa = *reinterpret_cast<const float4*>(&wb[wbase]);
          float4 wbq = *reinterpret_cast<const float4*>(&wb[wbase + 4]);
          float wv[8] = {wa.x, wa.y, wa.z, wa.w, wbq.x, wbq.y, wbq.z, wbq.w};
#pragma unroll
          for (int c = 0; c < 8; ++c)
#pragma unroll
            for (int xx = 0; xx < 8; ++xx)
              acc[c][xx] = fmaf(rv[xx + kx], wv[c], acc[c][xx]);
        }
      }
    }
    __syncthreads();
  }

#pragma unroll
  for (int c = 0; c < 8; ++c) {
    int co = coq * 8 + c;
    float bv = bias[co];
    int base = ((n * 32 + co) * 64 + y0 + ty) * 64 + xo * 8;
    float o[8];
#pragma unroll
    for (int xx = 0; xx < 8; ++xx) o[xx] = actf<1>(acc[c][xx] + bv);
    *reinterpret_cast<float4*>(&out[base]) = make_float4(o[0], o[1], o[2], o[3]);
    *reinterpret_cast<float4*>(&out[base + 4]) = make_float4(o[4], o[5], o[6], o[7]);
  }
}

// ---------------- dec3: fused upsample2x(ac) + 3x3 32->1 + relu ------------
// ci-groups of 4 (LDS ~28 KB -> 5 blocks/CU), b128 rv reads (stride 68).
__global__ __launch_bounds__(256) void k_dec3(
    const float* __restrict__ in, const float* __restrict__ w,
    const float* __restrict__ bias, float* __restrict__ out) {
  int bid = blockIdx.x;                  // 2048 = 128n * 8yT * 2xT
  int n = bid >> 4, yT = (bid >> 1) & 7, xT = bid & 1;
  int y0 = yT * 16, x0 = xT * 64;
  int t = threadIdx.x;
  int ty = t >> 4, xq = t & 15;          // 16 rows x 16 colgroups of 4

  __shared__ float s_up[4 * 18 * 68];
  __shared__ float s_src[4 * 11 * 35];
  __shared__ float s_w[288];
  __shared__ float s_wy[18], s_my[18];
  __shared__ int   s_ry0[18], s_ry1[18];
  __shared__ float s_wx[66], s_mx[66];
  __shared__ int   s_rx0[66], s_rx1[66];

  const float sc = 63.0f / 127.0f;
  int r0 = (y0 == 0) ? 0 : (int)floorf((float)(y0 - 1) * sc);
  int c0 = (x0 == 0) ? 0 : (int)floorf((float)(x0 - 1) * sc);

  if (t < 18) {
    int uy = y0 - 1 + t;
    int uyc = min(max(uy, 0), 127);
    float sy = (float)uyc * sc;
    int iy0 = (int)floorf(sy);
    s_wy[t] = sy - (float)iy0;
    s_my[t] = ((unsigned)uy < 128u) ? 1.f : 0.f;
    s_ry0[t] = iy0 - r0;
    s_ry1[t] = min(iy0 + 1, 63) - r0;
  }
  int xc = t - 64;
  if (xc >= 0 && xc < 66) {
    int ux = x0 - 1 + xc;
    int uxc = min(max(ux, 0), 127);
    float sx = (float)uxc * sc;
    int ix0 = (int)floorf(sx);
    s_wx[xc] = sx - (float)ix0;
    s_mx[xc] = ((unsigned)ux < 128u) ? 1.f : 0.f;
    s_rx0[xc] = ix0 - c0;
    s_rx1[xc] = min(ix0 + 1, 63) - c0;
  }
  for (int i = t; i < 288; i += 256) s_w[i] = w[i];   // [1][32][3][3]

  float acc[4] = {0.f, 0.f, 0.f, 0.f};

  // prologue stage g=0 (4 ci)
  for (int i = t; i < 4 * 11 * 35; i += 256) {
    int ci = i / 385, rem = i - ci * 385;
    int rr = rem / 35, cx = rem - rr * 35;
    int row = r0 + rr, col = c0 + cx;
    s_src[(ci * 11 + rr) * 35 + cx] =
        (row < 64 && col < 64) ? in[((n * 32 + ci) * 64 + row) * 64 + col] : 0.f;
  }
  __syncthreads();

  for (int g = 0; g < 8; ++g) {
    // ---- interp ----
    for (int i = t; i < 4 * 18 * 66; i += 256) {
      int ci = i / 1188, rem = i - ci * 1188;
      int uu = rem / 66, cc = rem - uu * 66;
      const float* sp = &s_src[ci * 385];
      int ry0 = s_ry0[uu], ry1 = s_ry1[uu];
      int rx0 = s_rx0[cc], rx1 = s_rx1[cc];
      float wy = s_wy[uu], wx = s_wx[cc];
      float m = s_my[uu] * s_mx[cc];
      float a00 = sp[ry0 * 35 + rx0], a01 = sp[ry0 * 35 + rx1];
      float a10 = sp[ry1 * 35 + rx0], a11 = sp[ry1 * 35 + rx1];
      float h0 = fmaf(a10 - a00, wy, a00);
      float h1 = fmaf(a11 - a01, wy, a01);
      s_up[(ci * 18 + uu) * 68 + cc] = m * fmaf(h1 - h0, wx, h0);
    }
    __syncthreads();

    // ---- stage next ci-group (overlaps conv) ----
    if (g < 7) {
      int ci0 = (g + 1) * 4;
      for (int i = t; i < 4 * 11 * 35; i += 256) {
        int ci = i / 385, rem = i - ci * 385;
        int rr = rem / 35, cx = rem - rr * 35;
        int row = r0 + rr, col = c0 + cx;
        s_src[(ci * 11 + rr) * 35 + cx] =
            (row < 64 && col < 64)
                ? in[((n * 32 + ci0 + ci) * 64 + row) * 64 + col] : 0.f;
      }
    }

    // ---- conv ----
    int ci0 = g * 4;
    for (int ci = 0; ci < 4; ++ci) {
#pragma unroll
      for (int ky = 0; ky < 3; ++ky) {
        int base = (ci * 18 + ty + ky) * 68 + xq * 4;
        float4 q0 = *reinterpret_cast<const float4*>(&s_up[base]);
        float4 q1 = *reinterpret_cast<const float4*>(&s_up[base + 4]);
        float rv[8] = {q0.x, q0.y, q0.z, q0.w, q1.x, q1.y, q1.z, q1.w};
#pragma unroll
        for (int kx = 0; kx < 3; ++kx) {
          float wv = s_w[(ci0 + ci) * 9 + ky * 3 + kx];
#pragma unroll
          for (int xx = 0; xx < 4; ++xx)
            acc[xx] = fmaf(rv[xx + kx], wv, acc[xx]);
        }
      }
    }
    __syncthreads();
  }
  float bv = bias[0];
  int base = n * 16384 + (y0 + ty) * 128 + x0 + xq * 4;
  *reinterpret_cast<float4*>(&out[base]) =
      make_float4(actf<2>(acc[0] + bv), actf<2>(acc[1] + bv),
                  actf<2>(acc[2] + bv), actf<2>(acc[3] + bv));
}

// ---------------------------------------------------------------------------
extern "C" void kernel_launch(void* const* d_in, const int* in_sizes, int n_in,
                              void* d_out, int out_size, void* d_ws, size_t ws_size,
                              hipStream_t stream) {
  (void)in_sizes; (void)n_in; (void)out_size; (void)ws_size;
  const float* x_in     = (const float*)d_in[0];
  const float* enc_w1   = (const float*)d_in[1];
  const float* enc_b1   = (const float*)d_in[2];
  const float* enc_w2   = (const float*)d_in[3];
  const float* enc_b2   = (const float*)d_in[4];
  const float* enc_w3   = (const float*)d_in[5];
  const float* enc_b3   = (const float*)d_in[6];
  const float* res_e_w1 = (const float*)d_in[7];
  const float* res_e_w2 = (const float*)d_in[8];
  const float* enc_w4   = (const float*)d_in[9];
  const float* enc_b4   = (const float*)d_in[10];
  const float* codebook = (const float*)d_in[11];
  const float* dec_w1   = (const float*)d_in[12];
  const float* dec_b1   = (const float*)d_in[13];
  const float* res_d_w1 = (const float*)d_in[14];
  const float* res_d_w2 = (const float*)d_in[15];
  const float* dec_w2   = (const float*)d_in[16];
  const float* dec_b2   = (const float*)d_in[17];
  const float* dec_w3   = (const float*)d_in[18];
  const float* dec_b3   = (const float*)d_in[19];
  float* out = (float*)d_out;

  char* ws = (char*)d_ws;
  float*  B0    = (float*)(ws);                         // 33.55 MB each
  float*  B1    = (float*)(ws + 33554432);
  float*  B2    = (float*)(ws + 67108864);
  float*  B3    = (float*)(ws + 100663296);
  float*  B4    = (float*)(ws + 134217728);             // 67.1 MB
  double* PART  = (double*)(ws + 201326592);            // 2048 doubles
  float*  CNORM = (float*)(ws + 201326592 + 16384);     // 512 floats
  float*  CBT   = (float*)(ws + 100663296);             // 128 KB in B3 region

  k_enc1<<<65536, 256, 0, stream>>>(x_in, enc_w1, enc_b1, B4);
  k_enc2<<<2048, 256, 0, stream>>>(B4, enc_w2, enc_b2, B0);
  k_conv3<1, true ><<<1024, 256, 0, stream>>>(B0, enc_w3, enc_b3, B1);
  k_conv3<2, false><<<1024, 256, 0, stream>>>(B1, res_e_w1, nullptr, B2);
  k_1x1<1, false, true ><<<512, 256, 0, stream>>>(B2, res_e_w2, nullptr, B1, B0);
  k_1x1<1, true,  false><<<512, 256, 0, stream>>>(B0, enc_w4, enc_b4, nullptr, B1);
  k_cbprep<<<128, 256, 0, stream>>>(codebook, CBT);
  k_cbnorm<<<2, 256, 0, stream>>>(codebook, CNORM);
  k_vq2<<<2048, 256, 0, stream>>>(B1, CBT, codebook, CNORM, B2, PART);
  k_conv3<1, true ><<<1024, 256, 0, stream>>>(B2, dec_w1, dec_b1, B0);
  k_conv3<2, false><<<1024, 256, 0, stream>>>(B0, res_d_w1, nullptr, B3);
  k_1x1<1, false, true ><<<512, 256, 0, stream>>>(B3, res_d_w2, nullptr, B0, B1);
  k_dec2<<<1024, 256, 0, stream>>>(B1, dec_w2, dec_b2, B4);
  k_dec3<<<2048, 256, 0, stream>>>(B4, dec_w3, dec_b3, out);
  k_loss<<<1, 256, 0, stream>>>(PART, out);
}

// Round 5
// 1385.522 us; speedup vs baseline: 3.0498x; 1.3764x over previous
//
#include <hip/hip_runtime.h>

// ---------------------------------------------------------------------------
// VQ-VAE forward.  N=128.  f32 everywhere except the four 3x3 64->64 convs,
// which run on MFMA via split-bf16 (hi/lo) 3-term products:
//   x*y ~= xh*yh + xh*yl + xl*yh   (each exact-ish in f32 MFMA accum)
// ---------------------------------------------------------------------------

template<int ACT> __device__ __forceinline__ float actf(float x){
  if (ACT == 1) return x > 0.f ? x : 0.01f * x;   // leaky relu, slope .01
  if (ACT == 2) return fmaxf(x, 0.f);             // relu
  return x;
}

typedef __bf16 bf16x8 __attribute__((ext_vector_type(8)));
typedef float f32x16 __attribute__((ext_vector_type(16)));
typedef unsigned int u32x4v __attribute__((ext_vector_type(4)));

__device__ __forceinline__ unsigned f2bf(unsigned u){   // RTNE f32->bf16 bits
  return (u + 0x7fffu + ((u >> 16) & 1u)) >> 16;
}

// ---------------- weight prep: f32 [64co][64ci][3][3] -> hi/lo bf16 --------
// dst linear idx = (((g*9+tap)*2+cot)*32+co)*16+ci16   (fragment-ready)
__global__ __launch_bounds__(256) void k_wprep(
    const float* __restrict__ w, unsigned short* __restrict__ wh,
    unsigned short* __restrict__ wl) {
  int i = blockIdx.x * 256 + threadIdx.x;           // 36864 = 4g*9tap*2*32*16
  if (i >= 36864) return;
  int ci16 = i & 15, co = (i >> 4) & 31, cot = (i >> 9) & 1;
  int rest = i >> 10, tap = rest % 9, g = rest / 9;
  float v = w[(cot * 32 + co) * 576 + (g * 16 + ci16) * 9 + tap];
  unsigned hi = f2bf(__float_as_uint(v));
  float lf = v - __uint_as_float(hi << 16);
  unsigned lo = f2bf(__float_as_uint(lf));
  wh[i] = (unsigned short)hi;
  wl[i] = (unsigned short)lo;
}

// ---------------- 3x3 64->64 stride1 pad1 @32x32 via MFMA ------------------
// block: (n, 8-row strip), all 64 co.  4 waves: cot = w&1 (32 co),
// rgroup = w>>1 (4 rows).  K-loop: 4 ci-groups of 16 x 9 taps x 3 splits.
template<int ACT, bool BIAS>
__global__ __launch_bounds__(256, 2) void k_conv3m(
    const float* __restrict__ in, const unsigned short* __restrict__ wh,
    const unsigned short* __restrict__ wl, const float* __restrict__ bias,
    float* __restrict__ out) {
  int n = blockIdx.x >> 2, y0 = (blockIdx.x & 3) * 8;
  int t = threadIdx.x;
  int lane = t & 63, wv = t >> 6;
  int cot = wv & 1, rgroup = wv >> 1;
  int cc = lane & 31, h = lane >> 5;

  __shared__ __align__(16) unsigned int s_x[6800];   // [10 r][34 c][pad 20 ci]

  const uint4* wh4 = reinterpret_cast<const uint4*>(wh);
  const uint4* wl4 = reinterpret_cast<const uint4*>(wl);

  f32x16 acc[4];
#pragma unroll
  for (int r = 0; r < 4; ++r)
#pragma unroll
    for (int j = 0; j < 16; ++j) acc[r][j] = 0.f;

  for (int g = 0; g < 4; ++g) {
    if (g) __syncthreads();
    // stage: 16 ci x 10 rows x 34 cols, f32 -> packed (hi | lo<<16)
    for (int i = t; i < 5440; i += 256) {
      int c = i % 34; int rem = i / 34; int r = rem % 10; int ci = rem / 10;
      int row = y0 - 1 + r, col = c - 1;
      float v = 0.f;
      if ((unsigned)row < 32u && (unsigned)col < 32u)
        v = in[(n * 64 + g * 16 + ci) * 1024 + row * 32 + col];
      unsigned hi = f2bf(__float_as_uint(v));
      float lf = v - __uint_as_float(hi << 16);
      unsigned lo = f2bf(__float_as_uint(lf));
      s_x[(r * 34 + c) * 20 + ci] = hi | (lo << 16);
    }
    __syncthreads();

#pragma unroll
    for (int kx = 0; kx < 3; ++kx) {
      bf16x8 Ah[3], Al[3];
#pragma unroll
      for (int ky = 0; ky < 3; ++ky) {
        int wi = ((g * 9 + ky * 3 + kx) * 2 + cot) * 64 + cc * 2 + h;
        Ah[ky] = __builtin_bit_cast(bf16x8, wh4[wi]);
        Al[ky] = __builtin_bit_cast(bf16x8, wl4[wi]);
      }
#pragma unroll
      for (int ir6 = 0; ir6 < 6; ++ir6) {
        int ir = rgroup * 4 + ir6;
        const uint4* xp = reinterpret_cast<const uint4*>(
            &s_x[(ir * 34 + cc + kx) * 20 + (h << 3)]);
        uint4 qa = xp[0], qb = xp[1];
        u32x4v bh, bl;
        bh[0] = (qa.x & 0xffffu) | (qa.y << 16);
        bh[1] = (qa.z & 0xffffu) | (qa.w << 16);
        bh[2] = (qb.x & 0xffffu) | (qb.y << 16);
        bh[3] = (qb.z & 0xffffu) | (qb.w << 16);
        bl[0] = (qa.x >> 16) | (qa.y & 0xffff0000u);
        bl[1] = (qa.z >> 16) | (qa.w & 0xffff0000u);
        bl[2] = (qb.x >> 16) | (qb.y & 0xffff0000u);
        bl[3] = (qb.z >> 16) | (qb.w & 0xffff0000u);
        bf16x8 Bh = __builtin_bit_cast(bf16x8, bh);
        bf16x8 Bl = __builtin_bit_cast(bf16x8, bl);
#pragma unroll
        for (int ky = 0; ky < 3; ++ky) {
          int rr = ir6 - ky;
          if (rr < 0 || rr > 3) continue;            // folds at compile time
          acc[rr] = __builtin_amdgcn_mfma_f32_32x32x16_bf16(Ah[ky], Bh, acc[rr], 0, 0, 0);
          acc[rr] = __builtin_amdgcn_mfma_f32_32x32x16_bf16(Ah[ky], Bl, acc[rr], 0, 0, 0);
          acc[rr] = __builtin_amdgcn_mfma_f32_32x32x16_bf16(Al[ky], Bh, acc[rr], 0, 0, 0);
        }
      }
    }
  }

  // epilogue: C/D layout col=lane&31, row=(reg&3)+8*(reg>>2)+4*(lane>>5)
  float bvv[16];
#pragma unroll
  for (int reg = 0; reg < 16; ++reg) {
    int row = (reg & 3) + 8 * (reg >> 2) + 4 * h;
    bvv[reg] = BIAS ? bias[cot * 32 + row] : 0.f;
  }
#pragma unroll
  for (int rr = 0; rr < 4; ++rr) {
    int y = y0 + rgroup * 4 + rr;
#pragma unroll
    for (int reg = 0; reg < 16; ++reg) {
      int row = (reg & 3) + 8 * (reg >> 2) + 4 * h;
      int co = cot * 32 + row;
      float v = acc[rr][reg] + bvv[reg];
      out[(n * 64 + co) * 1024 + y * 32 + cc] = actf<ACT>(v);
    }
  }
}

// ---------------- enc1: 1->32, 4x4 stride2 pad1, 128->64, lrelu ------------
__global__ __launch_bounds__(256) void k_enc1(
    const float* __restrict__ in, const float* __restrict__ w,
    const float* __restrict__ b, float* __restrict__ out) {
  int idx = blockIdx.x * 256 + threadIdx.x;        // [128,32,64,64]
  int ox = idx & 63, oy = (idx >> 6) & 63, co = (idx >> 12) & 31, n = idx >> 17;
  const float* ip = in + n * 16384;
  const float* wp = w + co * 16;
  float acc = b[co];
  int iy0 = 2 * oy - 1, ix0 = 2 * ox - 1;
#pragma unroll
  for (int ky = 0; ky < 4; ++ky) {
    int iy = iy0 + ky;
    if ((unsigned)iy >= 128u) continue;
#pragma unroll
    for (int kx = 0; kx < 4; ++kx) {
      int ix = ix0 + kx;
      if ((unsigned)ix >= 128u) continue;
      acc = fmaf(ip[iy * 128 + ix], wp[ky * 4 + kx], acc);
    }
  }
  out[idx] = actf<1>(acc);
}

// ---------------- enc2: 32->64, 4x4 s2 p1, 64->32, lrelu -------------------
__global__ __launch_bounds__(256) void k_enc2(
    const float* __restrict__ in, const float* __restrict__ w,
    const float* __restrict__ b, float* __restrict__ out) {
  int bid = blockIdx.x;                 // 2048 = 128n * 4coG * 4yT
  int n = bid >> 4, coG = (bid >> 2) & 3, yT = bid & 3;
  int co0 = coG * 16, y0 = yT * 8;
  int t = threadIdx.x;
  int coq = t >> 6, ty = (t >> 3) & 7, xq = t & 7;   // 4co x 8row x 8xg(4)

  __shared__ float s_in[2][4 * 18 * 68];
  __shared__ float s_w[2][4 * 16 * 16];   // [(ci*16+k)*16 + co]

  float acc[4][4];
#pragma unroll
  for (int c = 0; c < 4; ++c)
#pragma unroll
    for (int xx = 0; xx < 4; ++xx) acc[c][xx] = 0.f;

  {
    for (int i = t; i < 4 * 18 * 66; i += 256) {
      int ci = i / 1188, rem = i - ci * 1188;
      int r = rem / 66, c = rem - r * 66;
      int iy = 2 * y0 - 1 + r, ix = c - 1;
      float v = 0.f;
      if ((unsigned)iy < 64u && (unsigned)ix < 64u)
        v = in[((n * 32 + ci) * 64 + iy) * 64 + ix];
      s_in[0][(ci * 18 + r) * 68 + c] = v;
    }
    for (int i = t; i < 1024; i += 256) {
      int co = i & 15, j = i >> 4;
      int ci = j >> 4, k = j & 15;
      s_w[0][j * 16 + co] = w[((co0 + co) * 32 + ci) * 16 + k];
    }
  }
  __syncthreads();

  for (int g = 0; g < 8; ++g) {
    int buf = g & 1;
    if (g < 7) {
      int ci0 = (g + 1) * 4, nb = buf ^ 1;
      for (int i = t; i < 4 * 18 * 66; i += 256) {
        int ci = i / 1188, rem = i - ci * 1188;
        int r = rem / 66, c = rem - r * 66;
        int iy = 2 * y0 - 1 + r, ix = c - 1;
        float v = 0.f;
        if ((unsigned)iy < 64u && (unsigned)ix < 64u)
          v = in[((n * 32 + ci0 + ci) * 64 + iy) * 64 + ix];
        s_in[nb][(ci * 18 + r) * 68 + c] = v;
      }
      for (int i = t; i < 1024; i += 256) {
        int co = i & 15, j = i >> 4;
        int ci = j >> 4, k = j & 15;
        s_w[nb][j * 16 + co] = w[((co0 + co) * 32 + ci0 + ci) * 16 + k];
      }
    }
    for (int ci = 0; ci < 4; ++ci) {
#pragma unroll
      for (int ky = 0; ky < 4; ++ky) {
        int base = (ci * 18 + 2 * ty + ky) * 68 + xq * 8;
        float4 q0 = *reinterpret_cast<const float4*>(&s_in[buf][base]);
        float4 q1 = *reinterpret_cast<const float4*>(&s_in[buf][base + 4]);
        float4 q2 = *reinterpret_cast<const float4*>(&s_in[buf][base + 8]);
        float rv[12] = {q0.x, q0.y, q0.z, q0.w, q1.x, q1.y, q1.z, q1.w,
                        q2.x, q2.y, q2.z, q2.w};
#pragma unroll
        for (int kx = 0; kx < 4; ++kx) {
          float4 wq = *reinterpret_cast<const float4*>(
              &s_w[buf][(ci * 16 + ky * 4 + kx) * 16 + coq * 4]);
          float wvv[4] = {wq.x, wq.y, wq.z, wq.w};
#pragma unroll
          for (int c = 0; c < 4; ++c)
#pragma unroll
            for (int xx = 0; xx < 4; ++xx)
              acc[c][xx] = fmaf(rv[2 * xx + kx], wvv[c], acc[c][xx]);
        }
      }
    }
    __syncthreads();
  }
#pragma unroll
  for (int c = 0; c < 4; ++c) {
    int co = co0 + coq * 4 + c;
    float bv = b[co];
    int base = ((n * 64 + co) * 32 + y0 + ty) * 32 + xq * 4;
    float4 v = make_float4(actf<1>(acc[c][0] + bv), actf<1>(acc[c][1] + bv),
                           actf<1>(acc[c][2] + bv), actf<1>(acc[c][3] + bv));
    *reinterpret_cast<float4*>(&out[base]) = v;
  }
}

// ---------------- 1x1 64->64 (channel matmul), opt bias / add --------------
template<int ACT, bool BIAS, bool ADD>
__global__ __launch_bounds__(256) void k_1x1(
    const float* __restrict__ in, const float* __restrict__ w,
    const float* __restrict__ bias, const float* __restrict__ add,
    float* __restrict__ out) {
  int bid = blockIdx.x;                  // 512 = 128n * 4sT
  int n = bid >> 2;
  int s = ((bid & 3) << 8) + threadIdx.x;
  __shared__ float s_w[4096];
  for (int i = threadIdx.x; i < 4096; i += 256) s_w[i] = w[i];
  __syncthreads();
  float x[64];
#pragma unroll
  for (int ci = 0; ci < 64; ++ci) x[ci] = in[(n * 64 + ci) * 1024 + s];
  for (int co = 0; co < 64; ++co) {
    float acc = BIAS ? bias[co] : 0.f;
    const float* wr = &s_w[co * 64];
#pragma unroll
    for (int ci = 0; ci < 64; ++ci) acc = fmaf(wr[ci], x[ci], acc);
    if (ADD) acc += add[(n * 64 + co) * 1024 + s];
    out[(n * 64 + co) * 1024 + s] = actf<ACT>(acc);
  }
}

// ---------------- codebook prep: norms + k-major transpose -----------------
__global__ __launch_bounds__(256) void k_cbnorm(const float* __restrict__ cb,
                                                float* __restrict__ nrm) {
  int c = blockIdx.x * 256 + threadIdx.x;
  if (c < 512) {
    float s = 0.f;
    for (int k = 0; k < 64; ++k) { float v = cb[c * 64 + k]; s = fmaf(v, v, s); }
    nrm[c] = s;
  }
}

__global__ __launch_bounds__(256) void k_cbprep(const float* __restrict__ cb,
                                                float* __restrict__ cbT) {
  int i = blockIdx.x * 256 + threadIdx.x;   // 32768 = 512 codes x 64 dims
  int c = i >> 6, k = i & 63;
  cbT[k * 512 + c] = cb[i];
}

// ---------------- VQ: register-tiled distance GEMM + argmin ----------------
__global__ __launch_bounds__(256) void k_vq2(
    const float* __restrict__ lat, const float* __restrict__ cbT,
    const float* __restrict__ cb, const float* __restrict__ nrm,
    float* __restrict__ q, double* __restrict__ part) {
  int bid = blockIdx.x;                  // 2048 = 128 n x 16 s-tiles
  int n = bid >> 4, s0 = (bid & 15) << 6;
  int t = threadIdx.x;

  __shared__ float s_lat[64 * 64];
  __shared__ float s_cb[64 * 128];
  __shared__ float s_nrm[512];
  __shared__ int   s_sel[64];
  __shared__ double s_r[256];

  for (int i = t; i < 4096; i += 256) {
    int k = i >> 6, p = i & 63;
    s_lat[k * 64 + p] = lat[(n * 64 + k) * 1024 + s0 + p];
  }
  for (int i = t; i < 512; i += 256) s_nrm[i] = nrm[i];

  int cl = t & 15, pg = t >> 4;
  int p0 = pg * 4;
  float best[4] = {3.4e38f, 3.4e38f, 3.4e38f, 3.4e38f};
  int bidx[4] = {0, 0, 0, 0};

  for (int g = 0; g < 4; ++g) {
    __syncthreads();
    for (int i = t; i < 2048; i += 256) {
      int k = i >> 5, ccc = (i & 31) << 2;
      *reinterpret_cast<float4*>(&s_cb[k * 128 + ccc]) =
          *reinterpret_cast<const float4*>(&cbT[k * 512 + g * 128 + ccc]);
    }
    __syncthreads();

    float acc[4][8];
#pragma unroll
    for (int p = 0; p < 4; ++p)
#pragma unroll
      for (int c = 0; c < 8; ++c) acc[p][c] = 0.f;

#pragma unroll 4
    for (int k = 0; k < 64; ++k) {
      float4 lv = *reinterpret_cast<const float4*>(&s_lat[k * 64 + p0]);
      float4 ca = *reinterpret_cast<const float4*>(&s_cb[k * 128 + (cl << 2)]);
      float4 cbq = *reinterpret_cast<const float4*>(&s_cb[k * 128 + 64 + (cl << 2)]);
      float l[4] = {lv.x, lv.y, lv.z, lv.w};
      float cv[8] = {ca.x, ca.y, ca.z, ca.w, cbq.x, cbq.y, cbq.z, cbq.w};
#pragma unroll
      for (int p = 0; p < 4; ++p)
#pragma unroll
        for (int c = 0; c < 8; ++c)
          acc[p][c] = fmaf(l[p], cv[c], acc[p][c]);
    }

#pragma unroll
    for (int half = 0; half < 2; ++half)
#pragma unroll
      for (int j = 0; j < 4; ++j) {
        int c = half * 4 + j;
        int code = g * 128 + half * 64 + (cl << 2) + j;
        float nv = s_nrm[code];
#pragma unroll
        for (int p = 0; p < 4; ++p) {
          float d = fmaf(-2.f, acc[p][c], nv);
          if (d < best[p]) { best[p] = d; bidx[p] = code; }
        }
      }
  }

  __syncthreads();
  float* s_rd = s_cb;
  int*   s_ri = (int*)(s_cb + 1024);
#pragma unroll
  for (int p = 0; p < 4; ++p) {
    s_rd[(p0 + p) * 16 + cl] = best[p];
    s_ri[(p0 + p) * 16 + cl] = bidx[p];
  }
  __syncthreads();
  if (t < 64) {
    float bd = s_rd[t * 16]; int bi = s_ri[t * 16];
#pragma unroll
    for (int m = 1; m < 16; ++m) {
      float d = s_rd[t * 16 + m]; int ii = s_ri[t * 16 + m];
      if (d < bd || (d == bd && ii < bi)) { bd = d; bi = ii; }
    }
    s_sel[t] = bi;
  }
  __syncthreads();

  int pos = t & 63, dg = t >> 6;
  int bsel = s_sel[pos];
  const float* cw = cb + bsel * 64 + dg * 16;
  float psum = 0.f;
#pragma unroll
  for (int kk = 0; kk < 16; ++kk) {
    int k = dg * 16 + kk;
    float cv = cw[kk];
    float l = s_lat[k * 64 + pos];
    float df = cv - l;
    psum = fmaf(df, df, psum);
    q[(n * 64 + k) * 1024 + s0 + pos] = cv;
  }
  s_r[t] = (double)psum;
  __syncthreads();
  for (int str = 128; str > 0; str >>= 1) {
    if (t < str) s_r[t] += s_r[t + str];
    __syncthreads();
  }
  if (t == 0) part[bid] = s_r[0];
}

// ---------------- loss finalize --------------------------------------------
__global__ __launch_bounds__(256) void k_loss(const double* __restrict__ part,
                                              float* __restrict__ out) {
  __shared__ double s[256];
  int t = threadIdx.x;
  double acc = 0.0;
  for (int i = t; i < 2048; i += 256) acc += part[i];
  s[t] = acc;
  __syncthreads();
  for (int str = 128; str > 0; str >>= 1) {
    if (t < str) s[t] += s[t + str];
    __syncthreads();
  }
  if (t == 0) {
    double mean = s[0] / 8388608.0;
    out[2097152] = (float)mean;
    out[2097153] = (float)(0.25 * mean);
  }
}

// ---------------- dec2: fused upsample2x(ac) + 3x3 64->32 + lrelu ----------
__global__ __launch_bounds__(256) void k_dec2(
    const float* __restrict__ in, const float* __restrict__ w,
    const float* __restrict__ bias, float* __restrict__ out) {
  int bid = blockIdx.x;                  // 1024 = 128n * 8yT
  int n = bid >> 3, yT = bid & 7;
  int y0 = yT * 8;
  int t = threadIdx.x;
  int coq = t >> 6, ty = (t >> 3) & 7, xo = t & 7;

  __shared__ float s_src[8 * 8 * 33];
  __shared__ float s_up[8 * 10 * 68];
  __shared__ float s_w[2][72 * 32];
  __shared__ float s_wy[10], s_my[10];
  __shared__ int   s_ry0[10], s_ry1[10];
  __shared__ float s_wx[66], s_mx[66];
  __shared__ int   s_rx0[66], s_rx1[66];

  const float sc = 31.0f / 63.0f;
  int r0 = (y0 == 0) ? 0 : (int)floorf((float)(y0 - 1) * sc);

  if (t < 10) {
    int uy = y0 - 1 + t;
    int uyc = min(max(uy, 0), 63);
    float sy = (float)uyc * sc;
    int iy0 = (int)floorf(sy);
    s_wy[t] = sy - (float)iy0;
    s_my[t] = ((unsigned)uy < 64u) ? 1.f : 0.f;
    s_ry0[t] = iy0 - r0;
    s_ry1[t] = min(iy0 + 1, 31) - r0;
  }
  int xc = t - 64;
  if (xc >= 0 && xc < 66) {
    int ux = xc - 1;
    int uxc = min(max(ux, 0), 63);
    float sx = (float)uxc * sc;
    int ix0 = (int)floorf(sx);
    s_wx[xc] = sx - (float)ix0;
    s_mx[xc] = ((unsigned)ux < 64u) ? 1.f : 0.f;
    s_rx0[xc] = ix0;
    s_rx1[xc] = min(ix0 + 1, 31);
  }

  float acc[8][8];
#pragma unroll
  for (int c = 0; c < 8; ++c)
#pragma unroll
    for (int xx = 0; xx < 8; ++xx) acc[c][xx] = 0.f;

  for (int i = t; i < 2048; i += 256) {
    int ci = i >> 8, rem = i & 255;
    int rr = rem >> 5, cx = rem & 31;
    int row = r0 + rr;
    s_src[(ci * 8 + rr) * 33 + cx] =
        (row < 32) ? in[((n * 64 + ci) * 32 + row) * 32 + cx] : 0.f;
  }
  for (int i = t; i < 2304; i += 256) {
    int co = i & 31, j = i >> 5;
    int ci = j / 9, k = j - ci * 9;
    s_w[0][j * 32 + co] = w[(co * 64 + ci) * 9 + k];
  }
  __syncthreads();

  for (int g = 0; g < 8; ++g) {
    for (int i = t; i < 5280; i += 256) {
      int ci = i / 660, rem = i - ci * 660;
      int uu = rem / 66, ccx = rem - uu * 66;
      const float* sp = &s_src[ci * 264];
      int ry0 = s_ry0[uu], ry1 = s_ry1[uu];
      int rx0 = s_rx0[ccx], rx1 = s_rx1[ccx];
      float wy = s_wy[uu], wx = s_wx[ccx];
      float m = s_my[uu] * s_mx[ccx];
      float a00 = sp[ry0 * 33 + rx0], a01 = sp[ry0 * 33 + rx1];
      float a10 = sp[ry1 * 33 + rx0], a11 = sp[ry1 * 33 + rx1];
      float h0 = fmaf(a10 - a00, wy, a00);
      float h1 = fmaf(a11 - a01, wy, a01);
      s_up[(ci * 10 + uu) * 68 + ccx] = m * fmaf(h1 - h0, wx, h0);
    }
    __syncthreads();

    if (g < 7) {
      int ci0 = (g + 1) * 8;
      for (int i = t; i < 2048; i += 256) {
        int ci = i >> 8, rem = i & 255;
        int rr = rem >> 5, cx = rem & 31;
        int row = r0 + rr;
        s_src[(ci * 8 + rr) * 33 + cx] =
            (row < 32) ? in[((n * 64 + ci0 + ci) * 32 + row) * 32 + cx] : 0.f;
      }
      float* wb = s_w[(g + 1) & 1];
      for (int i = t; i < 2304; i += 256) {
        int co = i & 31, j = i >> 5;
        int ci = j / 9, k = j - ci * 9;
        wb[j * 32 + co] = w[(co * 64 + ci0 + ci) * 9 + k];
      }
    }

    const float* wb = s_w[g & 1];
    for (int ci = 0; ci < 8; ++ci) {
#pragma unroll
      for (int ky = 0; ky < 3; ++ky) {
        int base = (ci * 10 + ty + ky) * 68 + xo * 8;
        float4 q0 = *reinterpret_cast<const float4*>(&s_up[base]);
        float4 q1 = *reinterpret_cast<const float4*>(&s_up[base + 4]);
        float4 q2 = *reinterpret_cast<const float4*>(&s_up[base + 8]);
        float rv[12] = {q0.x, q0.y, q0.z, q0.w, q1.x, q1.y, q1.z, q1.w,
                        q2.x, q2.y, q2.z, q2.w};
#pragma unroll
        for (int kx = 0; kx < 3; ++kx) {
          int wbase = (ci * 9 + ky * 3 + kx) * 32 + coq * 8;
          float4 wa = *reinterpret_cast<const float4*>(&wb[wbase]);
          float4 wbq = *reinterpret_cast<const float4*>(&wb[wbase + 4]);
          float wvv[8] = {wa.x, wa.y, wa.z, wa.w, wbq.x, wbq.y, wbq.z, wbq.w};
#pragma unroll
          for (int c = 0; c < 8; ++c)
#pragma unroll
            for (int xx = 0; xx < 8; ++xx)
              acc[c][xx] = fmaf(rv[xx + kx], wvv[c], acc[c][xx]);
        }
      }
    }
    __syncthreads();
  }

#pragma unroll
  for (int c = 0; c < 8; ++c) {
    int co = coq * 8 + c;
    float bv = bias[co];
    int base = ((n * 32 + co) * 64 + y0 + ty) * 64 + xo * 8;
    float o[8];
#pragma unroll
    for (int xx = 0; xx < 8; ++xx) o[xx] = actf<1>(acc[c][xx] + bv);
    *reinterpret_cast<float4*>(&out[base]) = make_float4(o[0], o[1], o[2], o[3]);
    *reinterpret_cast<float4*>(&out[base + 4]) = make_float4(o[4], o[5], o[6], o[7]);
  }
}

// ---------------- dec3: fused upsample2x(ac) + 3x3 32->1 + relu ------------
__global__ __launch_bounds__(256) void k_dec3(
    const float* __restrict__ in, const float* __restrict__ w,
    const float* __restrict__ bias, float* __restrict__ out) {
  int bid = blockIdx.x;                  // 2048 = 128n * 8yT * 2xT
  int n = bid >> 4, yT = (bid >> 1) & 7, xT = bid & 1;
  int y0 = yT * 16, x0 = xT * 64;
  int t = threadIdx.x;
  int ty = t >> 4, xq = t & 15;

  __shared__ float s_up[4 * 18 * 68];
  __shared__ float s_src[4 * 11 * 35];
  __shared__ float s_w[288];
  __shared__ float s_wy[18], s_my[18];
  __shared__ int   s_ry0[18], s_ry1[18];
  __shared__ float s_wx[66], s_mx[66];
  __shared__ int   s_rx0[66], s_rx1[66];

  const float sc = 63.0f / 127.0f;
  int r0 = (y0 == 0) ? 0 : (int)floorf((float)(y0 - 1) * sc);
  int c0 = (x0 == 0) ? 0 : (int)floorf((float)(x0 - 1) * sc);

  if (t < 18) {
    int uy = y0 - 1 + t;
    int uyc = min(max(uy, 0), 127);
    float sy = (float)uyc * sc;
    int iy0 = (int)floorf(sy);
    s_wy[t] = sy - (float)iy0;
    s_my[t] = ((unsigned)uy < 128u) ? 1.f : 0.f;
    s_ry0[t] = iy0 - r0;
    s_ry1[t] = min(iy0 + 1, 63) - r0;
  }
  int xc = t - 64;
  if (xc >= 0 && xc < 66) {
    int ux = x0 - 1 + xc;
    int uxc = min(max(ux, 0), 127);
    float sx = (float)uxc * sc;
    int ix0 = (int)floorf(sx);
    s_wx[xc] = sx - (float)ix0;
    s_mx[xc] = ((unsigned)ux < 128u) ? 1.f : 0.f;
    s_rx0[xc] = ix0 - c0;
    s_rx1[xc] = min(ix0 + 1, 63) - c0;
  }
  for (int i = t; i < 288; i += 256) s_w[i] = w[i];

  float acc[4] = {0.f, 0.f, 0.f, 0.f};

  for (int i = t; i < 4 * 11 * 35; i += 256) {
    int ci = i / 385, rem = i - ci * 385;
    int rr = rem / 35, cx = rem - rr * 35;
    int row = r0 + rr, col = c0 + cx;
    s_src[(ci * 11 + rr) * 35 + cx] =
        (row < 64 && col < 64) ? in[((n * 32 + ci) * 64 + row) * 64 + col] : 0.f;
  }
  __syncthreads();

  for (int g = 0; g < 8; ++g) {
    for (int i = t; i < 4 * 18 * 66; i += 256) {
      int ci = i / 1188, rem = i - ci * 1188;
      int uu = rem / 66, ccx = rem - uu * 66;
      const float* sp = &s_src[ci * 385];
      int ry0 = s_ry0[uu], ry1 = s_ry1[uu];
      int rx0 = s_rx0[ccx], rx1 = s_rx1[ccx];
      float wy = s_wy[uu], wx = s_wx[ccx];
      float m = s_my[uu] * s_mx[ccx];
      float a00 = sp[ry0 * 35 + rx0], a01 = sp[ry0 * 35 + rx1];
      float a10 = sp[ry1 * 35 + rx0], a11 = sp[ry1 * 35 + rx1];
      float h0 = fmaf(a10 - a00, wy, a00);
      float h1 = fmaf(a11 - a01, wy, a01);
      s_up[(ci * 18 + uu) * 68 + ccx] = m * fmaf(h1 - h0, wx, h0);
    }
    __syncthreads();

    if (g < 7) {
      int ci0 = (g + 1) * 4;
      for (int i = t; i < 4 * 11 * 35; i += 256) {
        int ci = i / 385, rem = i - ci * 385;
        int rr = rem / 35, cx = rem - rr * 35;
        int row = r0 + rr, col = c0 + cx;
        s_src[(ci * 11 + rr) * 35 + cx] =
            (row < 64 && col < 64)
                ? in[((n * 32 + ci0 + ci) * 64 + row) * 64 + col] : 0.f;
      }
    }

    int ci0 = g * 4;
    for (int ci = 0; ci < 4; ++ci) {
#pragma unroll
      for (int ky = 0; ky < 3; ++ky) {
        int base = (ci * 18 + ty + ky) * 68 + xq * 4;
        float4 q0 = *reinterpret_cast<const float4*>(&s_up[base]);
        float4 q1 = *reinterpret_cast<const float4*>(&s_up[base + 4]);
        float rv[8] = {q0.x, q0.y, q0.z, q0.w, q1.x, q1.y, q1.z, q1.w};
#pragma unroll
        for (int kx = 0; kx < 3; ++kx) {
          float wv = s_w[(ci0 + ci) * 9 + ky * 3 + kx];
#pragma unroll
          for (int xx = 0; xx < 4; ++xx)
            acc[xx] = fmaf(rv[xx + kx], wv, acc[xx]);
        }
      }
    }
    __syncthreads();
  }
  float bv = bias[0];
  int base = n * 16384 + (y0 + ty) * 128 + x0 + xq * 4;
  *reinterpret_cast<float4*>(&out[base]) =
      make_float4(actf<2>(acc[0] + bv), actf<2>(acc[1] + bv),
                  actf<2>(acc[2] + bv), actf<2>(acc[3] + bv));
}

// ---------------------------------------------------------------------------
extern "C" void kernel_launch(void* const* d_in, const int* in_sizes, int n_in,
                              void* d_out, int out_size, void* d_ws, size_t ws_size,
                              hipStream_t stream) {
  (void)in_sizes; (void)n_in; (void)out_size; (void)ws_size;
  const float* x_in     = (const float*)d_in[0];
  const float* enc_w1   = (const float*)d_in[1];
  const float* enc_b1   = (const float*)d_in[2];
  const float* enc_w2   = (const float*)d_in[3];
  const float* enc_b2   = (const float*)d_in[4];
  const float* enc_w3   = (const float*)d_in[5];
  const float* enc_b3   = (const float*)d_in[6];
  const float* res_e_w1 = (const float*)d_in[7];
  const float* res_e_w2 = (const float*)d_in[8];
  const float* enc_w4   = (const float*)d_in[9];
  const float* enc_b4   = (const float*)d_in[10];
  const float* codebook = (const float*)d_in[11];
  const float* dec_w1   = (const float*)d_in[12];
  const float* dec_b1   = (const float*)d_in[13];
  const float* res_d_w1 = (const float*)d_in[14];
  const float* res_d_w2 = (const float*)d_in[15];
  const float* dec_w2   = (const float*)d_in[16];
  const float* dec_b2   = (const float*)d_in[17];
  const float* dec_w3   = (const float*)d_in[18];
  const float* dec_b3   = (const float*)d_in[19];
  float* out = (float*)d_out;

  char* ws = (char*)d_ws;
  float*  B0    = (float*)(ws);                         // 33.55 MB each
  float*  B1    = (float*)(ws + 33554432);
  float*  B2    = (float*)(ws + 67108864);
  float*  B3    = (float*)(ws + 100663296);
  float*  B4    = (float*)(ws + 134217728);             // 67.1 MB
  double* PART  = (double*)(ws + 201326592);            // 2048 doubles
  float*  CNORM = (float*)(ws + 201326592 + 16384);     // 512 floats
  float*  CBT   = (float*)(ws + 100663296);             // 128 KB in B3 region
  // split-bf16 weights for the 4 conv3 layers: 147456 B each (hi+lo)
  unsigned short* WH0 = (unsigned short*)(ws + 201359360);
  unsigned short* WL0 = WH0 + 36864;
  unsigned short* WH1 = (unsigned short*)(ws + 201359360 + 147456);
  unsigned short* WL1 = WH1 + 36864;
  unsigned short* WH2 = (unsigned short*)(ws + 201359360 + 294912);
  unsigned short* WL2 = WH2 + 36864;
  unsigned short* WH3 = (unsigned short*)(ws + 201359360 + 442368);
  unsigned short* WL3 = WH3 + 36864;

  k_wprep<<<144, 256, 0, stream>>>(enc_w3,   WH0, WL0);
  k_wprep<<<144, 256, 0, stream>>>(res_e_w1, WH1, WL1);
  k_wprep<<<144, 256, 0, stream>>>(dec_w1,   WH2, WL2);
  k_wprep<<<144, 256, 0, stream>>>(res_d_w1, WH3, WL3);

  k_enc1<<<65536, 256, 0, stream>>>(x_in, enc_w1, enc_b1, B4);
  k_enc2<<<2048, 256, 0, stream>>>(B4, enc_w2, enc_b2, B0);
  k_conv3m<1, true ><<<512, 256, 0, stream>>>(B0, WH0, WL0, enc_b3, B1);
  k_conv3m<2, false><<<512, 256, 0, stream>>>(B1, WH1, WL1, nullptr, B2);
  k_1x1<1, false, true ><<<512, 256, 0, stream>>>(B2, res_e_w2, nullptr, B1, B0);
  k_1x1<1, true,  false><<<512, 256, 0, stream>>>(B0, enc_w4, enc_b4, nullptr, B1);
  k_cbprep<<<128, 256, 0, stream>>>(codebook, CBT);
  k_cbnorm<<<2, 256, 0, stream>>>(codebook, CNORM);
  k_vq2<<<2048, 256, 0, stream>>>(B1, CBT, codebook, CNORM, B2, PART);
  k_conv3m<1, true ><<<512, 256, 0, stream>>>(B2, WH2, WL2, dec_b1, B0);
  k_conv3m<2, false><<<512, 256, 0, stream>>>(B0, WH3, WL3, nullptr, B3);
  k_1x1<1, false, true ><<<512, 256, 0, stream>>>(B3, res_d_w2, nullptr, B0, B1);
  k_dec2<<<1024, 256, 0, stream>>>(B1, dec_w2, dec_b2, B4);
  k_dec3<<<2048, 256, 0, stream>>>(B4, dec_w3, dec_b3, out);
  k_loss<<<1, 256, 0, stream>>>(PART, out);
}

// Round 7
// 1230.556 us; speedup vs baseline: 3.4339x; 1.1259x over previous
//
#include <hip/hip_runtime.h>

// ---------------------------------------------------------------------------
// VQ-VAE forward.  N=128.  MFMA (split-bf16 hi/lo, 3-term) for the four
// 3x3 64->64 convs AND dec2 (up2x + 3x3 64->32).  f32 VALU elsewhere.
//   x*y ~= xh*yh + xh*yl + xl*yh   (f32 MFMA accumulate)
// ---------------------------------------------------------------------------

template<int ACT> __device__ __forceinline__ float actf(float x){
  if (ACT == 1) return x > 0.f ? x : 0.01f * x;   // leaky relu, slope .01
  if (ACT == 2) return fmaxf(x, 0.f);             // relu
  return x;
}

typedef __bf16 bf16x8 __attribute__((ext_vector_type(8)));
typedef float f32x16 __attribute__((ext_vector_type(16)));
typedef unsigned int u32x4v __attribute__((ext_vector_type(4)));

__device__ __forceinline__ unsigned f2bf(unsigned u){   // RTNE f32->bf16 bits
  return (u + 0x7fffu + ((u >> 16) & 1u)) >> 16;
}

// ---------------- weight prep: f32 [64co][64ci][3][3] -> hi/lo bf16 --------
// dst linear idx = (((g*9+tap)*2+cot)*32+co)*16+ci16   (fragment-ready)
__global__ __launch_bounds__(256) void k_wprep(
    const float* __restrict__ w, unsigned short* __restrict__ wh,
    unsigned short* __restrict__ wl) {
  int i = blockIdx.x * 256 + threadIdx.x;           // 36864 = 4g*9tap*2*32*16
  if (i >= 36864) return;
  int ci16 = i & 15, co = (i >> 4) & 31, cot = (i >> 9) & 1;
  int rest = i >> 10, tap = rest % 9, g = rest / 9;
  float v = w[(cot * 32 + co) * 576 + (g * 16 + ci16) * 9 + tap];
  unsigned hi = f2bf(__float_as_uint(v));
  float lf = v - __uint_as_float(hi << 16);
  unsigned lo = f2bf(__float_as_uint(lf));
  wh[i] = (unsigned short)hi;
  wl[i] = (unsigned short)lo;
}

// ---------------- weight prep for dec2: f32 [32co][64ci][3][3] -------------
// dst idx = ((g*9+tap)*32+co)*16+ci16
__global__ __launch_bounds__(256) void k_wprep2(
    const float* __restrict__ w, unsigned short* __restrict__ wh,
    unsigned short* __restrict__ wl) {
  int i = blockIdx.x * 256 + threadIdx.x;           // 18432 = 4g*9tap*32*16
  if (i >= 18432) return;
  int ci16 = i & 15, co = (i >> 4) & 31;
  int rest = i >> 9, tap = rest % 9, g = rest / 9;
  float v = w[co * 576 + (g * 16 + ci16) * 9 + tap];
  unsigned hi = f2bf(__float_as_uint(v));
  float lf = v - __uint_as_float(hi << 16);
  unsigned lo = f2bf(__float_as_uint(lf));
  wh[i] = (unsigned short)hi;
  wl[i] = (unsigned short)lo;
}

// ---------------- 3x3 64->64 stride1 pad1 @32x32 via MFMA ------------------
template<int ACT, bool BIAS>
__global__ __launch_bounds__(256, 2) void k_conv3m(
    const float* __restrict__ in, const unsigned short* __restrict__ wh,
    const unsigned short* __restrict__ wl, const float* __restrict__ bias,
    float* __restrict__ out) {
  int n = blockIdx.x >> 2, y0 = (blockIdx.x & 3) * 8;
  int t = threadIdx.x;
  int lane = t & 63, wv = t >> 6;
  int cot = wv & 1, rgroup = wv >> 1;
  int cc = lane & 31, h = lane >> 5;

  __shared__ __align__(16) unsigned int s_x[6800];   // [10 r][34 c][pad 20 ci]

  const uint4* wh4 = reinterpret_cast<const uint4*>(wh);
  const uint4* wl4 = reinterpret_cast<const uint4*>(wl);

  f32x16 acc[4];
#pragma unroll
  for (int r = 0; r < 4; ++r)
#pragma unroll
    for (int j = 0; j < 16; ++j) acc[r][j] = 0.f;

  for (int g = 0; g < 4; ++g) {
    if (g) __syncthreads();
    for (int i = t; i < 5440; i += 256) {
      int c = i % 34; int rem = i / 34; int r = rem % 10; int ci = rem / 10;
      int row = y0 - 1 + r, col = c - 1;
      float v = 0.f;
      if ((unsigned)row < 32u && (unsigned)col < 32u)
        v = in[(n * 64 + g * 16 + ci) * 1024 + row * 32 + col];
      unsigned hi = f2bf(__float_as_uint(v));
      float lf = v - __uint_as_float(hi << 16);
      unsigned lo = f2bf(__float_as_uint(lf));
      s_x[(r * 34 + c) * 20 + ci] = hi | (lo << 16);
    }
    __syncthreads();

#pragma unroll
    for (int kx = 0; kx < 3; ++kx) {
      bf16x8 Ah[3], Al[3];
#pragma unroll
      for (int ky = 0; ky < 3; ++ky) {
        int wi = ((g * 9 + ky * 3 + kx) * 2 + cot) * 64 + cc * 2 + h;
        Ah[ky] = __builtin_bit_cast(bf16x8, wh4[wi]);
        Al[ky] = __builtin_bit_cast(bf16x8, wl4[wi]);
      }
#pragma unroll
      for (int ir6 = 0; ir6 < 6; ++ir6) {
        int ir = rgroup * 4 + ir6;
        const uint4* xp = reinterpret_cast<const uint4*>(
            &s_x[(ir * 34 + cc + kx) * 20 + (h << 3)]);
        uint4 qa = xp[0], qb = xp[1];
        u32x4v bh, bl;
        bh[0] = (qa.x & 0xffffu) | (qa.y << 16);
        bh[1] = (qa.z & 0xffffu) | (qa.w << 16);
        bh[2] = (qb.x & 0xffffu) | (qb.y << 16);
        bh[3] = (qb.z & 0xffffu) | (qb.w << 16);
        bl[0] = (qa.x >> 16) | (qa.y & 0xffff0000u);
        bl[1] = (qa.z >> 16) | (qa.w & 0xffff0000u);
        bl[2] = (qb.x >> 16) | (qb.y & 0xffff0000u);
        bl[3] = (qb.z >> 16) | (qb.w & 0xffff0000u);
        bf16x8 Bh = __builtin_bit_cast(bf16x8, bh);
        bf16x8 Bl = __builtin_bit_cast(bf16x8, bl);
#pragma unroll
        for (int ky = 0; ky < 3; ++ky) {
          int rr = ir6 - ky;
          if (rr < 0 || rr > 3) continue;
          acc[rr] = __builtin_amdgcn_mfma_f32_32x32x16_bf16(Ah[ky], Bh, acc[rr], 0, 0, 0);
          acc[rr] = __builtin_amdgcn_mfma_f32_32x32x16_bf16(Ah[ky], Bl, acc[rr], 0, 0, 0);
          acc[rr] = __builtin_amdgcn_mfma_f32_32x32x16_bf16(Al[ky], Bh, acc[rr], 0, 0, 0);
        }
      }
    }
  }

  float bvv[16];
#pragma unroll
  for (int reg = 0; reg < 16; ++reg) {
    int row = (reg & 3) + 8 * (reg >> 2) + 4 * h;
    bvv[reg] = BIAS ? bias[cot * 32 + row] : 0.f;
  }
#pragma unroll
  for (int rr = 0; rr < 4; ++rr) {
    int y = y0 + rgroup * 4 + rr;
#pragma unroll
    for (int reg = 0; reg < 16; ++reg) {
      int row = (reg & 3) + 8 * (reg >> 2) + 4 * h;
      int co = cot * 32 + row;
      float v = acc[rr][reg] + bvv[reg];
      out[(n * 64 + co) * 1024 + y * 32 + cc] = actf<ACT>(v);
    }
  }
}

// ---------------- dec2: up2x(ac) + 3x3 64->32 + lrelu, via MFMA ------------
// block: (n, 8-row out strip of 64x64).  4 waves: xh = w&1 (32-col half),
// rg = w>>1 (4 rows).  interp -> packed hi/lo LDS -> 32x32x16 MFMA.
__global__ __launch_bounds__(256, 2) void k_dec2m(
    const float* __restrict__ in, const unsigned short* __restrict__ wh,
    const unsigned short* __restrict__ wl, const float* __restrict__ bias,
    float* __restrict__ out) {
  int n = blockIdx.x >> 3, y0 = (blockIdx.x & 7) * 8;
  int t = threadIdx.x;
  int lane = t & 63, wv = t >> 6;
  int xh = wv & 1, rg = wv >> 1;
  int cc = lane & 31, h = lane >> 5;

  __shared__ __align__(16) unsigned int s_x[10 * 66 * 20];  // packed up-tile
  __shared__ float s_src[16 * 8 * 33];                      // [ci][r][c]
  __shared__ float s_wy[10], s_my[10];
  __shared__ int   s_ry0[10], s_ry1[10];
  __shared__ float s_wx[66], s_mx[66];
  __shared__ int   s_rx0[66], s_rx1[66];

  const float sc = 31.0f / 63.0f;
  int r0 = (y0 == 0) ? 0 : (int)floorf((float)(y0 - 1) * sc);

  if (t < 10) {
    int uy = y0 - 1 + t;
    int uyc = min(max(uy, 0), 63);
    float sy = (float)uyc * sc;
    int iy0 = (int)floorf(sy);
    s_wy[t] = sy - (float)iy0;
    s_my[t] = ((unsigned)uy < 64u) ? 1.f : 0.f;
    s_ry0[t] = iy0 - r0;
    s_ry1[t] = min(iy0 + 1, 31) - r0;
  }
  int xc = t - 64;
  if (xc >= 0 && xc < 66) {
    int ux = xc - 1;
    int uxc = min(max(ux, 0), 63);
    float sx = (float)uxc * sc;
    int ix0 = (int)floorf(sx);
    s_wx[xc] = sx - (float)ix0;
    s_mx[xc] = ((unsigned)ux < 64u) ? 1.f : 0.f;
    s_rx0[xc] = ix0;
    s_rx1[xc] = min(ix0 + 1, 31);
  }

  const uint4* wh4 = reinterpret_cast<const uint4*>(wh);
  const uint4* wl4 = reinterpret_cast<const uint4*>(wl);

  f32x16 acc[4];
#pragma unroll
  for (int r = 0; r < 4; ++r)
#pragma unroll
    for (int j = 0; j < 16; ++j) acc[r][j] = 0.f;

  // prologue: stage src ci-group 0
  for (int i = t; i < 4096; i += 256) {
    int ci = i >> 8, rem = i & 255;
    int r = rem >> 5, c = rem & 31;
    int row = r0 + r;
    s_src[ci * 264 + r * 33 + c] =
        (row < 32) ? in[(n * 64 + ci) * 1024 + row * 32 + c] : 0.f;
  }
  __syncthreads();

  for (int g = 0; g < 4; ++g) {
    // ---- interp + split-pack into s_x ----
    for (int i = t; i < 10560; i += 256) {            // 16ci x 10u x 66c
      int ci = i / 660, rem = i - ci * 660;
      int u = rem / 66, c = rem - u * 66;
      const float* sp = &s_src[ci * 264];
      int ry0 = s_ry0[u], ry1 = s_ry1[u];
      int rx0 = s_rx0[c], rx1 = s_rx1[c];
      float wy = s_wy[u], wx = s_wx[c];
      float m = s_my[u] * s_mx[c];
      float a00 = sp[ry0 * 33 + rx0], a01 = sp[ry0 * 33 + rx1];
      float a10 = sp[ry1 * 33 + rx0], a11 = sp[ry1 * 33 + rx1];
      float h0 = fmaf(a10 - a00, wy, a00);
      float h1 = fmaf(a11 - a01, wy, a01);
      float v = m * fmaf(h1 - h0, wx, h0);
      unsigned hi = f2bf(__float_as_uint(v));
      float lf = v - __uint_as_float(hi << 16);
      unsigned lo = f2bf(__float_as_uint(lf));
      s_x[(u * 66 + c) * 20 + ci] = hi | (lo << 16);
    }
    __syncthreads();

    // ---- stage next src group (overlaps MFMA below) ----
    if (g < 3) {
      int ci0 = (g + 1) * 16;
      for (int i = t; i < 4096; i += 256) {
        int ci = i >> 8, rem = i & 255;
        int r = rem >> 5, c = rem & 31;
        int row = r0 + r;
        s_src[ci * 264 + r * 33 + c] =
            (row < 32) ? in[(n * 64 + ci0 + ci) * 1024 + row * 32 + c] : 0.f;
      }
    }

    // ---- MFMA ----
#pragma unroll
    for (int kx = 0; kx < 3; ++kx) {
      bf16x8 Ah[3], Al[3];
#pragma unroll
      for (int ky = 0; ky < 3; ++ky) {
        int wi = (g * 9 + ky * 3 + kx) * 64 + cc * 2 + h;
        Ah[ky] = __builtin_bit_cast(bf16x8, wh4[wi]);
        Al[ky] = __builtin_bit_cast(bf16x8, wl4[wi]);
      }
#pragma unroll
      for (int u6 = 0; u6 < 6; ++u6) {
        int u = rg * 4 + u6;
        const uint4* xp = reinterpret_cast<const uint4*>(
            &s_x[(u * 66 + xh * 32 + cc + kx) * 20 + (h << 3)]);
        uint4 qa = xp[0], qb = xp[1];
        u32x4v bh, bl;
        bh[0] = (qa.x & 0xffffu) | (qa.y << 16);
        bh[1] = (qa.z & 0xffffu) | (qa.w << 16);
        bh[2] = (qb.x & 0xffffu) | (qb.y << 16);
        bh[3] = (qb.z & 0xffffu) | (qb.w << 16);
        bl[0] = (qa.x >> 16) | (qa.y & 0xffff0000u);
        bl[1] = (qa.z >> 16) | (qa.w & 0xffff0000u);
        bl[2] = (qb.x >> 16) | (qb.y & 0xffff0000u);
        bl[3] = (qb.z >> 16) | (qb.w & 0xffff0000u);
        bf16x8 Bh = __builtin_bit_cast(bf16x8, bh);
        bf16x8 Bl = __builtin_bit_cast(bf16x8, bl);
#pragma unroll
        for (int ky = 0; ky < 3; ++ky) {
          int rr = u6 - ky;
          if (rr < 0 || rr > 3) continue;
          acc[rr] = __builtin_amdgcn_mfma_f32_32x32x16_bf16(Ah[ky], Bh, acc[rr], 0, 0, 0);
          acc[rr] = __builtin_amdgcn_mfma_f32_32x32x16_bf16(Ah[ky], Bl, acc[rr], 0, 0, 0);
          acc[rr] = __builtin_amdgcn_mfma_f32_32x32x16_bf16(Al[ky], Bh, acc[rr], 0, 0, 0);
        }
      }
    }
    __syncthreads();
  }

  float bvv[16];
#pragma unroll
  for (int reg = 0; reg < 16; ++reg) {
    int co = (reg & 3) + 8 * (reg >> 2) + 4 * h;
    bvv[reg] = bias[co];
  }
#pragma unroll
  for (int rr = 0; rr < 4; ++rr) {
    int y = y0 + rg * 4 + rr;
#pragma unroll
    for (int reg = 0; reg < 16; ++reg) {
      int co = (reg & 3) + 8 * (reg >> 2) + 4 * h;
      float v = acc[rr][reg] + bvv[reg];
      out[(n * 32 + co) * 4096 + y * 64 + xh * 32 + cc] = actf<1>(v);
    }
  }
}

// ---------------- enc1: 1->32, 4x4 stride2 pad1, 128->64, lrelu ------------
__global__ __launch_bounds__(256) void k_enc1(
    const float* __restrict__ in, const float* __restrict__ w,
    const float* __restrict__ b, float* __restrict__ out) {
  int idx = blockIdx.x * 256 + threadIdx.x;        // [128,32,64,64]
  int ox = idx & 63, oy = (idx >> 6) & 63, co = (idx >> 12) & 31, n = idx >> 17;
  const float* ip = in + n * 16384;
  const float* wp = w + co * 16;
  float acc = b[co];
  int iy0 = 2 * oy - 1, ix0 = 2 * ox - 1;
#pragma unroll
  for (int ky = 0; ky < 4; ++ky) {
    int iy = iy0 + ky;
    if ((unsigned)iy >= 128u) continue;
#pragma unroll
    for (int kx = 0; kx < 4; ++kx) {
      int ix = ix0 + kx;
      if ((unsigned)ix >= 128u) continue;
      acc = fmaf(ip[iy * 128 + ix], wp[ky * 4 + kx], acc);
    }
  }
  out[idx] = actf<1>(acc);
}

// ---------------- enc2: 32->64, 4x4 s2 p1, 64->32, lrelu -------------------
__global__ __launch_bounds__(256) void k_enc2(
    const float* __restrict__ in, const float* __restrict__ w,
    const float* __restrict__ b, float* __restrict__ out) {
  int bid = blockIdx.x;                 // 2048 = 128n * 4coG * 4yT
  int n = bid >> 4, coG = (bid >> 2) & 3, yT = bid & 3;
  int co0 = coG * 16, y0 = yT * 8;
  int t = threadIdx.x;
  int coq = t >> 6, ty = (t >> 3) & 7, xq = t & 7;

  __shared__ float s_in[2][4 * 18 * 68];
  __shared__ float s_w[2][4 * 16 * 16];

  float acc[4][4];
#pragma unroll
  for (int c = 0; c < 4; ++c)
#pragma unroll
    for (int xx = 0; xx < 4; ++xx) acc[c][xx] = 0.f;

  {
    for (int i = t; i < 4 * 18 * 66; i += 256) {
      int ci = i / 1188, rem = i - ci * 1188;
      int r = rem / 66, c = rem - r * 66;
      int iy = 2 * y0 - 1 + r, ix = c - 1;
      float v = 0.f;
      if ((unsigned)iy < 64u && (unsigned)ix < 64u)
        v = in[((n * 32 + ci) * 64 + iy) * 64 + ix];
      s_in[0][(ci * 18 + r) * 68 + c] = v;
    }
    for (int i = t; i < 1024; i += 256) {
      int co = i & 15, j = i >> 4;
      int ci = j >> 4, k = j & 15;
      s_w[0][j * 16 + co] = w[((co0 + co) * 32 + ci) * 16 + k];
    }
  }
  __syncthreads();

  for (int g = 0; g < 8; ++g) {
    int buf = g & 1;
    if (g < 7) {
      int ci0 = (g + 1) * 4, nb = buf ^ 1;
      for (int i = t; i < 4 * 18 * 66; i += 256) {
        int ci = i / 1188, rem = i - ci * 1188;
        int r = rem / 66, c = rem - r * 66;
        int iy = 2 * y0 - 1 + r, ix = c - 1;
        float v = 0.f;
        if ((unsigned)iy < 64u && (unsigned)ix < 64u)
          v = in[((n * 32 + ci0 + ci) * 64 + iy) * 64 + ix];
        s_in[nb][(ci * 18 + r) * 68 + c] = v;
      }
      for (int i = t; i < 1024; i += 256) {
        int co = i & 15, j = i >> 4;
        int ci = j >> 4, k = j & 15;
        s_w[nb][j * 16 + co] = w[((co0 + co) * 32 + ci0 + ci) * 16 + k];
      }
    }
    for (int ci = 0; ci < 4; ++ci) {
#pragma unroll
      for (int ky = 0; ky < 4; ++ky) {
        int base = (ci * 18 + 2 * ty + ky) * 68 + xq * 8;
        float4 q0 = *reinterpret_cast<const float4*>(&s_in[buf][base]);
        float4 q1 = *reinterpret_cast<const float4*>(&s_in[buf][base + 4]);
        float4 q2 = *reinterpret_cast<const float4*>(&s_in[buf][base + 8]);
        float rv[12] = {q0.x, q0.y, q0.z, q0.w, q1.x, q1.y, q1.z, q1.w,
                        q2.x, q2.y, q2.z, q2.w};
#pragma unroll
        for (int kx = 0; kx < 4; ++kx) {
          float4 wq = *reinterpret_cast<const float4*>(
              &s_w[buf][(ci * 16 + ky * 4 + kx) * 16 + coq * 4]);
          float wvv[4] = {wq.x, wq.y, wq.z, wq.w};
#pragma unroll
          for (int c = 0; c < 4; ++c)
#pragma unroll
            for (int xx = 0; xx < 4; ++xx)
              acc[c][xx] = fmaf(rv[2 * xx + kx], wvv[c], acc[c][xx]);
        }
      }
    }
    __syncthreads();
  }
#pragma unroll
  for (int c = 0; c < 4; ++c) {
    int co = co0 + coq * 4 + c;
    float bv = b[co];
    int base = ((n * 64 + co) * 32 + y0 + ty) * 32 + xq * 4;
    float4 v = make_float4(actf<1>(acc[c][0] + bv), actf<1>(acc[c][1] + bv),
                           actf<1>(acc[c][2] + bv), actf<1>(acc[c][3] + bv));
    *reinterpret_cast<float4*>(&out[base]) = v;
  }
}

// ---------------- 1x1 64->64 (channel matmul), opt bias / add --------------
template<int ACT, bool BIAS, bool ADD>
__global__ __launch_bounds__(256) void k_1x1(
    const float* __restrict__ in, const float* __restrict__ w,
    const float* __restrict__ bias, const float* __restrict__ add,
    float* __restrict__ out) {
  int bid = blockIdx.x;
  int n = bid >> 2;
  int s = ((bid & 3) << 8) + threadIdx.x;
  __shared__ float s_w[4096];
  for (int i = threadIdx.x; i < 4096; i += 256) s_w[i] = w[i];
  __syncthreads();
  float x[64];
#pragma unroll
  for (int ci = 0; ci < 64; ++ci) x[ci] = in[(n * 64 + ci) * 1024 + s];
  for (int co = 0; co < 64; ++co) {
    float acc = BIAS ? bias[co] : 0.f;
    const float* wr = &s_w[co * 64];
#pragma unroll
    for (int ci = 0; ci < 64; ++ci) acc = fmaf(wr[ci], x[ci], acc);
    if (ADD) acc += add[(n * 64 + co) * 1024 + s];
    out[(n * 64 + co) * 1024 + s] = actf<ACT>(acc);
  }
}

// ---------------- codebook prep: norms + k-major transpose -----------------
__global__ __launch_bounds__(256) void k_cbnorm(const float* __restrict__ cb,
                                                float* __restrict__ nrm) {
  int c = blockIdx.x * 256 + threadIdx.x;
  if (c < 512) {
    float s = 0.f;
    for (int k = 0; k < 64; ++k) { float v = cb[c * 64 + k]; s = fmaf(v, v, s); }
    nrm[c] = s;
  }
}

__global__ __launch_bounds__(256) void k_cbprep(const float* __restrict__ cb,
                                                float* __restrict__ cbT) {
  int i = blockIdx.x * 256 + threadIdx.x;
  int c = i >> 6, k = i & 63;
  cbT[k * 512 + c] = cb[i];
}

// ---------------- VQ: register-tiled distance GEMM + argmin ----------------
__global__ __launch_bounds__(256) void k_vq2(
    const float* __restrict__ lat, const float* __restrict__ cbT,
    const float* __restrict__ cb, const float* __restrict__ nrm,
    float* __restrict__ q, double* __restrict__ part) {
  int bid = blockIdx.x;
  int n = bid >> 4, s0 = (bid & 15) << 6;
  int t = threadIdx.x;

  __shared__ float s_lat[64 * 64];
  __shared__ float s_cb[64 * 128];
  __shared__ float s_nrm[512];
  __shared__ int   s_sel[64];
  __shared__ double s_r[256];

  for (int i = t; i < 4096; i += 256) {
    int k = i >> 6, p = i & 63;
    s_lat[k * 64 + p] = lat[(n * 64 + k) * 1024 + s0 + p];
  }
  for (int i = t; i < 512; i += 256) s_nrm[i] = nrm[i];

  int cl = t & 15, pg = t >> 4;
  int p0 = pg * 4;
  float best[4] = {3.4e38f, 3.4e38f, 3.4e38f, 3.4e38f};
  int bidx[4] = {0, 0, 0, 0};

  for (int g = 0; g < 4; ++g) {
    __syncthreads();
    for (int i = t; i < 2048; i += 256) {
      int k = i >> 5, ccc = (i & 31) << 2;
      *reinterpret_cast<float4*>(&s_cb[k * 128 + ccc]) =
          *reinterpret_cast<const float4*>(&cbT[k * 512 + g * 128 + ccc]);
    }
    __syncthreads();

    float acc[4][8];
#pragma unroll
    for (int p = 0; p < 4; ++p)
#pragma unroll
      for (int c = 0; c < 8; ++c) acc[p][c] = 0.f;

#pragma unroll 4
    for (int k = 0; k < 64; ++k) {
      float4 lv = *reinterpret_cast<const float4*>(&s_lat[k * 64 + p0]);
      float4 ca = *reinterpret_cast<const float4*>(&s_cb[k * 128 + (cl << 2)]);
      float4 cbq = *reinterpret_cast<const float4*>(&s_cb[k * 128 + 64 + (cl << 2)]);
      float l[4] = {lv.x, lv.y, lv.z, lv.w};
      float cv[8] = {ca.x, ca.y, ca.z, ca.w, cbq.x, cbq.y, cbq.z, cbq.w};
#pragma unroll
      for (int p = 0; p < 4; ++p)
#pragma unroll
        for (int c = 0; c < 8; ++c)
          acc[p][c] = fmaf(l[p], cv[c], acc[p][c]);
    }

#pragma unroll
    for (int half = 0; half < 2; ++half)
#pragma unroll
      for (int j = 0; j < 4; ++j) {
        int c = half * 4 + j;
        int code = g * 128 + half * 64 + (cl << 2) + j;
        float nv = s_nrm[code];
#pragma unroll
        for (int p = 0; p < 4; ++p) {
          float d = fmaf(-2.f, acc[p][c], nv);
          if (d < best[p]) { best[p] = d; bidx[p] = code; }
        }
      }
  }

  __syncthreads();
  float* s_rd = s_cb;
  int*   s_ri = (int*)(s_cb + 1024);
#pragma unroll
  for (int p = 0; p < 4; ++p) {
    s_rd[(p0 + p) * 16 + cl] = best[p];
    s_ri[(p0 + p) * 16 + cl] = bidx[p];
  }
  __syncthreads();
  if (t < 64) {
    float bd = s_rd[t * 16]; int bi = s_ri[t * 16];
#pragma unroll
    for (int m = 1; m < 16; ++m) {
      float d = s_rd[t * 16 + m]; int ii = s_ri[t * 16 + m];
      if (d < bd || (d == bd && ii < bi)) { bd = d; bi = ii; }
    }
    s_sel[t] = bi;
  }
  __syncthreads();

  int pos = t & 63, dg = t >> 6;
  int bsel = s_sel[pos];
  const float* cw = cb + bsel * 64 + dg * 16;
  float psum = 0.f;
#pragma unroll
  for (int kk = 0; kk < 16; ++kk) {
    int k = dg * 16 + kk;
    float cv = cw[kk];
    float l = s_lat[k * 64 + pos];
    float df = cv - l;
    psum = fmaf(df, df, psum);
    q[(n * 64 + k) * 1024 + s0 + pos] = cv;
  }
  s_r[t] = (double)psum;
  __syncthreads();
  for (int str = 128; str > 0; str >>= 1) {
    if (t < str) s_r[t] += s_r[t + str];
    __syncthreads();
  }
  if (t == 0) part[bid] = s_r[0];
}

// ---------------- loss finalize --------------------------------------------
__global__ __launch_bounds__(256) void k_loss(const double* __restrict__ part,
                                              float* __restrict__ out) {
  __shared__ double s[256];
  int t = threadIdx.x;
  double acc = 0.0;
  for (int i = t; i < 2048; i += 256) acc += part[i];
  s[t] = acc;
  __syncthreads();
  for (int str = 128; str > 0; str >>= 1) {
    if (t < str) s[t] += s[t + str];
    __syncthreads();
  }
  if (t == 0) {
    double mean = s[0] / 8388608.0;
    out[2097152] = (float)mean;
    out[2097153] = (float)(0.25 * mean);
  }
}

// ---------------- dec3: fused upsample2x(ac) + 3x3 32->1 + relu ------------
__global__ __launch_bounds__(256) void k_dec3(
    const float* __restrict__ in, const float* __restrict__ w,
    const float* __restrict__ bias, float* __restrict__ out) {
  int bid = blockIdx.x;                  // 2048 = 128n * 8yT * 2xT
  int n = bid >> 4, yT = (bid >> 1) & 7, xT = bid & 1;
  int y0 = yT * 16, x0 = xT * 64;
  int t = threadIdx.x;
  int ty = t >> 4, xq = t & 15;

  __shared__ float s_up[4 * 18 * 68];
  __shared__ float s_src[4 * 11 * 35];
  __shared__ float s_w[288];
  __shared__ float s_wy[18], s_my[18];
  __shared__ int   s_ry0[18], s_ry1[18];
  __shared__ float s_wx[66], s_mx[66];
  __shared__ int   s_rx0[66], s_rx1[66];

  const float sc = 63.0f / 127.0f;
  int r0 = (y0 == 0) ? 0 : (int)floorf((float)(y0 - 1) * sc);
  int c0 = (x0 == 0) ? 0 : (int)floorf((float)(x0 - 1) * sc);

  if (t < 18) {
    int uy = y0 - 1 + t;
    int uyc = min(max(uy, 0), 127);
    float sy = (float)uyc * sc;
    int iy0 = (int)floorf(sy);
    s_wy[t] = sy - (float)iy0;
    s_my[t] = ((unsigned)uy < 128u) ? 1.f : 0.f;
    s_ry0[t] = iy0 - r0;
    s_ry1[t] = min(iy0 + 1, 63) - r0;
  }
  int xc = t - 64;
  if (xc >= 0 && xc < 66) {
    int ux = x0 - 1 + xc;
    int uxc = min(max(ux, 0), 127);
    float sx = (float)uxc * sc;
    int ix0 = (int)floorf(sx);
    s_wx[xc] = sx - (float)ix0;
    s_mx[xc] = ((unsigned)ux < 128u) ? 1.f : 0.f;
    s_rx0[xc] = ix0 - c0;
    s_rx1[xc] = min(ix0 + 1, 63) - c0;
  }
  for (int i = t; i < 288; i += 256) s_w[i] = w[i];

  float acc[4] = {0.f, 0.f, 0.f, 0.f};

  for (int i = t; i < 4 * 11 * 35; i += 256) {
    int ci = i / 385, rem = i - ci * 385;
    int rr = rem / 35, cx = rem - rr * 35;
    int row = r0 + rr, col = c0 + cx;
    s_src[(ci * 11 + rr) * 35 + cx] =
        (row < 64 && col < 64) ? in[((n * 32 + ci) * 64 + row) * 64 + col] : 0.f;
  }
  __syncthreads();

  for (int g = 0; g < 8; ++g) {
    for (int i = t; i < 4 * 18 * 66; i += 256) {
      int ci = i / 1188, rem = i - ci * 1188;
      int uu = rem / 66, ccx = rem - uu * 66;
      const float* sp = &s_src[ci * 385];
      int ry0 = s_ry0[uu], ry1 = s_ry1[uu];
      int rx0 = s_rx0[ccx], rx1 = s_rx1[ccx];
      float wy = s_wy[uu], wx = s_wx[ccx];
      float m = s_my[uu] * s_mx[ccx];
      float a00 = sp[ry0 * 35 + rx0], a01 = sp[ry0 * 35 + rx1];
      float a10 = sp[ry1 * 35 + rx0], a11 = sp[ry1 * 35 + rx1];
      float h0 = fmaf(a10 - a00, wy, a00);
      float h1 = fmaf(a11 - a01, wy, a01);
      s_up[(ci * 18 + uu) * 68 + ccx] = m * fmaf(h1 - h0, wx, h0);
    }
    __syncthreads();

    if (g < 7) {
      int ci0 = (g + 1) * 4;
      for (int i = t; i < 4 * 11 * 35; i += 256) {
        int ci = i / 385, rem = i - ci * 385;
        int rr = rem / 35, cx = rem - rr * 35;
        int row = r0 + rr, col = c0 + cx;
        s_src[(ci * 11 + rr) * 35 + cx] =
            (row < 64 && col < 64)
                ? in[((n * 32 + ci0 + ci) * 64 + row) * 64 + col] : 0.f;
      }
    }

    int ci0 = g * 4;
    for (int ci = 0; ci < 4; ++ci) {
#pragma unroll
      for (int ky = 0; ky < 3; ++ky) {
        int base = (ci * 18 + ty + ky) * 68 + xq * 4;
        float4 q0 = *reinterpret_cast<const float4*>(&s_up[base]);
        float4 q1 = *reinterpret_cast<const float4*>(&s_up[base + 4]);
        float rv[8] = {q0.x, q0.y, q0.z, q0.w, q1.x, q1.y, q1.z, q1.w};
#pragma unroll
        for (int kx = 0; kx < 3; ++kx) {
          float wv = s_w[(ci0 + ci) * 9 + ky * 3 + kx];
#pragma unroll
          for (int xx = 0; xx < 4; ++xx)
            acc[xx] = fmaf(rv[xx + kx], wv, acc[xx]);
        }
      }
    }
    __syncthreads();
  }
  float bv = bias[0];
  int base = n * 16384 + (y0 + ty) * 128 + x0 + xq * 4;
  *reinterpret_cast<float4*>(&out[base]) =
      make_float4(actf<2>(acc[0] + bv), actf<2>(acc[1] + bv),
                  actf<2>(acc[2] + bv), actf<2>(acc[3] + bv));
}

// ---------------------------------------------------------------------------
extern "C" void kernel_launch(void* const* d_in, const int* in_sizes, int n_in,
                              void* d_out, int out_size, void* d_ws, size_t ws_size,
                              hipStream_t stream) {
  (void)in_sizes; (void)n_in; (void)out_size; (void)ws_size;
  const float* x_in     = (const float*)d_in[0];
  const float* enc_w1   = (const float*)d_in[1];
  const float* enc_b1   = (const float*)d_in[2];
  const float* enc_w2   = (const float*)d_in[3];
  const float* enc_b2   = (const float*)d_in[4];
  const float* enc_w3   = (const float*)d_in[5];
  const float* enc_b3   = (const float*)d_in[6];
  const float* res_e_w1 = (const float*)d_in[7];
  const float* res_e_w2 = (const float*)d_in[8];
  const float* enc_w4   = (const float*)d_in[9];
  const float* enc_b4   = (const float*)d_in[10];
  const float* codebook = (const float*)d_in[11];
  const float* dec_w1   = (const float*)d_in[12];
  const float* dec_b1   = (const float*)d_in[13];
  const float* res_d_w1 = (const float*)d_in[14];
  const float* res_d_w2 = (const float*)d_in[15];
  const float* dec_w2   = (const float*)d_in[16];
  const float* dec_b2   = (const float*)d_in[17];
  const float* dec_w3   = (const float*)d_in[18];
  const float* dec_b3   = (const float*)d_in[19];
  float* out = (float*)d_out;

  char* ws = (char*)d_ws;
  float*  B0    = (float*)(ws);                         // 33.55 MB each
  float*  B1    = (float*)(ws + 33554432);
  float*  B2    = (float*)(ws + 67108864);
  float*  B3    = (float*)(ws + 100663296);
  float*  B4    = (float*)(ws + 134217728);             // enc1 out: 67.1 MB,
                                                        // FULL region in use
  double* PART  = (double*)(ws + 201326592);
  float*  CNORM = (float*)(ws + 201326592 + 16384);
  float*  CBT   = (float*)(ws + 100663296);             // in B3, pre-VQ only
  // split-bf16 weights, conv3 layers (147456 B each), tail region
  unsigned short* WH0 = (unsigned short*)(ws + 201359360);
  unsigned short* WL0 = WH0 + 36864;
  unsigned short* WH1 = (unsigned short*)(ws + 201359360 + 147456);
  unsigned short* WL1 = WH1 + 36864;
  unsigned short* WH2 = (unsigned short*)(ws + 201359360 + 294912);
  unsigned short* WL2 = WH2 + 36864;
  unsigned short* WH3 = (unsigned short*)(ws + 201359360 + 442368);
  unsigned short* WL3 = WH3 + 36864;
  // dec2 split weights: AFTER the conv3 weight blocks (NOT inside B4 -- that
  // aliased enc1's output in R5 and corrupted the weights)
  unsigned short* WH4 = (unsigned short*)(ws + 201359360 + 589824);
  unsigned short* WL4 = WH4 + 18432;

  k_wprep<<<144, 256, 0, stream>>>(enc_w3,   WH0, WL0);
  k_wprep<<<144, 256, 0, stream>>>(res_e_w1, WH1, WL1);
  k_wprep<<<144, 256, 0, stream>>>(dec_w1,   WH2, WL2);
  k_wprep<<<144, 256, 0, stream>>>(res_d_w1, WH3, WL3);
  k_wprep2<<<72, 256, 0, stream>>>(dec_w2,   WH4, WL4);

  k_enc1<<<65536, 256, 0, stream>>>(x_in, enc_w1, enc_b1, B4);
  k_enc2<<<2048, 256, 0, stream>>>(B4, enc_w2, enc_b2, B0);
  k_conv3m<1, true ><<<512, 256, 0, stream>>>(B0, WH0, WL0, enc_b3, B1);
  k_conv3m<2, false><<<512, 256, 0, stream>>>(B1, WH1, WL1, nullptr, B2);
  k_1x1<1, false, true ><<<512, 256, 0, stream>>>(B2, res_e_w2, nullptr, B1, B0);
  k_1x1<1, true,  false><<<512, 256, 0, stream>>>(B0, enc_w4, enc_b4, nullptr, B1);
  k_cbprep<<<128, 256, 0, stream>>>(codebook, CBT);
  k_cbnorm<<<2, 256, 0, stream>>>(codebook, CNORM);
  k_vq2<<<2048, 256, 0, stream>>>(B1, CBT, codebook, CNORM, B2, PART);
  k_conv3m<1, true ><<<512, 256, 0, stream>>>(B2, WH2, WL2, dec_b1, B0);
  k_conv3m<2, false><<<512, 256, 0, stream>>>(B0, WH3, WL3, nullptr, B3);
  k_1x1<1, false, true ><<<512, 256, 0, stream>>>(B3, res_d_w2, nullptr, B0, B1);
  k_dec2m<<<1024, 256, 0, stream>>>(B1, WH4, WL4, dec_b2, B4);
  k_dec3<<<2048, 256, 0, stream>>>(B4, dec_w3, dec_b3, out);
  k_loss<<<1, 256, 0, stream>>>(PART, out);
}

// Round 8
// 1059.942 us; speedup vs baseline: 3.9867x; 1.1610x over previous
//
#include <hip/hip_runtime.h>

// ---------------------------------------------------------------------------
// VQ-VAE forward.  N=128.  MFMA (split-bf16 hi/lo, 3-term) for the four
// 3x3 64->64 convs, dec2 (up2x + 3x3 64->32), and enc2 (4x4 s2 32->64).
//   x*y ~= xh*yh + xh*yl + xl*yh   (f32 MFMA accumulate)
// ---------------------------------------------------------------------------

template<int ACT> __device__ __forceinline__ float actf(float x){
  if (ACT == 1) return x > 0.f ? x : 0.01f * x;   // leaky relu, slope .01
  if (ACT == 2) return fmaxf(x, 0.f);             // relu
  return x;
}

typedef __bf16 bf16x8 __attribute__((ext_vector_type(8)));
typedef float f32x16 __attribute__((ext_vector_type(16)));
typedef unsigned int u32x4v __attribute__((ext_vector_type(4)));

__device__ __forceinline__ unsigned f2bf(unsigned u){   // RTNE f32->bf16 bits
  return (u + 0x7fffu + ((u >> 16) & 1u)) >> 16;
}

// ---------------- weight prep: f32 [64co][64ci][3][3] -> hi/lo bf16 --------
__global__ __launch_bounds__(256) void k_wprep(
    const float* __restrict__ w, unsigned short* __restrict__ wh,
    unsigned short* __restrict__ wl) {
  int i = blockIdx.x * 256 + threadIdx.x;           // 36864 = 4g*9tap*2*32*16
  if (i >= 36864) return;
  int ci16 = i & 15, co = (i >> 4) & 31, cot = (i >> 9) & 1;
  int rest = i >> 10, tap = rest % 9, g = rest / 9;
  float v = w[(cot * 32 + co) * 576 + (g * 16 + ci16) * 9 + tap];
  unsigned hi = f2bf(__float_as_uint(v));
  float lf = v - __uint_as_float(hi << 16);
  unsigned lo = f2bf(__float_as_uint(lf));
  wh[i] = (unsigned short)hi;
  wl[i] = (unsigned short)lo;
}

// ---------------- weight prep for dec2: f32 [32co][64ci][3][3] -------------
__global__ __launch_bounds__(256) void k_wprep2(
    const float* __restrict__ w, unsigned short* __restrict__ wh,
    unsigned short* __restrict__ wl) {
  int i = blockIdx.x * 256 + threadIdx.x;           // 18432 = 4g*9tap*32*16
  if (i >= 18432) return;
  int ci16 = i & 15, co = (i >> 4) & 31;
  int rest = i >> 9, tap = rest % 9, g = rest / 9;
  float v = w[co * 576 + (g * 16 + ci16) * 9 + tap];
  unsigned hi = f2bf(__float_as_uint(v));
  float lf = v - __uint_as_float(hi << 16);
  unsigned lo = f2bf(__float_as_uint(lf));
  wh[i] = (unsigned short)hi;
  wl[i] = (unsigned short)lo;
}

// ---------------- weight prep for enc2: f32 [64co][32ci][4][4] -------------
// dst ushort idx = (((g*16+tap)*2+cot)*32+co)*16+ci16, g=ci-group of 16
__global__ __launch_bounds__(256) void k_wprep_e2(
    const float* __restrict__ w, unsigned short* __restrict__ wh,
    unsigned short* __restrict__ wl) {
  int i = blockIdx.x * 256 + threadIdx.x;           // 32768 = 2g*16tap*2*32*16
  if (i >= 32768) return;
  int ci16 = i & 15, co = (i >> 4) & 31, cot = (i >> 9) & 1;
  int rest = i >> 10, tap = rest & 15, g = rest >> 4;
  float v = w[(cot * 32 + co) * 512 + (g * 16 + ci16) * 16 + tap];
  unsigned hi = f2bf(__float_as_uint(v));
  float lf = v - __uint_as_float(hi << 16);
  unsigned lo = f2bf(__float_as_uint(lf));
  wh[i] = (unsigned short)hi;
  wl[i] = (unsigned short)lo;
}

// ---------------- 3x3 64->64 stride1 pad1 @32x32 via MFMA ------------------
template<int ACT, bool BIAS>
__global__ __launch_bounds__(256, 2) void k_conv3m(
    const float* __restrict__ in, const unsigned short* __restrict__ wh,
    const unsigned short* __restrict__ wl, const float* __restrict__ bias,
    float* __restrict__ out) {
  int n = blockIdx.x >> 2, y0 = (blockIdx.x & 3) * 8;
  int t = threadIdx.x;
  int lane = t & 63, wv = t >> 6;
  int cot = wv & 1, rgroup = wv >> 1;
  int cc = lane & 31, h = lane >> 5;

  __shared__ __align__(16) unsigned int s_x[6800];   // [10 r][34 c][pad 20 ci]

  const uint4* wh4 = reinterpret_cast<const uint4*>(wh);
  const uint4* wl4 = reinterpret_cast<const uint4*>(wl);

  f32x16 acc[4];
#pragma unroll
  for (int r = 0; r < 4; ++r)
#pragma unroll
    for (int j = 0; j < 16; ++j) acc[r][j] = 0.f;

  for (int g = 0; g < 4; ++g) {
    if (g) __syncthreads();
    for (int i = t; i < 5440; i += 256) {
      int c = i % 34; int rem = i / 34; int r = rem % 10; int ci = rem / 10;
      int row = y0 - 1 + r, col = c - 1;
      float v = 0.f;
      if ((unsigned)row < 32u && (unsigned)col < 32u)
        v = in[(n * 64 + g * 16 + ci) * 1024 + row * 32 + col];
      unsigned hi = f2bf(__float_as_uint(v));
      float lf = v - __uint_as_float(hi << 16);
      unsigned lo = f2bf(__float_as_uint(lf));
      s_x[(r * 34 + c) * 20 + ci] = hi | (lo << 16);
    }
    __syncthreads();

#pragma unroll
    for (int kx = 0; kx < 3; ++kx) {
      bf16x8 Ah[3], Al[3];
#pragma unroll
      for (int ky = 0; ky < 3; ++ky) {
        int wi = ((g * 9 + ky * 3 + kx) * 2 + cot) * 64 + cc * 2 + h;
        Ah[ky] = __builtin_bit_cast(bf16x8, wh4[wi]);
        Al[ky] = __builtin_bit_cast(bf16x8, wl4[wi]);
      }
#pragma unroll
      for (int ir6 = 0; ir6 < 6; ++ir6) {
        int ir = rgroup * 4 + ir6;
        const uint4* xp = reinterpret_cast<const uint4*>(
            &s_x[(ir * 34 + cc + kx) * 20 + (h << 3)]);
        uint4 qa = xp[0], qb = xp[1];
        u32x4v bh, bl;
        bh[0] = (qa.x & 0xffffu) | (qa.y << 16);
        bh[1] = (qa.z & 0xffffu) | (qa.w << 16);
        bh[2] = (qb.x & 0xffffu) | (qb.y << 16);
        bh[3] = (qb.z & 0xffffu) | (qb.w << 16);
        bl[0] = (qa.x >> 16) | (qa.y & 0xffff0000u);
        bl[1] = (qa.z >> 16) | (qa.w & 0xffff0000u);
        bl[2] = (qb.x >> 16) | (qb.y & 0xffff0000u);
        bl[3] = (qb.z >> 16) | (qb.w & 0xffff0000u);
        bf16x8 Bh = __builtin_bit_cast(bf16x8, bh);
        bf16x8 Bl = __builtin_bit_cast(bf16x8, bl);
#pragma unroll
        for (int ky = 0; ky < 3; ++ky) {
          int rr = ir6 - ky;
          if (rr < 0 || rr > 3) continue;
          acc[rr] = __builtin_amdgcn_mfma_f32_32x32x16_bf16(Ah[ky], Bh, acc[rr], 0, 0, 0);
          acc[rr] = __builtin_amdgcn_mfma_f32_32x32x16_bf16(Ah[ky], Bl, acc[rr], 0, 0, 0);
          acc[rr] = __builtin_amdgcn_mfma_f32_32x32x16_bf16(Al[ky], Bh, acc[rr], 0, 0, 0);
        }
      }
    }
  }

  float bvv[16];
#pragma unroll
  for (int reg = 0; reg < 16; ++reg) {
    int row = (reg & 3) + 8 * (reg >> 2) + 4 * h;
    bvv[reg] = BIAS ? bias[cot * 32 + row] : 0.f;
  }
#pragma unroll
  for (int rr = 0; rr < 4; ++rr) {
    int y = y0 + rgroup * 4 + rr;
#pragma unroll
    for (int reg = 0; reg < 16; ++reg) {
      int row = (reg & 3) + 8 * (reg >> 2) + 4 * h;
      int co = cot * 32 + row;
      float v = acc[rr][reg] + bvv[reg];
      out[(n * 64 + co) * 1024 + y * 32 + cc] = actf<ACT>(v);
    }
  }
}

// ---------------- enc2: 32->64, 4x4 s2 p1, 64->32 via MFMA -----------------
// block: (n, 4-row out strip).  4 waves: cot = wv&1, rg = wv>>1 (2 rows).
// LDS: parity-deinterleaved packed tile [10 r][2 p][33 col][pad 20 ci].
__global__ __launch_bounds__(256, 2) void k_enc2m(
    const float* __restrict__ in, const unsigned short* __restrict__ wh,
    const unsigned short* __restrict__ wl, const float* __restrict__ bias,
    float* __restrict__ out) {
  int n = blockIdx.x >> 3, y0 = (blockIdx.x & 7) * 4;
  int t = threadIdx.x;
  int lane = t & 63, wv = t >> 6;
  int cot = wv & 1, rg = wv >> 1;
  int cc = lane & 31, h = lane >> 5;

  __shared__ __align__(16) unsigned int s_x[13200];  // [10][2][33][20]

  const uint4* wh4 = reinterpret_cast<const uint4*>(wh);
  const uint4* wl4 = reinterpret_cast<const uint4*>(wl);

  f32x16 acc[2];
#pragma unroll
  for (int r = 0; r < 2; ++r)
#pragma unroll
    for (int j = 0; j < 16; ++j) acc[r][j] = 0.f;

  for (int g = 0; g < 2; ++g) {
    if (g) __syncthreads();
    // stage 16 ci x 10 input rows x cols -1..64, parity-split
    for (int i = t; i < 10560; i += 256) {
      int ci = i / 660, rem = i - ci * 660;
      int r = rem / 66, c = rem - r * 66;
      int row = 2 * y0 - 1 + r, icol = c - 1;
      float v = 0.f;
      if ((unsigned)row < 64u && (unsigned)icol < 64u)
        v = in[((n * 32 + g * 16 + ci) * 64 + row) * 64 + icol];
      unsigned hi = f2bf(__float_as_uint(v));
      float lf = v - __uint_as_float(hi << 16);
      unsigned lo = f2bf(__float_as_uint(lf));
      int p = icol & 1;
      int idx = (icol + p) >> 1;
      s_x[((r * 2 + p) * 33 + idx) * 20 + ci] = hi | (lo << 16);
    }
    __syncthreads();

#pragma unroll
    for (int kx = 0; kx < 4; ++kx) {
      bf16x8 Ah[4], Al[4];
#pragma unroll
      for (int ky = 0; ky < 4; ++ky) {
        int wi = ((g * 16 + ky * 4 + kx) * 2 + cot) * 64 + cc * 2 + h;
        Ah[ky] = __builtin_bit_cast(bf16x8, wh4[wi]);
        Al[ky] = __builtin_bit_cast(bf16x8, wl4[wi]);
      }
      int p = (kx + 1) & 1;
      int idx = cc + (kx >> 1);
#pragma unroll
      for (int ir6 = 0; ir6 < 6; ++ir6) {
        int r = rg * 4 + ir6;
        const uint4* xp = reinterpret_cast<const uint4*>(
            &s_x[((r * 2 + p) * 33 + idx) * 20 + (h << 3)]);
        uint4 qa = xp[0], qb = xp[1];
        u32x4v bh, bl;
        bh[0] = (qa.x & 0xffffu) | (qa.y << 16);
        bh[1] = (qa.z & 0xffffu) | (qa.w << 16);
        bh[2] = (qb.x & 0xffffu) | (qb.y << 16);
        bh[3] = (qb.z & 0xffffu) | (qb.w << 16);
        bl[0] = (qa.x >> 16) | (qa.y & 0xffff0000u);
        bl[1] = (qa.z >> 16) | (qa.w & 0xffff0000u);
        bl[2] = (qb.x >> 16) | (qb.y & 0xffff0000u);
        bl[3] = (qb.z >> 16) | (qb.w & 0xffff0000u);
        bf16x8 Bh = __builtin_bit_cast(bf16x8, bh);
        bf16x8 Bl = __builtin_bit_cast(bf16x8, bl);
#pragma unroll
        for (int rr = 0; rr < 2; ++rr) {
          int ky = ir6 - 2 * rr;
          if (ky < 0 || ky > 3) continue;            // compile-time folds
          acc[rr] = __builtin_amdgcn_mfma_f32_32x32x16_bf16(Ah[ky], Bh, acc[rr], 0, 0, 0);
          acc[rr] = __builtin_amdgcn_mfma_f32_32x32x16_bf16(Ah[ky], Bl, acc[rr], 0, 0, 0);
          acc[rr] = __builtin_amdgcn_mfma_f32_32x32x16_bf16(Al[ky], Bh, acc[rr], 0, 0, 0);
        }
      }
    }
  }

#pragma unroll
  for (int rr = 0; rr < 2; ++rr) {
    int oy = y0 + rg * 2 + rr;
#pragma unroll
    for (int reg = 0; reg < 16; ++reg) {
      int corow = (reg & 3) + 8 * (reg >> 2) + 4 * h;
      int co = cot * 32 + corow;
      float v = acc[rr][reg] + bias[co];
      out[(n * 64 + co) * 1024 + oy * 32 + cc] = actf<1>(v);
    }
  }
}

// ---------------- dec2: up2x(ac) + 3x3 64->32 + lrelu, via MFMA ------------
__global__ __launch_bounds__(256, 2) void k_dec2m(
    const float* __restrict__ in, const unsigned short* __restrict__ wh,
    const unsigned short* __restrict__ wl, const float* __restrict__ bias,
    float* __restrict__ out) {
  int n = blockIdx.x >> 3, y0 = (blockIdx.x & 7) * 8;
  int t = threadIdx.x;
  int lane = t & 63, wv = t >> 6;
  int xh = wv & 1, rg = wv >> 1;
  int cc = lane & 31, h = lane >> 5;

  __shared__ __align__(16) unsigned int s_x[10 * 66 * 20];  // packed up-tile
  __shared__ float s_src[16 * 8 * 33];                      // [ci][r][c]
  __shared__ float s_wy[10], s_my[10];
  __shared__ int   s_ry0[10], s_ry1[10];
  __shared__ float s_wx[66], s_mx[66];
  __shared__ int   s_rx0[66], s_rx1[66];

  const float sc = 31.0f / 63.0f;
  int r0 = (y0 == 0) ? 0 : (int)floorf((float)(y0 - 1) * sc);

  if (t < 10) {
    int uy = y0 - 1 + t;
    int uyc = min(max(uy, 0), 63);
    float sy = (float)uyc * sc;
    int iy0 = (int)floorf(sy);
    s_wy[t] = sy - (float)iy0;
    s_my[t] = ((unsigned)uy < 64u) ? 1.f : 0.f;
    s_ry0[t] = iy0 - r0;
    s_ry1[t] = min(iy0 + 1, 31) - r0;
  }
  int xc = t - 64;
  if (xc >= 0 && xc < 66) {
    int ux = xc - 1;
    int uxc = min(max(ux, 0), 63);
    float sx = (float)uxc * sc;
    int ix0 = (int)floorf(sx);
    s_wx[xc] = sx - (float)ix0;
    s_mx[xc] = ((unsigned)ux < 64u) ? 1.f : 0.f;
    s_rx0[xc] = ix0;
    s_rx1[xc] = min(ix0 + 1, 31);
  }

  const uint4* wh4 = reinterpret_cast<const uint4*>(wh);
  const uint4* wl4 = reinterpret_cast<const uint4*>(wl);

  f32x16 acc[4];
#pragma unroll
  for (int r = 0; r < 4; ++r)
#pragma unroll
    for (int j = 0; j < 16; ++j) acc[r][j] = 0.f;

  for (int i = t; i < 4096; i += 256) {
    int ci = i >> 8, rem = i & 255;
    int r = rem >> 5, c = rem & 31;
    int row = r0 + r;
    s_src[ci * 264 + r * 33 + c] =
        (row < 32) ? in[(n * 64 + ci) * 1024 + row * 32 + c] : 0.f;
  }
  __syncthreads();

  for (int g = 0; g < 4; ++g) {
    for (int i = t; i < 10560; i += 256) {            // 16ci x 10u x 66c
      int ci = i / 660, rem = i - ci * 660;
      int u = rem / 66, c = rem - u * 66;
      const float* sp = &s_src[ci * 264];
      int ry0 = s_ry0[u], ry1 = s_ry1[u];
      int rx0 = s_rx0[c], rx1 = s_rx1[c];
      float wy = s_wy[u], wx = s_wx[c];
      float m = s_my[u] * s_mx[c];
      float a00 = sp[ry0 * 33 + rx0], a01 = sp[ry0 * 33 + rx1];
      float a10 = sp[ry1 * 33 + rx0], a11 = sp[ry1 * 33 + rx1];
      float h0 = fmaf(a10 - a00, wy, a00);
      float h1 = fmaf(a11 - a01, wy, a01);
      float v = m * fmaf(h1 - h0, wx, h0);
      unsigned hi = f2bf(__float_as_uint(v));
      float lf = v - __uint_as_float(hi << 16);
      unsigned lo = f2bf(__float_as_uint(lf));
      s_x[(u * 66 + c) * 20 + ci] = hi | (lo << 16);
    }
    __syncthreads();

    if (g < 3) {
      int ci0 = (g + 1) * 16;
      for (int i = t; i < 4096; i += 256) {
        int ci = i >> 8, rem = i & 255;
        int r = rem >> 5, c = rem & 31;
        int row = r0 + r;
        s_src[ci * 264 + r * 33 + c] =
            (row < 32) ? in[(n * 64 + ci0 + ci) * 1024 + row * 32 + c] : 0.f;
      }
    }

#pragma unroll
    for (int kx = 0; kx < 3; ++kx) {
      bf16x8 Ah[3], Al[3];
#pragma unroll
      for (int ky = 0; ky < 3; ++ky) {
        int wi = (g * 9 + ky * 3 + kx) * 64 + cc * 2 + h;
        Ah[ky] = __builtin_bit_cast(bf16x8, wh4[wi]);
        Al[ky] = __builtin_bit_cast(bf16x8, wl4[wi]);
      }
#pragma unroll
      for (int u6 = 0; u6 < 6; ++u6) {
        int u = rg * 4 + u6;
        const uint4* xp = reinterpret_cast<const uint4*>(
            &s_x[(u * 66 + xh * 32 + cc + kx) * 20 + (h << 3)]);
        uint4 qa = xp[0], qb = xp[1];
        u32x4v bh, bl;
        bh[0] = (qa.x & 0xffffu) | (qa.y << 16);
        bh[1] = (qa.z & 0xffffu) | (qa.w << 16);
        bh[2] = (qb.x & 0xffffu) | (qb.y << 16);
        bh[3] = (qb.z & 0xffffu) | (qb.w << 16);
        bl[0] = (qa.x >> 16) | (qa.y & 0xffff0000u);
        bl[1] = (qa.z >> 16) | (qa.w & 0xffff0000u);
        bl[2] = (qb.x >> 16) | (qb.y & 0xffff0000u);
        bl[3] = (qb.z >> 16) | (qb.w & 0xffff0000u);
        bf16x8 Bh = __builtin_bit_cast(bf16x8, bh);
        bf16x8 Bl = __builtin_bit_cast(bf16x8, bl);
#pragma unroll
        for (int ky = 0; ky < 3; ++ky) {
          int rr = u6 - ky;
          if (rr < 0 || rr > 3) continue;
          acc[rr] = __builtin_amdgcn_mfma_f32_32x32x16_bf16(Ah[ky], Bh, acc[rr], 0, 0, 0);
          acc[rr] = __builtin_amdgcn_mfma_f32_32x32x16_bf16(Ah[ky], Bl, acc[rr], 0, 0, 0);
          acc[rr] = __builtin_amdgcn_mfma_f32_32x32x16_bf16(Al[ky], Bh, acc[rr], 0, 0, 0);
        }
      }
    }
    __syncthreads();
  }

  float bvv[16];
#pragma unroll
  for (int reg = 0; reg < 16; ++reg) {
    int co = (reg & 3) + 8 * (reg >> 2) + 4 * h;
    bvv[reg] = bias[co];
  }
#pragma unroll
  for (int rr = 0; rr < 4; ++rr) {
    int y = y0 + rg * 4 + rr;
#pragma unroll
    for (int reg = 0; reg < 16; ++reg) {
      int co = (reg & 3) + 8 * (reg >> 2) + 4 * h;
      float v = acc[rr][reg] + bvv[reg];
      out[(n * 32 + co) * 4096 + y * 64 + xh * 32 + cc] = actf<1>(v);
    }
  }
}

// ---------------- enc1: 1->32, 4x4 stride2 pad1, 128->64, lrelu ------------
__global__ __launch_bounds__(256) void k_enc1(
    const float* __restrict__ in, const float* __restrict__ w,
    const float* __restrict__ b, float* __restrict__ out) {
  int idx = blockIdx.x * 256 + threadIdx.x;        // [128,32,64,64]
  int ox = idx & 63, oy = (idx >> 6) & 63, co = (idx >> 12) & 31, n = idx >> 17;
  const float* ip = in + n * 16384;
  const float* wp = w + co * 16;
  float acc = b[co];
  int iy0 = 2 * oy - 1, ix0 = 2 * ox - 1;
#pragma unroll
  for (int ky = 0; ky < 4; ++ky) {
    int iy = iy0 + ky;
    if ((unsigned)iy >= 128u) continue;
#pragma unroll
    for (int kx = 0; kx < 4; ++kx) {
      int ix = ix0 + kx;
      if ((unsigned)ix >= 128u) continue;
      acc = fmaf(ip[iy * 128 + ix], wp[ky * 4 + kx], acc);
    }
  }
  out[idx] = actf<1>(acc);
}

// ---------------- 1x1 64->64 (channel matmul), opt bias / add --------------
template<int ACT, bool BIAS, bool ADD>
__global__ __launch_bounds__(256) void k_1x1(
    const float* __restrict__ in, const float* __restrict__ w,
    const float* __restrict__ bias, const float* __restrict__ add,
    float* __restrict__ out) {
  int bid = blockIdx.x;
  int n = bid >> 2;
  int s = ((bid & 3) << 8) + threadIdx.x;
  __shared__ float s_w[4096];
  for (int i = threadIdx.x; i < 4096; i += 256) s_w[i] = w[i];
  __syncthreads();
  float x[64];
#pragma unroll
  for (int ci = 0; ci < 64; ++ci) x[ci] = in[(n * 64 + ci) * 1024 + s];
  for (int co = 0; co < 64; ++co) {
    float acc = BIAS ? bias[co] : 0.f;
    const float* wr = &s_w[co * 64];
#pragma unroll
    for (int ci = 0; ci < 64; ++ci) acc = fmaf(wr[ci], x[ci], acc);
    if (ADD) acc += add[(n * 64 + co) * 1024 + s];
    out[(n * 64 + co) * 1024 + s] = actf<ACT>(acc);
  }
}

// ---------------- codebook prep: norms + k-major transpose -----------------
__global__ __launch_bounds__(256) void k_cbnorm(const float* __restrict__ cb,
                                                float* __restrict__ nrm) {
  int c = blockIdx.x * 256 + threadIdx.x;
  if (c < 512) {
    float s = 0.f;
    for (int k = 0; k < 64; ++k) { float v = cb[c * 64 + k]; s = fmaf(v, v, s); }
    nrm[c] = s;
  }
}

__global__ __launch_bounds__(256) void k_cbprep(const float* __restrict__ cb,
                                                float* __restrict__ cbT) {
  int i = blockIdx.x * 256 + threadIdx.x;
  int c = i >> 6, k = i & 63;
  cbT[k * 512 + c] = cb[i];
}

// ---------------- VQ: register-tiled distance GEMM + argmin ----------------
__global__ __launch_bounds__(256) void k_vq2(
    const float* __restrict__ lat, const float* __restrict__ cbT,
    const float* __restrict__ cb, const float* __restrict__ nrm,
    float* __restrict__ q, double* __restrict__ part) {
  int bid = blockIdx.x;
  int n = bid >> 4, s0 = (bid & 15) << 6;
  int t = threadIdx.x;

  __shared__ float s_lat[64 * 64];
  __shared__ float s_cb[64 * 128];
  __shared__ float s_nrm[512];
  __shared__ int   s_sel[64];
  __shared__ double s_r[256];

  for (int i = t; i < 4096; i += 256) {
    int k = i >> 6, p = i & 63;
    s_lat[k * 64 + p] = lat[(n * 64 + k) * 1024 + s0 + p];
  }
  for (int i = t; i < 512; i += 256) s_nrm[i] = nrm[i];

  int cl = t & 15, pg = t >> 4;
  int p0 = pg * 4;
  float best[4] = {3.4e38f, 3.4e38f, 3.4e38f, 3.4e38f};
  int bidx[4] = {0, 0, 0, 0};

  for (int g = 0; g < 4; ++g) {
    __syncthreads();
    for (int i = t; i < 2048; i += 256) {
      int k = i >> 5, ccc = (i & 31) << 2;
      *reinterpret_cast<float4*>(&s_cb[k * 128 + ccc]) =
          *reinterpret_cast<const float4*>(&cbT[k * 512 + g * 128 + ccc]);
    }
    __syncthreads();

    float acc[4][8];
#pragma unroll
    for (int p = 0; p < 4; ++p)
#pragma unroll
      for (int c = 0; c < 8; ++c) acc[p][c] = 0.f;

#pragma unroll 4
    for (int k = 0; k < 64; ++k) {
      float4 lv = *reinterpret_cast<const float4*>(&s_lat[k * 64 + p0]);
      float4 ca = *reinterpret_cast<const float4*>(&s_cb[k * 128 + (cl << 2)]);
      float4 cbq = *reinterpret_cast<const float4*>(&s_cb[k * 128 + 64 + (cl << 2)]);
      float l[4] = {lv.x, lv.y, lv.z, lv.w};
      float cv[8] = {ca.x, ca.y, ca.z, ca.w, cbq.x, cbq.y, cbq.z, cbq.w};
#pragma unroll
      for (int p = 0; p < 4; ++p)
#pragma unroll
        for (int c = 0; c < 8; ++c)
          acc[p][c] = fmaf(l[p], cv[c], acc[p][c]);
    }

#pragma unroll
    for (int half = 0; half < 2; ++half)
#pragma unroll
      for (int j = 0; j < 4; ++j) {
        int c = half * 4 + j;
        int code = g * 128 + half * 64 + (cl << 2) + j;
        float nv = s_nrm[code];
#pragma unroll
        for (int p = 0; p < 4; ++p) {
          float d = fmaf(-2.f, acc[p][c], nv);
          if (d < best[p]) { best[p] = d; bidx[p] = code; }
        }
      }
  }

  __syncthreads();
  float* s_rd = s_cb;
  int*   s_ri = (int*)(s_cb + 1024);
#pragma unroll
  for (int p = 0; p < 4; ++p) {
    s_rd[(p0 + p) * 16 + cl] = best[p];
    s_ri[(p0 + p) * 16 + cl] = bidx[p];
  }
  __syncthreads();
  if (t < 64) {
    float bd = s_rd[t * 16]; int bi = s_ri[t * 16];
#pragma unroll
    for (int m = 1; m < 16; ++m) {
      float d = s_rd[t * 16 + m]; int ii = s_ri[t * 16 + m];
      if (d < bd || (d == bd && ii < bi)) { bd = d; bi = ii; }
    }
    s_sel[t] = bi;
  }
  __syncthreads();

  int pos = t & 63, dg = t >> 6;
  int bsel = s_sel[pos];
  const float* cw = cb + bsel * 64 + dg * 16;
  float psum = 0.f;
#pragma unroll
  for (int kk = 0; kk < 16; ++kk) {
    int k = dg * 16 + kk;
    float cv = cw[kk];
    float l = s_lat[k * 64 + pos];
    float df = cv - l;
    psum = fmaf(df, df, psum);
    q[(n * 64 + k) * 1024 + s0 + pos] = cv;
  }
  s_r[t] = (double)psum;
  __syncthreads();
  for (int str = 128; str > 0; str >>= 1) {
    if (t < str) s_r[t] += s_r[t + str];
    __syncthreads();
  }
  if (t == 0) part[bid] = s_r[0];
}

// ---------------- loss finalize --------------------------------------------
__global__ __launch_bounds__(256) void k_loss(const double* __restrict__ part,
                                              float* __restrict__ out) {
  __shared__ double s[256];
  int t = threadIdx.x;
  double acc = 0.0;
  for (int i = t; i < 2048; i += 256) acc += part[i];
  s[t] = acc;
  __syncthreads();
  for (int str = 128; str > 0; str >>= 1) {
    if (t < str) s[t] += s[t + str];
    __syncthreads();
  }
  if (t == 0) {
    double mean = s[0] / 8388608.0;
    out[2097152] = (float)mean;
    out[2097153] = (float)(0.25 * mean);
  }
}

// ---------------- dec3: fused upsample2x(ac) + 3x3 32->1 + relu ------------
__global__ __launch_bounds__(256) void k_dec3(
    const float* __restrict__ in, const float* __restrict__ w,
    const float* __restrict__ bias, float* __restrict__ out) {
  int bid = blockIdx.x;                  // 2048 = 128n * 8yT * 2xT
  int n = bid >> 4, yT = (bid >> 1) & 7, xT = bid & 1;
  int y0 = yT * 16, x0 = xT * 64;
  int t = threadIdx.x;
  int ty = t >> 4, xq = t & 15;

  __shared__ float s_up[4 * 18 * 68];
  __shared__ float s_src[4 * 11 * 35];
  __shared__ float s_w[288];
  __shared__ float s_wy[18], s_my[18];
  __shared__ int   s_ry0[18], s_ry1[18];
  __shared__ float s_wx[66], s_mx[66];
  __shared__ int   s_rx0[66], s_rx1[66];

  const float sc = 63.0f / 127.0f;
  int r0 = (y0 == 0) ? 0 : (int)floorf((float)(y0 - 1) * sc);
  int c0 = (x0 == 0) ? 0 : (int)floorf((float)(x0 - 1) * sc);

  if (t < 18) {
    int uy = y0 - 1 + t;
    int uyc = min(max(uy, 0), 127);
    float sy = (float)uyc * sc;
    int iy0 = (int)floorf(sy);
    s_wy[t] = sy - (float)iy0;
    s_my[t] = ((unsigned)uy < 128u) ? 1.f : 0.f;
    s_ry0[t] = iy0 - r0;
    s_ry1[t] = min(iy0 + 1, 63) - r0;
  }
  int xc = t - 64;
  if (xc >= 0 && xc < 66) {
    int ux = x0 - 1 + xc;
    int uxc = min(max(ux, 0), 127);
    float sx = (float)uxc * sc;
    int ix0 = (int)floorf(sx);
    s_wx[xc] = sx - (float)ix0;
    s_mx[xc] = ((unsigned)ux < 128u) ? 1.f : 0.f;
    s_rx0[xc] = ix0 - c0;
    s_rx1[xc] = min(ix0 + 1, 63) - c0;
  }
  for (int i = t; i < 288; i += 256) s_w[i] = w[i];

  float acc[4] = {0.f, 0.f, 0.f, 0.f};

  for (int i = t; i < 4 * 11 * 35; i += 256) {
    int ci = i / 385, rem = i - ci * 385;
    int rr = rem / 35, cx = rem - rr * 35;
    int row = r0 + rr, col = c0 + cx;
    s_src[(ci * 11 + rr) * 35 + cx] =
        (row < 64 && col < 64) ? in[((n * 32 + ci) * 64 + row) * 64 + col] : 0.f;
  }
  __syncthreads();

  for (int g = 0; g < 8; ++g) {
    for (int i = t; i < 4 * 18 * 66; i += 256) {
      int ci = i / 1188, rem = i - ci * 1188;
      int uu = rem / 66, ccx = rem - uu * 66;
      const float* sp = &s_src[ci * 385];
      int ry0 = s_ry0[uu], ry1 = s_ry1[uu];
      int rx0 = s_rx0[ccx], rx1 = s_rx1[ccx];
      float wy = s_wy[uu], wx = s_wx[ccx];
      float m = s_my[uu] * s_mx[ccx];
      float a00 = sp[ry0 * 35 + rx0], a01 = sp[ry0 * 35 + rx1];
      float a10 = sp[ry1 * 35 + rx0], a11 = sp[ry1 * 35 + rx1];
      float h0 = fmaf(a10 - a00, wy, a00);
      float h1 = fmaf(a11 - a01, wy, a01);
      s_up[(ci * 18 + uu) * 68 + ccx] = m * fmaf(h1 - h0, wx, h0);
    }
    __syncthreads();

    if (g < 7) {
      int ci0 = (g + 1) * 4;
      for (int i = t; i < 4 * 11 * 35; i += 256) {
        int ci = i / 385, rem = i - ci * 385;
        int rr = rem / 35, cx = rem - rr * 35;
        int row = r0 + rr, col = c0 + cx;
        s_src[(ci * 11 + rr) * 35 + cx] =
            (row < 64 && col < 64)
                ? in[((n * 32 + ci0 + ci) * 64 + row) * 64 + col] : 0.f;
      }
    }

    int ci0 = g * 4;
    for (int ci = 0; ci < 4; ++ci) {
#pragma unroll
      for (int ky = 0; ky < 3; ++ky) {
        int base = (ci * 18 + ty + ky) * 68 + xq * 4;
        float4 q0 = *reinterpret_cast<const float4*>(&s_up[base]);
        float4 q1 = *reinterpret_cast<const float4*>(&s_up[base + 4]);
        float rv[8] = {q0.x, q0.y, q0.z, q0.w, q1.x, q1.y, q1.z, q1.w};
#pragma unroll
        for (int kx = 0; kx < 3; ++kx) {
          float wv = s_w[(ci0 + ci) * 9 + ky * 3 + kx];
#pragma unroll
          for (int xx = 0; xx < 4; ++xx)
            acc[xx] = fmaf(rv[xx + kx], wv, acc[xx]);
        }
      }
    }
    __syncthreads();
  }
  float bv = bias[0];
  int base = n * 16384 + (y0 + ty) * 128 + x0 + xq * 4;
  *reinterpret_cast<float4*>(&out[base]) =
      make_float4(actf<2>(acc[0] + bv), actf<2>(acc[1] + bv),
                  actf<2>(acc[2] + bv), actf<2>(acc[3] + bv));
}

// ---------------------------------------------------------------------------
extern "C" void kernel_launch(void* const* d_in, const int* in_sizes, int n_in,
                              void* d_out, int out_size, void* d_ws, size_t ws_size,
                              hipStream_t stream) {
  (void)in_sizes; (void)n_in; (void)out_size; (void)ws_size;
  const float* x_in     = (const float*)d_in[0];
  const float* enc_w1   = (const float*)d_in[1];
  const float* enc_b1   = (const float*)d_in[2];
  const float* enc_w2   = (const float*)d_in[3];
  const float* enc_b2   = (const float*)d_in[4];
  const float* enc_w3   = (const float*)d_in[5];
  const float* enc_b3   = (const float*)d_in[6];
  const float* res_e_w1 = (const float*)d_in[7];
  const float* res_e_w2 = (const float*)d_in[8];
  const float* enc_w4   = (const float*)d_in[9];
  const float* enc_b4   = (const float*)d_in[10];
  const float* codebook = (const float*)d_in[11];
  const float* dec_w1   = (const float*)d_in[12];
  const float* dec_b1   = (const float*)d_in[13];
  const float* res_d_w1 = (const float*)d_in[14];
  const float* res_d_w2 = (const float*)d_in[15];
  const float* dec_w2   = (const float*)d_in[16];
  const float* dec_b2   = (const float*)d_in[17];
  const float* dec_w3   = (const float*)d_in[18];
  const float* dec_b3   = (const float*)d_in[19];
  float* out = (float*)d_out;

  char* ws = (char*)d_ws;
  float*  B0    = (float*)(ws);                         // 33.55 MB each
  float*  B1    = (float*)(ws + 33554432);
  float*  B2    = (float*)(ws + 67108864);
  float*  B3    = (float*)(ws + 100663296);
  float*  B4    = (float*)(ws + 134217728);             // enc1 out: 67.1 MB
  double* PART  = (double*)(ws + 201326592);
  float*  CNORM = (float*)(ws + 201326592 + 16384);
  float*  CBT   = (float*)(ws + 100663296);             // in B3, pre-VQ only
  // split-bf16 weight tail region (after PART/CNORM page)
  unsigned short* WH0 = (unsigned short*)(ws + 201359360);
  unsigned short* WL0 = WH0 + 36864;
  unsigned short* WH1 = (unsigned short*)(ws + 201359360 + 147456);
  unsigned short* WL1 = WH1 + 36864;
  unsigned short* WH2 = (unsigned short*)(ws + 201359360 + 294912);
  unsigned short* WL2 = WH2 + 36864;
  unsigned short* WH3 = (unsigned short*)(ws + 201359360 + 442368);
  unsigned short* WL3 = WH3 + 36864;
  unsigned short* WH4 = (unsigned short*)(ws + 201359360 + 589824);   // dec2
  unsigned short* WL4 = WH4 + 18432;
  unsigned short* WH5 = (unsigned short*)(ws + 201359360 + 663552);   // enc2
  unsigned short* WL5 = WH5 + 32768;

  k_wprep<<<144, 256, 0, stream>>>(enc_w3,   WH0, WL0);
  k_wprep<<<144, 256, 0, stream>>>(res_e_w1, WH1, WL1);
  k_wprep<<<144, 256, 0, stream>>>(dec_w1,   WH2, WL2);
  k_wprep<<<144, 256, 0, stream>>>(res_d_w1, WH3, WL3);
  k_wprep2<<<72, 256, 0, stream>>>(dec_w2,   WH4, WL4);
  k_wprep_e2<<<128, 256, 0, stream>>>(enc_w2, WH5, WL5);

  k_enc1<<<65536, 256, 0, stream>>>(x_in, enc_w1, enc_b1, B4);
  k_enc2m<<<1024, 256, 0, stream>>>(B4, WH5, WL5, enc_b2, B0);
  k_conv3m<1, true ><<<512, 256, 0, stream>>>(B0, WH0, WL0, enc_b3, B1);
  k_conv3m<2, false><<<512, 256, 0, stream>>>(B1, WH1, WL1, nullptr, B2);
  k_1x1<1, false, true ><<<512, 256, 0, stream>>>(B2, res_e_w2, nullptr, B1, B0);
  k_1x1<1, true,  false><<<512, 256, 0, stream>>>(B0, enc_w4, enc_b4, nullptr, B1);
  k_cbprep<<<128, 256, 0, stream>>>(codebook, CBT);
  k_cbnorm<<<2, 256, 0, stream>>>(codebook, CNORM);
  k_vq2<<<2048, 256, 0, stream>>>(B1, CBT, codebook, CNORM, B2, PART);
  k_conv3m<1, true ><<<512, 256, 0, stream>>>(B2, WH2, WL2, dec_b1, B0);
  k_conv3m<2, false><<<512, 256, 0, stream>>>(B0, WH3, WL3, nullptr, B3);
  k_1x1<1, false, true ><<<512, 256, 0, stream>>>(B3, res_d_w2, nullptr, B0, B1);
  k_dec2m<<<1024, 256, 0, stream>>>(B1, WH4, WL4, dec_b2, B4);
  k_dec3<<<2048, 256, 0, stream>>>(B4, dec_w3, dec_b3, out);
  k_loss<<<1, 256, 0, stream>>>(PART, out);
}

// Round 9
// 938.260 us; speedup vs baseline: 4.5037x; 1.1297x over previous
//
#include <hip/hip_runtime.h>

// ---------------------------------------------------------------------------
// VQ-VAE forward.  N=128.  MFMA (split-bf16 hi/lo, 3-term) for the four
// 3x3 64->64 convs, dec2 (up2x + 3x3 64->32), enc2 (4x4 s2 32->64), and
// the VQ distance GEMM.  f32 VALU elsewhere.
//   x*y ~= xh*yh + xh*yl + xl*yh   (f32 MFMA accumulate)
// ---------------------------------------------------------------------------

template<int ACT> __device__ __forceinline__ float actf(float x){
  if (ACT == 1) return x > 0.f ? x : 0.01f * x;   // leaky relu, slope .01
  if (ACT == 2) return fmaxf(x, 0.f);             // relu
  return x;
}

typedef __bf16 bf16x8 __attribute__((ext_vector_type(8)));
typedef float f32x16 __attribute__((ext_vector_type(16)));
typedef unsigned int u32x4v __attribute__((ext_vector_type(4)));

__device__ __forceinline__ unsigned f2bf(unsigned u){   // RTNE f32->bf16 bits
  return (u + 0x7fffu + ((u >> 16) & 1u)) >> 16;
}

// ---------------- weight prep: f32 [64co][64ci][3][3] -> hi/lo bf16 --------
__global__ __launch_bounds__(256) void k_wprep(
    const float* __restrict__ w, unsigned short* __restrict__ wh,
    unsigned short* __restrict__ wl) {
  int i = blockIdx.x * 256 + threadIdx.x;           // 36864 = 4g*9tap*2*32*16
  if (i >= 36864) return;
  int ci16 = i & 15, co = (i >> 4) & 31, cot = (i >> 9) & 1;
  int rest = i >> 10, tap = rest % 9, g = rest / 9;
  float v = w[(cot * 32 + co) * 576 + (g * 16 + ci16) * 9 + tap];
  unsigned hi = f2bf(__float_as_uint(v));
  float lf = v - __uint_as_float(hi << 16);
  unsigned lo = f2bf(__float_as_uint(lf));
  wh[i] = (unsigned short)hi;
  wl[i] = (unsigned short)lo;
}

// ---------------- weight prep for dec2: f32 [32co][64ci][3][3] -------------
__global__ __launch_bounds__(256) void k_wprep2(
    const float* __restrict__ w, unsigned short* __restrict__ wh,
    unsigned short* __restrict__ wl) {
  int i = blockIdx.x * 256 + threadIdx.x;           // 18432 = 4g*9tap*32*16
  if (i >= 18432) return;
  int ci16 = i & 15, co = (i >> 4) & 31;
  int rest = i >> 9, tap = rest % 9, g = rest / 9;
  float v = w[co * 576 + (g * 16 + ci16) * 9 + tap];
  unsigned hi = f2bf(__float_as_uint(v));
  float lf = v - __uint_as_float(hi << 16);
  unsigned lo = f2bf(__float_as_uint(lf));
  wh[i] = (unsigned short)hi;
  wl[i] = (unsigned short)lo;
}

// ---------------- weight prep for enc2: f32 [64co][32ci][4][4] -------------
__global__ __launch_bounds__(256) void k_wprep_e2(
    const float* __restrict__ w, unsigned short* __restrict__ wh,
    unsigned short* __restrict__ wl) {
  int i = blockIdx.x * 256 + threadIdx.x;           // 32768 = 2g*16tap*2*32*16
  if (i >= 32768) return;
  int ci16 = i & 15, co = (i >> 4) & 31, cot = (i >> 9) & 1;
  int rest = i >> 10, tap = rest & 15, g = rest >> 4;
  float v = w[(cot * 32 + co) * 512 + (g * 16 + ci16) * 16 + tap];
  unsigned hi = f2bf(__float_as_uint(v));
  float lf = v - __uint_as_float(hi << 16);
  unsigned lo = f2bf(__float_as_uint(lf));
  wh[i] = (unsigned short)hi;
  wl[i] = (unsigned short)lo;
}

// ---------------- codebook prep for VQ MFMA: fragment-ordered hi/lo --------
// ushort idx = ((ct*4+s)*32+cc)*16 + ci16; code=ct*32+cc, k=s*16+ci16
__global__ __launch_bounds__(256) void k_cbprep_m(
    const float* __restrict__ cb, unsigned short* __restrict__ ch,
    unsigned short* __restrict__ cl_) {
  int i = blockIdx.x * 256 + threadIdx.x;           // 32768 = 16ct*4s*32*16
  if (i >= 32768) return;
  int ci16 = i & 15, cc = (i >> 4) & 31, ct4s = i >> 9;
  int s = ct4s & 3, ct = ct4s >> 2;
  float v = cb[(ct * 32 + cc) * 64 + s * 16 + ci16];
  unsigned hi = f2bf(__float_as_uint(v));
  float lf = v - __uint_as_float(hi << 16);
  unsigned lo = f2bf(__float_as_uint(lf));
  ch[i] = (unsigned short)hi;
  cl_[i] = (unsigned short)lo;
}

// ---------------- codebook squared norms -----------------------------------
__global__ __launch_bounds__(256) void k_cbnorm(const float* __restrict__ cb,
                                                float* __restrict__ nrm) {
  int c = blockIdx.x * 256 + threadIdx.x;
  if (c < 512) {
    float s = 0.f;
    for (int k = 0; k < 64; ++k) { float v = cb[c * 64 + k]; s = fmaf(v, v, s); }
    nrm[c] = s;
  }
}

// ---------------- 3x3 64->64 stride1 pad1 @32x32 via MFMA ------------------
template<int ACT, bool BIAS>
__global__ __launch_bounds__(256, 2) void k_conv3m(
    const float* __restrict__ in, const unsigned short* __restrict__ wh,
    const unsigned short* __restrict__ wl, const float* __restrict__ bias,
    float* __restrict__ out) {
  int n = blockIdx.x >> 2, y0 = (blockIdx.x & 3) * 8;
  int t = threadIdx.x;
  int lane = t & 63, wv = t >> 6;
  int cot = wv & 1, rgroup = wv >> 1;
  int cc = lane & 31, h = lane >> 5;

  __shared__ __align__(16) unsigned int s_x[6800];   // [10 r][34 c][pad 20 ci]

  const uint4* wh4 = reinterpret_cast<const uint4*>(wh);
  const uint4* wl4 = reinterpret_cast<const uint4*>(wl);

  f32x16 acc[4];
#pragma unroll
  for (int r = 0; r < 4; ++r)
#pragma unroll
    for (int j = 0; j < 16; ++j) acc[r][j] = 0.f;

  for (int g = 0; g < 4; ++g) {
    if (g) __syncthreads();
    for (int i = t; i < 5440; i += 256) {
      int c = i % 34; int rem = i / 34; int r = rem % 10; int ci = rem / 10;
      int row = y0 - 1 + r, col = c - 1;
      float v = 0.f;
      if ((unsigned)row < 32u && (unsigned)col < 32u)
        v = in[(n * 64 + g * 16 + ci) * 1024 + row * 32 + col];
      unsigned hi = f2bf(__float_as_uint(v));
      float lf = v - __uint_as_float(hi << 16);
      unsigned lo = f2bf(__float_as_uint(lf));
      s_x[(r * 34 + c) * 20 + ci] = hi | (lo << 16);
    }
    __syncthreads();

#pragma unroll
    for (int kx = 0; kx < 3; ++kx) {
      bf16x8 Ah[3], Al[3];
#pragma unroll
      for (int ky = 0; ky < 3; ++ky) {
        int wi = ((g * 9 + ky * 3 + kx) * 2 + cot) * 64 + cc * 2 + h;
        Ah[ky] = __builtin_bit_cast(bf16x8, wh4[wi]);
        Al[ky] = __builtin_bit_cast(bf16x8, wl4[wi]);
      }
#pragma unroll
      for (int ir6 = 0; ir6 < 6; ++ir6) {
        int ir = rgroup * 4 + ir6;
        const uint4* xp = reinterpret_cast<const uint4*>(
            &s_x[(ir * 34 + cc + kx) * 20 + (h << 3)]);
        uint4 qa = xp[0], qb = xp[1];
        u32x4v bh, bl;
        bh[0] = (qa.x & 0xffffu) | (qa.y << 16);
        bh[1] = (qa.z & 0xffffu) | (qa.w << 16);
        bh[2] = (qb.x & 0xffffu) | (qb.y << 16);
        bh[3] = (qb.z & 0xffffu) | (qb.w << 16);
        bl[0] = (qa.x >> 16) | (qa.y & 0xffff0000u);
        bl[1] = (qa.z >> 16) | (qa.w & 0xffff0000u);
        bl[2] = (qb.x >> 16) | (qb.y & 0xffff0000u);
        bl[3] = (qb.z >> 16) | (qb.w & 0xffff0000u);
        bf16x8 Bh = __builtin_bit_cast(bf16x8, bh);
        bf16x8 Bl = __builtin_bit_cast(bf16x8, bl);
#pragma unroll
        for (int ky = 0; ky < 3; ++ky) {
          int rr = ir6 - ky;
          if (rr < 0 || rr > 3) continue;
          acc[rr] = __builtin_amdgcn_mfma_f32_32x32x16_bf16(Ah[ky], Bh, acc[rr], 0, 0, 0);
          acc[rr] = __builtin_amdgcn_mfma_f32_32x32x16_bf16(Ah[ky], Bl, acc[rr], 0, 0, 0);
          acc[rr] = __builtin_amdgcn_mfma_f32_32x32x16_bf16(Al[ky], Bh, acc[rr], 0, 0, 0);
        }
      }
    }
  }

  float bvv[16];
#pragma unroll
  for (int reg = 0; reg < 16; ++reg) {
    int row = (reg & 3) + 8 * (reg >> 2) + 4 * h;
    bvv[reg] = BIAS ? bias[cot * 32 + row] : 0.f;
  }
#pragma unroll
  for (int rr = 0; rr < 4; ++rr) {
    int y = y0 + rgroup * 4 + rr;
#pragma unroll
    for (int reg = 0; reg < 16; ++reg) {
      int row = (reg & 3) + 8 * (reg >> 2) + 4 * h;
      int co = cot * 32 + row;
      float v = acc[rr][reg] + bvv[reg];
      out[(n * 64 + co) * 1024 + y * 32 + cc] = actf<ACT>(v);
    }
  }
}

// ---------------- enc2: 32->64, 4x4 s2 p1, 64->32 via MFMA -----------------
__global__ __launch_bounds__(256, 2) void k_enc2m(
    const float* __restrict__ in, const unsigned short* __restrict__ wh,
    const unsigned short* __restrict__ wl, const float* __restrict__ bias,
    float* __restrict__ out) {
  int n = blockIdx.x >> 3, y0 = (blockIdx.x & 7) * 4;
  int t = threadIdx.x;
  int lane = t & 63, wv = t >> 6;
  int cot = wv & 1, rg = wv >> 1;
  int cc = lane & 31, h = lane >> 5;

  __shared__ __align__(16) unsigned int s_x[13200];  // [10][2][33][20]

  const uint4* wh4 = reinterpret_cast<const uint4*>(wh);
  const uint4* wl4 = reinterpret_cast<const uint4*>(wl);

  f32x16 acc[2];
#pragma unroll
  for (int r = 0; r < 2; ++r)
#pragma unroll
    for (int j = 0; j < 16; ++j) acc[r][j] = 0.f;

  for (int g = 0; g < 2; ++g) {
    if (g) __syncthreads();
    for (int i = t; i < 10560; i += 256) {
      int ci = i / 660, rem = i - ci * 660;
      int r = rem / 66, c = rem - r * 66;
      int row = 2 * y0 - 1 + r, icol = c - 1;
      float v = 0.f;
      if ((unsigned)row < 64u && (unsigned)icol < 64u)
        v = in[((n * 32 + g * 16 + ci) * 64 + row) * 64 + icol];
      unsigned hi = f2bf(__float_as_uint(v));
      float lf = v - __uint_as_float(hi << 16);
      unsigned lo = f2bf(__float_as_uint(lf));
      int p = icol & 1;
      int idx = (icol + p) >> 1;
      s_x[((r * 2 + p) * 33 + idx) * 20 + ci] = hi | (lo << 16);
    }
    __syncthreads();

#pragma unroll
    for (int kx = 0; kx < 4; ++kx) {
      bf16x8 Ah[4], Al[4];
#pragma unroll
      for (int ky = 0; ky < 4; ++ky) {
        int wi = ((g * 16 + ky * 4 + kx) * 2 + cot) * 64 + cc * 2 + h;
        Ah[ky] = __builtin_bit_cast(bf16x8, wh4[wi]);
        Al[ky] = __builtin_bit_cast(bf16x8, wl4[wi]);
      }
      int p = (kx + 1) & 1;
      int idx = cc + (kx >> 1);
#pragma unroll
      for (int ir6 = 0; ir6 < 6; ++ir6) {
        int r = rg * 4 + ir6;
        const uint4* xp = reinterpret_cast<const uint4*>(
            &s_x[((r * 2 + p) * 33 + idx) * 20 + (h << 3)]);
        uint4 qa = xp[0], qb = xp[1];
        u32x4v bh, bl;
        bh[0] = (qa.x & 0xffffu) | (qa.y << 16);
        bh[1] = (qa.z & 0xffffu) | (qa.w << 16);
        bh[2] = (qb.x & 0xffffu) | (qb.y << 16);
        bh[3] = (qb.z & 0xffffu) | (qb.w << 16);
        bl[0] = (qa.x >> 16) | (qa.y & 0xffff0000u);
        bl[1] = (qa.z >> 16) | (qa.w & 0xffff0000u);
        bl[2] = (qb.x >> 16) | (qb.y & 0xffff0000u);
        bl[3] = (qb.z >> 16) | (qb.w & 0xffff0000u);
        bf16x8 Bh = __builtin_bit_cast(bf16x8, bh);
        bf16x8 Bl = __builtin_bit_cast(bf16x8, bl);
#pragma unroll
        for (int rr = 0; rr < 2; ++rr) {
          int ky = ir6 - 2 * rr;
          if (ky < 0 || ky > 3) continue;
          acc[rr] = __builtin_amdgcn_mfma_f32_32x32x16_bf16(Ah[ky], Bh, acc[rr], 0, 0, 0);
          acc[rr] = __builtin_amdgcn_mfma_f32_32x32x16_bf16(Ah[ky], Bl, acc[rr], 0, 0, 0);
          acc[rr] = __builtin_amdgcn_mfma_f32_32x32x16_bf16(Al[ky], Bh, acc[rr], 0, 0, 0);
        }
      }
    }
  }

#pragma unroll
  for (int rr = 0; rr < 2; ++rr) {
    int oy = y0 + rg * 2 + rr;
#pragma unroll
    for (int reg = 0; reg < 16; ++reg) {
      int corow = (reg & 3) + 8 * (reg >> 2) + 4 * h;
      int co = cot * 32 + corow;
      float v = acc[rr][reg] + bias[co];
      out[(n * 64 + co) * 1024 + oy * 32 + cc] = actf<1>(v);
    }
  }
}

// ---------------- VQ via MFMA: dist GEMM + argmin + q + loss ---------------
// block: 64 positions.  A = codebook (M=32 codes/tile), B = lat (N=32 pos).
// Wave wv covers code-tiles wv*4..wv*4+3; per lane: 2 pos (pt*32+cc).
__global__ __launch_bounds__(256, 2) void k_vq2m(
    const float* __restrict__ lat, const unsigned short* __restrict__ cbh,
    const unsigned short* __restrict__ cbl, const float* __restrict__ cb,
    const float* __restrict__ nrm, float* __restrict__ q,
    double* __restrict__ part) {
  int bid = blockIdx.x;                  // 2048 = 128 n x 16 s-tiles
  int n = bid >> 4, s0 = (bid & 15) << 6;
  int t = threadIdx.x;
  int lane = t & 63, wv = t >> 6;
  int cc = lane & 31, h = lane >> 5;

  __shared__ __align__(16) unsigned int s_pk[5120];   // [4 s][64 pos][pad 20]
  __shared__ float s_lat_f[4096];                     // [k][pos]
  __shared__ float s_nrm[512];
  __shared__ float s_rd[512];                         // [pos][8 slots]
  __shared__ int   s_ri[512];
  __shared__ int   s_sel[64];
  __shared__ double s_r[256];

  for (int i = t; i < 4096; i += 256) {
    int pos = i & 63, k = i >> 6;
    float v = lat[(n * 64 + k) * 1024 + s0 + pos];
    s_lat_f[k * 64 + pos] = v;
    unsigned hi = f2bf(__float_as_uint(v));
    float lf = v - __uint_as_float(hi << 16);
    unsigned lo = f2bf(__float_as_uint(lf));
    s_pk[(((k >> 4) * 64) + pos) * 20 + (k & 15)] = hi | (lo << 16);
  }
  for (int i = t; i < 512; i += 256) s_nrm[i] = nrm[i];
  __syncthreads();

  const uint4* ah4 = reinterpret_cast<const uint4*>(cbh);
  const uint4* al4 = reinterpret_cast<const uint4*>(cbl);

  float best[2] = {3.4e38f, 3.4e38f};
  int bidx[2] = {0, 0};

#pragma unroll
  for (int ip = 0; ip < 2; ++ip) {
    f32x16 acc[2][2];
#pragma unroll
    for (int a = 0; a < 2; ++a)
#pragma unroll
      for (int b = 0; b < 2; ++b)
#pragma unroll
        for (int j = 0; j < 16; ++j) acc[a][b][j] = 0.f;

#pragma unroll
    for (int s = 0; s < 4; ++s) {
      bf16x8 Bh[2], Bl[2];
#pragma unroll
      for (int pt = 0; pt < 2; ++pt) {
        const uint4* xp = reinterpret_cast<const uint4*>(
            &s_pk[((s * 64) + pt * 32 + cc) * 20 + (h << 3)]);
        uint4 qa = xp[0], qb = xp[1];
        u32x4v bh, bl;
        bh[0] = (qa.x & 0xffffu) | (qa.y << 16);
        bh[1] = (qa.z & 0xffffu) | (qa.w << 16);
        bh[2] = (qb.x & 0xffffu) | (qb.y << 16);
        bh[3] = (qb.z & 0xffffu) | (qb.w << 16);
        bl[0] = (qa.x >> 16) | (qa.y & 0xffff0000u);
        bl[1] = (qa.z >> 16) | (qa.w & 0xffff0000u);
        bl[2] = (qb.x >> 16) | (qb.y & 0xffff0000u);
        bl[3] = (qb.z >> 16) | (qb.w & 0xffff0000u);
        Bh[pt] = __builtin_bit_cast(bf16x8, bh);
        Bl[pt] = __builtin_bit_cast(bf16x8, bl);
      }
#pragma unroll
      for (int it2 = 0; it2 < 2; ++it2) {
        int ct = wv * 4 + ip * 2 + it2;
        int wi = (ct * 4 + s) * 64 + cc * 2 + h;
        bf16x8 Ah = __builtin_bit_cast(bf16x8, ah4[wi]);
        bf16x8 Al = __builtin_bit_cast(bf16x8, al4[wi]);
#pragma unroll
        for (int pt = 0; pt < 2; ++pt) {
          acc[it2][pt] = __builtin_amdgcn_mfma_f32_32x32x16_bf16(Ah, Bh[pt], acc[it2][pt], 0, 0, 0);
          acc[it2][pt] = __builtin_amdgcn_mfma_f32_32x32x16_bf16(Ah, Bl[pt], acc[it2][pt], 0, 0, 0);
          acc[it2][pt] = __builtin_amdgcn_mfma_f32_32x32x16_bf16(Al, Bh[pt], acc[it2][pt], 0, 0, 0);
        }
      }
    }

    // fold argmin (tie-break: lowest code index)
#pragma unroll
    for (int it2 = 0; it2 < 2; ++it2) {
      int ct = wv * 4 + ip * 2 + it2;
#pragma unroll
      for (int pt = 0; pt < 2; ++pt) {
#pragma unroll
        for (int reg = 0; reg < 16; ++reg) {
          int code = ct * 32 + (reg & 3) + 8 * (reg >> 2) + 4 * h;
          float d = fmaf(-2.f, acc[it2][pt][reg], s_nrm[code]);
          if (d < best[pt] || (d == best[pt] && code < bidx[pt])) {
            best[pt] = d; bidx[pt] = code;
          }
        }
      }
    }
  }

  // per-pos reduction over 8 slots (4 waves x 2 h)
#pragma unroll
  for (int pt = 0; pt < 2; ++pt) {
    int pos = pt * 32 + cc;
    s_rd[pos * 8 + wv * 2 + h] = best[pt];
    s_ri[pos * 8 + wv * 2 + h] = bidx[pt];
  }
  __syncthreads();
  if (t < 64) {
    float bd = s_rd[t * 8]; int bi = s_ri[t * 8];
#pragma unroll
    for (int m = 1; m < 8; ++m) {
      float d = s_rd[t * 8 + m]; int ii = s_ri[t * 8 + m];
      if (d < bd || (d == bd && ii < bi)) { bd = d; bi = ii; }
    }
    s_sel[t] = bi;
  }
  __syncthreads();

  int pos = t & 63, dg = t >> 6;
  int bsel = s_sel[pos];
  const float* cw = cb + bsel * 64 + dg * 16;
  float psum = 0.f;
#pragma unroll
  for (int kk = 0; kk < 16; ++kk) {
    int k = dg * 16 + kk;
    float cv = cw[kk];
    float l = s_lat_f[k * 64 + pos];
    float df = cv - l;
    psum = fmaf(df, df, psum);
    q[(n * 64 + k) * 1024 + s0 + pos] = cv;
  }
  s_r[t] = (double)psum;
  __syncthreads();
  for (int str = 128; str > 0; str >>= 1) {
    if (t < str) s_r[t] += s_r[t + str];
    __syncthreads();
  }
  if (t == 0) part[bid] = s_r[0];
}

// ---------------- dec2: up2x(ac) + 3x3 64->32 + lrelu, via MFMA ------------
__global__ __launch_bounds__(256, 2) void k_dec2m(
    const float* __restrict__ in, const unsigned short* __restrict__ wh,
    const unsigned short* __restrict__ wl, const float* __restrict__ bias,
    float* __restrict__ out) {
  int n = blockIdx.x >> 3, y0 = (blockIdx.x & 7) * 8;
  int t = threadIdx.x;
  int lane = t & 63, wv = t >> 6;
  int xh = wv & 1, rg = wv >> 1;
  int cc = lane & 31, h = lane >> 5;

  __shared__ __align__(16) unsigned int s_x[10 * 66 * 20];  // packed up-tile
  __shared__ float s_src[16 * 8 * 33];                      // [ci][r][c]
  __shared__ float s_wy[10], s_my[10];
  __shared__ int   s_ry0[10], s_ry1[10];
  __shared__ float s_wx[66], s_mx[66];
  __shared__ int   s_rx0[66], s_rx1[66];

  const float sc = 31.0f / 63.0f;
  int r0 = (y0 == 0) ? 0 : (int)floorf((float)(y0 - 1) * sc);

  if (t < 10) {
    int uy = y0 - 1 + t;
    int uyc = min(max(uy, 0), 63);
    float sy = (float)uyc * sc;
    int iy0 = (int)floorf(sy);
    s_wy[t] = sy - (float)iy0;
    s_my[t] = ((unsigned)uy < 64u) ? 1.f : 0.f;
    s_ry0[t] = iy0 - r0;
    s_ry1[t] = min(iy0 + 1, 31) - r0;
  }
  int xc = t - 64;
  if (xc >= 0 && xc < 66) {
    int ux = xc - 1;
    int uxc = min(max(ux, 0), 63);
    float sx = (float)uxc * sc;
    int ix0 = (int)floorf(sx);
    s_wx[xc] = sx - (float)ix0;
    s_mx[xc] = ((unsigned)ux < 64u) ? 1.f : 0.f;
    s_rx0[xc] = ix0;
    s_rx1[xc] = min(ix0 + 1, 31);
  }

  const uint4* wh4 = reinterpret_cast<const uint4*>(wh);
  const uint4* wl4 = reinterpret_cast<const uint4*>(wl);

  f32x16 acc[4];
#pragma unroll
  for (int r = 0; r < 4; ++r)
#pragma unroll
    for (int j = 0; j < 16; ++j) acc[r][j] = 0.f;

  for (int i = t; i < 4096; i += 256) {
    int ci = i >> 8, rem = i & 255;
    int r = rem >> 5, c = rem & 31;
    int row = r0 + r;
    s_src[ci * 264 + r * 33 + c] =
        (row < 32) ? in[(n * 64 + ci) * 1024 + row * 32 + c] : 0.f;
  }
  __syncthreads();

  for (int g = 0; g < 4; ++g) {
    for (int i = t; i < 10560; i += 256) {            // 16ci x 10u x 66c
      int ci = i / 660, rem = i - ci * 660;
      int u = rem / 66, c = rem - u * 66;
      const float* sp = &s_src[ci * 264];
      int ry0 = s_ry0[u], ry1 = s_ry1[u];
      int rx0 = s_rx0[c], rx1 = s_rx1[c];
      float wy = s_wy[u], wx = s_wx[c];
      float m = s_my[u] * s_mx[c];
      float a00 = sp[ry0 * 33 + rx0], a01 = sp[ry0 * 33 + rx1];
      float a10 = sp[ry1 * 33 + rx0], a11 = sp[ry1 * 33 + rx1];
      float h0 = fmaf(a10 - a00, wy, a00);
      float h1 = fmaf(a11 - a01, wy, a01);
      float v = m * fmaf(h1 - h0, wx, h0);
      unsigned hi = f2bf(__float_as_uint(v));
      float lf = v - __uint_as_float(hi << 16);
      unsigned lo = f2bf(__float_as_uint(lf));
      s_x[(u * 66 + c) * 20 + ci] = hi | (lo << 16);
    }
    __syncthreads();

    if (g < 3) {
      int ci0 = (g + 1) * 16;
      for (int i = t; i < 4096; i += 256) {
        int ci = i >> 8, rem = i & 255;
        int r = rem >> 5, c = rem & 31;
        int row = r0 + r;
        s_src[ci * 264 + r * 33 + c] =
            (row < 32) ? in[(n * 64 + ci0 + ci) * 1024 + row * 32 + c] : 0.f;
      }
    }

#pragma unroll
    for (int kx = 0; kx < 3; ++kx) {
      bf16x8 Ah[3], Al[3];
#pragma unroll
      for (int ky = 0; ky < 3; ++ky) {
        int wi = (g * 9 + ky * 3 + kx) * 64 + cc * 2 + h;
        Ah[ky] = __builtin_bit_cast(bf16x8, wh4[wi]);
        Al[ky] = __builtin_bit_cast(bf16x8, wl4[wi]);
      }
#pragma unroll
      for (int u6 = 0; u6 < 6; ++u6) {
        int u = rg * 4 + u6;
        const uint4* xp = reinterpret_cast<const uint4*>(
            &s_x[(u * 66 + xh * 32 + cc + kx) * 20 + (h << 3)]);
        uint4 qa = xp[0], qb = xp[1];
        u32x4v bh, bl;
        bh[0] = (qa.x & 0xffffu) | (qa.y << 16);
        bh[1] = (qa.z & 0xffffu) | (qa.w << 16);
        bh[2] = (qb.x & 0xffffu) | (qb.y << 16);
        bh[3] = (qb.z & 0xffffu) | (qb.w << 16);
        bl[0] = (qa.x >> 16) | (qa.y & 0xffff0000u);
        bl[1] = (qa.z >> 16) | (qa.w & 0xffff0000u);
        bl[2] = (qb.x >> 16) | (qb.y & 0xffff0000u);
        bl[3] = (qb.z >> 16) | (qb.w & 0xffff0000u);
        bf16x8 Bh = __builtin_bit_cast(bf16x8, bh);
        bf16x8 Bl = __builtin_bit_cast(bf16x8, bl);
#pragma unroll
        for (int ky = 0; ky < 3; ++ky) {
          int rr = u6 - ky;
          if (rr < 0 || rr > 3) continue;
          acc[rr] = __builtin_amdgcn_mfma_f32_32x32x16_bf16(Ah[ky], Bh, acc[rr], 0, 0, 0);
          acc[rr] = __builtin_amdgcn_mfma_f32_32x32x16_bf16(Ah[ky], Bl, acc[rr], 0, 0, 0);
          acc[rr] = __builtin_amdgcn_mfma_f32_32x32x16_bf16(Al[ky], Bh, acc[rr], 0, 0, 0);
        }
      }
    }
    __syncthreads();
  }

  float bvv[16];
#pragma unroll
  for (int reg = 0; reg < 16; ++reg) {
    int co = (reg & 3) + 8 * (reg >> 2) + 4 * h;
    bvv[reg] = bias[co];
  }
#pragma unroll
  for (int rr = 0; rr < 4; ++rr) {
    int y = y0 + rg * 4 + rr;
#pragma unroll
    for (int reg = 0; reg < 16; ++reg) {
      int co = (reg & 3) + 8 * (reg >> 2) + 4 * h;
      float v = acc[rr][reg] + bvv[reg];
      out[(n * 32 + co) * 4096 + y * 64 + xh * 32 + cc] = actf<1>(v);
    }
  }
}

// ---------------- enc1: 1->32, 4x4 stride2 pad1, 128->64, lrelu ------------
__global__ __launch_bounds__(256) void k_enc1(
    const float* __restrict__ in, const float* __restrict__ w,
    const float* __restrict__ b, float* __restrict__ out) {
  int idx = blockIdx.x * 256 + threadIdx.x;        // [128,32,64,64]
  int ox = idx & 63, oy = (idx >> 6) & 63, co = (idx >> 12) & 31, n = idx >> 17;
  const float* ip = in + n * 16384;
  const float* wp = w + co * 16;
  float acc = b[co];
  int iy0 = 2 * oy - 1, ix0 = 2 * ox - 1;
#pragma unroll
  for (int ky = 0; ky < 4; ++ky) {
    int iy = iy0 + ky;
    if ((unsigned)iy >= 128u) continue;
#pragma unroll
    for (int kx = 0; kx < 4; ++kx) {
      int ix = ix0 + kx;
      if ((unsigned)ix >= 128u) continue;
      acc = fmaf(ip[iy * 128 + ix], wp[ky * 4 + kx], acc);
    }
  }
  out[idx] = actf<1>(acc);
}

// ---------------- 1x1 64->64 (channel matmul), opt bias / add --------------
template<int ACT, bool BIAS, bool ADD>
__global__ __launch_bounds__(256) void k_1x1(
    const float* __restrict__ in, const float* __restrict__ w,
    const float* __restrict__ bias, const float* __restrict__ add,
    float* __restrict__ out) {
  int bid = blockIdx.x;
  int n = bid >> 2;
  int s = ((bid & 3) << 8) + threadIdx.x;
  __shared__ float s_w[4096];
  for (int i = threadIdx.x; i < 4096; i += 256) s_w[i] = w[i];
  __syncthreads();
  float x[64];
#pragma unroll
  for (int ci = 0; ci < 64; ++ci) x[ci] = in[(n * 64 + ci) * 1024 + s];
  for (int co = 0; co < 64; ++co) {
    float acc = BIAS ? bias[co] : 0.f;
    const float* wr = &s_w[co * 64];
#pragma unroll
    for (int ci = 0; ci < 64; ++ci) acc = fmaf(wr[ci], x[ci], acc);
    if (ADD) acc += add[(n * 64 + co) * 1024 + s];
    out[(n * 64 + co) * 1024 + s] = actf<ACT>(acc);
  }
}

// ---------------- loss finalize --------------------------------------------
__global__ __launch_bounds__(256) void k_loss(const double* __restrict__ part,
                                              float* __restrict__ out) {
  __shared__ double s[256];
  int t = threadIdx.x;
  double acc = 0.0;
  for (int i = t; i < 2048; i += 256) acc += part[i];
  s[t] = acc;
  __syncthreads();
  for (int str = 128; str > 0; str >>= 1) {
    if (t < str) s[t] += s[t + str];
    __syncthreads();
  }
  if (t == 0) {
    double mean = s[0] / 8388608.0;
    out[2097152] = (float)mean;
    out[2097153] = (float)(0.25 * mean);
  }
}

// ---------------- dec3: fused upsample2x(ac) + 3x3 32->1 + relu ------------
__global__ __launch_bounds__(256) void k_dec3(
    const float* __restrict__ in, const float* __restrict__ w,
    const float* __restrict__ bias, float* __restrict__ out) {
  int bid = blockIdx.x;                  // 2048 = 128n * 8yT * 2xT
  int n = bid >> 4, yT = (bid >> 1) & 7, xT = bid & 1;
  int y0 = yT * 16, x0 = xT * 64;
  int t = threadIdx.x;
  int ty = t >> 4, xq = t & 15;

  __shared__ float s_up[4 * 18 * 68];
  __shared__ float s_src[4 * 11 * 35];
  __shared__ float s_w[288];
  __shared__ float s_wy[18], s_my[18];
  __shared__ int   s_ry0[18], s_ry1[18];
  __shared__ float s_wx[66], s_mx[66];
  __shared__ int   s_rx0[66], s_rx1[66];

  const float sc = 63.0f / 127.0f;
  int r0 = (y0 == 0) ? 0 : (int)floorf((float)(y0 - 1) * sc);
  int c0 = (x0 == 0) ? 0 : (int)floorf((float)(x0 - 1) * sc);

  if (t < 18) {
    int uy = y0 - 1 + t;
    int uyc = min(max(uy, 0), 127);
    float sy = (float)uyc * sc;
    int iy0 = (int)floorf(sy);
    s_wy[t] = sy - (float)iy0;
    s_my[t] = ((unsigned)uy < 128u) ? 1.f : 0.f;
    s_ry0[t] = iy0 - r0;
    s_ry1[t] = min(iy0 + 1, 63) - r0;
  }
  int xc = t - 64;
  if (xc >= 0 && xc < 66) {
    int ux = x0 - 1 + xc;
    int uxc = min(max(ux, 0), 127);
    float sx = (float)uxc * sc;
    int ix0 = (int)floorf(sx);
    s_wx[xc] = sx - (float)ix0;
    s_mx[xc] = ((unsigned)ux < 128u) ? 1.f : 0.f;
    s_rx0[xc] = ix0 - c0;
    s_rx1[xc] = min(ix0 + 1, 63) - c0;
  }
  for (int i = t; i < 288; i += 256) s_w[i] = w[i];

  float acc[4] = {0.f, 0.f, 0.f, 0.f};

  for (int i = t; i < 4 * 11 * 35; i += 256) {
    int ci = i / 385, rem = i - ci * 385;
    int rr = rem / 35, cx = rem - rr * 35;
    int row = r0 + rr, col = c0 + cx;
    s_src[(ci * 11 + rr) * 35 + cx] =
        (row < 64 && col < 64) ? in[((n * 32 + ci) * 64 + row) * 64 + col] : 0.f;
  }
  __syncthreads();

  for (int g = 0; g < 8; ++g) {
    for (int i = t; i < 4 * 18 * 66; i += 256) {
      int ci = i / 1188, rem = i - ci * 1188;
      int uu = rem / 66, ccx = rem - uu * 66;
      const float* sp = &s_src[ci * 385];
      int ry0 = s_ry0[uu], ry1 = s_ry1[uu];
      int rx0 = s_rx0[ccx], rx1 = s_rx1[ccx];
      float wy = s_wy[uu], wx = s_wx[ccx];
      float m = s_my[uu] * s_mx[ccx];
      float a00 = sp[ry0 * 35 + rx0], a01 = sp[ry0 * 35 + rx1];
      float a10 = sp[ry1 * 35 + rx0], a11 = sp[ry1 * 35 + rx1];
      float h0 = fmaf(a10 - a00, wy, a00);
      float h1 = fmaf(a11 - a01, wy, a01);
      s_up[(ci * 18 + uu) * 68 + ccx] = m * fmaf(h1 - h0, wx, h0);
    }
    __syncthreads();

    if (g < 7) {
      int ci0 = (g + 1) * 4;
      for (int i = t; i < 4 * 11 * 35; i += 256) {
        int ci = i / 385, rem = i - ci * 385;
        int rr = rem / 35, cx = rem - rr * 35;
        int row = r0 + rr, col = c0 + cx;
        s_src[(ci * 11 + rr) * 35 + cx] =
            (row < 64 && col < 64)
                ? in[((n * 32 + ci0 + ci) * 64 + row) * 64 + col] : 0.f;
      }
    }

    int ci0 = g * 4;
    for (int ci = 0; ci < 4; ++ci) {
#pragma unroll
      for (int ky = 0; ky < 3; ++ky) {
        int base = (ci * 18 + ty + ky) * 68 + xq * 4;
        float4 q0 = *reinterpret_cast<const float4*>(&s_up[base]);
        float4 q1 = *reinterpret_cast<const float4*>(&s_up[base + 4]);
        float rv[8] = {q0.x, q0.y, q0.z, q0.w, q1.x, q1.y, q1.z, q1.w};
#pragma unroll
        for (int kx = 0; kx < 3; ++kx) {
          float wv = s_w[(ci0 + ci) * 9 + ky * 3 + kx];
#pragma unroll
          for (int xx = 0; xx < 4; ++xx)
            acc[xx] = fmaf(rv[xx + kx], wv, acc[xx]);
        }
      }
    }
    __syncthreads();
  }
  float bv = bias[0];
  int base = n * 16384 + (y0 + ty) * 128 + x0 + xq * 4;
  *reinterpret_cast<float4*>(&out[base]) =
      make_float4(actf<2>(acc[0] + bv), actf<2>(acc[1] + bv),
                  actf<2>(acc[2] + bv), actf<2>(acc[3] + bv));
}

// ---------------------------------------------------------------------------
extern "C" void kernel_launch(void* const* d_in, const int* in_sizes, int n_in,
                              void* d_out, int out_size, void* d_ws, size_t ws_size,
                              hipStream_t stream) {
  (void)in_sizes; (void)n_in; (void)out_size; (void)ws_size;
  const float* x_in     = (const float*)d_in[0];
  const float* enc_w1   = (const float*)d_in[1];
  const float* enc_b1   = (const float*)d_in[2];
  const float* enc_w2   = (const float*)d_in[3];
  const float* enc_b2   = (const float*)d_in[4];
  const float* enc_w3   = (const float*)d_in[5];
  const float* enc_b3   = (const float*)d_in[6];
  const float* res_e_w1 = (const float*)d_in[7];
  const float* res_e_w2 = (const float*)d_in[8];
  const float* enc_w4   = (const float*)d_in[9];
  const float* enc_b4   = (const float*)d_in[10];
  const float* codebook = (const float*)d_in[11];
  const float* dec_w1   = (const float*)d_in[12];
  const float* dec_b1   = (const float*)d_in[13];
  const float* res_d_w1 = (const float*)d_in[14];
  const float* res_d_w2 = (const float*)d_in[15];
  const float* dec_w2   = (const float*)d_in[16];
  const float* dec_b2   = (const float*)d_in[17];
  const float* dec_w3   = (const float*)d_in[18];
  const float* dec_b3   = (const float*)d_in[19];
  float* out = (float*)d_out;

  char* ws = (char*)d_ws;
  float*  B0    = (float*)(ws);                         // 33.55 MB each
  float*  B1    = (float*)(ws + 33554432);
  float*  B2    = (float*)(ws + 67108864);
  float*  B3    = (float*)(ws + 100663296);
  float*  B4    = (float*)(ws + 134217728);             // enc1 out: 67.1 MB
  double* PART  = (double*)(ws + 201326592);
  float*  CNORM = (float*)(ws + 201326592 + 16384);
  // VQ codebook split-bf16 fragments: in B3 region (B3 used post-VQ only)
  unsigned short* CBH = (unsigned short*)(ws + 100663296);
  unsigned short* CBL = CBH + 32768;
  // split-bf16 weight tail region
  unsigned short* WH0 = (unsigned short*)(ws + 201359360);
  unsigned short* WL0 = WH0 + 36864;
  unsigned short* WH1 = (unsigned short*)(ws + 201359360 + 147456);
  unsigned short* WL1 = WH1 + 36864;
  unsigned short* WH2 = (unsigned short*)(ws + 201359360 + 294912);
  unsigned short* WL2 = WH2 + 36864;
  unsigned short* WH3 = (unsigned short*)(ws + 201359360 + 442368);
  unsigned short* WL3 = WH3 + 36864;
  unsigned short* WH4 = (unsigned short*)(ws + 201359360 + 589824);   // dec2
  unsigned short* WL4 = WH4 + 18432;
  unsigned short* WH5 = (unsigned short*)(ws + 201359360 + 663552);   // enc2
  unsigned short* WL5 = WH5 + 32768;

  k_wprep<<<144, 256, 0, stream>>>(enc_w3,   WH0, WL0);
  k_wprep<<<144, 256, 0, stream>>>(res_e_w1, WH1, WL1);
  k_wprep<<<144, 256, 0, stream>>>(dec_w1,   WH2, WL2);
  k_wprep<<<144, 256, 0, stream>>>(res_d_w1, WH3, WL3);
  k_wprep2<<<72, 256, 0, stream>>>(dec_w2,   WH4, WL4);
  k_wprep_e2<<<128, 256, 0, stream>>>(enc_w2, WH5, WL5);
  k_cbprep_m<<<128, 256, 0, stream>>>(codebook, CBH, CBL);
  k_cbnorm<<<2, 256, 0, stream>>>(codebook, CNORM);

  k_enc1<<<65536, 256, 0, stream>>>(x_in, enc_w1, enc_b1, B4);
  k_enc2m<<<1024, 256, 0, stream>>>(B4, WH5, WL5, enc_b2, B0);
  k_conv3m<1, true ><<<512, 256, 0, stream>>>(B0, WH0, WL0, enc_b3, B1);
  k_conv3m<2, false><<<512, 256, 0, stream>>>(B1, WH1, WL1, nullptr, B2);
  k_1x1<1, false, true ><<<512, 256, 0, stream>>>(B2, res_e_w2, nullptr, B1, B0);
  k_1x1<1, true,  false><<<512, 256, 0, stream>>>(B0, enc_w4, enc_b4, nullptr, B1);
  k_vq2m<<<2048, 256, 0, stream>>>(B1, CBH, CBL, codebook, CNORM, B2, PART);
  k_conv3m<1, true ><<<512, 256, 0, stream>>>(B2, WH2, WL2, dec_b1, B0);
  k_conv3m<2, false><<<512, 256, 0, stream>>>(B0, WH3, WL3, nullptr, B3);
  k_1x1<1, false, true ><<<512, 256, 0, stream>>>(B3, res_d_w2, nullptr, B0, B1);
  k_dec2m<<<1024, 256, 0, stream>>>(B1, WH4, WL4, dec_b2, B4);
  k_dec3<<<2048, 256, 0, stream>>>(B4, dec_w3, dec_b3, out);
  k_loss<<<1, 256, 0, stream>>>(PART, out);
}

// Round 10
// 867.904 us; speedup vs baseline: 4.8688x; 1.0811x over previous
//
#include <hip/hip_runtime.h>

// ---------------------------------------------------------------------------
// VQ-VAE forward.  N=128.  MFMA (split-bf16 hi/lo, 3-term) for the four
// 3x3 64->64 convs, dec2 (up2x + 3x3 64->32), enc2 (4x4 s2 32->64), and
// the VQ distance GEMM.  f32 VALU elsewhere.
//   x*y ~= xh*yh + xh*yl + xl*yh   (f32 MFMA accumulate)
// ---------------------------------------------------------------------------

template<int ACT> __device__ __forceinline__ float actf(float x){
  if (ACT == 1) return x > 0.f ? x : 0.01f * x;   // leaky relu, slope .01
  if (ACT == 2) return fmaxf(x, 0.f);             // relu
  return x;
}

typedef __bf16 bf16x8 __attribute__((ext_vector_type(8)));
typedef float f32x16 __attribute__((ext_vector_type(16)));
typedef unsigned int u32x4v __attribute__((ext_vector_type(4)));

__device__ __forceinline__ unsigned f2bf(unsigned u){   // RTNE f32->bf16 bits
  return (u + 0x7fffu + ((u >> 16) & 1u)) >> 16;
}

// ---------------- weight prep: f32 [64co][64ci][3][3] -> hi/lo bf16 --------
__global__ __launch_bounds__(256) void k_wprep(
    const float* __restrict__ w, unsigned short* __restrict__ wh,
    unsigned short* __restrict__ wl) {
  int i = blockIdx.x * 256 + threadIdx.x;           // 36864 = 4g*9tap*2*32*16
  if (i >= 36864) return;
  int ci16 = i & 15, co = (i >> 4) & 31, cot = (i >> 9) & 1;
  int rest = i >> 10, tap = rest % 9, g = rest / 9;
  float v = w[(cot * 32 + co) * 576 + (g * 16 + ci16) * 9 + tap];
  unsigned hi = f2bf(__float_as_uint(v));
  float lf = v - __uint_as_float(hi << 16);
  unsigned lo = f2bf(__float_as_uint(lf));
  wh[i] = (unsigned short)hi;
  wl[i] = (unsigned short)lo;
}

// ---------------- weight prep for dec2: f32 [32co][64ci][3][3] -------------
__global__ __launch_bounds__(256) void k_wprep2(
    const float* __restrict__ w, unsigned short* __restrict__ wh,
    unsigned short* __restrict__ wl) {
  int i = blockIdx.x * 256 + threadIdx.x;           // 18432 = 4g*9tap*32*16
  if (i >= 18432) return;
  int ci16 = i & 15, co = (i >> 4) & 31;
  int rest = i >> 9, tap = rest % 9, g = rest / 9;
  float v = w[co * 576 + (g * 16 + ci16) * 9 + tap];
  unsigned hi = f2bf(__float_as_uint(v));
  float lf = v - __uint_as_float(hi << 16);
  unsigned lo = f2bf(__float_as_uint(lf));
  wh[i] = (unsigned short)hi;
  wl[i] = (unsigned short)lo;
}

// ---------------- weight prep for enc2: f32 [64co][32ci][4][4] -------------
__global__ __launch_bounds__(256) void k_wprep_e2(
    const float* __restrict__ w, unsigned short* __restrict__ wh,
    unsigned short* __restrict__ wl) {
  int i = blockIdx.x * 256 + threadIdx.x;           // 32768 = 2g*16tap*2*32*16
  if (i >= 32768) return;
  int ci16 = i & 15, co = (i >> 4) & 31, cot = (i >> 9) & 1;
  int rest = i >> 10, tap = rest & 15, g = rest >> 4;
  float v = w[(cot * 32 + co) * 512 + (g * 16 + ci16) * 16 + tap];
  unsigned hi = f2bf(__float_as_uint(v));
  float lf = v - __uint_as_float(hi << 16);
  unsigned lo = f2bf(__float_as_uint(lf));
  wh[i] = (unsigned short)hi;
  wl[i] = (unsigned short)lo;
}

// ---------------- codebook prep for VQ MFMA: fragment-ordered hi/lo --------
__global__ __launch_bounds__(256) void k_cbprep_m(
    const float* __restrict__ cb, unsigned short* __restrict__ ch,
    unsigned short* __restrict__ cl_) {
  int i = blockIdx.x * 256 + threadIdx.x;           // 32768 = 16ct*4s*32*16
  if (i >= 32768) return;
  int ci16 = i & 15, cc = (i >> 4) & 31, ct4s = i >> 9;
  int s = ct4s & 3, ct = ct4s >> 2;
  float v = cb[(ct * 32 + cc) * 64 + s * 16 + ci16];
  unsigned hi = f2bf(__float_as_uint(v));
  float lf = v - __uint_as_float(hi << 16);
  unsigned lo = f2bf(__float_as_uint(lf));
  ch[i] = (unsigned short)hi;
  cl_[i] = (unsigned short)lo;
}

// ---------------- codebook squared norms -----------------------------------
__global__ __launch_bounds__(256) void k_cbnorm(const float* __restrict__ cb,
                                                float* __restrict__ nrm) {
  int c = blockIdx.x * 256 + threadIdx.x;
  if (c < 512) {
    float s = 0.f;
    for (int k = 0; k < 64; ++k) { float v = cb[c * 64 + k]; s = fmaf(v, v, s); }
    nrm[c] = s;
  }
}

// ---------------- enc1: 1->32, 4x4 s2 p1, 128->64, lrelu (LDS-staged) ------
// block: (n, 8-row out strip).  Input (1 channel) staged parity-split so
// stride-2 reads become lane-stride-1.  Weights broadcast from LDS.
__global__ __launch_bounds__(256) void k_enc1m(
    const float* __restrict__ in, const float* __restrict__ w,
    const float* __restrict__ b, float* __restrict__ out) {
  int n = blockIdx.x >> 3, y0 = (blockIdx.x & 7) * 8;
  int t = threadIdx.x;
  __shared__ float s_in[18 * 2 * 66];   // [r][parity][col/2], cols -1..128
  __shared__ float s_w[512];
  __shared__ float s_b[32];
  const float* ip = in + n * 16384;
  for (int i = t; i < 18 * 130; i += 256) {
    int r = i / 130, c = i - r * 130;
    int iy = 2 * y0 - 1 + r, ix = c - 1;
    float v = 0.f;
    if ((unsigned)iy < 128u && (unsigned)ix < 128u) v = ip[iy * 128 + ix];
    s_in[(r * 2 + (c & 1)) * 66 + (c >> 1)] = v;
  }
  for (int i = t; i < 512; i += 256) s_w[i] = w[i];
  if (t < 32) s_b[t] = b[t];
  __syncthreads();
  int ox = t & 63, wv = t >> 6;
#pragma unroll
  for (int rr = 0; rr < 2; ++rr) {
    int oyl = wv * 2 + rr;
    float x[16];
#pragma unroll
    for (int ky = 0; ky < 4; ++ky) {
      int r = 2 * oyl + ky;
#pragma unroll
      for (int kx = 0; kx < 4; ++kx) {
        // staged col = 2*ox + kx ; parity = kx&1, idx = ox + (kx>>1)
        x[ky * 4 + kx] = s_in[(r * 2 + (kx & 1)) * 66 + ox + (kx >> 1)];
      }
    }
    int obase = (n * 32) * 4096 + (y0 + oyl) * 64 + ox;
    for (int co = 0; co < 32; ++co) {
      float acc = s_b[co];
      const float* wr = &s_w[co * 16];
#pragma unroll
      for (int k = 0; k < 16; ++k) acc = fmaf(x[k], wr[k], acc);
      out[obase + co * 4096] = actf<1>(acc);
    }
  }
}

// ---------------- 3x3 64->64 stride1 pad1 @32x32 via MFMA ------------------
template<int ACT, bool BIAS>
__global__ __launch_bounds__(256, 2) void k_conv3m(
    const float* __restrict__ in, const unsigned short* __restrict__ wh,
    const unsigned short* __restrict__ wl, const float* __restrict__ bias,
    float* __restrict__ out) {
  int n = blockIdx.x >> 2, y0 = (blockIdx.x & 3) * 8;
  int t = threadIdx.x;
  int lane = t & 63, wv = t >> 6;
  int cot = wv & 1, rgroup = wv >> 1;
  int cc = lane & 31, h = lane >> 5;

  __shared__ __align__(16) unsigned int s_x[6800];   // [10 r][34 c][pad 20 ci]

  const uint4* wh4 = reinterpret_cast<const uint4*>(wh);
  const uint4* wl4 = reinterpret_cast<const uint4*>(wl);

  f32x16 acc[4];
#pragma unroll
  for (int r = 0; r < 4; ++r)
#pragma unroll
    for (int j = 0; j < 16; ++j) acc[r][j] = 0.f;

  for (int g = 0; g < 4; ++g) {
    if (g) __syncthreads();
    for (int i = t; i < 5440; i += 256) {
      int c = i % 34; int rem = i / 34; int r = rem % 10; int ci = rem / 10;
      int row = y0 - 1 + r, col = c - 1;
      float v = 0.f;
      if ((unsigned)row < 32u && (unsigned)col < 32u)
        v = in[(n * 64 + g * 16 + ci) * 1024 + row * 32 + col];
      unsigned hi = f2bf(__float_as_uint(v));
      float lf = v - __uint_as_float(hi << 16);
      unsigned lo = f2bf(__float_as_uint(lf));
      s_x[(r * 34 + c) * 20 + ci] = hi | (lo << 16);
    }
    __syncthreads();

#pragma unroll
    for (int kx = 0; kx < 3; ++kx) {
      bf16x8 Ah[3], Al[3];
#pragma unroll
      for (int ky = 0; ky < 3; ++ky) {
        int wi = ((g * 9 + ky * 3 + kx) * 2 + cot) * 64 + cc * 2 + h;
        Ah[ky] = __builtin_bit_cast(bf16x8, wh4[wi]);
        Al[ky] = __builtin_bit_cast(bf16x8, wl4[wi]);
      }
#pragma unroll
      for (int ir6 = 0; ir6 < 6; ++ir6) {
        int ir = rgroup * 4 + ir6;
        const uint4* xp = reinterpret_cast<const uint4*>(
            &s_x[(ir * 34 + cc + kx) * 20 + (h << 3)]);
        uint4 qa = xp[0], qb = xp[1];
        u32x4v bh, bl;
        bh[0] = (qa.x & 0xffffu) | (qa.y << 16);
        bh[1] = (qa.z & 0xffffu) | (qa.w << 16);
        bh[2] = (qb.x & 0xffffu) | (qb.y << 16);
        bh[3] = (qb.z & 0xffffu) | (qb.w << 16);
        bl[0] = (qa.x >> 16) | (qa.y & 0xffff0000u);
        bl[1] = (qa.z >> 16) | (qa.w & 0xffff0000u);
        bl[2] = (qb.x >> 16) | (qb.y & 0xffff0000u);
        bl[3] = (qb.z >> 16) | (qb.w & 0xffff0000u);
        bf16x8 Bh = __builtin_bit_cast(bf16x8, bh);
        bf16x8 Bl = __builtin_bit_cast(bf16x8, bl);
#pragma unroll
        for (int ky = 0; ky < 3; ++ky) {
          int rr = ir6 - ky;
          if (rr < 0 || rr > 3) continue;
          acc[rr] = __builtin_amdgcn_mfma_f32_32x32x16_bf16(Ah[ky], Bh, acc[rr], 0, 0, 0);
          acc[rr] = __builtin_amdgcn_mfma_f32_32x32x16_bf16(Ah[ky], Bl, acc[rr], 0, 0, 0);
          acc[rr] = __builtin_amdgcn_mfma_f32_32x32x16_bf16(Al[ky], Bh, acc[rr], 0, 0, 0);
        }
      }
    }
  }

  float bvv[16];
#pragma unroll
  for (int reg = 0; reg < 16; ++reg) {
    int row = (reg & 3) + 8 * (reg >> 2) + 4 * h;
    bvv[reg] = BIAS ? bias[cot * 32 + row] : 0.f;
  }
#pragma unroll
  for (int rr = 0; rr < 4; ++rr) {
    int y = y0 + rgroup * 4 + rr;
#pragma unroll
    for (int reg = 0; reg < 16; ++reg) {
      int row = (reg & 3) + 8 * (reg >> 2) + 4 * h;
      int co = cot * 32 + row;
      float v = acc[rr][reg] + bvv[reg];
      out[(n * 64 + co) * 1024 + y * 32 + cc] = actf<ACT>(v);
    }
  }
}

// ---------------- enc2: 32->64, 4x4 s2 p1, 64->32 via MFMA -----------------
__global__ __launch_bounds__(256, 2) void k_enc2m(
    const float* __restrict__ in, const unsigned short* __restrict__ wh,
    const unsigned short* __restrict__ wl, const float* __restrict__ bias,
    float* __restrict__ out) {
  int n = blockIdx.x >> 3, y0 = (blockIdx.x & 7) * 4;
  int t = threadIdx.x;
  int lane = t & 63, wv = t >> 6;
  int cot = wv & 1, rg = wv >> 1;
  int cc = lane & 31, h = lane >> 5;

  __shared__ __align__(16) unsigned int s_x[13200];  // [10][2][33][20]

  const uint4* wh4 = reinterpret_cast<const uint4*>(wh);
  const uint4* wl4 = reinterpret_cast<const uint4*>(wl);

  f32x16 acc[2];
#pragma unroll
  for (int r = 0; r < 2; ++r)
#pragma unroll
    for (int j = 0; j < 16; ++j) acc[r][j] = 0.f;

  for (int g = 0; g < 2; ++g) {
    if (g) __syncthreads();
    for (int i = t; i < 10560; i += 256) {
      int ci = i / 660, rem = i - ci * 660;
      int r = rem / 66, c = rem - r * 66;
      int row = 2 * y0 - 1 + r, icol = c - 1;
      float v = 0.f;
      if ((unsigned)row < 64u && (unsigned)icol < 64u)
        v = in[((n * 32 + g * 16 + ci) * 64 + row) * 64 + icol];
      unsigned hi = f2bf(__float_as_uint(v));
      float lf = v - __uint_as_float(hi << 16);
      unsigned lo = f2bf(__float_as_uint(lf));
      int p = icol & 1;
      int idx = (icol + p) >> 1;
      s_x[((r * 2 + p) * 33 + idx) * 20 + ci] = hi | (lo << 16);
    }
    __syncthreads();

#pragma unroll
    for (int kx = 0; kx < 4; ++kx) {
      bf16x8 Ah[4], Al[4];
#pragma unroll
      for (int ky = 0; ky < 4; ++ky) {
        int wi = ((g * 16 + ky * 4 + kx) * 2 + cot) * 64 + cc * 2 + h;
        Ah[ky] = __builtin_bit_cast(bf16x8, wh4[wi]);
        Al[ky] = __builtin_bit_cast(bf16x8, wl4[wi]);
      }
      int p = (kx + 1) & 1;
      int idx = cc + (kx >> 1);
#pragma unroll
      for (int ir6 = 0; ir6 < 6; ++ir6) {
        int r = rg * 4 + ir6;
        const uint4* xp = reinterpret_cast<const uint4*>(
            &s_x[((r * 2 + p) * 33 + idx) * 20 + (h << 3)]);
        uint4 qa = xp[0], qb = xp[1];
        u32x4v bh, bl;
        bh[0] = (qa.x & 0xffffu) | (qa.y << 16);
        bh[1] = (qa.z & 0xffffu) | (qa.w << 16);
        bh[2] = (qb.x & 0xffffu) | (qb.y << 16);
        bh[3] = (qb.z & 0xffffu) | (qb.w << 16);
        bl[0] = (qa.x >> 16) | (qa.y & 0xffff0000u);
        bl[1] = (qa.z >> 16) | (qa.w & 0xffff0000u);
        bl[2] = (qb.x >> 16) | (qb.y & 0xffff0000u);
        bl[3] = (qb.z >> 16) | (qb.w & 0xffff0000u);
        bf16x8 Bh = __builtin_bit_cast(bf16x8, bh);
        bf16x8 Bl = __builtin_bit_cast(bf16x8, bl);
#pragma unroll
        for (int rr = 0; rr < 2; ++rr) {
          int ky = ir6 - 2 * rr;
          if (ky < 0 || ky > 3) continue;
          acc[rr] = __builtin_amdgcn_mfma_f32_32x32x16_bf16(Ah[ky], Bh, acc[rr], 0, 0, 0);
          acc[rr] = __builtin_amdgcn_mfma_f32_32x32x16_bf16(Ah[ky], Bl, acc[rr], 0, 0, 0);
          acc[rr] = __builtin_amdgcn_mfma_f32_32x32x16_bf16(Al[ky], Bh, acc[rr], 0, 0, 0);
        }
      }
    }
  }

#pragma unroll
  for (int rr = 0; rr < 2; ++rr) {
    int oy = y0 + rg * 2 + rr;
#pragma unroll
    for (int reg = 0; reg < 16; ++reg) {
      int corow = (reg & 3) + 8 * (reg >> 2) + 4 * h;
      int co = cot * 32 + corow;
      float v = acc[rr][reg] + bias[co];
      out[(n * 64 + co) * 1024 + oy * 32 + cc] = actf<1>(v);
    }
  }
}

// ---------------- VQ via MFMA: dist GEMM + argmin + q + loss ---------------
__global__ __launch_bounds__(256, 2) void k_vq2m(
    const float* __restrict__ lat, const unsigned short* __restrict__ cbh,
    const unsigned short* __restrict__ cbl, const float* __restrict__ cb,
    const float* __restrict__ nrm, float* __restrict__ q,
    double* __restrict__ part) {
  int bid = blockIdx.x;                  // 2048 = 128 n x 16 s-tiles
  int n = bid >> 4, s0 = (bid & 15) << 6;
  int t = threadIdx.x;
  int lane = t & 63, wv = t >> 6;
  int cc = lane & 31, h = lane >> 5;

  __shared__ __align__(16) unsigned int s_pk[5120];   // [4 s][64 pos][pad 20]
  __shared__ float s_lat_f[4096];                     // [k][pos]
  __shared__ float s_nrm[512];
  __shared__ float s_rd[512];                         // [pos][8 slots]
  __shared__ int   s_ri[512];
  __shared__ int   s_sel[64];
  __shared__ double s_r[256];

  for (int i = t; i < 4096; i += 256) {
    int pos = i & 63, k = i >> 6;
    float v = lat[(n * 64 + k) * 1024 + s0 + pos];
    s_lat_f[k * 64 + pos] = v;
    unsigned hi = f2bf(__float_as_uint(v));
    float lf = v - __uint_as_float(hi << 16);
    unsigned lo = f2bf(__float_as_uint(lf));
    s_pk[(((k >> 4) * 64) + pos) * 20 + (k & 15)] = hi | (lo << 16);
  }
  for (int i = t; i < 512; i += 256) s_nrm[i] = nrm[i];
  __syncthreads();

  const uint4* ah4 = reinterpret_cast<const uint4*>(cbh);
  const uint4* al4 = reinterpret_cast<const uint4*>(cbl);

  float best[2] = {3.4e38f, 3.4e38f};
  int bidx[2] = {0, 0};

#pragma unroll
  for (int ip = 0; ip < 2; ++ip) {
    f32x16 acc[2][2];
#pragma unroll
    for (int a = 0; a < 2; ++a)
#pragma unroll
      for (int b = 0; b < 2; ++b)
#pragma unroll
        for (int j = 0; j < 16; ++j) acc[a][b][j] = 0.f;

#pragma unroll
    for (int s = 0; s < 4; ++s) {
      bf16x8 Bh[2], Bl[2];
#pragma unroll
      for (int pt = 0; pt < 2; ++pt) {
        const uint4* xp = reinterpret_cast<const uint4*>(
            &s_pk[((s * 64) + pt * 32 + cc) * 20 + (h << 3)]);
        uint4 qa = xp[0], qb = xp[1];
        u32x4v bh, bl;
        bh[0] = (qa.x & 0xffffu) | (qa.y << 16);
        bh[1] = (qa.z & 0xffffu) | (qa.w << 16);
        bh[2] = (qb.x & 0xffffu) | (qb.y << 16);
        bh[3] = (qb.z & 0xffffu) | (qb.w << 16);
        bl[0] = (qa.x >> 16) | (qa.y & 0xffff0000u);
        bl[1] = (qa.z >> 16) | (qa.w & 0xffff0000u);
        bl[2] = (qb.x >> 16) | (qb.y & 0xffff0000u);
        bl[3] = (qb.z >> 16) | (qb.w & 0xffff0000u);
        Bh[pt] = __builtin_bit_cast(bf16x8, bh);
        Bl[pt] = __builtin_bit_cast(bf16x8, bl);
      }
#pragma unroll
      for (int it2 = 0; it2 < 2; ++it2) {
        int ct = wv * 4 + ip * 2 + it2;
        int wi = (ct * 4 + s) * 64 + cc * 2 + h;
        bf16x8 Ah = __builtin_bit_cast(bf16x8, ah4[wi]);
        bf16x8 Al = __builtin_bit_cast(bf16x8, al4[wi]);
#pragma unroll
        for (int pt = 0; pt < 2; ++pt) {
          acc[it2][pt] = __builtin_amdgcn_mfma_f32_32x32x16_bf16(Ah, Bh[pt], acc[it2][pt], 0, 0, 0);
          acc[it2][pt] = __builtin_amdgcn_mfma_f32_32x32x16_bf16(Ah, Bl[pt], acc[it2][pt], 0, 0, 0);
          acc[it2][pt] = __builtin_amdgcn_mfma_f32_32x32x16_bf16(Al, Bh[pt], acc[it2][pt], 0, 0, 0);
        }
      }
    }

#pragma unroll
    for (int it2 = 0; it2 < 2; ++it2) {
      int ct = wv * 4 + ip * 2 + it2;
#pragma unroll
      for (int pt = 0; pt < 2; ++pt) {
#pragma unroll
        for (int reg = 0; reg < 16; ++reg) {
          int code = ct * 32 + (reg & 3) + 8 * (reg >> 2) + 4 * h;
          float d = fmaf(-2.f, acc[it2][pt][reg], s_nrm[code]);
          if (d < best[pt] || (d == best[pt] && code < bidx[pt])) {
            best[pt] = d; bidx[pt] = code;
          }
        }
      }
    }
  }

#pragma unroll
  for (int pt = 0; pt < 2; ++pt) {
    int pos = pt * 32 + cc;
    s_rd[pos * 8 + wv * 2 + h] = best[pt];
    s_ri[pos * 8 + wv * 2 + h] = bidx[pt];
  }
  __syncthreads();
  if (t < 64) {
    float bd = s_rd[t * 8]; int bi = s_ri[t * 8];
#pragma unroll
    for (int m = 1; m < 8; ++m) {
      float d = s_rd[t * 8 + m]; int ii = s_ri[t * 8 + m];
      if (d < bd || (d == bd && ii < bi)) { bd = d; bi = ii; }
    }
    s_sel[t] = bi;
  }
  __syncthreads();

  int pos = t & 63, dg = t >> 6;
  int bsel = s_sel[pos];
  const float* cw = cb + bsel * 64 + dg * 16;
  float psum = 0.f;
#pragma unroll
  for (int kk = 0; kk < 16; ++kk) {
    int k = dg * 16 + kk;
    float cv = cw[kk];
    float l = s_lat_f[k * 64 + pos];
    float df = cv - l;
    psum = fmaf(df, df, psum);
    q[(n * 64 + k) * 1024 + s0 + pos] = cv;
  }
  s_r[t] = (double)psum;
  __syncthreads();
  for (int str = 128; str > 0; str >>= 1) {
    if (t < str) s_r[t] += s_r[t + str];
    __syncthreads();
  }
  if (t == 0) part[bid] = s_r[0];
}

// ---------------- dec2: up2x(ac) + 3x3 64->32 + lrelu, via MFMA ------------
__global__ __launch_bounds__(256, 2) void k_dec2m(
    const float* __restrict__ in, const unsigned short* __restrict__ wh,
    const unsigned short* __restrict__ wl, const float* __restrict__ bias,
    float* __restrict__ out) {
  int n = blockIdx.x >> 3, y0 = (blockIdx.x & 7) * 8;
  int t = threadIdx.x;
  int lane = t & 63, wv = t >> 6;
  int xh = wv & 1, rg = wv >> 1;
  int cc = lane & 31, h = lane >> 5;

  __shared__ __align__(16) unsigned int s_x[10 * 66 * 20];  // packed up-tile
  __shared__ float s_src[16 * 8 * 33];                      // [ci][r][c]
  __shared__ float s_wy[10], s_my[10];
  __shared__ int   s_ry0[10], s_ry1[10];
  __shared__ float s_wx[66], s_mx[66];
  __shared__ int   s_rx0[66], s_rx1[66];

  const float sc = 31.0f / 63.0f;
  int r0 = (y0 == 0) ? 0 : (int)floorf((float)(y0 - 1) * sc);

  if (t < 10) {
    int uy = y0 - 1 + t;
    int uyc = min(max(uy, 0), 63);
    float sy = (float)uyc * sc;
    int iy0 = (int)floorf(sy);
    s_wy[t] = sy - (float)iy0;
    s_my[t] = ((unsigned)uy < 64u) ? 1.f : 0.f;
    s_ry0[t] = iy0 - r0;
    s_ry1[t] = min(iy0 + 1, 31) - r0;
  }
  int xc = t - 64;
  if (xc >= 0 && xc < 66) {
    int ux = xc - 1;
    int uxc = min(max(ux, 0), 63);
    float sx = (float)uxc * sc;
    int ix0 = (int)floorf(sx);
    s_wx[xc] = sx - (float)ix0;
    s_mx[xc] = ((unsigned)ux < 64u) ? 1.f : 0.f;
    s_rx0[xc] = ix0;
    s_rx1[xc] = min(ix0 + 1, 31);
  }

  const uint4* wh4 = reinterpret_cast<const uint4*>(wh);
  const uint4* wl4 = reinterpret_cast<const uint4*>(wl);

  f32x16 acc[4];
#pragma unroll
  for (int r = 0; r < 4; ++r)
#pragma unroll
    for (int j = 0; j < 16; ++j) acc[r][j] = 0.f;

  for (int i = t; i < 4096; i += 256) {
    int ci = i >> 8, rem = i & 255;
    int r = rem >> 5, c = rem & 31;
    int row = r0 + r;
    s_src[ci * 264 + r * 33 + c] =
        (row < 32) ? in[(n * 64 + ci) * 1024 + row * 32 + c] : 0.f;
  }
  __syncthreads();

  for (int g = 0; g < 4; ++g) {
    for (int i = t; i < 10560; i += 256) {            // 16ci x 10u x 66c
      int ci = i / 660, rem = i - ci * 660;
      int u = rem / 66, c = rem - u * 66;
      const float* sp = &s_src[ci * 264];
      int ry0 = s_ry0[u], ry1 = s_ry1[u];
      int rx0 = s_rx0[c], rx1 = s_rx1[c];
      float wy = s_wy[u], wx = s_wx[c];
      float m = s_my[u] * s_mx[c];
      float a00 = sp[ry0 * 33 + rx0], a01 = sp[ry0 * 33 + rx1];
      float a10 = sp[ry1 * 33 + rx0], a11 = sp[ry1 * 33 + rx1];
      float h0 = fmaf(a10 - a00, wy, a00);
      float h1 = fmaf(a11 - a01, wy, a01);
      float v = m * fmaf(h1 - h0, wx, h0);
      unsigned hi = f2bf(__float_as_uint(v));
      float lf = v - __uint_as_float(hi << 16);
      unsigned lo = f2bf(__float_as_uint(lf));
      s_x[(u * 66 + c) * 20 + ci] = hi | (lo << 16);
    }
    __syncthreads();

    if (g < 3) {
      int ci0 = (g + 1) * 16;
      for (int i = t; i < 4096; i += 256) {
        int ci = i >> 8, rem = i & 255;
        int r = rem >> 5, c = rem & 31;
        int row = r0 + r;
        s_src[ci * 264 + r * 33 + c] =
            (row < 32) ? in[(n * 64 + ci0 + ci) * 1024 + row * 32 + c] : 0.f;
      }
    }

#pragma unroll
    for (int kx = 0; kx < 3; ++kx) {
      bf16x8 Ah[3], Al[3];
#pragma unroll
      for (int ky = 0; ky < 3; ++ky) {
        int wi = (g * 9 + ky * 3 + kx) * 64 + cc * 2 + h;
        Ah[ky] = __builtin_bit_cast(bf16x8, wh4[wi]);
        Al[ky] = __builtin_bit_cast(bf16x8, wl4[wi]);
      }
#pragma unroll
      for (int u6 = 0; u6 < 6; ++u6) {
        int u = rg * 4 + u6;
        const uint4* xp = reinterpret_cast<const uint4*>(
            &s_x[(u * 66 + xh * 32 + cc + kx) * 20 + (h << 3)]);
        uint4 qa = xp[0], qb = xp[1];
        u32x4v bh, bl;
        bh[0] = (qa.x & 0xffffu) | (qa.y << 16);
        bh[1] = (qa.z & 0xffffu) | (qa.w << 16);
        bh[2] = (qb.x & 0xffffu) | (qb.y << 16);
        bh[3] = (qb.z & 0xffffu) | (qb.w << 16);
        bl[0] = (qa.x >> 16) | (qa.y & 0xffff0000u);
        bl[1] = (qa.z >> 16) | (qa.w & 0xffff0000u);
        bl[2] = (qb.x >> 16) | (qb.y & 0xffff0000u);
        bl[3] = (qb.z >> 16) | (qb.w & 0xffff0000u);
        bf16x8 Bh = __builtin_bit_cast(bf16x8, bh);
        bf16x8 Bl = __builtin_bit_cast(bf16x8, bl);
#pragma unroll
        for (int ky = 0; ky < 3; ++ky) {
          int rr = u6 - ky;
          if (rr < 0 || rr > 3) continue;
          acc[rr] = __builtin_amdgcn_mfma_f32_32x32x16_bf16(Ah[ky], Bh, acc[rr], 0, 0, 0);
          acc[rr] = __builtin_amdgcn_mfma_f32_32x32x16_bf16(Ah[ky], Bl, acc[rr], 0, 0, 0);
          acc[rr] = __builtin_amdgcn_mfma_f32_32x32x16_bf16(Al[ky], Bh, acc[rr], 0, 0, 0);
        }
      }
    }
    __syncthreads();
  }

  float bvv[16];
#pragma unroll
  for (int reg = 0; reg < 16; ++reg) {
    int co = (reg & 3) + 8 * (reg >> 2) + 4 * h;
    bvv[reg] = bias[co];
  }
#pragma unroll
  for (int rr = 0; rr < 4; ++rr) {
    int y = y0 + rg * 4 + rr;
#pragma unroll
    for (int reg = 0; reg < 16; ++reg) {
      int co = (reg & 3) + 8 * (reg >> 2) + 4 * h;
      float v = acc[rr][reg] + bvv[reg];
      out[(n * 32 + co) * 4096 + y * 64 + xh * 32 + cc] = actf<1>(v);
    }
  }
}

// ---------------- 1x1 64->64 (channel matmul), opt bias / add --------------
template<int ACT, bool BIAS, bool ADD>
__global__ __launch_bounds__(256) void k_1x1(
    const float* __restrict__ in, const float* __restrict__ w,
    const float* __restrict__ bias, const float* __restrict__ add,
    float* __restrict__ out) {
  int bid = blockIdx.x;
  int n = bid >> 2;
  int s = ((bid & 3) << 8) + threadIdx.x;
  __shared__ float s_w[4096];
  for (int i = threadIdx.x; i < 4096; i += 256) s_w[i] = w[i];
  __syncthreads();
  float x[64];
#pragma unroll
  for (int ci = 0; ci < 64; ++ci) x[ci] = in[(n * 64 + ci) * 1024 + s];
  for (int co = 0; co < 64; ++co) {
    float acc = BIAS ? bias[co] : 0.f;
    const float* wr = &s_w[co * 64];
#pragma unroll
    for (int ci = 0; ci < 64; ++ci) acc = fmaf(wr[ci], x[ci], acc);
    if (ADD) acc += add[(n * 64 + co) * 1024 + s];
    out[(n * 64 + co) * 1024 + s] = actf<ACT>(acc);
  }
}

// ---------------- loss finalize --------------------------------------------
__global__ __launch_bounds__(256) void k_loss(const double* __restrict__ part,
                                              float* __restrict__ out) {
  __shared__ double s[256];
  int t = threadIdx.x;
  double acc = 0.0;
  for (int i = t; i < 2048; i += 256) acc += part[i];
  s[t] = acc;
  __syncthreads();
  for (int str = 128; str > 0; str >>= 1) {
    if (t < str) s[t] += s[t + str];
    __syncthreads();
  }
  if (t == 0) {
    double mean = s[0] / 8388608.0;
    out[2097152] = (float)mean;
    out[2097153] = (float)(0.25 * mean);
  }
}

// ---------------- dec3: up2x(ac) + 3x3 32->1 + relu (two-pass interp) ------
__global__ __launch_bounds__(256) void k_dec3(
    const float* __restrict__ in, const float* __restrict__ w,
    const float* __restrict__ bias, float* __restrict__ out) {
  int bid = blockIdx.x;                  // 2048 = 128n * 8yT * 2xT
  int n = bid >> 4, yT = (bid >> 1) & 7, xT = bid & 1;
  int y0 = yT * 16, x0 = xT * 64;
  int t = threadIdx.x;
  int ty = t >> 4, xq = t & 15;

  __shared__ float s_up[4 * 18 * 68];
  __shared__ float s_v[4 * 18 * 36];     // vertical-lerp buffer
  __shared__ float s_src[4 * 11 * 35];
  __shared__ float s_w[288];
  __shared__ float2 s_wmy[18];           // (wy, my)
  __shared__ int2   s_ry[18];            // (ry0, ry1)
  __shared__ float2 s_wmx[66];           // (wx, mx)
  __shared__ int2   s_rx[66];            // (rx0, rx1)

  const float sc = 63.0f / 127.0f;
  int r0 = (y0 == 0) ? 0 : (int)floorf((float)(y0 - 1) * sc);
  int c0 = (x0 == 0) ? 0 : (int)floorf((float)(x0 - 1) * sc);

  if (t < 18) {
    int uy = y0 - 1 + t;
    int uyc = min(max(uy, 0), 127);
    float sy = (float)uyc * sc;
    int iy0 = (int)floorf(sy);
    s_wmy[t] = make_float2(sy - (float)iy0, ((unsigned)uy < 128u) ? 1.f : 0.f);
    s_ry[t] = make_int2(iy0 - r0, min(iy0 + 1, 63) - r0);
  }
  int xc = t - 64;
  if (xc >= 0 && xc < 66) {
    int ux = x0 - 1 + xc;
    int uxc = min(max(ux, 0), 127);
    float sx = (float)uxc * sc;
    int ix0 = (int)floorf(sx);
    s_wmx[xc] = make_float2(sx - (float)ix0, ((unsigned)ux < 128u) ? 1.f : 0.f);
    s_rx[xc] = make_int2(ix0 - c0, min(ix0 + 1, 63) - c0);
  }
  for (int i = t; i < 288; i += 256) s_w[i] = w[i];

  float acc[4] = {0.f, 0.f, 0.f, 0.f};

  // prologue stage g=0 (4 ci)
  for (int i = t; i < 4 * 11 * 35; i += 256) {
    int ci = i / 385, rem = i - ci * 385;
    int rr = rem / 35, cx = rem - rr * 35;
    int row = r0 + rr, col = c0 + cx;
    s_src[(ci * 11 + rr) * 35 + cx] =
        (row < 64 && col < 64) ? in[((n * 32 + ci) * 64 + row) * 64 + col] : 0.f;
  }
  __syncthreads();

  for (int g = 0; g < 8; ++g) {
    // ---- V pass: src -> s_v (row-lerp, row-mask folded in) ----
    for (int e = t; e < 4 * 18 * 35; e += 256) {
      int ci = e / 630, rem = e - ci * 630;
      int u = rem / 35, c = rem - u * 35;
      const float* sp = &s_src[ci * 385];
      float2 wm = s_wmy[u];
      int2 ry = s_ry[u];
      float a0 = sp[ry.x * 35 + c], a1 = sp[ry.y * 35 + c];
      s_v[(ci * 18 + u) * 36 + c] = wm.y * fmaf(a1 - a0, wm.x, a0);
    }
    __syncthreads();

    // ---- H pass: s_v -> s_up ; overlap: stage next src group ----
    for (int e = t; e < 4 * 18 * 66; e += 256) {
      int ci = e / 1188, rem = e - ci * 1188;
      int u = rem / 66, c = rem - u * 66;
      const float* vp = &s_v[(ci * 18 + u) * 36];
      float2 wm = s_wmx[c];
      int2 rx = s_rx[c];
      float v0 = vp[rx.x], v1 = vp[rx.y];
      s_up[(ci * 18 + u) * 68 + c] = wm.y * fmaf(v1 - v0, wm.x, v0);
    }
    if (g < 7) {
      int ci0 = (g + 1) * 4;
      for (int i = t; i < 4 * 11 * 35; i += 256) {
        int ci = i / 385, rem = i - ci * 385;
        int rr = rem / 35, cx = rem - rr * 35;
        int row = r0 + rr, col = c0 + cx;
        s_src[(ci * 11 + rr) * 35 + cx] =
            (row < 64 && col < 64)
                ? in[((n * 32 + ci0 + ci) * 64 + row) * 64 + col] : 0.f;
      }
    }
    __syncthreads();

    // ---- conv ----
    int ci0 = g * 4;
    for (int ci = 0; ci < 4; ++ci) {
#pragma unroll
      for (int ky = 0; ky < 3; ++ky) {
        int base = (ci * 18 + ty + ky) * 68 + xq * 4;
        float4 q0 = *reinterpret_cast<const float4*>(&s_up[base]);
        float4 q1 = *reinterpret_cast<const float4*>(&s_up[base + 4]);
        float rv[8] = {q0.x, q0.y, q0.z, q0.w, q1.x, q1.y, q1.z, q1.w};
#pragma unroll
        for (int kx = 0; kx < 3; ++kx) {
          float wv = s_w[(ci0 + ci) * 9 + ky * 3 + kx];
#pragma unroll
          for (int xx = 0; xx < 4; ++xx)
            acc[xx] = fmaf(rv[xx + kx], wv, acc[xx]);
        }
      }
    }
    __syncthreads();
  }
  float bv = bias[0];
  int base = n * 16384 + (y0 + ty) * 128 + x0 + xq * 4;
  *reinterpret_cast<float4*>(&out[base]) =
      make_float4(actf<2>(acc[0] + bv), actf<2>(acc[1] + bv),
                  actf<2>(acc[2] + bv), actf<2>(acc[3] + bv));
}

// ---------------------------------------------------------------------------
extern "C" void kernel_launch(void* const* d_in, const int* in_sizes, int n_in,
                              void* d_out, int out_size, void* d_ws, size_t ws_size,
                              hipStream_t stream) {
  (void)in_sizes; (void)n_in; (void)out_size; (void)ws_size;
  const float* x_in     = (const float*)d_in[0];
  const float* enc_w1   = (const float*)d_in[1];
  const float* enc_b1   = (const float*)d_in[2];
  const float* enc_w2   = (const float*)d_in[3];
  const float* enc_b2   = (const float*)d_in[4];
  const float* enc_w3   = (const float*)d_in[5];
  const float* enc_b3   = (const float*)d_in[6];
  const float* res_e_w1 = (const float*)d_in[7];
  const float* res_e_w2 = (const float*)d_in[8];
  const float* enc_w4   = (const float*)d_in[9];
  const float* enc_b4   = (const float*)d_in[10];
  const float* codebook = (const float*)d_in[11];
  const float* dec_w1   = (const float*)d_in[12];
  const float* dec_b1   = (const float*)d_in[13];
  const float* res_d_w1 = (const float*)d_in[14];
  const float* res_d_w2 = (const float*)d_in[15];
  const float* dec_w2   = (const float*)d_in[16];
  const float* dec_b2   = (const float*)d_in[17];
  const float* dec_w3   = (const float*)d_in[18];
  const float* dec_b3   = (const float*)d_in[19];
  float* out = (float*)d_out;

  char* ws = (char*)d_ws;
  float*  B0    = (float*)(ws);                         // 33.55 MB each
  float*  B1    = (float*)(ws + 33554432);
  float*  B2    = (float*)(ws + 67108864);
  float*  B3    = (float*)(ws + 100663296);
  float*  B4    = (float*)(ws + 134217728);             // enc1 out: 67.1 MB
  double* PART  = (double*)(ws + 201326592);
  float*  CNORM = (float*)(ws + 201326592 + 16384);
  // VQ codebook split-bf16 fragments: in B3 region (B3 used post-VQ only)
  unsigned short* CBH = (unsigned short*)(ws + 100663296);
  unsigned short* CBL = CBH + 32768;
  // split-bf16 weight tail region
  unsigned short* WH0 = (unsigned short*)(ws + 201359360);
  unsigned short* WL0 = WH0 + 36864;
  unsigned short* WH1 = (unsigned short*)(ws + 201359360 + 147456);
  unsigned short* WL1 = WH1 + 36864;
  unsigned short* WH2 = (unsigned short*)(ws + 201359360 + 294912);
  unsigned short* WL2 = WH2 + 36864;
  unsigned short* WH3 = (unsigned short*)(ws + 201359360 + 442368);
  unsigned short* WL3 = WH3 + 36864;
  unsigned short* WH4 = (unsigned short*)(ws + 201359360 + 589824);   // dec2
  unsigned short* WL4 = WH4 + 18432;
  unsigned short* WH5 = (unsigned short*)(ws + 201359360 + 663552);   // enc2
  unsigned short* WL5 = WH5 + 32768;

  k_wprep<<<144, 256, 0, stream>>>(enc_w3,   WH0, WL0);
  k_wprep<<<144, 256, 0, stream>>>(res_e_w1, WH1, WL1);
  k_wprep<<<144, 256, 0, stream>>>(dec_w1,   WH2, WL2);
  k_wprep<<<144, 256, 0, stream>>>(res_d_w1, WH3, WL3);
  k_wprep2<<<72, 256, 0, stream>>>(dec_w2,   WH4, WL4);
  k_wprep_e2<<<128, 256, 0, stream>>>(enc_w2, WH5, WL5);
  k_cbprep_m<<<128, 256, 0, stream>>>(codebook, CBH, CBL);
  k_cbnorm<<<2, 256, 0, stream>>>(codebook, CNORM);

  k_enc1m<<<1024, 256, 0, stream>>>(x_in, enc_w1, enc_b1, B4);
  k_enc2m<<<1024, 256, 0, stream>>>(B4, WH5, WL5, enc_b2, B0);
  k_conv3m<1, true ><<<512, 256, 0, stream>>>(B0, WH0, WL0, enc_b3, B1);
  k_conv3m<2, false><<<512, 256, 0, stream>>>(B1, WH1, WL1, nullptr, B2);
  k_1x1<1, false, true ><<<512, 256, 0, stream>>>(B2, res_e_w2, nullptr, B1, B0);
  k_1x1<1, true,  false><<<512, 256, 0, stream>>>(B0, enc_w4, enc_b4, nullptr, B1);
  k_vq2m<<<2048, 256, 0, stream>>>(B1, CBH, CBL, codebook, CNORM, B2, PART);
  k_conv3m<1, true ><<<512, 256, 0, stream>>>(B2, WH2, WL2, dec_b1, B0);
  k_conv3m<2, false><<<512, 256, 0, stream>>>(B0, WH3, WL3, nullptr, B3);
  k_1x1<1, false, true ><<<512, 256, 0, stream>>>(B3, res_d_w2, nullptr, B0, B1);
  k_dec2m<<<1024, 256, 0, stream>>>(B1, WH4, WL4, dec_b2, B4);
  k_dec3<<<2048, 256, 0, stream>>>(B4, dec_w3, dec_b3, out);
  k_loss<<<1, 256, 0, stream>>>(PART, out);
}

// Round 11
// 864.554 us; speedup vs baseline: 4.8876x; 1.0039x over previous
//
#include <hip/hip_runtime.h>

// ---------------------------------------------------------------------------
// VQ-VAE forward.  N=128.  MFMA (split-bf16 hi/lo, 3-term) for the four
// 3x3 64->64 convs, dec2 (up2x + 3x3 64->32), enc2 (4x4 s2 32->64), and
// the VQ distance GEMM.  f32 VALU elsewhere.
//   x*y ~= xh*yh + xh*yl + xl*yh   (f32 MFMA accumulate)
// ---------------------------------------------------------------------------

template<int ACT> __device__ __forceinline__ float actf(float x){
  if (ACT == 1) return x > 0.f ? x : 0.01f * x;   // leaky relu, slope .01
  if (ACT == 2) return fmaxf(x, 0.f);             // relu
  return x;
}

typedef __bf16 bf16x8 __attribute__((ext_vector_type(8)));
typedef float f32x16 __attribute__((ext_vector_type(16)));
typedef unsigned int u32x4v __attribute__((ext_vector_type(4)));

__device__ __forceinline__ unsigned f2bf(unsigned u){   // RTNE f32->bf16 bits
  return (u + 0x7fffu + ((u >> 16) & 1u)) >> 16;
}

// ---------------- weight prep: f32 [64co][64ci][3][3] -> hi/lo bf16 --------
__global__ __launch_bounds__(256) void k_wprep(
    const float* __restrict__ w, unsigned short* __restrict__ wh,
    unsigned short* __restrict__ wl) {
  int i = blockIdx.x * 256 + threadIdx.x;           // 36864 = 4g*9tap*2*32*16
  if (i >= 36864) return;
  int ci16 = i & 15, co = (i >> 4) & 31, cot = (i >> 9) & 1;
  int rest = i >> 10, tap = rest % 9, g = rest / 9;
  float v = w[(cot * 32 + co) * 576 + (g * 16 + ci16) * 9 + tap];
  unsigned hi = f2bf(__float_as_uint(v));
  float lf = v - __uint_as_float(hi << 16);
  unsigned lo = f2bf(__float_as_uint(lf));
  wh[i] = (unsigned short)hi;
  wl[i] = (unsigned short)lo;
}

// ---------------- weight prep for dec2: f32 [32co][64ci][3][3] -------------
__global__ __launch_bounds__(256) void k_wprep2(
    const float* __restrict__ w, unsigned short* __restrict__ wh,
    unsigned short* __restrict__ wl) {
  int i = blockIdx.x * 256 + threadIdx.x;           // 18432 = 4g*9tap*32*16
  if (i >= 18432) return;
  int ci16 = i & 15, co = (i >> 4) & 31;
  int rest = i >> 9, tap = rest % 9, g = rest / 9;
  float v = w[co * 576 + (g * 16 + ci16) * 9 + tap];
  unsigned hi = f2bf(__float_as_uint(v));
  float lf = v - __uint_as_float(hi << 16);
  unsigned lo = f2bf(__float_as_uint(lf));
  wh[i] = (unsigned short)hi;
  wl[i] = (unsigned short)lo;
}

// ---------------- weight prep for enc2: f32 [64co][32ci][4][4] -------------
__global__ __launch_bounds__(256) void k_wprep_e2(
    const float* __restrict__ w, unsigned short* __restrict__ wh,
    unsigned short* __restrict__ wl) {
  int i = blockIdx.x * 256 + threadIdx.x;           // 32768 = 2g*16tap*2*32*16
  if (i >= 32768) return;
  int ci16 = i & 15, co = (i >> 4) & 31, cot = (i >> 9) & 1;
  int rest = i >> 10, tap = rest & 15, g = rest >> 4;
  float v = w[(cot * 32 + co) * 512 + (g * 16 + ci16) * 16 + tap];
  unsigned hi = f2bf(__float_as_uint(v));
  float lf = v - __uint_as_float(hi << 16);
  unsigned lo = f2bf(__float_as_uint(lf));
  wh[i] = (unsigned short)hi;
  wl[i] = (unsigned short)lo;
}

// ---------------- codebook prep for VQ MFMA: fragment-ordered hi/lo --------
__global__ __launch_bounds__(256) void k_cbprep_m(
    const float* __restrict__ cb, unsigned short* __restrict__ ch,
    unsigned short* __restrict__ cl_) {
  int i = blockIdx.x * 256 + threadIdx.x;           // 32768 = 16ct*4s*32*16
  if (i >= 32768) return;
  int ci16 = i & 15, cc = (i >> 4) & 31, ct4s = i >> 9;
  int s = ct4s & 3, ct = ct4s >> 2;
  float v = cb[(ct * 32 + cc) * 64 + s * 16 + ci16];
  unsigned hi = f2bf(__float_as_uint(v));
  float lf = v - __uint_as_float(hi << 16);
  unsigned lo = f2bf(__float_as_uint(lf));
  ch[i] = (unsigned short)hi;
  cl_[i] = (unsigned short)lo;
}

// ---------------- codebook squared norms -----------------------------------
__global__ __launch_bounds__(256) void k_cbnorm(const float* __restrict__ cb,
                                                float* __restrict__ nrm) {
  int c = blockIdx.x * 256 + threadIdx.x;
  if (c < 512) {
    float s = 0.f;
    for (int k = 0; k < 64; ++k) { float v = cb[c * 64 + k]; s = fmaf(v, v, s); }
    nrm[c] = s;
  }
}

// ---------------- enc1: 1->32, 4x4 s2 p1, 128->64, lrelu (LDS-staged) ------
__global__ __launch_bounds__(256) void k_enc1m(
    const float* __restrict__ in, const float* __restrict__ w,
    const float* __restrict__ b, float* __restrict__ out) {
  int n = blockIdx.x >> 3, y0 = (blockIdx.x & 7) * 8;
  int t = threadIdx.x;
  __shared__ float s_in[18 * 2 * 66];   // [r][parity][col/2], cols -1..128
  __shared__ float s_w[512];
  __shared__ float s_b[32];
  const float* ip = in + n * 16384;
  for (int i = t; i < 18 * 130; i += 256) {
    int r = i / 130, c = i - r * 130;
    int iy = 2 * y0 - 1 + r, ix = c - 1;
    float v = 0.f;
    if ((unsigned)iy < 128u && (unsigned)ix < 128u) v = ip[iy * 128 + ix];
    s_in[(r * 2 + (c & 1)) * 66 + (c >> 1)] = v;
  }
  for (int i = t; i < 512; i += 256) s_w[i] = w[i];
  if (t < 32) s_b[t] = b[t];
  __syncthreads();
  int ox = t & 63, wv = t >> 6;
#pragma unroll
  for (int rr = 0; rr < 2; ++rr) {
    int oyl = wv * 2 + rr;
    float x[16];
#pragma unroll
    for (int ky = 0; ky < 4; ++ky) {
      int r = 2 * oyl + ky;
#pragma unroll
      for (int kx = 0; kx < 4; ++kx) {
        x[ky * 4 + kx] = s_in[(r * 2 + (kx & 1)) * 66 + ox + (kx >> 1)];
      }
    }
    int obase = (n * 32) * 4096 + (y0 + oyl) * 64 + ox;
    for (int co = 0; co < 32; ++co) {
      float acc = s_b[co];
      const float* wr = &s_w[co * 16];
#pragma unroll
      for (int k = 0; k < 16; ++k) acc = fmaf(x[k], wr[k], acc);
      out[obase + co * 4096] = actf<1>(acc);
    }
  }
}

// ---------------- 3x3 64->64 stride1 pad1 @32x32 via MFMA ------------------
template<int ACT, bool BIAS>
__global__ __launch_bounds__(256, 2) void k_conv3m(
    const float* __restrict__ in, const unsigned short* __restrict__ wh,
    const unsigned short* __restrict__ wl, const float* __restrict__ bias,
    float* __restrict__ out) {
  int n = blockIdx.x >> 2, y0 = (blockIdx.x & 3) * 8;
  int t = threadIdx.x;
  int lane = t & 63, wv = t >> 6;
  int cot = wv & 1, rgroup = wv >> 1;
  int cc = lane & 31, h = lane >> 5;

  __shared__ __align__(16) unsigned int s_x[6800];   // [10 r][34 c][pad 20 ci]

  const uint4* wh4 = reinterpret_cast<const uint4*>(wh);
  const uint4* wl4 = reinterpret_cast<const uint4*>(wl);

  f32x16 acc[4];
#pragma unroll
  for (int r = 0; r < 4; ++r)
#pragma unroll
    for (int j = 0; j < 16; ++j) acc[r][j] = 0.f;

  for (int g = 0; g < 4; ++g) {
    if (g) __syncthreads();
    for (int i = t; i < 5440; i += 256) {
      int c = i % 34; int rem = i / 34; int r = rem % 10; int ci = rem / 10;
      int row = y0 - 1 + r, col = c - 1;
      float v = 0.f;
      if ((unsigned)row < 32u && (unsigned)col < 32u)
        v = in[(n * 64 + g * 16 + ci) * 1024 + row * 32 + col];
      unsigned hi = f2bf(__float_as_uint(v));
      float lf = v - __uint_as_float(hi << 16);
      unsigned lo = f2bf(__float_as_uint(lf));
      s_x[(r * 34 + c) * 20 + ci] = hi | (lo << 16);
    }
    __syncthreads();

#pragma unroll
    for (int kx = 0; kx < 3; ++kx) {
      bf16x8 Ah[3], Al[3];
#pragma unroll
      for (int ky = 0; ky < 3; ++ky) {
        int wi = ((g * 9 + ky * 3 + kx) * 2 + cot) * 64 + cc * 2 + h;
        Ah[ky] = __builtin_bit_cast(bf16x8, wh4[wi]);
        Al[ky] = __builtin_bit_cast(bf16x8, wl4[wi]);
      }
#pragma unroll
      for (int ir6 = 0; ir6 < 6; ++ir6) {
        int ir = rgroup * 4 + ir6;
        const uint4* xp = reinterpret_cast<const uint4*>(
            &s_x[(ir * 34 + cc + kx) * 20 + (h << 3)]);
        uint4 qa = xp[0], qb = xp[1];
        u32x4v bh, bl;
        bh[0] = (qa.x & 0xffffu) | (qa.y << 16);
        bh[1] = (qa.z & 0xffffu) | (qa.w << 16);
        bh[2] = (qb.x & 0xffffu) | (qb.y << 16);
        bh[3] = (qb.z & 0xffffu) | (qb.w << 16);
        bl[0] = (qa.x >> 16) | (qa.y & 0xffff0000u);
        bl[1] = (qa.z >> 16) | (qa.w & 0xffff0000u);
        bl[2] = (qb.x >> 16) | (qb.y & 0xffff0000u);
        bl[3] = (qb.z >> 16) | (qb.w & 0xffff0000u);
        bf16x8 Bh = __builtin_bit_cast(bf16x8, bh);
        bf16x8 Bl = __builtin_bit_cast(bf16x8, bl);
#pragma unroll
        for (int ky = 0; ky < 3; ++ky) {
          int rr = ir6 - ky;
          if (rr < 0 || rr > 3) continue;
          acc[rr] = __builtin_amdgcn_mfma_f32_32x32x16_bf16(Ah[ky], Bh, acc[rr], 0, 0, 0);
          acc[rr] = __builtin_amdgcn_mfma_f32_32x32x16_bf16(Ah[ky], Bl, acc[rr], 0, 0, 0);
          acc[rr] = __builtin_amdgcn_mfma_f32_32x32x16_bf16(Al[ky], Bh, acc[rr], 0, 0, 0);
        }
      }
    }
  }

  float bvv[16];
#pragma unroll
  for (int reg = 0; reg < 16; ++reg) {
    int row = (reg & 3) + 8 * (reg >> 2) + 4 * h;
    bvv[reg] = BIAS ? bias[cot * 32 + row] : 0.f;
  }
#pragma unroll
  for (int rr = 0; rr < 4; ++rr) {
    int y = y0 + rgroup * 4 + rr;
#pragma unroll
    for (int reg = 0; reg < 16; ++reg) {
      int row = (reg & 3) + 8 * (reg >> 2) + 4 * h;
      int co = cot * 32 + row;
      float v = acc[rr][reg] + bvv[reg];
      out[(n * 64 + co) * 1024 + y * 32 + cc] = actf<ACT>(v);
    }
  }
}

// ---------------- enc2: 32->64, 4x4 s2 p1, 64->32 via MFMA -----------------
__global__ __launch_bounds__(256, 2) void k_enc2m(
    const float* __restrict__ in, const unsigned short* __restrict__ wh,
    const unsigned short* __restrict__ wl, const float* __restrict__ bias,
    float* __restrict__ out) {
  int n = blockIdx.x >> 3, y0 = (blockIdx.x & 7) * 4;
  int t = threadIdx.x;
  int lane = t & 63, wv = t >> 6;
  int cot = wv & 1, rg = wv >> 1;
  int cc = lane & 31, h = lane >> 5;

  __shared__ __align__(16) unsigned int s_x[13200];  // [10][2][33][20]

  const uint4* wh4 = reinterpret_cast<const uint4*>(wh);
  const uint4* wl4 = reinterpret_cast<const uint4*>(wl);

  f32x16 acc[2];
#pragma unroll
  for (int r = 0; r < 2; ++r)
#pragma unroll
    for (int j = 0; j < 16; ++j) acc[r][j] = 0.f;

  for (int g = 0; g < 2; ++g) {
    if (g) __syncthreads();
    for (int i = t; i < 10560; i += 256) {
      int ci = i / 660, rem = i - ci * 660;
      int r = rem / 66, c = rem - r * 66;
      int row = 2 * y0 - 1 + r, icol = c - 1;
      float v = 0.f;
      if ((unsigned)row < 64u && (unsigned)icol < 64u)
        v = in[((n * 32 + g * 16 + ci) * 64 + row) * 64 + icol];
      unsigned hi = f2bf(__float_as_uint(v));
      float lf = v - __uint_as_float(hi << 16);
      unsigned lo = f2bf(__float_as_uint(lf));
      int p = icol & 1;
      int idx = (icol + p) >> 1;
      s_x[((r * 2 + p) * 33 + idx) * 20 + ci] = hi | (lo << 16);
    }
    __syncthreads();

#pragma unroll
    for (int kx = 0; kx < 4; ++kx) {
      bf16x8 Ah[4], Al[4];
#pragma unroll
      for (int ky = 0; ky < 4; ++ky) {
        int wi = ((g * 16 + ky * 4 + kx) * 2 + cot) * 64 + cc * 2 + h;
        Ah[ky] = __builtin_bit_cast(bf16x8, wh4[wi]);
        Al[ky] = __builtin_bit_cast(bf16x8, wl4[wi]);
      }
      int p = (kx + 1) & 1;
      int idx = cc + (kx >> 1);
#pragma unroll
      for (int ir6 = 0; ir6 < 6; ++ir6) {
        int r = rg * 4 + ir6;
        const uint4* xp = reinterpret_cast<const uint4*>(
            &s_x[((r * 2 + p) * 33 + idx) * 20 + (h << 3)]);
        uint4 qa = xp[0], qb = xp[1];
        u32x4v bh, bl;
        bh[0] = (qa.x & 0xffffu) | (qa.y << 16);
        bh[1] = (qa.z & 0xffffu) | (qa.w << 16);
        bh[2] = (qb.x & 0xffffu) | (qb.y << 16);
        bh[3] = (qb.z & 0xffffu) | (qb.w << 16);
        bl[0] = (qa.x >> 16) | (qa.y & 0xffff0000u);
        bl[1] = (qa.z >> 16) | (qa.w & 0xffff0000u);
        bl[2] = (qb.x >> 16) | (qb.y & 0xffff0000u);
        bl[3] = (qb.z >> 16) | (qb.w & 0xffff0000u);
        bf16x8 Bh = __builtin_bit_cast(bf16x8, bh);
        bf16x8 Bl = __builtin_bit_cast(bf16x8, bl);
#pragma unroll
        for (int rr = 0; rr < 2; ++rr) {
          int ky = ir6 - 2 * rr;
          if (ky < 0 || ky > 3) continue;
          acc[rr] = __builtin_amdgcn_mfma_f32_32x32x16_bf16(Ah[ky], Bh, acc[rr], 0, 0, 0);
          acc[rr] = __builtin_amdgcn_mfma_f32_32x32x16_bf16(Ah[ky], Bl, acc[rr], 0, 0, 0);
          acc[rr] = __builtin_amdgcn_mfma_f32_32x32x16_bf16(Al[ky], Bh, acc[rr], 0, 0, 0);
        }
      }
    }
  }

#pragma unroll
  for (int rr = 0; rr < 2; ++rr) {
    int oy = y0 + rg * 2 + rr;
#pragma unroll
    for (int reg = 0; reg < 16; ++reg) {
      int corow = (reg & 3) + 8 * (reg >> 2) + 4 * h;
      int co = cot * 32 + corow;
      float v = acc[rr][reg] + bias[co];
      out[(n * 64 + co) * 1024 + oy * 32 + cc] = actf<1>(v);
    }
  }
}

// ---------------- VQ via MFMA: dist GEMM + argmin + q + loss ---------------
__global__ __launch_bounds__(256, 2) void k_vq2m(
    const float* __restrict__ lat, const unsigned short* __restrict__ cbh,
    const unsigned short* __restrict__ cbl, const float* __restrict__ cb,
    const float* __restrict__ nrm, float* __restrict__ q,
    double* __restrict__ part) {
  int bid = blockIdx.x;                  // 2048 = 128 n x 16 s-tiles
  int n = bid >> 4, s0 = (bid & 15) << 6;
  int t = threadIdx.x;
  int lane = t & 63, wv = t >> 6;
  int cc = lane & 31, h = lane >> 5;

  __shared__ __align__(16) unsigned int s_pk[5120];   // [4 s][64 pos][pad 20]
  __shared__ float s_lat_f[4096];                     // [k][pos]
  __shared__ float s_nrm[512];
  __shared__ float s_rd[512];                         // [pos][8 slots]
  __shared__ int   s_ri[512];
  __shared__ int   s_sel[64];
  __shared__ double s_r[256];

  for (int i = t; i < 4096; i += 256) {
    int pos = i & 63, k = i >> 6;
    float v = lat[(n * 64 + k) * 1024 + s0 + pos];
    s_lat_f[k * 64 + pos] = v;
    unsigned hi = f2bf(__float_as_uint(v));
    float lf = v - __uint_as_float(hi << 16);
    unsigned lo = f2bf(__float_as_uint(lf));
    s_pk[(((k >> 4) * 64) + pos) * 20 + (k & 15)] = hi | (lo << 16);
  }
  for (int i = t; i < 512; i += 256) s_nrm[i] = nrm[i];
  __syncthreads();

  const uint4* ah4 = reinterpret_cast<const uint4*>(cbh);
  const uint4* al4 = reinterpret_cast<const uint4*>(cbl);

  float best[2] = {3.4e38f, 3.4e38f};
  int bidx[2] = {0, 0};

#pragma unroll
  for (int ip = 0; ip < 2; ++ip) {
    f32x16 acc[2][2];
#pragma unroll
    for (int a = 0; a < 2; ++a)
#pragma unroll
      for (int b = 0; b < 2; ++b)
#pragma unroll
        for (int j = 0; j < 16; ++j) acc[a][b][j] = 0.f;

#pragma unroll
    for (int s = 0; s < 4; ++s) {
      bf16x8 Bh[2], Bl[2];
#pragma unroll
      for (int pt = 0; pt < 2; ++pt) {
        const uint4* xp = reinterpret_cast<const uint4*>(
            &s_pk[((s * 64) + pt * 32 + cc) * 20 + (h << 3)]);
        uint4 qa = xp[0], qb = xp[1];
        u32x4v bh, bl;
        bh[0] = (qa.x & 0xffffu) | (qa.y << 16);
        bh[1] = (qa.z & 0xffffu) | (qa.w << 16);
        bh[2] = (qb.x & 0xffffu) | (qb.y << 16);
        bh[3] = (qb.z & 0xffffu) | (qb.w << 16);
        bl[0] = (qa.x >> 16) | (qa.y & 0xffff0000u);
        bl[1] = (qa.z >> 16) | (qa.w & 0xffff0000u);
        bl[2] = (qb.x >> 16) | (qb.y & 0xffff0000u);
        bl[3] = (qb.z >> 16) | (qb.w & 0xffff0000u);
        Bh[pt] = __builtin_bit_cast(bf16x8, bh);
        Bl[pt] = __builtin_bit_cast(bf16x8, bl);
      }
#pragma unroll
      for (int it2 = 0; it2 < 2; ++it2) {
        int ct = wv * 4 + ip * 2 + it2;
        int wi = (ct * 4 + s) * 64 + cc * 2 + h;
        bf16x8 Ah = __builtin_bit_cast(bf16x8, ah4[wi]);
        bf16x8 Al = __builtin_bit_cast(bf16x8, al4[wi]);
#pragma unroll
        for (int pt = 0; pt < 2; ++pt) {
          acc[it2][pt] = __builtin_amdgcn_mfma_f32_32x32x16_bf16(Ah, Bh[pt], acc[it2][pt], 0, 0, 0);
          acc[it2][pt] = __builtin_amdgcn_mfma_f32_32x32x16_bf16(Ah, Bl[pt], acc[it2][pt], 0, 0, 0);
          acc[it2][pt] = __builtin_amdgcn_mfma_f32_32x32x16_bf16(Al, Bh[pt], acc[it2][pt], 0, 0, 0);
        }
      }
    }

#pragma unroll
    for (int it2 = 0; it2 < 2; ++it2) {
      int ct = wv * 4 + ip * 2 + it2;
#pragma unroll
      for (int pt = 0; pt < 2; ++pt) {
#pragma unroll
        for (int reg = 0; reg < 16; ++reg) {
          int code = ct * 32 + (reg & 3) + 8 * (reg >> 2) + 4 * h;
          float d = fmaf(-2.f, acc[it2][pt][reg], s_nrm[code]);
          if (d < best[pt] || (d == best[pt] && code < bidx[pt])) {
            best[pt] = d; bidx[pt] = code;
          }
        }
      }
    }
  }

#pragma unroll
  for (int pt = 0; pt < 2; ++pt) {
    int pos = pt * 32 + cc;
    s_rd[pos * 8 + wv * 2 + h] = best[pt];
    s_ri[pos * 8 + wv * 2 + h] = bidx[pt];
  }
  __syncthreads();
  if (t < 64) {
    float bd = s_rd[t * 8]; int bi = s_ri[t * 8];
#pragma unroll
    for (int m = 1; m < 8; ++m) {
      float d = s_rd[t * 8 + m]; int ii = s_ri[t * 8 + m];
      if (d < bd || (d == bd && ii < bi)) { bd = d; bi = ii; }
    }
    s_sel[t] = bi;
  }
  __syncthreads();

  int pos = t & 63, dg = t >> 6;
  int bsel = s_sel[pos];
  const float* cw = cb + bsel * 64 + dg * 16;
  float psum = 0.f;
#pragma unroll
  for (int kk = 0; kk < 16; ++kk) {
    int k = dg * 16 + kk;
    float cv = cw[kk];
    float l = s_lat_f[k * 64 + pos];
    float df = cv - l;
    psum = fmaf(df, df, psum);
    q[(n * 64 + k) * 1024 + s0 + pos] = cv;
  }
  s_r[t] = (double)psum;
  __syncthreads();
  for (int str = 128; str > 0; str >>= 1) {
    if (t < str) s_r[t] += s_r[t + str];
    __syncthreads();
  }
  if (t == 0) part[bid] = s_r[0];
}

// ---------------- dec2: up2x(ac) + 3x3 64->32 + lrelu, via MFMA ------------
// interp loop is division-free: per-ci outer, inner 10x64 (shifts) + 2-col tail
__global__ __launch_bounds__(256, 2) void k_dec2m(
    const float* __restrict__ in, const unsigned short* __restrict__ wh,
    const unsigned short* __restrict__ wl, const float* __restrict__ bias,
    float* __restrict__ out) {
  int n = blockIdx.x >> 3, y0 = (blockIdx.x & 7) * 8;
  int t = threadIdx.x;
  int lane = t & 63, wv = t >> 6;
  int xh = wv & 1, rg = wv >> 1;
  int cc = lane & 31, h = lane >> 5;

  __shared__ __align__(16) unsigned int s_x[10 * 66 * 20];  // packed up-tile
  __shared__ float s_src[16 * 8 * 33];                      // [ci][r][c]
  __shared__ float2 s_wmy[10];           // (wy, my)
  __shared__ int2   s_ryp[10];           // (ry0, ry1)
  __shared__ float2 s_wmx[66];           // (wx, mx)
  __shared__ int2   s_rxp[66];           // (rx0, rx1)

  const float sc = 31.0f / 63.0f;
  int r0 = (y0 == 0) ? 0 : (int)floorf((float)(y0 - 1) * sc);

  if (t < 10) {
    int uy = y0 - 1 + t;
    int uyc = min(max(uy, 0), 63);
    float sy = (float)uyc * sc;
    int iy0 = (int)floorf(sy);
    s_wmy[t] = make_float2(sy - (float)iy0, ((unsigned)uy < 64u) ? 1.f : 0.f);
    s_ryp[t] = make_int2(iy0 - r0, min(iy0 + 1, 31) - r0);
  }
  int xc = t - 64;
  if (xc >= 0 && xc < 66) {
    int ux = xc - 1;
    int uxc = min(max(ux, 0), 63);
    float sx = (float)uxc * sc;
    int ix0 = (int)floorf(sx);
    s_wmx[xc] = make_float2(sx - (float)ix0, ((unsigned)ux < 64u) ? 1.f : 0.f);
    s_rxp[xc] = make_int2(ix0, min(ix0 + 1, 31));
  }

  const uint4* wh4 = reinterpret_cast<const uint4*>(wh);
  const uint4* wl4 = reinterpret_cast<const uint4*>(wl);

  f32x16 acc[4];
#pragma unroll
  for (int r = 0; r < 4; ++r)
#pragma unroll
    for (int j = 0; j < 16; ++j) acc[r][j] = 0.f;

  for (int i = t; i < 4096; i += 256) {
    int ci = i >> 8, rem = i & 255;
    int r = rem >> 5, c = rem & 31;
    int row = r0 + r;
    s_src[ci * 264 + r * 33 + c] =
        (row < 32) ? in[(n * 64 + ci) * 1024 + row * 32 + c] : 0.f;
  }
  __syncthreads();

  for (int g = 0; g < 4; ++g) {
    // ---- interp + split-pack into s_x (div-free) ----
    for (int ci = 0; ci < 16; ++ci) {
      const float* sp = &s_src[ci * 264];
      for (int i = t; i < 640; i += 256) {            // 10u x 64c
        int u = i >> 6, c = i & 63;
        float2 wmy = s_wmy[u]; int2 ry = s_ryp[u];
        float2 wmx = s_wmx[c]; int2 rx = s_rxp[c];
        const float* r0p = sp + ry.x * 33;
        const float* r1p = sp + ry.y * 33;
        float a00 = r0p[rx.x], a01 = r0p[rx.y];
        float a10 = r1p[rx.x], a11 = r1p[rx.y];
        float h0 = fmaf(a10 - a00, wmy.x, a00);
        float h1 = fmaf(a11 - a01, wmy.x, a01);
        float v = (wmy.y * wmx.y) * fmaf(h1 - h0, wmx.x, h0);
        unsigned hi = f2bf(__float_as_uint(v));
        float lf = v - __uint_as_float(hi << 16);
        unsigned lo = f2bf(__float_as_uint(lf));
        s_x[(u * 66 + c) * 20 + ci] = hi | (lo << 16);
      }
      if (t < 20) {                                   // cols 64,65
        int u = t >> 1, c = 64 + (t & 1);
        float2 wmy = s_wmy[u]; int2 ry = s_ryp[u];
        float2 wmx = s_wmx[c]; int2 rx = s_rxp[c];
        const float* r0p = sp + ry.x * 33;
        const float* r1p = sp + ry.y * 33;
        float a00 = r0p[rx.x], a01 = r0p[rx.y];
        float a10 = r1p[rx.x], a11 = r1p[rx.y];
        float h0 = fmaf(a10 - a00, wmy.x, a00);
        float h1 = fmaf(a11 - a01, wmy.x, a01);
        float v = (wmy.y * wmx.y) * fmaf(h1 - h0, wmx.x, h0);
        unsigned hi = f2bf(__float_as_uint(v));
        float lf = v - __uint_as_float(hi << 16);
        unsigned lo = f2bf(__float_as_uint(lf));
        s_x[(u * 66 + c) * 20 + ci] = hi | (lo << 16);
      }
    }
    __syncthreads();

    if (g < 3) {
      int ci0 = (g + 1) * 16;
      for (int i = t; i < 4096; i += 256) {
        int ci = i >> 8, rem = i & 255;
        int r = rem >> 5, c = rem & 31;
        int row = r0 + r;
        s_src[ci * 264 + r * 33 + c] =
            (row < 32) ? in[(n * 64 + ci0 + ci) * 1024 + row * 32 + c] : 0.f;
      }
    }

#pragma unroll
    for (int kx = 0; kx < 3; ++kx) {
      bf16x8 Ah[3], Al[3];
#pragma unroll
      for (int ky = 0; ky < 3; ++ky) {
        int wi = (g * 9 + ky * 3 + kx) * 64 + cc * 2 + h;
        Ah[ky] = __builtin_bit_cast(bf16x8, wh4[wi]);
        Al[ky] = __builtin_bit_cast(bf16x8, wl4[wi]);
      }
#pragma unroll
      for (int u6 = 0; u6 < 6; ++u6) {
        int u = rg * 4 + u6;
        const uint4* xp = reinterpret_cast<const uint4*>(
            &s_x[(u * 66 + xh * 32 + cc + kx) * 20 + (h << 3)]);
        uint4 qa = xp[0], qb = xp[1];
        u32x4v bh, bl;
        bh[0] = (qa.x & 0xffffu) | (qa.y << 16);
        bh[1] = (qa.z & 0xffffu) | (qa.w << 16);
        bh[2] = (qb.x & 0xffffu) | (qb.y << 16);
        bh[3] = (qb.z & 0xffffu) | (qb.w << 16);
        bl[0] = (qa.x >> 16) | (qa.y & 0xffff0000u);
        bl[1] = (qa.z >> 16) | (qa.w & 0xffff0000u);
        bl[2] = (qb.x >> 16) | (qb.y & 0xffff0000u);
        bl[3] = (qb.z >> 16) | (qb.w & 0xffff0000u);
        bf16x8 Bh = __builtin_bit_cast(bf16x8, bh);
        bf16x8 Bl = __builtin_bit_cast(bf16x8, bl);
#pragma unroll
        for (int ky = 0; ky < 3; ++ky) {
          int rr = u6 - ky;
          if (rr < 0 || rr > 3) continue;
          acc[rr] = __builtin_amdgcn_mfma_f32_32x32x16_bf16(Ah[ky], Bh, acc[rr], 0, 0, 0);
          acc[rr] = __builtin_amdgcn_mfma_f32_32x32x16_bf16(Ah[ky], Bl, acc[rr], 0, 0, 0);
          acc[rr] = __builtin_amdgcn_mfma_f32_32x32x16_bf16(Al[ky], Bh, acc[rr], 0, 0, 0);
        }
      }
    }
    __syncthreads();
  }

  float bvv[16];
#pragma unroll
  for (int reg = 0; reg < 16; ++reg) {
    int co = (reg & 3) + 8 * (reg >> 2) + 4 * h;
    bvv[reg] = bias[co];
  }
#pragma unroll
  for (int rr = 0; rr < 4; ++rr) {
    int y = y0 + rg * 4 + rr;
#pragma unroll
    for (int reg = 0; reg < 16; ++reg) {
      int co = (reg & 3) + 8 * (reg >> 2) + 4 * h;
      float v = acc[rr][reg] + bvv[reg];
      out[(n * 32 + co) * 4096 + y * 64 + xh * 32 + cc] = actf<1>(v);
    }
  }
}

// ---------------- 1x1 64->64 (channel matmul), opt bias / add --------------
template<int ACT, bool BIAS, bool ADD>
__global__ __launch_bounds__(256) void k_1x1(
    const float* __restrict__ in, const float* __restrict__ w,
    const float* __restrict__ bias, const float* __restrict__ add,
    float* __restrict__ out) {
  int bid = blockIdx.x;
  int n = bid >> 2;
  int s = ((bid & 3) << 8) + threadIdx.x;
  __shared__ float s_w[4096];
  for (int i = threadIdx.x; i < 4096; i += 256) s_w[i] = w[i];
  __syncthreads();
  float x[64];
#pragma unroll
  for (int ci = 0; ci < 64; ++ci) x[ci] = in[(n * 64 + ci) * 1024 + s];
  for (int co = 0; co < 64; ++co) {
    float acc = BIAS ? bias[co] : 0.f;
    const float* wr = &s_w[co * 64];
#pragma unroll
    for (int ci = 0; ci < 64; ++ci) acc = fmaf(wr[ci], x[ci], acc);
    if (ADD) acc += add[(n * 64 + co) * 1024 + s];
    out[(n * 64 + co) * 1024 + s] = actf<ACT>(acc);
  }
}

// ---------------- loss finalize --------------------------------------------
__global__ __launch_bounds__(256) void k_loss(const double* __restrict__ part,
                                              float* __restrict__ out) {
  __shared__ double s[256];
  int t = threadIdx.x;
  double acc = 0.0;
  for (int i = t; i < 2048; i += 256) acc += part[i];
  s[t] = acc;
  __syncthreads();
  for (int str = 128; str > 0; str >>= 1) {
    if (t < str) s[t] += s[t + str];
    __syncthreads();
  }
  if (t == 0) {
    double mean = s[0] / 8388608.0;
    out[2097152] = (float)mean;
    out[2097153] = (float)(0.25 * mean);
  }
}

// ---------------- dec3: up2x(ac) + 3x3 32->1 + relu (div-free interp) ------
__global__ __launch_bounds__(256) void k_dec3(
    const float* __restrict__ in, const float* __restrict__ w,
    const float* __restrict__ bias, float* __restrict__ out) {
  int bid = blockIdx.x;                  // 2048 = 128n * 8yT * 2xT
  int n = bid >> 4, yT = (bid >> 1) & 7, xT = bid & 1;
  int y0 = yT * 16, x0 = xT * 64;
  int t = threadIdx.x;
  int ty = t >> 4, xq = t & 15;

  __shared__ float s_up[4 * 18 * 68];
  __shared__ float s_src[4 * 11 * 35];
  __shared__ float s_w[288];
  __shared__ float2 s_wmy[18];           // (wy, my)
  __shared__ int2   s_ryp[18];           // (ry0, ry1)
  __shared__ float2 s_wmx[66];           // (wx, mx)
  __shared__ int2   s_rxp[66];           // (rx0, rx1)

  const float sc = 63.0f / 127.0f;
  int r0 = (y0 == 0) ? 0 : (int)floorf((float)(y0 - 1) * sc);
  int c0 = (x0 == 0) ? 0 : (int)floorf((float)(x0 - 1) * sc);

  if (t < 18) {
    int uy = y0 - 1 + t;
    int uyc = min(max(uy, 0), 127);
    float sy = (float)uyc * sc;
    int iy0 = (int)floorf(sy);
    s_wmy[t] = make_float2(sy - (float)iy0, ((unsigned)uy < 128u) ? 1.f : 0.f);
    s_ryp[t] = make_int2(iy0 - r0, min(iy0 + 1, 63) - r0);
  }
  int xc = t - 64;
  if (xc >= 0 && xc < 66) {
    int ux = x0 - 1 + xc;
    int uxc = min(max(ux, 0), 127);
    float sx = (float)uxc * sc;
    int ix0 = (int)floorf(sx);
    s_wmx[xc] = make_float2(sx - (float)ix0, ((unsigned)ux < 128u) ? 1.f : 0.f);
    s_rxp[xc] = make_int2(ix0 - c0, min(ix0 + 1, 63) - c0);
  }
  for (int i = t; i < 288; i += 256) s_w[i] = w[i];

  float acc[4] = {0.f, 0.f, 0.f, 0.f};

  // prologue stage g=0 (4 ci)
  for (int i = t; i < 4 * 11 * 35; i += 256) {
    int ci = i / 385, rem = i - ci * 385;
    int rr = rem / 35, cx = rem - rr * 35;
    int row = r0 + rr, col = c0 + cx;
    s_src[(ci * 11 + rr) * 35 + cx] =
        (row < 64 && col < 64) ? in[((n * 32 + ci) * 64 + row) * 64 + col] : 0.f;
  }
  __syncthreads();

  for (int g = 0; g < 8; ++g) {
    // ---- interp (single pass, div-free) ----
    for (int ci = 0; ci < 4; ++ci) {
      const float* sp = &s_src[ci * 385];
      float* up = &s_up[ci * 1224];                   // 18*68
      for (int i = t; i < 1152; i += 256) {           // 18u x 64c
        int u = i >> 6, c = i & 63;
        float2 wmy = s_wmy[u]; int2 ry = s_ryp[u];
        float2 wmx = s_wmx[c]; int2 rx = s_rxp[c];
        const float* r0p = sp + ry.x * 35;
        const float* r1p = sp + ry.y * 35;
        float a00 = r0p[rx.x], a01 = r0p[rx.y];
        float a10 = r1p[rx.x], a11 = r1p[rx.y];
        float h0 = fmaf(a10 - a00, wmy.x, a00);
        float h1 = fmaf(a11 - a01, wmy.x, a01);
        up[u * 68 + c] = (wmy.y * wmx.y) * fmaf(h1 - h0, wmx.x, h0);
      }
      if (t < 36) {                                   // cols 64,65
        int u = t >> 1, c = 64 + (t & 1);
        float2 wmy = s_wmy[u]; int2 ry = s_ryp[u];
        float2 wmx = s_wmx[c]; int2 rx = s_rxp[c];
        const float* r0p = sp + ry.x * 35;
        const float* r1p = sp + ry.y * 35;
        float a00 = r0p[rx.x], a01 = r0p[rx.y];
        float a10 = r1p[rx.x], a11 = r1p[rx.y];
        float h0 = fmaf(a10 - a00, wmy.x, a00);
        float h1 = fmaf(a11 - a01, wmy.x, a01);
        up[u * 68 + c] = (wmy.y * wmx.y) * fmaf(h1 - h0, wmx.x, h0);
      }
    }
    __syncthreads();

    // ---- conv (reads s_up) ; overlap: stage next src group ----
    if (g < 7) {
      int ci0 = (g + 1) * 4;
      for (int i = t; i < 4 * 11 * 35; i += 256) {
        int ci = i / 385, rem = i - ci * 385;
        int rr = rem / 35, cx = rem - rr * 35;
        int row = r0 + rr, col = c0 + cx;
        s_src[(ci * 11 + rr) * 35 + cx] =
            (row < 64 && col < 64)
                ? in[((n * 32 + ci0 + ci) * 64 + row) * 64 + col] : 0.f;
      }
    }

    int ci0 = g * 4;
    for (int ci = 0; ci < 4; ++ci) {
#pragma unroll
      for (int ky = 0; ky < 3; ++ky) {
        int base = (ci * 18 + ty + ky) * 68 + xq * 4;
        float4 q0 = *reinterpret_cast<const float4*>(&s_up[base]);
        float4 q1 = *reinterpret_cast<const float4*>(&s_up[base + 4]);
        float rv[8] = {q0.x, q0.y, q0.z, q0.w, q1.x, q1.y, q1.z, q1.w};
#pragma unroll
        for (int kx = 0; kx < 3; ++kx) {
          float wv = s_w[(ci0 + ci) * 9 + ky * 3 + kx];
#pragma unroll
          for (int xx = 0; xx < 4; ++xx)
            acc[xx] = fmaf(rv[xx + kx], wv, acc[xx]);
        }
      }
    }
    __syncthreads();
  }
  float bv = bias[0];
  int base = n * 16384 + (y0 + ty) * 128 + x0 + xq * 4;
  *reinterpret_cast<float4*>(&out[base]) =
      make_float4(actf<2>(acc[0] + bv), actf<2>(acc[1] + bv),
                  actf<2>(acc[2] + bv), actf<2>(acc[3] + bv));
}

// ---------------------------------------------------------------------------
extern "C" void kernel_launch(void* const* d_in, const int* in_sizes, int n_in,
                              void* d_out, int out_size, void* d_ws, size_t ws_size,
                              hipStream_t stream) {
  (void)in_sizes; (void)n_in; (void)out_size; (void)ws_size;
  const float* x_in     = (const float*)d_in[0];
  const float* enc_w1   = (const float*)d_in[1];
  const float* enc_b1   = (const float*)d_in[2];
  const float* enc_w2   = (const float*)d_in[3];
  const float* enc_b2   = (const float*)d_in[4];
  const float* enc_w3   = (const float*)d_in[5];
  const float* enc_b3   = (const float*)d_in[6];
  const float* res_e_w1 = (const float*)d_in[7];
  const float* res_e_w2 = (const float*)d_in[8];
  const float* enc_w4   = (const float*)d_in[9];
  const float* enc_b4   = (const float*)d_in[10];
  const float* codebook = (const float*)d_in[11];
  const float* dec_w1   = (const float*)d_in[12];
  const float* dec_b1   = (const float*)d_in[13];
  const float* res_d_w1 = (const float*)d_in[14];
  const float* res_d_w2 = (const float*)d_in[15];
  const float* dec_w2   = (const float*)d_in[16];
  const float* dec_b2   = (const float*)d_in[17];
  const float* dec_w3   = (const float*)d_in[18];
  const float* dec_b3   = (const float*)d_in[19];
  float* out = (float*)d_out;

  char* ws = (char*)d_ws;
  float*  B0    = (float*)(ws);                         // 33.55 MB each
  float*  B1    = (float*)(ws + 33554432);
  float*  B2    = (float*)(ws + 67108864);
  float*  B3    = (float*)(ws + 100663296);
  float*  B4    = (float*)(ws + 134217728);             // enc1 out: 67.1 MB
  double* PART  = (double*)(ws + 201326592);
  float*  CNORM = (float*)(ws + 201326592 + 16384);
  unsigned short* CBH = (unsigned short*)(ws + 100663296);  // B3, pre-VQ only
  unsigned short* CBL = CBH + 32768;
  unsigned short* WH0 = (unsigned short*)(ws + 201359360);
  unsigned short* WL0 = WH0 + 36864;
  unsigned short* WH1 = (unsigned short*)(ws + 201359360 + 147456);
  unsigned short* WL1 = WH1 + 36864;
  unsigned short* WH2 = (unsigned short*)(ws + 201359360 + 294912);
  unsigned short* WL2 = WH2 + 36864;
  unsigned short* WH3 = (unsigned short*)(ws + 201359360 + 442368);
  unsigned short* WL3 = WH3 + 36864;
  unsigned short* WH4 = (unsigned short*)(ws + 201359360 + 589824);   // dec2
  unsigned short* WL4 = WH4 + 18432;
  unsigned short* WH5 = (unsigned short*)(ws + 201359360 + 663552);   // enc2
  unsigned short* WL5 = WH5 + 32768;

  k_wprep<<<144, 256, 0, stream>>>(enc_w3,   WH0, WL0);
  k_wprep<<<144, 256, 0, stream>>>(res_e_w1, WH1, WL1);
  k_wprep<<<144, 256, 0, stream>>>(dec_w1,   WH2, WL2);
  k_wprep<<<144, 256, 0, stream>>>(res_d_w1, WH3, WL3);
  k_wprep2<<<72, 256, 0, stream>>>(dec_w2,   WH4, WL4);
  k_wprep_e2<<<128, 256, 0, stream>>>(enc_w2, WH5, WL5);
  k_cbprep_m<<<128, 256, 0, stream>>>(codebook, CBH, CBL);
  k_cbnorm<<<2, 256, 0, stream>>>(codebook, CNORM);

  k_enc1m<<<1024, 256, 0, stream>>>(x_in, enc_w1, enc_b1, B4);
  k_enc2m<<<1024, 256, 0, stream>>>(B4, WH5, WL5, enc_b2, B0);
  k_conv3m<1, true ><<<512, 256, 0, stream>>>(B0, WH0, WL0, enc_b3, B1);
  k_conv3m<2, false><<<512, 256, 0, stream>>>(B1, WH1, WL1, nullptr, B2);
  k_1x1<1, false, true ><<<512, 256, 0, stream>>>(B2, res_e_w2, nullptr, B1, B0);
  k_1x1<1, true,  false><<<512, 256, 0, stream>>>(B0, enc_w4, enc_b4, nullptr, B1);
  k_vq2m<<<2048, 256, 0, stream>>>(B1, CBH, CBL, codebook, CNORM, B2, PART);
  k_conv3m<1, true ><<<512, 256, 0, stream>>>(B2, WH2, WL2, dec_b1, B0);
  k_conv3m<2, false><<<512, 256, 0, stream>>>(B0, WH3, WL3, nullptr, B3);
  k_1x1<1, false, true ><<<512, 256, 0, stream>>>(B3, res_d_w2, nullptr, B0, B1);
  k_dec2m<<<1024, 256, 0, stream>>>(B1, WH4, WL4, dec_b2, B4);
  k_dec3<<<2048, 256, 0, stream>>>(B4, dec_w3, dec_b3, out);
  k_loss<<<1, 256, 0, stream>>>(PART, out);
}

// Round 12
// 840.493 us; speedup vs baseline: 5.0276x; 1.0286x over previous
//
#include <hip/hip_runtime.h>

// ---------------------------------------------------------------------------
// VQ-VAE forward.  N=128.  MFMA (split-bf16 hi/lo, 3-term) for the four
// 3x3 64->64 convs, dec2 (up2x + 3x3 64->32), enc2 (4x4 s2 32->64), and
// the VQ distance GEMM.  f32 VALU elsewhere.
//   x*y ~= xh*yh + xh*yl + xl*yh   (f32 MFMA accumulate)
// ---------------------------------------------------------------------------

template<int ACT> __device__ __forceinline__ float actf(float x){
  if (ACT == 1) return x > 0.f ? x : 0.01f * x;   // leaky relu, slope .01
  if (ACT == 2) return fmaxf(x, 0.f);             // relu
  return x;
}

typedef __bf16 bf16x8 __attribute__((ext_vector_type(8)));
typedef float f32x16 __attribute__((ext_vector_type(16)));
typedef unsigned int u32x4v __attribute__((ext_vector_type(4)));

__device__ __forceinline__ unsigned f2bf(unsigned u){   // RTNE f32->bf16 bits
  return (u + 0x7fffu + ((u >> 16) & 1u)) >> 16;
}

// ---------------- weight prep: f32 [64co][64ci][3][3] -> hi/lo bf16 --------
__global__ __launch_bounds__(256) void k_wprep(
    const float* __restrict__ w, unsigned short* __restrict__ wh,
    unsigned short* __restrict__ wl) {
  int i = blockIdx.x * 256 + threadIdx.x;           // 36864 = 4g*9tap*2*32*16
  if (i >= 36864) return;
  int ci16 = i & 15, co = (i >> 4) & 31, cot = (i >> 9) & 1;
  int rest = i >> 10, tap = rest % 9, g = rest / 9;
  float v = w[(cot * 32 + co) * 576 + (g * 16 + ci16) * 9 + tap];
  unsigned hi = f2bf(__float_as_uint(v));
  float lf = v - __uint_as_float(hi << 16);
  unsigned lo = f2bf(__float_as_uint(lf));
  wh[i] = (unsigned short)hi;
  wl[i] = (unsigned short)lo;
}

// ---------------- weight prep for dec2: f32 [32co][64ci][3][3] -------------
__global__ __launch_bounds__(256) void k_wprep2(
    const float* __restrict__ w, unsigned short* __restrict__ wh,
    unsigned short* __restrict__ wl) {
  int i = blockIdx.x * 256 + threadIdx.x;           // 18432 = 4g*9tap*32*16
  if (i >= 18432) return;
  int ci16 = i & 15, co = (i >> 4) & 31;
  int rest = i >> 9, tap = rest % 9, g = rest / 9;
  float v = w[co * 576 + (g * 16 + ci16) * 9 + tap];
  unsigned hi = f2bf(__float_as_uint(v));
  float lf = v - __uint_as_float(hi << 16);
  unsigned lo = f2bf(__float_as_uint(lf));
  wh[i] = (unsigned short)hi;
  wl[i] = (unsigned short)lo;
}

// ---------------- weight prep for enc2: f32 [64co][32ci][4][4] -------------
__global__ __launch_bounds__(256) void k_wprep_e2(
    const float* __restrict__ w, unsigned short* __restrict__ wh,
    unsigned short* __restrict__ wl) {
  int i = blockIdx.x * 256 + threadIdx.x;           // 32768 = 2g*16tap*2*32*16
  if (i >= 32768) return;
  int ci16 = i & 15, co = (i >> 4) & 31, cot = (i >> 9) & 1;
  int rest = i >> 10, tap = rest & 15, g = rest >> 4;
  float v = w[(cot * 32 + co) * 512 + (g * 16 + ci16) * 16 + tap];
  unsigned hi = f2bf(__float_as_uint(v));
  float lf = v - __uint_as_float(hi << 16);
  unsigned lo = f2bf(__float_as_uint(lf));
  wh[i] = (unsigned short)hi;
  wl[i] = (unsigned short)lo;
}

// ---------------- codebook prep for VQ MFMA: fragment-ordered hi/lo --------
__global__ __launch_bounds__(256) void k_cbprep_m(
    const float* __restrict__ cb, unsigned short* __restrict__ ch,
    unsigned short* __restrict__ cl_) {
  int i = blockIdx.x * 256 + threadIdx.x;           // 32768 = 16ct*4s*32*16
  if (i >= 32768) return;
  int ci16 = i & 15, cc = (i >> 4) & 31, ct4s = i >> 9;
  int s = ct4s & 3, ct = ct4s >> 2;
  float v = cb[(ct * 32 + cc) * 64 + s * 16 + ci16];
  unsigned hi = f2bf(__float_as_uint(v));
  float lf = v - __uint_as_float(hi << 16);
  unsigned lo = f2bf(__float_as_uint(lf));
  ch[i] = (unsigned short)hi;
  cl_[i] = (unsigned short)lo;
}

// ---------------- codebook squared norms -----------------------------------
__global__ __launch_bounds__(256) void k_cbnorm(const float* __restrict__ cb,
                                                float* __restrict__ nrm) {
  int c = blockIdx.x * 256 + threadIdx.x;
  if (c < 512) {
    float s = 0.f;
    for (int k = 0; k < 64; ++k) { float v = cb[c * 64 + k]; s = fmaf(v, v, s); }
    nrm[c] = s;
  }
}

// ---------------- enc1: 1->32, 4x4 s2 p1, 128->64, lrelu (LDS-staged) ------
__global__ __launch_bounds__(256) void k_enc1m(
    const float* __restrict__ in, const float* __restrict__ w,
    const float* __restrict__ b, float* __restrict__ out) {
  int n = blockIdx.x >> 3, y0 = (blockIdx.x & 7) * 8;
  int t = threadIdx.x;
  __shared__ float s_in[18 * 2 * 66];   // [r][parity][col/2], cols -1..128
  __shared__ float s_w[512];
  __shared__ float s_b[32];
  const float* ip = in + n * 16384;
  for (int i = t; i < 18 * 130; i += 256) {
    int r = i / 130, c = i - r * 130;
    int iy = 2 * y0 - 1 + r, ix = c - 1;
    float v = 0.f;
    if ((unsigned)iy < 128u && (unsigned)ix < 128u) v = ip[iy * 128 + ix];
    s_in[(r * 2 + (c & 1)) * 66 + (c >> 1)] = v;
  }
  for (int i = t; i < 512; i += 256) s_w[i] = w[i];
  if (t < 32) s_b[t] = b[t];
  __syncthreads();
  int ox = t & 63, wv = t >> 6;
#pragma unroll
  for (int rr = 0; rr < 2; ++rr) {
    int oyl = wv * 2 + rr;
    float x[16];
#pragma unroll
    for (int ky = 0; ky < 4; ++ky) {
      int r = 2 * oyl + ky;
#pragma unroll
      for (int kx = 0; kx < 4; ++kx) {
        x[ky * 4 + kx] = s_in[(r * 2 + (kx & 1)) * 66 + ox + (kx >> 1)];
      }
    }
    int obase = (n * 32) * 4096 + (y0 + oyl) * 64 + ox;
    for (int co = 0; co < 32; ++co) {
      float acc = s_b[co];
      const float* wr = &s_w[co * 16];
#pragma unroll
      for (int k = 0; k < 16; ++k) acc = fmaf(x[k], wr[k], acc);
      out[obase + co * 4096] = actf<1>(acc);
    }
  }
}

// ---------------- 3x3 64->64 stride1 pad1 @32x32 via MFMA ------------------
template<int ACT, bool BIAS>
__global__ __launch_bounds__(256, 2) void k_conv3m(
    const float* __restrict__ in, const unsigned short* __restrict__ wh,
    const unsigned short* __restrict__ wl, const float* __restrict__ bias,
    float* __restrict__ out) {
  int n = blockIdx.x >> 2, y0 = (blockIdx.x & 3) * 8;
  int t = threadIdx.x;
  int lane = t & 63, wv = t >> 6;
  int cot = wv & 1, rgroup = wv >> 1;
  int cc = lane & 31, h = lane >> 5;

  __shared__ __align__(16) unsigned int s_x[6800];   // [10 r][34 c][pad 20 ci]

  const uint4* wh4 = reinterpret_cast<const uint4*>(wh);
  const uint4* wl4 = reinterpret_cast<const uint4*>(wl);

  f32x16 acc[4];
#pragma unroll
  for (int r = 0; r < 4; ++r)
#pragma unroll
    for (int j = 0; j < 16; ++j) acc[r][j] = 0.f;

  for (int g = 0; g < 4; ++g) {
    if (g) __syncthreads();
    for (int i = t; i < 5440; i += 256) {
      int c = i % 34; int rem = i / 34; int r = rem % 10; int ci = rem / 10;
      int row = y0 - 1 + r, col = c - 1;
      float v = 0.f;
      if ((unsigned)row < 32u && (unsigned)col < 32u)
        v = in[(n * 64 + g * 16 + ci) * 1024 + row * 32 + col];
      unsigned hi = f2bf(__float_as_uint(v));
      float lf = v - __uint_as_float(hi << 16);
      unsigned lo = f2bf(__float_as_uint(lf));
      s_x[(r * 34 + c) * 20 + ci] = hi | (lo << 16);
    }
    __syncthreads();

#pragma unroll
    for (int kx = 0; kx < 3; ++kx) {
      bf16x8 Ah[3], Al[3];
#pragma unroll
      for (int ky = 0; ky < 3; ++ky) {
        int wi = ((g * 9 + ky * 3 + kx) * 2 + cot) * 64 + cc * 2 + h;
        Ah[ky] = __builtin_bit_cast(bf16x8, wh4[wi]);
        Al[ky] = __builtin_bit_cast(bf16x8, wl4[wi]);
      }
#pragma unroll
      for (int ir6 = 0; ir6 < 6; ++ir6) {
        int ir = rgroup * 4 + ir6;
        const uint4* xp = reinterpret_cast<const uint4*>(
            &s_x[(ir * 34 + cc + kx) * 20 + (h << 3)]);
        uint4 qa = xp[0], qb = xp[1];
        u32x4v bh, bl;
        bh[0] = (qa.x & 0xffffu) | (qa.y << 16);
        bh[1] = (qa.z & 0xffffu) | (qa.w << 16);
        bh[2] = (qb.x & 0xffffu) | (qb.y << 16);
        bh[3] = (qb.z & 0xffffu) | (qb.w << 16);
        bl[0] = (qa.x >> 16) | (qa.y & 0xffff0000u);
        bl[1] = (qa.z >> 16) | (qa.w & 0xffff0000u);
        bl[2] = (qb.x >> 16) | (qb.y & 0xffff0000u);
        bl[3] = (qb.z >> 16) | (qb.w & 0xffff0000u);
        bf16x8 Bh = __builtin_bit_cast(bf16x8, bh);
        bf16x8 Bl = __builtin_bit_cast(bf16x8, bl);
#pragma unroll
        for (int ky = 0; ky < 3; ++ky) {
          int rr = ir6 - ky;
          if (rr < 0 || rr > 3) continue;
          acc[rr] = __builtin_amdgcn_mfma_f32_32x32x16_bf16(Ah[ky], Bh, acc[rr], 0, 0, 0);
          acc[rr] = __builtin_amdgcn_mfma_f32_32x32x16_bf16(Ah[ky], Bl, acc[rr], 0, 0, 0);
          acc[rr] = __builtin_amdgcn_mfma_f32_32x32x16_bf16(Al[ky], Bh, acc[rr], 0, 0, 0);
        }
      }
    }
  }

  float bvv[16];
#pragma unroll
  for (int reg = 0; reg < 16; ++reg) {
    int row = (reg & 3) + 8 * (reg >> 2) + 4 * h;
    bvv[reg] = BIAS ? bias[cot * 32 + row] : 0.f;
  }
#pragma unroll
  for (int rr = 0; rr < 4; ++rr) {
    int y = y0 + rgroup * 4 + rr;
#pragma unroll
    for (int reg = 0; reg < 16; ++reg) {
      int row = (reg & 3) + 8 * (reg >> 2) + 4 * h;
      int co = cot * 32 + row;
      float v = acc[rr][reg] + bvv[reg];
      out[(n * 64 + co) * 1024 + y * 32 + cc] = actf<ACT>(v);
    }
  }
}

// ---------------- enc2: 32->64, 4x4 s2 p1, 64->32 via MFMA -----------------
__global__ __launch_bounds__(256, 2) void k_enc2m(
    const float* __restrict__ in, const unsigned short* __restrict__ wh,
    const unsigned short* __restrict__ wl, const float* __restrict__ bias,
    float* __restrict__ out) {
  int n = blockIdx.x >> 3, y0 = (blockIdx.x & 7) * 4;
  int t = threadIdx.x;
  int lane = t & 63, wv = t >> 6;
  int cot = wv & 1, rg = wv >> 1;
  int cc = lane & 31, h = lane >> 5;

  __shared__ __align__(16) unsigned int s_x[13200];  // [10][2][33][20]

  const uint4* wh4 = reinterpret_cast<const uint4*>(wh);
  const uint4* wl4 = reinterpret_cast<const uint4*>(wl);

  f32x16 acc[2];
#pragma unroll
  for (int r = 0; r < 2; ++r)
#pragma unroll
    for (int j = 0; j < 16; ++j) acc[r][j] = 0.f;

  for (int g = 0; g < 2; ++g) {
    if (g) __syncthreads();
    for (int i = t; i < 10560; i += 256) {
      int ci = i / 660, rem = i - ci * 660;
      int r = rem / 66, c = rem - r * 66;
      int row = 2 * y0 - 1 + r, icol = c - 1;
      float v = 0.f;
      if ((unsigned)row < 64u && (unsigned)icol < 64u)
        v = in[((n * 32 + g * 16 + ci) * 64 + row) * 64 + icol];
      unsigned hi = f2bf(__float_as_uint(v));
      float lf = v - __uint_as_float(hi << 16);
      unsigned lo = f2bf(__float_as_uint(lf));
      int p = icol & 1;
      int idx = (icol + p) >> 1;
      s_x[((r * 2 + p) * 33 + idx) * 20 + ci] = hi | (lo << 16);
    }
    __syncthreads();

#pragma unroll
    for (int kx = 0; kx < 4; ++kx) {
      bf16x8 Ah[4], Al[4];
#pragma unroll
      for (int ky = 0; ky < 4; ++ky) {
        int wi = ((g * 16 + ky * 4 + kx) * 2 + cot) * 64 + cc * 2 + h;
        Ah[ky] = __builtin_bit_cast(bf16x8, wh4[wi]);
        Al[ky] = __builtin_bit_cast(bf16x8, wl4[wi]);
      }
      int p = (kx + 1) & 1;
      int idx = cc + (kx >> 1);
#pragma unroll
      for (int ir6 = 0; ir6 < 6; ++ir6) {
        int r = rg * 4 + ir6;
        const uint4* xp = reinterpret_cast<const uint4*>(
            &s_x[((r * 2 + p) * 33 + idx) * 20 + (h << 3)]);
        uint4 qa = xp[0], qb = xp[1];
        u32x4v bh, bl;
        bh[0] = (qa.x & 0xffffu) | (qa.y << 16);
        bh[1] = (qa.z & 0xffffu) | (qa.w << 16);
        bh[2] = (qb.x & 0xffffu) | (qb.y << 16);
        bh[3] = (qb.z & 0xffffu) | (qb.w << 16);
        bl[0] = (qa.x >> 16) | (qa.y & 0xffff0000u);
        bl[1] = (qa.z >> 16) | (qa.w & 0xffff0000u);
        bl[2] = (qb.x >> 16) | (qb.y & 0xffff0000u);
        bl[3] = (qb.z >> 16) | (qb.w & 0xffff0000u);
        bf16x8 Bh = __builtin_bit_cast(bf16x8, bh);
        bf16x8 Bl = __builtin_bit_cast(bf16x8, bl);
#pragma unroll
        for (int rr = 0; rr < 2; ++rr) {
          int ky = ir6 - 2 * rr;
          if (ky < 0 || ky > 3) continue;
          acc[rr] = __builtin_amdgcn_mfma_f32_32x32x16_bf16(Ah[ky], Bh, acc[rr], 0, 0, 0);
          acc[rr] = __builtin_amdgcn_mfma_f32_32x32x16_bf16(Ah[ky], Bl, acc[rr], 0, 0, 0);
          acc[rr] = __builtin_amdgcn_mfma_f32_32x32x16_bf16(Al[ky], Bh, acc[rr], 0, 0, 0);
        }
      }
    }
  }

#pragma unroll
  for (int rr = 0; rr < 2; ++rr) {
    int oy = y0 + rg * 2 + rr;
#pragma unroll
    for (int reg = 0; reg < 16; ++reg) {
      int corow = (reg & 3) + 8 * (reg >> 2) + 4 * h;
      int co = cot * 32 + corow;
      float v = acc[rr][reg] + bias[co];
      out[(n * 64 + co) * 1024 + oy * 32 + cc] = actf<1>(v);
    }
  }
}

// ---------------- VQ via MFMA: dist GEMM + argmin + q + loss ---------------
__global__ __launch_bounds__(256, 2) void k_vq2m(
    const float* __restrict__ lat, const unsigned short* __restrict__ cbh,
    const unsigned short* __restrict__ cbl, const float* __restrict__ cb,
    const float* __restrict__ nrm, float* __restrict__ q,
    double* __restrict__ part) {
  int bid = blockIdx.x;                  // 2048 = 128 n x 16 s-tiles
  int n = bid >> 4, s0 = (bid & 15) << 6;
  int t = threadIdx.x;
  int lane = t & 63, wv = t >> 6;
  int cc = lane & 31, h = lane >> 5;

  __shared__ __align__(16) unsigned int s_pk[5120];   // [4 s][64 pos][pad 20]
  __shared__ float s_lat_f[4096];                     // [k][pos]
  __shared__ float s_nrm[512];
  __shared__ float s_rd[512];                         // [pos][8 slots]
  __shared__ int   s_ri[512];
  __shared__ int   s_sel[64];
  __shared__ double s_r[256];

  for (int i = t; i < 4096; i += 256) {
    int pos = i & 63, k = i >> 6;
    float v = lat[(n * 64 + k) * 1024 + s0 + pos];
    s_lat_f[k * 64 + pos] = v;
    unsigned hi = f2bf(__float_as_uint(v));
    float lf = v - __uint_as_float(hi << 16);
    unsigned lo = f2bf(__float_as_uint(lf));
    s_pk[(((k >> 4) * 64) + pos) * 20 + (k & 15)] = hi | (lo << 16);
  }
  for (int i = t; i < 512; i += 256) s_nrm[i] = nrm[i];
  __syncthreads();

  const uint4* ah4 = reinterpret_cast<const uint4*>(cbh);
  const uint4* al4 = reinterpret_cast<const uint4*>(cbl);

  float best[2] = {3.4e38f, 3.4e38f};
  int bidx[2] = {0, 0};

#pragma unroll
  for (int ip = 0; ip < 2; ++ip) {
    f32x16 acc[2][2];
#pragma unroll
    for (int a = 0; a < 2; ++a)
#pragma unroll
      for (int b = 0; b < 2; ++b)
#pragma unroll
        for (int j = 0; j < 16; ++j) acc[a][b][j] = 0.f;

#pragma unroll
    for (int s = 0; s < 4; ++s) {
      bf16x8 Bh[2], Bl[2];
#pragma unroll
      for (int pt = 0; pt < 2; ++pt) {
        const uint4* xp = reinterpret_cast<const uint4*>(
            &s_pk[((s * 64) + pt * 32 + cc) * 20 + (h << 3)]);
        uint4 qa = xp[0], qb = xp[1];
        u32x4v bh, bl;
        bh[0] = (qa.x & 0xffffu) | (qa.y << 16);
        bh[1] = (qa.z & 0xffffu) | (qa.w << 16);
        bh[2] = (qb.x & 0xffffu) | (qb.y << 16);
        bh[3] = (qb.z & 0xffffu) | (qb.w << 16);
        bl[0] = (qa.x >> 16) | (qa.y & 0xffff0000u);
        bl[1] = (qa.z >> 16) | (qa.w & 0xffff0000u);
        bl[2] = (qb.x >> 16) | (qb.y & 0xffff0000u);
        bl[3] = (qb.z >> 16) | (qb.w & 0xffff0000u);
        Bh[pt] = __builtin_bit_cast(bf16x8, bh);
        Bl[pt] = __builtin_bit_cast(bf16x8, bl);
      }
#pragma unroll
      for (int it2 = 0; it2 < 2; ++it2) {
        int ct = wv * 4 + ip * 2 + it2;
        int wi = (ct * 4 + s) * 64 + cc * 2 + h;
        bf16x8 Ah = __builtin_bit_cast(bf16x8, ah4[wi]);
        bf16x8 Al = __builtin_bit_cast(bf16x8, al4[wi]);
#pragma unroll
        for (int pt = 0; pt < 2; ++pt) {
          acc[it2][pt] = __builtin_amdgcn_mfma_f32_32x32x16_bf16(Ah, Bh[pt], acc[it2][pt], 0, 0, 0);
          acc[it2][pt] = __builtin_amdgcn_mfma_f32_32x32x16_bf16(Ah, Bl[pt], acc[it2][pt], 0, 0, 0);
          acc[it2][pt] = __builtin_amdgcn_mfma_f32_32x32x16_bf16(Al, Bh[pt], acc[it2][pt], 0, 0, 0);
        }
      }
    }

#pragma unroll
    for (int it2 = 0; it2 < 2; ++it2) {
      int ct = wv * 4 + ip * 2 + it2;
#pragma unroll
      for (int pt = 0; pt < 2; ++pt) {
#pragma unroll
        for (int reg = 0; reg < 16; ++reg) {
          int code = ct * 32 + (reg & 3) + 8 * (reg >> 2) + 4 * h;
          float d = fmaf(-2.f, acc[it2][pt][reg], s_nrm[code]);
          if (d < best[pt] || (d == best[pt] && code < bidx[pt])) {
            best[pt] = d; bidx[pt] = code;
          }
        }
      }
    }
  }

#pragma unroll
  for (int pt = 0; pt < 2; ++pt) {
    int pos = pt * 32 + cc;
    s_rd[pos * 8 + wv * 2 + h] = best[pt];
    s_ri[pos * 8 + wv * 2 + h] = bidx[pt];
  }
  __syncthreads();
  if (t < 64) {
    float bd = s_rd[t * 8]; int bi = s_ri[t * 8];
#pragma unroll
    for (int m = 1; m < 8; ++m) {
      float d = s_rd[t * 8 + m]; int ii = s_ri[t * 8 + m];
      if (d < bd || (d == bd && ii < bi)) { bd = d; bi = ii; }
    }
    s_sel[t] = bi;
  }
  __syncthreads();

  int pos = t & 63, dg = t >> 6;
  int bsel = s_sel[pos];
  const float* cw = cb + bsel * 64 + dg * 16;
  float psum = 0.f;
#pragma unroll
  for (int kk = 0; kk < 16; ++kk) {
    int k = dg * 16 + kk;
    float cv = cw[kk];
    float l = s_lat_f[k * 64 + pos];
    float df = cv - l;
    psum = fmaf(df, df, psum);
    q[(n * 64 + k) * 1024 + s0 + pos] = cv;
  }
  s_r[t] = (double)psum;
  __syncthreads();
  for (int str = 128; str > 0; str >>= 1) {
    if (t < str) s_r[t] += s_r[t + str];
    __syncthreads();
  }
  if (t == 0) part[bid] = s_r[0];
}

// ---------------- dec2: up2x(ac) + 3x3 64->32 + lrelu, via MFMA ------------
// 4-row strips (grid 2048), ~43 KB LDS -> 3 blocks/CU.  Interp uses
// register-hoisted per-position tables/offsets (no per-element addr math).
__global__ __launch_bounds__(256, 3) void k_dec2m(
    const float* __restrict__ in, const unsigned short* __restrict__ wh,
    const unsigned short* __restrict__ wl, const float* __restrict__ bias,
    float* __restrict__ out) {
  int n = blockIdx.x >> 4, y0 = (blockIdx.x & 15) * 4;
  int t = threadIdx.x;
  int lane = t & 63, wv = t >> 6;
  int xh = wv & 1, rg = wv >> 1;
  int cc = lane & 31, h = lane >> 5;

  __shared__ __align__(16) unsigned int s_x[6 * 66 * 20];   // packed up-tile
  __shared__ float s_src[16 * 165];                         // [ci][5r][33]
  __shared__ float2 s_wmy[6];
  __shared__ int2   s_ryp[6];
  __shared__ float2 s_wmx[66];
  __shared__ int2   s_rxp[66];

  const float sc = 31.0f / 63.0f;
  int r0 = (y0 == 0) ? 0 : (int)floorf((float)(y0 - 1) * sc);

  if (t < 6) {
    int uy = y0 - 1 + t;
    int uyc = min(max(uy, 0), 63);
    float sy = (float)uyc * sc;
    int iy0 = (int)floorf(sy);
    s_wmy[t] = make_float2(sy - (float)iy0, ((unsigned)uy < 64u) ? 1.f : 0.f);
    s_ryp[t] = make_int2(iy0 - r0, min(iy0 + 1, 31) - r0);
  }
  int xc = t - 64;
  if (xc >= 0 && xc < 66) {
    int ux = xc - 1;
    int uxc = min(max(ux, 0), 63);
    float sx = (float)uxc * sc;
    int ix0 = (int)floorf(sx);
    s_wmx[xc] = make_float2(sx - (float)ix0, ((unsigned)ux < 64u) ? 1.f : 0.f);
    s_rxp[xc] = make_int2(ix0, min(ix0 + 1, 31));
  }

  // stage g=0 src: 16 ci x 5 rows x 32 cols
  for (int i = t; i < 2560; i += 256) {
    int ci = i / 160, rem = i - ci * 160;
    int rr = rem >> 5, c = rem & 31;
    int row = r0 + rr;
    s_src[ci * 165 + rr * 33 + c] =
        (row < 32) ? in[(n * 64 + ci) * 1024 + row * 32 + c] : 0.f;
  }
  __syncthreads();

  // slot setup: each thread owns <=2 fixed (u,c) positions (396 total)
  int so00[2], so01[2], so10[2], so11[2], spos[2];
  float swy[2], swx[2], smm[2];
  bool sval[2];
#pragma unroll
  for (int k = 0; k < 2; ++k) {
    int pos = t + (k << 8);
    sval[k] = pos < 396;
    int p = sval[k] ? pos : 0;
    int u = p / 66, c = p - u * 66;
    float2 wmy = s_wmy[u]; int2 ry = s_ryp[u];
    float2 wmx = s_wmx[c]; int2 rx = s_rxp[c];
    swy[k] = wmy.x; swx[k] = wmx.x; smm[k] = wmy.y * wmx.y;
    so00[k] = ry.x * 33 + rx.x; so01[k] = ry.x * 33 + rx.y;
    so10[k] = ry.y * 33 + rx.x; so11[k] = ry.y * 33 + rx.y;
    spos[k] = p * 20;
  }

  const uint4* wh4 = reinterpret_cast<const uint4*>(wh);
  const uint4* wl4 = reinterpret_cast<const uint4*>(wl);

  f32x16 acc[2];
#pragma unroll
  for (int r = 0; r < 2; ++r)
#pragma unroll
    for (int j = 0; j < 16; ++j) acc[r][j] = 0.f;

  for (int g = 0; g < 4; ++g) {
    // ---- interp + split-pack (register-hoisted offsets) ----
#pragma unroll 2
    for (int ci = 0; ci < 16; ++ci) {
      const float* sp = s_src + ci * 165;
#pragma unroll
      for (int k = 0; k < 2; ++k) {
        if (!sval[k]) continue;
        float a00 = sp[so00[k]], a01 = sp[so01[k]];
        float a10 = sp[so10[k]], a11 = sp[so11[k]];
        float h0 = fmaf(a10 - a00, swy[k], a00);
        float h1 = fmaf(a11 - a01, swy[k], a01);
        float v = smm[k] * fmaf(h1 - h0, swx[k], h0);
        __bf16 hb = (__bf16)v;
        float hf = (float)hb;
        __bf16 lb = (__bf16)(v - hf);
        unsigned hbits = (unsigned)__builtin_bit_cast(unsigned short, hb);
        unsigned lbits = (unsigned)__builtin_bit_cast(unsigned short, lb);
        s_x[spos[k] + ci] = hbits | (lbits << 16);
      }
    }
    __syncthreads();

    // ---- stage next src group (overlaps MFMA) ----
    if (g < 3) {
      int ci0 = (g + 1) * 16;
      for (int i = t; i < 2560; i += 256) {
        int ci = i / 160, rem = i - ci * 160;
        int rr = rem >> 5, c = rem & 31;
        int row = r0 + rr;
        s_src[ci * 165 + rr * 33 + c] =
            (row < 32) ? in[(n * 64 + ci0 + ci) * 1024 + row * 32 + c] : 0.f;
      }
    }

    // ---- MFMA ----
#pragma unroll
    for (int kx = 0; kx < 3; ++kx) {
      bf16x8 Ah[3], Al[3];
#pragma unroll
      for (int ky = 0; ky < 3; ++ky) {
        int wi = (g * 9 + ky * 3 + kx) * 64 + cc * 2 + h;
        Ah[ky] = __builtin_bit_cast(bf16x8, wh4[wi]);
        Al[ky] = __builtin_bit_cast(bf16x8, wl4[wi]);
      }
#pragma unroll
      for (int u6 = 0; u6 < 4; ++u6) {
        int u = rg * 2 + u6;
        const uint4* xp = reinterpret_cast<const uint4*>(
            &s_x[(u * 66 + xh * 32 + cc + kx) * 20 + (h << 3)]);
        uint4 qa = xp[0], qb = xp[1];
        u32x4v bh, bl;
        bh[0] = (qa.x & 0xffffu) | (qa.y << 16);
        bh[1] = (qa.z & 0xffffu) | (qa.w << 16);
        bh[2] = (qb.x & 0xffffu) | (qb.y << 16);
        bh[3] = (qb.z & 0xffffu) | (qb.w << 16);
        bl[0] = (qa.x >> 16) | (qa.y & 0xffff0000u);
        bl[1] = (qa.z >> 16) | (qa.w & 0xffff0000u);
        bl[2] = (qb.x >> 16) | (qb.y & 0xffff0000u);
        bl[3] = (qb.z >> 16) | (qb.w & 0xffff0000u);
        bf16x8 Bh = __builtin_bit_cast(bf16x8, bh);
        bf16x8 Bl = __builtin_bit_cast(bf16x8, bl);
#pragma unroll
        for (int ky = 0; ky < 3; ++ky) {
          int rr = u6 - ky;
          if (rr < 0 || rr > 1) continue;
          acc[rr] = __builtin_amdgcn_mfma_f32_32x32x16_bf16(Ah[ky], Bh, acc[rr], 0, 0, 0);
          acc[rr] = __builtin_amdgcn_mfma_f32_32x32x16_bf16(Ah[ky], Bl, acc[rr], 0, 0, 0);
          acc[rr] = __builtin_amdgcn_mfma_f32_32x32x16_bf16(Al[ky], Bh, acc[rr], 0, 0, 0);
        }
      }
    }
    __syncthreads();
  }

  float bvv[16];
#pragma unroll
  for (int reg = 0; reg < 16; ++reg) {
    int co = (reg & 3) + 8 * (reg >> 2) + 4 * h;
    bvv[reg] = bias[co];
  }
#pragma unroll
  for (int rr = 0; rr < 2; ++rr) {
    int y = y0 + rg * 2 + rr;
#pragma unroll
    for (int reg = 0; reg < 16; ++reg) {
      int co = (reg & 3) + 8 * (reg >> 2) + 4 * h;
      float v = acc[rr][reg] + bvv[reg];
      out[(n * 32 + co) * 4096 + y * 64 + xh * 32 + cc] = actf<1>(v);
    }
  }
}

// ---------------- 1x1 64->64 (channel matmul), opt bias / add --------------
template<int ACT, bool BIAS, bool ADD>
__global__ __launch_bounds__(256) void k_1x1(
    const float* __restrict__ in, const float* __restrict__ w,
    const float* __restrict__ bias, const float* __restrict__ add,
    float* __restrict__ out) {
  int bid = blockIdx.x;
  int n = bid >> 2;
  int s = ((bid & 3) << 8) + threadIdx.x;
  __shared__ float s_w[4096];
  for (int i = threadIdx.x; i < 4096; i += 256) s_w[i] = w[i];
  __syncthreads();
  float x[64];
#pragma unroll
  for (int ci = 0; ci < 64; ++ci) x[ci] = in[(n * 64 + ci) * 1024 + s];
  for (int co = 0; co < 64; ++co) {
    float acc = BIAS ? bias[co] : 0.f;
    const float* wr = &s_w[co * 64];
#pragma unroll
    for (int ci = 0; ci < 64; ++ci) acc = fmaf(wr[ci], x[ci], acc);
    if (ADD) acc += add[(n * 64 + co) * 1024 + s];
    out[(n * 64 + co) * 1024 + s] = actf<ACT>(acc);
  }
}

// ---------------- loss finalize --------------------------------------------
__global__ __launch_bounds__(256) void k_loss(const double* __restrict__ part,
                                              float* __restrict__ out) {
  __shared__ double s[256];
  int t = threadIdx.x;
  double acc = 0.0;
  for (int i = t; i < 2048; i += 256) acc += part[i];
  s[t] = acc;
  __syncthreads();
  for (int str = 128; str > 0; str >>= 1) {
    if (t < str) s[t] += s[t + str];
    __syncthreads();
  }
  if (t == 0) {
    double mean = s[0] / 8388608.0;
    out[2097152] = (float)mean;
    out[2097153] = (float)(0.25 * mean);
  }
}

// ---------------- dec3: up2x(ac) + 3x3 32->1 + relu ------------------------
// Register-hoisted interp (5 fixed positions/thread over the 18x66 tile).
__global__ __launch_bounds__(256, 4) void k_dec3(
    const float* __restrict__ in, const float* __restrict__ w,
    const float* __restrict__ bias, float* __restrict__ out) {
  int bid = blockIdx.x;                  // 2048 = 128n * 8yT * 2xT
  int n = bid >> 4, yT = (bid >> 1) & 7, xT = bid & 1;
  int y0 = yT * 16, x0 = xT * 64;
  int t = threadIdx.x;
  int ty = t >> 4, xq = t & 15;

  __shared__ float s_up[4 * 18 * 68];
  __shared__ float s_src[4 * 11 * 35];
  __shared__ float s_w[288];
  __shared__ float2 s_wmy[18];
  __shared__ int2   s_ryp[18];
  __shared__ float2 s_wmx[66];
  __shared__ int2   s_rxp[66];

  const float sc = 63.0f / 127.0f;
  int r0 = (y0 == 0) ? 0 : (int)floorf((float)(y0 - 1) * sc);
  int c0 = (x0 == 0) ? 0 : (int)floorf((float)(x0 - 1) * sc);

  if (t < 18) {
    int uy = y0 - 1 + t;
    int uyc = min(max(uy, 0), 127);
    float sy = (float)uyc * sc;
    int iy0 = (int)floorf(sy);
    s_wmy[t] = make_float2(sy - (float)iy0, ((unsigned)uy < 128u) ? 1.f : 0.f);
    s_ryp[t] = make_int2(iy0 - r0, min(iy0 + 1, 63) - r0);
  }
  int xc = t - 64;
  if (xc >= 0 && xc < 66) {
    int ux = x0 - 1 + xc;
    int uxc = min(max(ux, 0), 127);
    float sx = (float)uxc * sc;
    int ix0 = (int)floorf(sx);
    s_wmx[xc] = make_float2(sx - (float)ix0, ((unsigned)ux < 128u) ? 1.f : 0.f);
    s_rxp[xc] = make_int2(ix0 - c0, min(ix0 + 1, 63) - c0);
  }
  for (int i = t; i < 288; i += 256) s_w[i] = w[i];

  float acc[4] = {0.f, 0.f, 0.f, 0.f};

  // prologue stage g=0 (4 ci)
  for (int i = t; i < 4 * 11 * 35; i += 256) {
    int ci = i / 385, rem = i - ci * 385;
    int rr = rem / 35, cx = rem - rr * 35;
    int row = r0 + rr, col = c0 + cx;
    s_src[(ci * 11 + rr) * 35 + cx] =
        (row < 64 && col < 64) ? in[((n * 32 + ci) * 64 + row) * 64 + col] : 0.f;
  }
  __syncthreads();

  // slot setup: 1188 positions, <=5 per thread
  int so00[5], so01[5], so10[5], so11[5], suoff[5];
  float swy[5], swx[5], smm[5];
  bool sval[5];
#pragma unroll
  for (int k = 0; k < 5; ++k) {
    int pos = t + (k << 8);
    sval[k] = pos < 1188;
    int p = sval[k] ? pos : 0;
    int u = p / 66, c = p - u * 66;
    float2 wmy = s_wmy[u]; int2 ry = s_ryp[u];
    float2 wmx = s_wmx[c]; int2 rx = s_rxp[c];
    swy[k] = wmy.x; swx[k] = wmx.x; smm[k] = wmy.y * wmx.y;
    so00[k] = ry.x * 35 + rx.x; so01[k] = ry.x * 35 + rx.y;
    so10[k] = ry.y * 35 + rx.x; so11[k] = ry.y * 35 + rx.y;
    suoff[k] = u * 68 + c;
  }

  for (int g = 0; g < 8; ++g) {
    // ---- interp (register-hoisted) ----
#pragma unroll
    for (int ci = 0; ci < 4; ++ci) {
      const float* sp = s_src + ci * 385;
      float* up = s_up + ci * 1224;
#pragma unroll
      for (int k = 0; k < 5; ++k) {
        if (!sval[k]) continue;
        float a00 = sp[so00[k]], a01 = sp[so01[k]];
        float a10 = sp[so10[k]], a11 = sp[so11[k]];
        float h0 = fmaf(a10 - a00, swy[k], a00);
        float h1 = fmaf(a11 - a01, swy[k], a01);
        up[suoff[k]] = smm[k] * fmaf(h1 - h0, swx[k], h0);
      }
    }
    __syncthreads();

    // ---- conv ; overlap: stage next src group ----
    if (g < 7) {
      int ci0 = (g + 1) * 4;
      for (int i = t; i < 4 * 11 * 35; i += 256) {
        int ci = i / 385, rem = i - ci * 385;
        int rr = rem / 35, cx = rem - rr * 35;
        int row = r0 + rr, col = c0 + cx;
        s_src[(ci * 11 + rr) * 35 + cx] =
            (row < 64 && col < 64)
                ? in[((n * 32 + ci0 + ci) * 64 + row) * 64 + col] : 0.f;
      }
    }

    int ci0 = g * 4;
    for (int ci = 0; ci < 4; ++ci) {
#pragma unroll
      for (int ky = 0; ky < 3; ++ky) {
        int base = (ci * 18 + ty + ky) * 68 + xq * 4;
        float4 q0 = *reinterpret_cast<const float4*>(&s_up[base]);
        float4 q1 = *reinterpret_cast<const float4*>(&s_up[base + 4]);
        float rv[8] = {q0.x, q0.y, q0.z, q0.w, q1.x, q1.y, q1.z, q1.w};
#pragma unroll
        for (int kx = 0; kx < 3; ++kx) {
          float wv = s_w[(ci0 + ci) * 9 + ky * 3 + kx];
#pragma unroll
          for (int xx = 0; xx < 4; ++xx)
            acc[xx] = fmaf(rv[xx + kx], wv, acc[xx]);
        }
      }
    }
    __syncthreads();
  }
  float bv = bias[0];
  int base = n * 16384 + (y0 + ty) * 128 + x0 + xq * 4;
  *reinterpret_cast<float4*>(&out[base]) =
      make_float4(actf<2>(acc[0] + bv), actf<2>(acc[1] + bv),
                  actf<2>(acc[2] + bv), actf<2>(acc[3] + bv));
}

// ---------------------------------------------------------------------------
extern "C" void kernel_launch(void* const* d_in, const int* in_sizes, int n_in,
                              void* d_out, int out_size, void* d_ws, size_t ws_size,
                              hipStream_t stream) {
  (void)in_sizes; (void)n_in; (void)out_size; (void)ws_size;
  const float* x_in     = (const float*)d_in[0];
  const float* enc_w1   = (const float*)d_in[1];
  const float* enc_b1   = (const float*)d_in[2];
  const float* enc_w2   = (const float*)d_in[3];
  const float* enc_b2   = (const float*)d_in[4];
  const float* enc_w3   = (const float*)d_in[5];
  const float* enc_b3   = (const float*)d_in[6];
  const float* res_e_w1 = (const float*)d_in[7];
  const float* res_e_w2 = (const float*)d_in[8];
  const float* enc_w4   = (const float*)d_in[9];
  const float* enc_b4   = (const float*)d_in[10];
  const float* codebook = (const float*)d_in[11];
  const float* dec_w1   = (const float*)d_in[12];
  const float* dec_b1   = (const float*)d_in[13];
  const float* res_d_w1 = (const float*)d_in[14];
  const float* res_d_w2 = (const float*)d_in[15];
  const float* dec_w2   = (const float*)d_in[16];
  const float* dec_b2   = (const float*)d_in[17];
  const float* dec_w3   = (const float*)d_in[18];
  const float* dec_b3   = (const float*)d_in[19];
  float* out = (float*)d_out;

  char* ws = (char*)d_ws;
  float*  B0    = (float*)(ws);                         // 33.55 MB each
  float*  B1    = (float*)(ws + 33554432);
  float*  B2    = (float*)(ws + 67108864);
  float*  B3    = (float*)(ws + 100663296);
  float*  B4    = (float*)(ws + 134217728);             // enc1 out: 67.1 MB
  double* PART  = (double*)(ws + 201326592);
  float*  CNORM = (float*)(ws + 201326592 + 16384);
  unsigned short* CBH = (unsigned short*)(ws + 100663296);  // B3, pre-VQ only
  unsigned short* CBL = CBH + 32768;
  unsigned short* WH0 = (unsigned short*)(ws + 201359360);
  unsigned short* WL0 = WH0 + 36864;
  unsigned short* WH1 = (unsigned short*)(ws + 201359360 + 147456);
  unsigned short* WL1 = WH1 + 36864;
  unsigned short* WH2 = (unsigned short*)(ws + 201359360 + 294912);
  unsigned short* WL2 = WH2 + 36864;
  unsigned short* WH3 = (unsigned short*)(ws + 201359360 + 442368);
  unsigned short* WL3 = WH3 + 36864;
  unsigned short* WH4 = (unsigned short*)(ws + 201359360 + 589824);   // dec2
  unsigned short* WL4 = WH4 + 18432;
  unsigned short* WH5 = (unsigned short*)(ws + 201359360 + 663552);   // enc2
  unsigned short* WL5 = WH5 + 32768;

  k_wprep<<<144, 256, 0, stream>>>(enc_w3,   WH0, WL0);
  k_wprep<<<144, 256, 0, stream>>>(res_e_w1, WH1, WL1);
  k_wprep<<<144, 256, 0, stream>>>(dec_w1,   WH2, WL2);
  k_wprep<<<144, 256, 0, stream>>>(res_d_w1, WH3, WL3);
  k_wprep2<<<72, 256, 0, stream>>>(dec_w2,   WH4, WL4);
  k_wprep_e2<<<128, 256, 0, stream>>>(enc_w2, WH5, WL5);
  k_cbprep_m<<<128, 256, 0, stream>>>(codebook, CBH, CBL);
  k_cbnorm<<<2, 256, 0, stream>>>(codebook, CNORM);

  k_enc1m<<<1024, 256, 0, stream>>>(x_in, enc_w1, enc_b1, B4);
  k_enc2m<<<1024, 256, 0, stream>>>(B4, WH5, WL5, enc_b2, B0);
  k_conv3m<1, true ><<<512, 256, 0, stream>>>(B0, WH0, WL0, enc_b3, B1);
  k_conv3m<2, false><<<512, 256, 0, stream>>>(B1, WH1, WL1, nullptr, B2);
  k_1x1<1, false, true ><<<512, 256, 0, stream>>>(B2, res_e_w2, nullptr, B1, B0);
  k_1x1<1, true,  false><<<512, 256, 0, stream>>>(B0, enc_w4, enc_b4, nullptr, B1);
  k_vq2m<<<2048, 256, 0, stream>>>(B1, CBH, CBL, codebook, CNORM, B2, PART);
  k_conv3m<1, true ><<<512, 256, 0, stream>>>(B2, WH2, WL2, dec_b1, B0);
  k_conv3m<2, false><<<512, 256, 0, stream>>>(B0, WH3, WL3, nullptr, B3);
  k_1x1<1, false, true ><<<512, 256, 0, stream>>>(B3, res_d_w2, nullptr, B0, B1);
  k_dec2m<<<2048, 256, 0, stream>>>(B1, WH4, WL4, dec_b2, B4);
  k_dec3<<<2048, 256, 0, stream>>>(B4, dec_w3, dec_b3, out);
  k_loss<<<1, 256, 0, stream>>>(PART, out);
}